// Round 4
// baseline (806.664 us; speedup 1.0000x reference)
//
#include <hip/hip_runtime.h>

#define NN 16384
#define CC 512
#define EE 524288
#define BB 64
#define HH 8
#define EFD 16

typedef __bf16 bf16_t;
typedef __bf16 bf16x4 __attribute__((ext_vector_type(4)));
typedef __bf16 bf16x8 __attribute__((ext_vector_type(8)));
typedef float f32x4v __attribute__((ext_vector_type(4)));

// ---------------- init / edge pre-pass ----------------

__global__ void init_kernel(float* deg, int* cnt_dst, int* cnt_src) {
  int i = blockIdx.x * 256 + threadIdx.x;
  if (i < NN) { deg[i] = 1.0f; cnt_dst[i] = 0; cnt_src[i] = 0; }
}

__global__ void edge_pass1(const float* __restrict__ ea, const int* __restrict__ src,
                           const int* __restrict__ dst, float* __restrict__ ew,
                           float* deg, int* cnt_dst, int* cnt_src) {
  int e = blockIdx.x * 256 + threadIdx.x;
  if (e >= EE) return;
  const float4* p = (const float4*)(ea + (size_t)e * EFD);
  float s = 0.f;
#pragma unroll
  for (int i = 0; i < 4; ++i) {
    float4 v = p[i];
    s += v.x * v.x + v.y * v.y + v.z * v.z + v.w * v.w;
  }
  float w = sqrtf(s);
  ew[e] = w;
  atomicAdd(&deg[dst[e]], w);
  atomicAdd(&cnt_dst[dst[e]], 1);
  atomicAdd(&cnt_src[src[e]], 1);
}

__global__ void node_pass(const float* __restrict__ deg, float* __restrict__ dinv) {
  int i = blockIdx.x * 256 + threadIdx.x;
  if (i >= NN) return;
  float d = deg[i];
  dinv[i] = d > 0.f ? rsqrtf(fmaxf(d, 1e-12f)) : 0.f;
}

// exclusive scan of n<=16384 ints, single block of 1024 threads (16/thread)
__global__ __launch_bounds__(1024) void exscan_kernel(const int* __restrict__ cnt,
                                                      int* __restrict__ start,
                                                      int* __restrict__ cur, int n) {
  __shared__ int sums[1024];
  int tid = threadIdx.x;
  int base = tid * 16;
  int loc[16];
  int s = 0;
#pragma unroll
  for (int k = 0; k < 16; ++k) {
    int idx = base + k;
    int v = (idx < n) ? cnt[idx] : 0;
    loc[k] = v;
    s += v;
  }
  sums[tid] = s;
  __syncthreads();
  for (int off = 1; off < 1024; off <<= 1) {
    int v = (tid >= off) ? sums[tid - off] : 0;
    __syncthreads();
    sums[tid] += v;
    __syncthreads();
  }
  int pre = (tid == 0) ? 0 : sums[tid - 1];
#pragma unroll
  for (int k = 0; k < 16; ++k) {
    int idx = base + k;
    if (idx < n) { start[idx] = pre; cur[idx] = pre; pre += loc[k]; }
  }
  if (tid == 1023) start[n] = pre;
}

__global__ void fill_kernel(const int* __restrict__ src, const int* __restrict__ dst,
                            int* cur_dst, int* cur_src, int* __restrict__ elist_dst,
                            int* __restrict__ elist_src) {
  int e = blockIdx.x * 256 + threadIdx.x;
  if (e >= EE) return;
  int pd = atomicAdd(&cur_dst[dst[e]], 1);
  elist_dst[pd] = e;
  int ps = atomicAdd(&cur_src[src[e]], 1);
  elist_src[ps] = e;
}

// ---------------- conversions ----------------

__global__ void cvt_bf16_kernel(const float* __restrict__ in, bf16_t* __restrict__ out,
                                int n4) {
  int i = blockIdx.x * 256 + threadIdx.x;
  if (i >= n4) return;
  float4 v = ((const float4*)in)[i];
  bf16x4 o;
  o[0] = (bf16_t)v.x; o[1] = (bf16_t)v.y; o[2] = (bf16_t)v.z; o[3] = (bf16_t)v.w;
  ((bf16x4*)out)[i] = o;
}

// W: f32 [K][N] row-major -> Wt: bf16 [N][K] row-major
__global__ __launch_bounds__(256) void wt_kernel(const float* __restrict__ W,
                                                 bf16_t* __restrict__ Wt, int K, int N) {
  __shared__ float tile[32][33];
  int bx = blockIdx.x * 32;  // N offset
  int by = blockIdx.y * 32;  // K offset
  int tx = threadIdx.x & 31, ty = threadIdx.x >> 5;  // ty 0..7
#pragma unroll
  for (int i = 0; i < 32; i += 8)
    tile[ty + i][tx] = W[(size_t)(by + ty + i) * N + bx + tx];
  __syncthreads();
#pragma unroll
  for (int i = 0; i < 32; i += 8)
    Wt[(size_t)(bx + ty + i) * K + by + tx] = (bf16_t)tile[tx][ty + i];
}

// ---------------- GCN conv gather (CSR by dst), bf16 xw ----------------
// x_conv[i] = dinv[i]^2*xw[i] + sum_{e: dst=i} dinv[src]*ew*dinv[i]*xw[src] + gcn_b
__global__ __launch_bounds__(256) void xconv_kernel(
    const bf16_t* __restrict__ xwb, const float* __restrict__ ew,
    const float* __restrict__ dinv, const int* __restrict__ src,
    const int* __restrict__ elist, const int* __restrict__ start,
    const float* __restrict__ gcn_b, float* __restrict__ xconv,
    bf16_t* __restrict__ xcb) {
  int i = blockIdx.x;
  int tid = threadIdx.x;
  int st = start[i], en = start[i + 1];
  float di = dinv[i];
  int c0 = tid * 2;
  __shared__ float2 scS[256];  // {coef, as_float(src_node)}
  union { unsigned u; struct { unsigned short lo, hi; } s; } pk;
  pk.u = *(const unsigned*)(xwb + (size_t)i * CC + c0);
  union { unsigned short us; bf16_t b; } c0v, c1v;
  c0v.us = pk.s.lo; c1v.us = pk.s.hi;
  float sc = di * di;
  float a0 = sc * (float)c0v.b + gcn_b[c0];
  float a1 = sc * (float)c1v.b + gcn_b[c0 + 1];
  for (int p0 = st; p0 < en; p0 += 256) {
    int m = min(256, en - p0);
    __syncthreads();
    if (tid < m) {
      int e = elist[p0 + tid];
      int sn = src[e];
      scS[tid] = make_float2(dinv[sn] * ew[e] * di, __int_as_float(sn));
    }
    __syncthreads();
    for (int j = 0; j < m; ++j) {
      float2 scv = scS[j];
      int sn = __float_as_int(scv.y);
      union { unsigned u; struct { unsigned short lo, hi; } s; } q;
      q.u = *(const unsigned*)(xwb + (size_t)sn * CC + c0);
      union { unsigned short us; bf16_t b; } v0, v1;
      v0.us = q.s.lo; v1.us = q.s.hi;
      a0 += scv.x * (float)v0.b;
      a1 += scv.x * (float)v1.b;
    }
  }
  *(float2*)(xconv + (size_t)i * CC + c0) = make_float2(a0, a1);
  xcb[(size_t)i * (2 * CC) + c0] = (bf16_t)a0;
  xcb[(size_t)i * (2 * CC) + c0 + 1] = (bf16_t)a1;
}

// ---------------- edge projection (CSR by src): wave per node, no LDS -------
// ef[i] = sum_{e: src=i} relu(edge_attr[e] @ ep_w + ep_b); lane owns 8 cols
__device__ __forceinline__ f32x4v vmax0(f32x4v v) {
  f32x4v r;
  r[0] = fmaxf(v[0], 0.f); r[1] = fmaxf(v[1], 0.f);
  r[2] = fmaxf(v[2], 0.f); r[3] = fmaxf(v[3], 0.f);
  return r;
}

__global__ __launch_bounds__(256) void ef_kernel(
    const float* __restrict__ ea, const float* __restrict__ ep_w,
    const float* __restrict__ ep_b, const int* __restrict__ elist,
    const int* __restrict__ start, float* __restrict__ ef, bf16_t* __restrict__ efb) {
  const int lane = threadIdx.x & 63;
  const int node = blockIdx.x * 4 + (threadIdx.x >> 6);
  const int c0 = lane * 8;
  f32x4v wlo[16], whi[16];
#pragma unroll
  for (int k = 0; k < 16; ++k) {
    wlo[k] = *(const f32x4v*)(ep_w + k * CC + c0);
    whi[k] = *(const f32x4v*)(ep_w + k * CC + c0 + 4);
  }
  const f32x4v blo = *(const f32x4v*)(ep_b + c0);
  const f32x4v bhi = *(const f32x4v*)(ep_b + c0 + 4);
  f32x4v alo = {0.f, 0.f, 0.f, 0.f}, ahi = {0.f, 0.f, 0.f, 0.f};
  const int st = start[node], en = start[node + 1];
  f32x4v f0 = {}, f1 = {}, f2 = {}, f3 = {};
  int eN = 0;
  if (st < en) {
    const f32x4v* p = (const f32x4v*)(ea + (size_t)elist[st] * EFD);
    f0 = p[0]; f1 = p[1]; f2 = p[2]; f3 = p[3];
  }
  if (st + 1 < en) eN = elist[st + 1];
  for (int p = st; p < en; ++p) {
    f32x4v g0 = {}, g1 = {}, g2 = {}, g3 = {};
    int eN2 = 0;
    if (p + 1 < en) {
      const f32x4v* q = (const f32x4v*)(ea + (size_t)eN * EFD);
      g0 = q[0]; g1 = q[1]; g2 = q[2]; g3 = q[3];
    }
    if (p + 2 < en) eN2 = elist[p + 2];
    f32x4v tl = blo, th = bhi;
    tl += f0[0] * wlo[0]; th += f0[0] * whi[0];
    tl += f0[1] * wlo[1]; th += f0[1] * whi[1];
    tl += f0[2] * wlo[2]; th += f0[2] * whi[2];
    tl += f0[3] * wlo[3]; th += f0[3] * whi[3];
    tl += f1[0] * wlo[4]; th += f1[0] * whi[4];
    tl += f1[1] * wlo[5]; th += f1[1] * whi[5];
    tl += f1[2] * wlo[6]; th += f1[2] * whi[6];
    tl += f1[3] * wlo[7]; th += f1[3] * whi[7];
    tl += f2[0] * wlo[8]; th += f2[0] * whi[8];
    tl += f2[1] * wlo[9]; th += f2[1] * whi[9];
    tl += f2[2] * wlo[10]; th += f2[2] * whi[10];
    tl += f2[3] * wlo[11]; th += f2[3] * whi[11];
    tl += f3[0] * wlo[12]; th += f3[0] * whi[12];
    tl += f3[1] * wlo[13]; th += f3[1] * whi[13];
    tl += f3[2] * wlo[14]; th += f3[2] * whi[14];
    tl += f3[3] * wlo[15]; th += f3[3] * whi[15];
    alo += vmax0(tl);
    ahi += vmax0(th);
    f0 = g0; f1 = g1; f2 = g2; f3 = g3;
    eN = eN2;
  }
  *(f32x4v*)(ef + (size_t)node * CC + c0) = alo;
  *(f32x4v*)(ef + (size_t)node * CC + c0 + 4) = ahi;
  bf16x8 pk;
#pragma unroll
  for (int r = 0; r < 4; ++r) { pk[r] = (bf16_t)alo[r]; pk[r + 4] = (bf16_t)ahi[r]; }
  *(bf16x8*)(efb + (size_t)node * (2 * CC) + CC + c0) = pk;
}

// ---------------- bf16 MFMA GEMM (m97 structure) ----------------
__device__ __forceinline__ void gl_lds16(const bf16_t* g, bf16_t* l) {
  __builtin_amdgcn_global_load_lds(
      (const __attribute__((address_space(1))) void*)g,
      (__attribute__((address_space(3))) void*)l, 16, 0, 0);
}

template <int ACT, int OUT>
__global__ __launch_bounds__(256) void gemm_bf16_kernel(
    const bf16_t* __restrict__ A, const bf16_t* __restrict__ Bt,
    const float* __restrict__ bias, void* __restrict__ Cout, int M, int N, int K) {
  __shared__ __align__(16) bf16_t Al[128 * 32];
  __shared__ __align__(16) bf16_t Bl[128 * 32];
  const int tid = threadIdx.x;
  const int lane = tid & 63;
  const int wave = tid >> 6;
  const int row0 = blockIdx.y * 128;
  const int col0 = blockIdx.x * 128;
  const int wm = (wave >> 1) * 64;
  const int wn = (wave & 1) * 64;
  f32x4v acc[4][4] = {};
  const bf16_t* aBase = A + (size_t)(row0 + (tid >> 2)) * K + (tid & 3) * 8;
  const bf16_t* bBase = Bt + (size_t)(col0 + (tid >> 2)) * K + (tid & 3) * 8;
  bf16_t* al0 = Al + wave * 512;
  bf16_t* al1 = Al + 2048 + wave * 512;
  bf16_t* bl0 = Bl + wave * 512;
  bf16_t* bl1 = Bl + 2048 + wave * 512;
  const int fr = lane & 15;
  const int fk = (lane >> 4) * 8;
  for (int k0 = 0; k0 < K; k0 += 32) {
    gl_lds16(aBase + k0, al0);
    gl_lds16(aBase + (size_t)64 * K + k0, al1);
    gl_lds16(bBase + k0, bl0);
    gl_lds16(bBase + (size_t)64 * K + k0, bl1);
    __syncthreads();
    bf16x8 af[4], bfv[4];
#pragma unroll
    for (int m = 0; m < 4; ++m)
      af[m] = *(const bf16x8*)(Al + (wm + m * 16 + fr) * 32 + fk);
#pragma unroll
    for (int n = 0; n < 4; ++n)
      bfv[n] = *(const bf16x8*)(Bl + (wn + n * 16 + fr) * 32 + fk);
#pragma unroll
    for (int m = 0; m < 4; ++m)
#pragma unroll
      for (int n = 0; n < 4; ++n)
        acc[m][n] =
            __builtin_amdgcn_mfma_f32_16x16x32_bf16(af[m], bfv[n], acc[m][n], 0, 0, 0);
    __syncthreads();
  }
  const int fq = (lane >> 4) * 4;
#pragma unroll
  for (int m = 0; m < 4; ++m) {
    int grb = row0 + wm + m * 16 + fq;
#pragma unroll
    for (int n = 0; n < 4; ++n) {
      int gc = col0 + wn + n * 16 + fr;
      float bv = bias ? bias[gc] : 0.f;
#pragma unroll
      for (int r = 0; r < 4; ++r) {
        float v = acc[m][n][r] + bv;
        if (ACT == 1) v = v / (1.f + __expf(-v));
        if (OUT == 0)
          ((float*)Cout)[(size_t)(grb + r) * N + gc] = v;
        else
          ((bf16_t*)Cout)[(size_t)(grb + r) * N + gc] = (bf16_t)v;
      }
    }
  }
}

// ---------------- layernorm fused kernels ----------------

__device__ inline void block_reduce2(float& s, float& q, float* red) {
#pragma unroll
  for (int off = 32; off >= 1; off >>= 1) {
    s += __shfl_xor(s, off, 64);
    q += __shfl_xor(q, off, 64);
  }
  int wid = threadIdx.x >> 6;
  if ((threadIdx.x & 63) == 0) { red[wid * 2] = s; red[wid * 2 + 1] = q; }
  __syncthreads();
  s = red[0] + red[2] + red[4] + red[6];
  q = red[1] + red[3] + red[5] + red[7];
}

__global__ __launch_bounds__(256) void ln_add_kernel(const float* __restrict__ A,
                                                     const float* __restrict__ Bb,
                                                     const float* __restrict__ g,
                                                     const float* __restrict__ be,
                                                     float* __restrict__ out,
                                                     bf16_t* __restrict__ bout) {
  int row = blockIdx.x, tid = threadIdx.x, c0 = tid * 2;
  __shared__ float red[8];
  float2 a = *(const float2*)(A + (size_t)row * CC + c0);
  float2 b = *(const float2*)(Bb + (size_t)row * CC + c0);
  float x0 = a.x + b.x, x1 = a.y + b.y;
  float s = x0 + x1, q = x0 * x0 + x1 * x1;
  block_reduce2(s, q, red);
  float mean = s * (1.f / CC);
  float var = q * (1.f / CC) - mean * mean;
  float rs = rsqrtf(var + 1e-5f);
  float o0 = (x0 - mean) * rs * g[c0] + be[c0];
  float o1 = (x1 - mean) * rs * g[c0 + 1] + be[c0 + 1];
  *(float2*)(out + (size_t)row * CC + c0) = make_float2(o0, o1);
  if (bout) {
    bout[(size_t)row * CC + c0] = (bf16_t)o0;
    bout[(size_t)row * CC + c0 + 1] = (bf16_t)o1;
  }
}

__global__ __launch_bounds__(256) void ln_gate_kernel(
    const float* __restrict__ gpre, const float* __restrict__ gate_b,
    const float* __restrict__ xc, const float* __restrict__ ef,
    const float* __restrict__ n1g, const float* __restrict__ n1b,
    const float* __restrict__ xin, float* __restrict__ x2, bf16_t* __restrict__ x2b) {
  int row = blockIdx.x, tid = threadIdx.x, c0 = tid * 2;
  __shared__ float red[8];
  float2 gp = *(const float2*)(gpre + (size_t)row * CC + c0);
  float2 xcv = *(const float2*)(xc + (size_t)row * CC + c0);
  float2 efv = *(const float2*)(ef + (size_t)row * CC + c0);
  float g0 = 1.f / (1.f + __expf(-(gp.x + gate_b[c0])));
  float g1 = 1.f / (1.f + __expf(-(gp.y + gate_b[c0 + 1])));
  float x0 = g0 * xcv.x + (1.f - g0) * efv.x;
  float x1 = g1 * xcv.y + (1.f - g1) * efv.y;
  float s = x0 + x1, q = x0 * x0 + x1 * x1;
  block_reduce2(s, q, red);
  float mean = s * (1.f / CC);
  float var = q * (1.f / CC) - mean * mean;
  float rs = rsqrtf(var + 1e-5f);
  float2 xi = *(const float2*)(xin + (size_t)row * CC + c0);
  float o0 = fmaxf((x0 - mean) * rs * n1g[c0] + n1b[c0], 0.f) + xi.x;
  float o1 = fmaxf((x1 - mean) * rs * n1g[c0 + 1] + n1b[c0 + 1], 0.f) + xi.y;
  *(float2*)(x2 + (size_t)row * CC + c0) = make_float2(o0, o1);
  x2b[(size_t)row * CC + c0] = (bf16_t)o0;
  x2b[(size_t)row * CC + c0 + 1] = (bf16_t)o1;
}

// ---------------- V^T pack (pre-swizzled for attn LDS) ----------------
__global__ __launch_bounds__(256) void vt_pack_kernel(const bf16_t* __restrict__ qkvb,
                                                      bf16_t* __restrict__ vt) {
  int b = blockIdx.x >> 3, h = blockIdx.x & 7;
  int nb = b * 256;
  size_t voff = 1024 + (size_t)h * 64;
  char* out = (char*)(vt + (size_t)blockIdx.x * (64 * 256));
  __shared__ bf16_t tile[64][80];
  int tid = threadIdx.x;
  for (int kb = 0; kb < 4; ++kb) {
    __syncthreads();
#pragma unroll
    for (int p = 0; p < 2; ++p) {
      int k = p * 32 + (tid >> 3);
      int d8 = tid & 7;
      bf16x8 v = *(const bf16x8*)(qkvb + (size_t)(nb + kb * 64 + k) * 1536 + voff + d8 * 8);
      *(bf16x8*)(&tile[k][d8 * 8]) = v;
    }
    __syncthreads();
#pragma unroll
    for (int p = 0; p < 2; ++p) {
      int d = p * 32 + (tid >> 3);
      int k8 = tid & 7;
      bf16x8 v;
#pragma unroll
      for (int j = 0; j < 8; ++j) v[j] = tile[k8 * 8 + j][d];
      int byteoff = d * 512 + ((kb * 128 + k8 * 16) ^ ((d & 7) << 4));
      *(bf16x8*)(out + byteoff) = v;
    }
  }
}

// ---------------- MFMA attention: one block per (b,h), 4 waves x 64 q-rows --
__global__ __launch_bounds__(256, 2) void attn_mfma_kernel(
    const bf16_t* __restrict__ qkvb, const bf16_t* __restrict__ vt,
    bf16_t* __restrict__ o) {
  const int b = blockIdx.x >> 3;
  const int h = blockIdx.x & 7;
  const int nb = b * 256;
  const int tid = threadIdx.x;
  const int lane = tid & 63;
  const int wv = tid >> 6;
  const int l15 = lane & 15;
  const int g = lane >> 4;
  const int swzk = (l15 & 7) << 4;
  __shared__ __align__(16) bf16_t Klds[256 * 64];
  __shared__ __align__(16) bf16_t Vtlds[64 * 256];
  const size_t qoff = (size_t)h * 64;
  const size_t koff = 512 + (size_t)h * 64;

  {
    const int dcol = 16 * ((tid & 7) ^ ((tid >> 3) & 7));
    const bf16_t* srcb = qkvb + koff + (dcol >> 1);
#pragma unroll
    for (int i = 0; i < 8; ++i) {
      int k = i * 32 + (tid >> 3);
      gl_lds16(srcb + (size_t)(nb + k) * 1536, Klds + ((i * 4096 + wv * 1024) >> 1));
    }
  }
  {
    const bf16_t* vsrc = vt + (size_t)blockIdx.x * (64 * 256);
#pragma unroll
    for (int i = 0; i < 8; ++i) {
      int base = i * 4096 + wv * 1024;
      gl_lds16(vsrc + ((base >> 1) + lane * 8), Vtlds + (base >> 1));
    }
  }

  bf16x8 qf[4][2];
#pragma unroll
  for (int n = 0; n < 4; ++n) {
    const bf16_t* qp = qkvb + (size_t)(nb + wv * 64 + 16 * n + l15) * 1536 + qoff + g * 8;
    qf[n][0] = *(const bf16x8*)(qp);
    qf[n][1] = *(const bf16x8*)(qp + 32);
  }

  __syncthreads();

  f32x4v oacc[4][4] = {};
  float mrun[4] = {-1e30f, -1e30f, -1e30f, -1e30f};
  float lrun[4] = {0.f, 0.f, 0.f, 0.f};
  const int srcA = ((g & 1) << 5) | l15;
  const int srcB = srcA | 16;

  for (int kc = 0; kc < 4; ++kc) {
    f32x4v sacc[4][4] = {};
    const int kb128 = (kc * 64 + l15) * 128;
#pragma unroll
    for (int m = 0; m < 4; ++m) {
      bf16x8 a0 = *(const bf16x8*)(Klds + ((kb128 + m * 2048 + ((g * 16) ^ swzk)) >> 1));
      bf16x8 a1 =
          *(const bf16x8*)(Klds + ((kb128 + m * 2048 + ((64 + g * 16) ^ swzk)) >> 1));
#pragma unroll
      for (int n = 0; n < 4; ++n) {
        sacc[m][n] = __builtin_amdgcn_mfma_f32_16x16x32_bf16(a0, qf[n][0], sacc[m][n], 0, 0, 0);
        sacc[m][n] = __builtin_amdgcn_mfma_f32_16x16x32_bf16(a1, qf[n][1], sacc[m][n], 0, 0, 0);
      }
    }
    uint2 pb[4][4];
#pragma unroll
    for (int n = 0; n < 4; ++n) {
      float mx = sacc[0][n][0];
#pragma unroll
      for (int m = 0; m < 4; ++m)
#pragma unroll
        for (int r = 0; r < 4; ++r) mx = fmaxf(mx, sacc[m][n][r]);
      mx = fmaxf(mx, __shfl_xor(mx, 16));
      mx = fmaxf(mx, __shfl_xor(mx, 32));
      float mnew = fmaxf(mrun[n], mx);
      float c = __expf((mrun[n] - mnew) * 0.125f);
      mrun[n] = mnew;
      float s = 0.f;
#pragma unroll
      for (int m = 0; m < 4; ++m) {
        float p0 = __expf((sacc[m][n][0] - mnew) * 0.125f);
        float p1 = __expf((sacc[m][n][1] - mnew) * 0.125f);
        float p2 = __expf((sacc[m][n][2] - mnew) * 0.125f);
        float p3 = __expf((sacc[m][n][3] - mnew) * 0.125f);
        s += (p0 + p1) + (p2 + p3);
        union { bf16x4 v; uint2 u; } cv;
        cv.v[0] = (bf16_t)p0; cv.v[1] = (bf16_t)p1;
        cv.v[2] = (bf16_t)p2; cv.v[3] = (bf16_t)p3;
        pb[m][n] = cv.u;
      }
      s += __shfl_xor(s, 16);
      s += __shfl_xor(s, 32);
      lrun[n] = lrun[n] * c + s;
#pragma unroll
      for (int m = 0; m < 4; ++m)
#pragma unroll
        for (int r = 0; r < 4; ++r) oacc[m][n][r] *= c;
    }
#pragma unroll
    for (int h2 = 0; h2 < 2; ++h2) {
      bf16x8 vf[4];
#pragma unroll
      for (int m = 0; m < 4; ++m)
        vf[m] = *(const bf16x8*)(Vtlds + (((16 * m + l15) * 512 +
                                          ((kc * 128 + h2 * 64 + g * 16) ^ swzk)) >> 1));
#pragma unroll
      for (int n = 0; n < 4; ++n) {
        int a0 = __shfl((int)pb[2 * h2][n].x, srcA);
        int b0 = __shfl((int)pb[2 * h2 + 1][n].x, srcA);
        int a1 = __shfl((int)pb[2 * h2][n].y, srcA);
        int b1 = __shfl((int)pb[2 * h2 + 1][n].y, srcA);
        int a2 = __shfl((int)pb[2 * h2][n].x, srcB);
        int b2 = __shfl((int)pb[2 * h2 + 1][n].x, srcB);
        int a3 = __shfl((int)pb[2 * h2][n].y, srcB);
        int b3 = __shfl((int)pb[2 * h2 + 1][n].y, srcB);
        union { int u[4]; bf16x8 v; } pf;
        bool hi = (g >= 2);
        pf.u[0] = hi ? b0 : a0;
        pf.u[1] = hi ? b1 : a1;
        pf.u[2] = hi ? b2 : a2;
        pf.u[3] = hi ? b3 : a3;
#pragma unroll
        for (int m = 0; m < 4; ++m)
          oacc[m][n] =
              __builtin_amdgcn_mfma_f32_16x16x32_bf16(vf[m], pf.v, oacc[m][n], 0, 0, 0);
      }
    }
  }
  float inv[4];
#pragma unroll
  for (int n = 0; n < 4; ++n) inv[n] = 1.0f / lrun[n];
#pragma unroll
  for (int m = 0; m < 4; ++m)
#pragma unroll
    for (int n = 0; n < 4; ++n) {
      bf16x4 pk;
#pragma unroll
      for (int r = 0; r < 4; ++r) pk[r] = (bf16_t)(oacc[m][n][r] * inv[n]);
      *(bf16x4*)(o + (size_t)(nb + wv * 64 + 16 * n + l15) * 512 + h * 64 + 16 * m +
                 4 * g) = pk;
    }
}

// ---------------- launch ----------------

static inline char* alignp(char* p, size_t a) {
  return (char*)(((uintptr_t)p + a - 1) & ~(uintptr_t)(a - 1));
}

extern "C" void kernel_launch(void* const* d_in, const int* in_sizes, int n_in,
                              void* d_out, int out_size, void* d_ws, size_t ws_size,
                              hipStream_t stream) {
  const float* x = (const float*)d_in[0];
  const float* edge_attr = (const float*)d_in[1];
  const float* gcn_w = (const float*)d_in[2];
  const float* gcn_b = (const float*)d_in[3];
  const float* ep_w = (const float*)d_in[4];
  const float* ep_b = (const float*)d_in[5];
  const float* gate_w = (const float*)d_in[6];
  const float* gate_b = (const float*)d_in[7];
  const float* n1_g = (const float*)d_in[8];
  const float* n1_b = (const float*)d_in[9];
  const float* in_w = (const float*)d_in[10];
  const float* in_b = (const float*)d_in[11];
  const float* out_w = (const float*)d_in[12];
  const float* out_b = (const float*)d_in[13];
  const float* tn_g = (const float*)d_in[14];
  const float* tn_b = (const float*)d_in[15];
  const float* m_w1 = (const float*)d_in[16];
  const float* m_b1 = (const float*)d_in[17];
  const float* m_w2 = (const float*)d_in[18];
  const float* m_b2 = (const float*)d_in[19];
  const float* fn_g = (const float*)d_in[20];
  const float* fn_b = (const float*)d_in[21];
  const int* eidx = (const int*)d_in[22];
  const int* src = eidx;
  const int* dst = eidx + EE;

  float* ws = (float*)d_ws;
  float* R1 = ws;
  float* R2 = R1 + (size_t)NN * 3 * CC;
  float* R3 = R2 + (size_t)NN * CC;
  float* R4 = R3 + (size_t)NN * CC;
  float* ew = R4 + (size_t)NN * CC;
  float* deg = ew + EE;
  float* dinv = deg + NN;
  int* ip = (int*)(dinv + NN);
  int* cnt_dst = ip;    ip += NN;
  int* start_dst = ip;  ip += NN + 1;
  int* cur_dst = ip;    ip += NN;
  int* cnt_src = ip;    ip += NN;
  int* start_src = ip;  ip += NN + 1;
  int* cur_src = ip;    ip += NN;
  int* elist_dst = ip;  ip += EE;
  int* elist_src = ip;  ip += EE;
  char* bp = alignp((char*)ip, 64);
  bf16_t* x2b = (bf16_t*)bp;          bp += (size_t)NN * CC * 2;
  bf16_t* gcn_wt = (bf16_t*)bp;       bp += (size_t)CC * CC * 2;
  bf16_t* gate_wt = (bf16_t*)bp;      bp += (size_t)CC * 2 * CC * 2;
  bf16_t* in_wt = (bf16_t*)bp;        bp += (size_t)3 * CC * CC * 2;
  bf16_t* out_wt = (bf16_t*)bp;       bp += (size_t)CC * CC * 2;
  bf16_t* m_w1t = (bf16_t*)bp;        bp += (size_t)2 * CC * CC * 2;
  bf16_t* m_w2t = (bf16_t*)bp;        bp += (size_t)CC * 2 * CC * 2;

  bf16_t* xb = (bf16_t*)R1;      // bf16(x)
  bf16_t* xcefb = (bf16_t*)R1;   // [x_conv | ef] bf16 N x 2C
  bf16_t* qkvb = (bf16_t*)R1;    // qkv bf16 N x 1536
  bf16_t* hb = (bf16_t*)R1;      // mlp hidden bf16 N x 2C
  bf16_t* xwb = (bf16_t*)R2;     // bf16 xw (GCN GEMM out)
  bf16_t* ob = (bf16_t*)R2;      // attn out bf16 (first half of R2)
  bf16_t* vt = ob + (size_t)NN * CC;  // V^T packed (second half of R2)
  bf16_t* x3b = (bf16_t*)R2;     // bf16(x3) (after ob dead)
  float* x2 = (float*)d_out;

  // --- edge prep ---
  init_kernel<<<(NN + 255) / 256, 256, 0, stream>>>(deg, cnt_dst, cnt_src);
  edge_pass1<<<(EE + 255) / 256, 256, 0, stream>>>(edge_attr, src, dst, ew, deg,
                                                   cnt_dst, cnt_src);
  node_pass<<<(NN + 255) / 256, 256, 0, stream>>>(deg, dinv);
  exscan_kernel<<<1, 1024, 0, stream>>>(cnt_dst, start_dst, cur_dst, NN);
  exscan_kernel<<<1, 1024, 0, stream>>>(cnt_src, start_src, cur_src, NN);
  fill_kernel<<<(EE + 255) / 256, 256, 0, stream>>>(src, dst, cur_dst, cur_src,
                                                    elist_dst, elist_src);

  // --- weight transposes ---
  wt_kernel<<<dim3(CC / 32, CC / 32), 256, 0, stream>>>(gcn_w, gcn_wt, CC, CC);
  wt_kernel<<<dim3(CC / 32, 2 * CC / 32), 256, 0, stream>>>(gate_w, gate_wt, 2 * CC, CC);
  wt_kernel<<<dim3(3 * CC / 32, CC / 32), 256, 0, stream>>>(in_w, in_wt, CC, 3 * CC);
  wt_kernel<<<dim3(CC / 32, CC / 32), 256, 0, stream>>>(out_w, out_wt, CC, CC);
  wt_kernel<<<dim3(2 * CC / 32, CC / 32), 256, 0, stream>>>(m_w1, m_w1t, CC, 2 * CC);
  wt_kernel<<<dim3(CC / 32, 2 * CC / 32), 256, 0, stream>>>(m_w2, m_w2t, 2 * CC, CC);

  // --- GCN conv ---
  cvt_bf16_kernel<<<(NN * CC / 4 + 255) / 256, 256, 0, stream>>>(x, xb, NN * CC / 4);
  dim3 gA(CC / 128, NN / 128);
  gemm_bf16_kernel<0, 1><<<gA, 256, 0, stream>>>(xb, gcn_wt, nullptr, xwb, NN, CC, CC);
  xconv_kernel<<<NN, 256, 0, stream>>>(xwb, ew, dinv, src, elist_dst, start_dst,
                                       gcn_b, R3, xcefb);
  ef_kernel<<<NN / 4, 256, 0, stream>>>(edge_attr, ep_w, ep_b, elist_src, start_src,
                                        R4, xcefb);
  gemm_bf16_kernel<0, 0><<<gA, 256, 0, stream>>>(xcefb, gate_wt, nullptr, R2, NN, CC,
                                                 2 * CC);
  ln_gate_kernel<<<NN, 256, 0, stream>>>(R2, gate_b, R3, R4, n1_g, n1_b, x, x2, x2b);

  // --- MHA ---
  dim3 gQ(3 * CC / 128, NN / 128);
  gemm_bf16_kernel<0, 1><<<gQ, 256, 0, stream>>>(x2b, in_wt, in_b, qkvb, NN, 3 * CC, CC);
  vt_pack_kernel<<<BB * HH, 256, 0, stream>>>(qkvb, vt);
  attn_mfma_kernel<<<BB * HH, 256, 0, stream>>>(qkvb, vt, ob);
  gemm_bf16_kernel<0, 0><<<gA, 256, 0, stream>>>(ob, out_wt, out_b, R4, NN, CC, CC);
  ln_add_kernel<<<NN, 256, 0, stream>>>(x2, R4, tn_g, tn_b, R3, x3b);

  // --- MLP ---
  dim3 gH(2 * CC / 128, NN / 128);
  gemm_bf16_kernel<1, 1><<<gH, 256, 0, stream>>>(x3b, m_w1t, m_b1, hb, NN, 2 * CC, CC);
  gemm_bf16_kernel<0, 0><<<gA, 256, 0, stream>>>(hb, m_w2t, m_b2, R4, NN, CC, 2 * CC);
  ln_add_kernel<<<NN, 256, 0, stream>>>(R3, R4, fn_g, fn_b, (float*)d_out, nullptr);
}

// Round 5
// 677.508 us; speedup vs baseline: 1.1906x; 1.1906x over previous
//
#include <hip/hip_runtime.h>

#define NN 16384
#define CC 512
#define EE 524288
#define BB 64
#define HH 8
#define EFD 16

typedef __bf16 bf16_t;
typedef __bf16 bf16x4 __attribute__((ext_vector_type(4)));
typedef __bf16 bf16x8 __attribute__((ext_vector_type(8)));
typedef float f32x4v __attribute__((ext_vector_type(4)));

// ---------------- init / edge pre-pass ----------------

__global__ void init_kernel(float* deg, int* cnt_dst, int* cnt_src, int* nid_src) {
  int i = blockIdx.x * 256 + threadIdx.x;
  if (i < NN) { deg[i] = 1.0f; cnt_dst[i] = 0; cnt_src[i] = 0; }
  if (i < 32) nid_src[EE + i] = -1;  // pad for ef chunk tail
}

__global__ void edge_pass1(const float* __restrict__ ea, const int* __restrict__ src,
                           const int* __restrict__ dst, float* __restrict__ ew,
                           float* deg, int* cnt_dst, int* cnt_src) {
  int e = blockIdx.x * 256 + threadIdx.x;
  if (e >= EE) return;
  const float4* p = (const float4*)(ea + (size_t)e * EFD);
  float s = 0.f;
#pragma unroll
  for (int i = 0; i < 4; ++i) {
    float4 v = p[i];
    s += v.x * v.x + v.y * v.y + v.z * v.z + v.w * v.w;
  }
  float w = sqrtf(s);
  ew[e] = w;
  atomicAdd(&deg[dst[e]], w);
  atomicAdd(&cnt_dst[dst[e]], 1);
  atomicAdd(&cnt_src[src[e]], 1);
}

__global__ void node_pass(const float* __restrict__ deg, float* __restrict__ dinv) {
  int i = blockIdx.x * 256 + threadIdx.x;
  if (i >= NN) return;
  float d = deg[i];
  dinv[i] = d > 0.f ? rsqrtf(fmaxf(d, 1e-12f)) : 0.f;
}

// exclusive scan of n<=16384 ints, single block of 1024 threads (16/thread)
__global__ __launch_bounds__(1024) void exscan_kernel(const int* __restrict__ cnt,
                                                      int* __restrict__ start,
                                                      int* __restrict__ cur, int n) {
  __shared__ int sums[1024];
  int tid = threadIdx.x;
  int base = tid * 16;
  int loc[16];
  int s = 0;
#pragma unroll
  for (int k = 0; k < 16; ++k) {
    int idx = base + k;
    int v = (idx < n) ? cnt[idx] : 0;
    loc[k] = v;
    s += v;
  }
  sums[tid] = s;
  __syncthreads();
  for (int off = 1; off < 1024; off <<= 1) {
    int v = (tid >= off) ? sums[tid - off] : 0;
    __syncthreads();
    sums[tid] += v;
    __syncthreads();
  }
  int pre = (tid == 0) ? 0 : sums[tid - 1];
#pragma unroll
  for (int k = 0; k < 16; ++k) {
    int idx = base + k;
    if (idx < n) { start[idx] = pre; cur[idx] = pre; pre += loc[k]; }
  }
  if (tid == 1023) start[n] = pre;
}

__global__ void fill_kernel(const int* __restrict__ src, const int* __restrict__ dst,
                            int* cur_dst, int* cur_src, int* __restrict__ elist_dst,
                            int* __restrict__ elist_src, int* __restrict__ nid_src) {
  int e = blockIdx.x * 256 + threadIdx.x;
  if (e >= EE) return;
  int pd = atomicAdd(&cur_dst[dst[e]], 1);
  elist_dst[pd] = e;
  int s = src[e];
  int ps = atomicAdd(&cur_src[s], 1);
  elist_src[ps] = e;
  nid_src[ps] = s;
}

// ---------------- conversions ----------------

__global__ void cvt_bf16_kernel(const float* __restrict__ in, bf16_t* __restrict__ out,
                                int n4) {
  int i = blockIdx.x * 256 + threadIdx.x;
  if (i >= n4) return;
  float4 v = ((const float4*)in)[i];
  bf16x4 o;
  o[0] = (bf16_t)v.x; o[1] = (bf16_t)v.y; o[2] = (bf16_t)v.z; o[3] = (bf16_t)v.w;
  ((bf16x4*)out)[i] = o;
}

// W: f32 [K][N] row-major -> Wt: bf16 [N][K] row-major
__global__ __launch_bounds__(256) void wt_kernel(const float* __restrict__ W,
                                                 bf16_t* __restrict__ Wt, int K, int N) {
  __shared__ float tile[32][33];
  int bx = blockIdx.x * 32;  // N offset
  int by = blockIdx.y * 32;  // K offset
  int tx = threadIdx.x & 31, ty = threadIdx.x >> 5;  // ty 0..7
#pragma unroll
  for (int i = 0; i < 32; i += 8)
    tile[ty + i][tx] = W[(size_t)(by + ty + i) * N + bx + tx];
  __syncthreads();
#pragma unroll
  for (int i = 0; i < 32; i += 8)
    Wt[(size_t)(bx + ty + i) * K + by + tx] = (bf16_t)tile[tx][ty + i];
}

// ---------------- GCN conv gather (CSR by dst), bf16 xw ----------------
__global__ __launch_bounds__(256) void xconv_kernel(
    const bf16_t* __restrict__ xwb, const float* __restrict__ ew,
    const float* __restrict__ dinv, const int* __restrict__ src,
    const int* __restrict__ elist, const int* __restrict__ start,
    const float* __restrict__ gcn_b, float* __restrict__ xconv,
    bf16_t* __restrict__ xcb) {
  int i = blockIdx.x;
  int tid = threadIdx.x;
  int st = start[i], en = start[i + 1];
  float di = dinv[i];
  int c0 = tid * 2;
  __shared__ float2 scS[256];  // {coef, as_float(src_node)}
  union { unsigned u; struct { unsigned short lo, hi; } s; } pk;
  pk.u = *(const unsigned*)(xwb + (size_t)i * CC + c0);
  union { unsigned short us; bf16_t b; } c0v, c1v;
  c0v.us = pk.s.lo; c1v.us = pk.s.hi;
  float sc = di * di;
  float a0 = sc * (float)c0v.b + gcn_b[c0];
  float a1 = sc * (float)c1v.b + gcn_b[c0 + 1];
  for (int p0 = st; p0 < en; p0 += 256) {
    int m = min(256, en - p0);
    __syncthreads();
    if (tid < m) {
      int e = elist[p0 + tid];
      int sn = src[e];
      scS[tid] = make_float2(dinv[sn] * ew[e] * di, __int_as_float(sn));
    }
    __syncthreads();
    for (int j = 0; j < m; ++j) {
      float2 scv = scS[j];
      int sn = __float_as_int(scv.y);
      union { unsigned u; struct { unsigned short lo, hi; } s; } q;
      q.u = *(const unsigned*)(xwb + (size_t)sn * CC + c0);
      union { unsigned short us; bf16_t b; } v0, v1;
      v0.us = q.s.lo; v1.us = q.s.hi;
      a0 += scv.x * (float)v0.b;
      a1 += scv.x * (float)v1.b;
    }
  }
  *(float2*)(xconv + (size_t)i * CC + c0) = make_float2(a0, a1);
  xcb[(size_t)i * (2 * CC) + c0] = (bf16_t)a0;
  xcb[(size_t)i * (2 * CC) + c0 + 1] = (bf16_t)a1;
}

// ---------------- edge projection via double-MFMA ----------------
// ef = S . relu(ea @ W + b) per 32-node block; S = 0/1 selection (nodes x edges)
// 8 waves/block; wave owns 64 cols (4 col-tiles). Edge chunks of 32 (K=32, pad).
__global__ __launch_bounds__(512) void ef_mfma_kernel(
    const float* __restrict__ ea, const float* __restrict__ ep_w,
    const float* __restrict__ ep_b, const int* __restrict__ elist,
    const int* __restrict__ nid, const int* __restrict__ start,
    float* __restrict__ ef, bf16_t* __restrict__ efb) {
  const int tid = threadIdx.x;
  const int lane = tid & 63;
  const int wv = tid >> 6;    // 0..7
  const int l15 = lane & 15;
  const int g = lane >> 4;    // 0..3
  const int n0 = blockIdx.x * 32;
  const int cbase = wv * 64;

  // W B-frags (loop-invariant): k=g*8+j; k<16 -> ep_w, k==16 -> bias (A has 1.0)
  bf16x8 wfr[4];
#pragma unroll
  for (int t = 0; t < 4; ++t) {
    bf16x8 f = {};
    int c = cbase + t * 16 + l15;
    if (g < 2) {
#pragma unroll
      for (int j = 0; j < 8; ++j) f[j] = (bf16_t)ep_w[(g * 8 + j) * CC + c];
    } else if (g == 2) {
      f[0] = (bf16_t)ep_b[c];
    }
    wfr[t] = f;
  }

  const int st = start[n0];
  const int en = start[n0 + 32];

  f32x4v eacc[2][4] = {};
  const int srcA = ((g & 1) << 5) | l15;
  const int srcB = srcA | 16;
  const bool hi = (g >= 2);

  for (int cb = st; cb < en; cb += 32) {
    // ---- A-frags: ea rows for 32 edges (2 tiles of 16), K padded to 32 ----
    bf16x8 af[2];
#pragma unroll
    for (int mE = 0; mE < 2; ++mE) {
      int epos = cb + mE * 16 + l15;
      bool v = epos < en;
      bf16x8 f = {};
      if (g < 2) {
        if (v) {
          int eid = elist[epos];
          const f32x4v* p = (const f32x4v*)(ea + (size_t)eid * EFD + g * 8);
          f32x4v u0 = p[0], u1 = p[1];
#pragma unroll
          for (int r = 0; r < 4; ++r) {
            f[r] = (bf16_t)u0[r];
            f[4 + r] = (bf16_t)u1[r];
          }
        }
      } else if (g == 2) {
        if (v) f[0] = (bf16_t)1.0f;  // bias feature
      }
      af[mE] = f;
    }
    // ---- S-frags: S[node l15][edge g*8+j] ----
    int ids[8];
    {
      int e0 = cb + g * 8;
#pragma unroll
      for (int j = 0; j < 8; ++j) ids[j] = nid[e0 + j];  // padded -1 past EE
    }
    bf16x8 sf[2];
#pragma unroll
    for (int mN = 0; mN < 2; ++mN) {
      int tgt = n0 + mN * 16 + l15;
      bf16x8 f;
#pragma unroll
      for (int j = 0; j < 8; ++j)
        f[j] = (ids[j] == tgt) ? (bf16_t)1.0f : (bf16_t)0.0f;
      sf[mN] = f;
    }
    // ---- GEMM1: T = relu(ea@W + b), packed to bf16 in D-layout ----
    uint2 pb[2][4];
#pragma unroll
    for (int t = 0; t < 4; ++t) {
      f32x4v s0 = {}, s1 = {};
      s0 = __builtin_amdgcn_mfma_f32_16x16x32_bf16(af[0], wfr[t], s0, 0, 0, 0);
      s1 = __builtin_amdgcn_mfma_f32_16x16x32_bf16(af[1], wfr[t], s1, 0, 0, 0);
      union { bf16x4 v; uint2 u; } c0, c1;
#pragma unroll
      for (int r = 0; r < 4; ++r) {
        c0.v[r] = (bf16_t)fmaxf(s0[r], 0.f);
        c1.v[r] = (bf16_t)fmaxf(s1[r], 0.f);
      }
      pb[0][t] = c0.u;
      pb[1][t] = c1.u;
    }
    // ---- remap D->B frag (attn-verified shuffle pattern) + GEMM2 ----
#pragma unroll
    for (int t = 0; t < 4; ++t) {
      int a0 = __shfl((int)pb[0][t].x, srcA);
      int b0 = __shfl((int)pb[1][t].x, srcA);
      int a1 = __shfl((int)pb[0][t].y, srcA);
      int b1 = __shfl((int)pb[1][t].y, srcA);
      int a2 = __shfl((int)pb[0][t].x, srcB);
      int b2 = __shfl((int)pb[1][t].x, srcB);
      int a3 = __shfl((int)pb[0][t].y, srcB);
      int b3 = __shfl((int)pb[1][t].y, srcB);
      union { int u[4]; bf16x8 v; } pf;
      pf.u[0] = hi ? b0 : a0;
      pf.u[1] = hi ? b1 : a1;
      pf.u[2] = hi ? b2 : a2;
      pf.u[3] = hi ? b3 : a3;
      eacc[0][t] =
          __builtin_amdgcn_mfma_f32_16x16x32_bf16(sf[0], pf.v, eacc[0][t], 0, 0, 0);
      eacc[1][t] =
          __builtin_amdgcn_mfma_f32_16x16x32_bf16(sf[1], pf.v, eacc[1][t], 0, 0, 0);
    }
  }
  // ---- epilogue: D[col=l15, node=mN*16+g*4+r] ----
#pragma unroll
  for (int mN = 0; mN < 2; ++mN) {
#pragma unroll
    for (int t = 0; t < 4; ++t) {
      int c = cbase + t * 16 + l15;
#pragma unroll
      for (int r = 0; r < 4; ++r) {
        int node = n0 + mN * 16 + g * 4 + r;
        float v = eacc[mN][t][r];
        ef[(size_t)node * CC + c] = v;
        efb[(size_t)node * (2 * CC) + CC + c] = (bf16_t)v;
      }
    }
  }
}

// ---------------- bf16 MFMA GEMM (m97 structure) ----------------
__device__ __forceinline__ void gl_lds16(const bf16_t* g, bf16_t* l) {
  __builtin_amdgcn_global_load_lds(
      (const __attribute__((address_space(1))) void*)g,
      (__attribute__((address_space(3))) void*)l, 16, 0, 0);
}

template <int ACT, int OUT>
__global__ __launch_bounds__(256) void gemm_bf16_kernel(
    const bf16_t* __restrict__ A, const bf16_t* __restrict__ Bt,
    const float* __restrict__ bias, void* __restrict__ Cout, int M, int N, int K) {
  __shared__ __align__(16) bf16_t Al[128 * 32];
  __shared__ __align__(16) bf16_t Bl[128 * 32];
  const int tid = threadIdx.x;
  const int lane = tid & 63;
  const int wave = tid >> 6;
  const int row0 = blockIdx.y * 128;
  const int col0 = blockIdx.x * 128;
  const int wm = (wave >> 1) * 64;
  const int wn = (wave & 1) * 64;
  f32x4v acc[4][4] = {};
  const bf16_t* aBase = A + (size_t)(row0 + (tid >> 2)) * K + (tid & 3) * 8;
  const bf16_t* bBase = Bt + (size_t)(col0 + (tid >> 2)) * K + (tid & 3) * 8;
  bf16_t* al0 = Al + wave * 512;
  bf16_t* al1 = Al + 2048 + wave * 512;
  bf16_t* bl0 = Bl + wave * 512;
  bf16_t* bl1 = Bl + 2048 + wave * 512;
  const int fr = lane & 15;
  const int fk = (lane >> 4) * 8;
  for (int k0 = 0; k0 < K; k0 += 32) {
    gl_lds16(aBase + k0, al0);
    gl_lds16(aBase + (size_t)64 * K + k0, al1);
    gl_lds16(bBase + k0, bl0);
    gl_lds16(bBase + (size_t)64 * K + k0, bl1);
    __syncthreads();
    bf16x8 af[4], bfv[4];
#pragma unroll
    for (int m = 0; m < 4; ++m)
      af[m] = *(const bf16x8*)(Al + (wm + m * 16 + fr) * 32 + fk);
#pragma unroll
    for (int n = 0; n < 4; ++n)
      bfv[n] = *(const bf16x8*)(Bl + (wn + n * 16 + fr) * 32 + fk);
#pragma unroll
    for (int m = 0; m < 4; ++m)
#pragma unroll
      for (int n = 0; n < 4; ++n)
        acc[m][n] =
            __builtin_amdgcn_mfma_f32_16x16x32_bf16(af[m], bfv[n], acc[m][n], 0, 0, 0);
    __syncthreads();
  }
  const int fq = (lane >> 4) * 4;
#pragma unroll
  for (int m = 0; m < 4; ++m) {
    int grb = row0 + wm + m * 16 + fq;
#pragma unroll
    for (int n = 0; n < 4; ++n) {
      int gc = col0 + wn + n * 16 + fr;
      float bv = bias ? bias[gc] : 0.f;
#pragma unroll
      for (int r = 0; r < 4; ++r) {
        float v = acc[m][n][r] + bv;
        if (ACT == 1) v = v / (1.f + __expf(-v));
        if (OUT == 0)
          ((float*)Cout)[(size_t)(grb + r) * N + gc] = v;
        else
          ((bf16_t*)Cout)[(size_t)(grb + r) * N + gc] = (bf16_t)v;
      }
    }
  }
}

// ---------------- layernorm fused kernels ----------------

__device__ inline void block_reduce2(float& s, float& q, float* red) {
#pragma unroll
  for (int off = 32; off >= 1; off >>= 1) {
    s += __shfl_xor(s, off, 64);
    q += __shfl_xor(q, off, 64);
  }
  int wid = threadIdx.x >> 6;
  if ((threadIdx.x & 63) == 0) { red[wid * 2] = s; red[wid * 2 + 1] = q; }
  __syncthreads();
  s = red[0] + red[2] + red[4] + red[6];
  q = red[1] + red[3] + red[5] + red[7];
}

__global__ __launch_bounds__(256) void ln_add_kernel(const float* __restrict__ A,
                                                     const float* __restrict__ Bb,
                                                     const float* __restrict__ g,
                                                     const float* __restrict__ be,
                                                     float* __restrict__ out,
                                                     bf16_t* __restrict__ bout) {
  int row = blockIdx.x, tid = threadIdx.x, c0 = tid * 2;
  __shared__ float red[8];
  float2 a = *(const float2*)(A + (size_t)row * CC + c0);
  float2 b = *(const float2*)(Bb + (size_t)row * CC + c0);
  float x0 = a.x + b.x, x1 = a.y + b.y;
  float s = x0 + x1, q = x0 * x0 + x1 * x1;
  block_reduce2(s, q, red);
  float mean = s * (1.f / CC);
  float var = q * (1.f / CC) - mean * mean;
  float rs = rsqrtf(var + 1e-5f);
  float o0 = (x0 - mean) * rs * g[c0] + be[c0];
  float o1 = (x1 - mean) * rs * g[c0 + 1] + be[c0 + 1];
  *(float2*)(out + (size_t)row * CC + c0) = make_float2(o0, o1);
  if (bout) {
    bout[(size_t)row * CC + c0] = (bf16_t)o0;
    bout[(size_t)row * CC + c0 + 1] = (bf16_t)o1;
  }
}

__global__ __launch_bounds__(256) void ln_gate_kernel(
    const float* __restrict__ gpre, const float* __restrict__ gate_b,
    const float* __restrict__ xc, const float* __restrict__ ef,
    const float* __restrict__ n1g, const float* __restrict__ n1b,
    const float* __restrict__ xin, float* __restrict__ x2, bf16_t* __restrict__ x2b) {
  int row = blockIdx.x, tid = threadIdx.x, c0 = tid * 2;
  __shared__ float red[8];
  float2 gp = *(const float2*)(gpre + (size_t)row * CC + c0);
  float2 xcv = *(const float2*)(xc + (size_t)row * CC + c0);
  float2 efv = *(const float2*)(ef + (size_t)row * CC + c0);
  float g0 = 1.f / (1.f + __expf(-(gp.x + gate_b[c0])));
  float g1 = 1.f / (1.f + __expf(-(gp.y + gate_b[c0 + 1])));
  float x0 = g0 * xcv.x + (1.f - g0) * efv.x;
  float x1 = g1 * xcv.y + (1.f - g1) * efv.y;
  float s = x0 + x1, q = x0 * x0 + x1 * x1;
  block_reduce2(s, q, red);
  float mean = s * (1.f / CC);
  float var = q * (1.f / CC) - mean * mean;
  float rs = rsqrtf(var + 1e-5f);
  float2 xi = *(const float2*)(xin + (size_t)row * CC + c0);
  float o0 = fmaxf((x0 - mean) * rs * n1g[c0] + n1b[c0], 0.f) + xi.x;
  float o1 = fmaxf((x1 - mean) * rs * n1g[c0 + 1] + n1b[c0 + 1], 0.f) + xi.y;
  *(float2*)(x2 + (size_t)row * CC + c0) = make_float2(o0, o1);
  x2b[(size_t)row * CC + c0] = (bf16_t)o0;
  x2b[(size_t)row * CC + c0 + 1] = (bf16_t)o1;
}

// ---------------- V^T pack (pre-swizzled for attn LDS) ----------------
__global__ __launch_bounds__(256) void vt_pack_kernel(const bf16_t* __restrict__ qkvb,
                                                      bf16_t* __restrict__ vt) {
  int b = blockIdx.x >> 3, h = blockIdx.x & 7;
  int nb = b * 256;
  size_t voff = 1024 + (size_t)h * 64;
  char* out = (char*)(vt + (size_t)blockIdx.x * (64 * 256));
  __shared__ bf16_t tile[64][80];
  int tid = threadIdx.x;
  for (int kb = 0; kb < 4; ++kb) {
    __syncthreads();
#pragma unroll
    for (int p = 0; p < 2; ++p) {
      int k = p * 32 + (tid >> 3);
      int d8 = tid & 7;
      bf16x8 v = *(const bf16x8*)(qkvb + (size_t)(nb + kb * 64 + k) * 1536 + voff + d8 * 8);
      *(bf16x8*)(&tile[k][d8 * 8]) = v;
    }
    __syncthreads();
#pragma unroll
    for (int p = 0; p < 2; ++p) {
      int d = p * 32 + (tid >> 3);
      int k8 = tid & 7;
      bf16x8 v;
#pragma unroll
      for (int j = 0; j < 8; ++j) v[j] = tile[k8 * 8 + j][d];
      int byteoff = d * 512 + ((kb * 128 + k8 * 16) ^ ((d & 7) << 4));
      *(bf16x8*)(out + byteoff) = v;
    }
  }
}

// ---------------- MFMA attention: one block per (b,h), 4 waves x 64 q-rows --
__global__ __launch_bounds__(256, 2) void attn_mfma_kernel(
    const bf16_t* __restrict__ qkvb, const bf16_t* __restrict__ vt,
    bf16_t* __restrict__ o) {
  const int b = blockIdx.x >> 3;
  const int h = blockIdx.x & 7;
  const int nb = b * 256;
  const int tid = threadIdx.x;
  const int lane = tid & 63;
  const int wv = tid >> 6;
  const int l15 = lane & 15;
  const int g = lane >> 4;
  const int swzk = (l15 & 7) << 4;
  __shared__ __align__(16) bf16_t Klds[256 * 64];
  __shared__ __align__(16) bf16_t Vtlds[64 * 256];
  const size_t qoff = (size_t)h * 64;
  const size_t koff = 512 + (size_t)h * 64;

  {
    const int dcol = 16 * ((tid & 7) ^ ((tid >> 3) & 7));
    const bf16_t* srcb = qkvb + koff + (dcol >> 1);
#pragma unroll
    for (int i = 0; i < 8; ++i) {
      int k = i * 32 + (tid >> 3);
      gl_lds16(srcb + (size_t)(nb + k) * 1536, Klds + ((i * 4096 + wv * 1024) >> 1));
    }
  }
  {
    const bf16_t* vsrc = vt + (size_t)blockIdx.x * (64 * 256);
#pragma unroll
    for (int i = 0; i < 8; ++i) {
      int base = i * 4096 + wv * 1024;
      gl_lds16(vsrc + ((base >> 1) + lane * 8), Vtlds + (base >> 1));
    }
  }

  bf16x8 qf[4][2];
#pragma unroll
  for (int n = 0; n < 4; ++n) {
    const bf16_t* qp = qkvb + (size_t)(nb + wv * 64 + 16 * n + l15) * 1536 + qoff + g * 8;
    qf[n][0] = *(const bf16x8*)(qp);
    qf[n][1] = *(const bf16x8*)(qp + 32);
  }

  __syncthreads();

  f32x4v oacc[4][4] = {};
  float mrun[4] = {-1e30f, -1e30f, -1e30f, -1e30f};
  float lrun[4] = {0.f, 0.f, 0.f, 0.f};
  const int srcA = ((g & 1) << 5) | l15;
  const int srcB = srcA | 16;

  for (int kc = 0; kc < 4; ++kc) {
    f32x4v sacc[4][4] = {};
    const int kb128 = (kc * 64 + l15) * 128;
#pragma unroll
    for (int m = 0; m < 4; ++m) {
      bf16x8 a0 = *(const bf16x8*)(Klds + ((kb128 + m * 2048 + ((g * 16) ^ swzk)) >> 1));
      bf16x8 a1 =
          *(const bf16x8*)(Klds + ((kb128 + m * 2048 + ((64 + g * 16) ^ swzk)) >> 1));
#pragma unroll
      for (int n = 0; n < 4; ++n) {
        sacc[m][n] = __builtin_amdgcn_mfma_f32_16x16x32_bf16(a0, qf[n][0], sacc[m][n], 0, 0, 0);
        sacc[m][n] = __builtin_amdgcn_mfma_f32_16x16x32_bf16(a1, qf[n][1], sacc[m][n], 0, 0, 0);
      }
    }
    uint2 pb[4][4];
#pragma unroll
    for (int n = 0; n < 4; ++n) {
      float mx = sacc[0][n][0];
#pragma unroll
      for (int m = 0; m < 4; ++m)
#pragma unroll
        for (int r = 0; r < 4; ++r) mx = fmaxf(mx, sacc[m][n][r]);
      mx = fmaxf(mx, __shfl_xor(mx, 16));
      mx = fmaxf(mx, __shfl_xor(mx, 32));
      float mnew = fmaxf(mrun[n], mx);
      float c = __expf((mrun[n] - mnew) * 0.125f);
      mrun[n] = mnew;
      float s = 0.f;
#pragma unroll
      for (int m = 0; m < 4; ++m) {
        float p0 = __expf((sacc[m][n][0] - mnew) * 0.125f);
        float p1 = __expf((sacc[m][n][1] - mnew) * 0.125f);
        float p2 = __expf((sacc[m][n][2] - mnew) * 0.125f);
        float p3 = __expf((sacc[m][n][3] - mnew) * 0.125f);
        s += (p0 + p1) + (p2 + p3);
        union { bf16x4 v; uint2 u; } cv;
        cv.v[0] = (bf16_t)p0; cv.v[1] = (bf16_t)p1;
        cv.v[2] = (bf16_t)p2; cv.v[3] = (bf16_t)p3;
        pb[m][n] = cv.u;
      }
      s += __shfl_xor(s, 16);
      s += __shfl_xor(s, 32);
      lrun[n] = lrun[n] * c + s;
#pragma unroll
      for (int m = 0; m < 4; ++m)
#pragma unroll
        for (int r = 0; r < 4; ++r) oacc[m][n][r] *= c;
    }
#pragma unroll
    for (int h2 = 0; h2 < 2; ++h2) {
      bf16x8 vf[4];
#pragma unroll
      for (int m = 0; m < 4; ++m)
        vf[m] = *(const bf16x8*)(Vtlds + (((16 * m + l15) * 512 +
                                          ((kc * 128 + h2 * 64 + g * 16) ^ swzk)) >> 1));
#pragma unroll
      for (int n = 0; n < 4; ++n) {
        int a0 = __shfl((int)pb[2 * h2][n].x, srcA);
        int b0 = __shfl((int)pb[2 * h2 + 1][n].x, srcA);
        int a1 = __shfl((int)pb[2 * h2][n].y, srcA);
        int b1 = __shfl((int)pb[2 * h2 + 1][n].y, srcA);
        int a2 = __shfl((int)pb[2 * h2][n].x, srcB);
        int b2 = __shfl((int)pb[2 * h2 + 1][n].x, srcB);
        int a3 = __shfl((int)pb[2 * h2][n].y, srcB);
        int b3 = __shfl((int)pb[2 * h2 + 1][n].y, srcB);
        union { int u[4]; bf16x8 v; } pf;
        bool hi = (g >= 2);
        pf.u[0] = hi ? b0 : a0;
        pf.u[1] = hi ? b1 : a1;
        pf.u[2] = hi ? b2 : a2;
        pf.u[3] = hi ? b3 : a3;
#pragma unroll
        for (int m = 0; m < 4; ++m)
          oacc[m][n] =
              __builtin_amdgcn_mfma_f32_16x16x32_bf16(vf[m], pf.v, oacc[m][n], 0, 0, 0);
      }
    }
  }
  float inv[4];
#pragma unroll
  for (int n = 0; n < 4; ++n) inv[n] = 1.0f / lrun[n];
#pragma unroll
  for (int m = 0; m < 4; ++m)
#pragma unroll
    for (int n = 0; n < 4; ++n) {
      bf16x4 pk;
#pragma unroll
      for (int r = 0; r < 4; ++r) pk[r] = (bf16_t)(oacc[m][n][r] * inv[n]);
      *(bf16x4*)(o + (size_t)(nb + wv * 64 + 16 * n + l15) * 512 + h * 64 + 16 * m +
                 4 * g) = pk;
    }
}

// ---------------- launch ----------------

static inline char* alignp(char* p, size_t a) {
  return (char*)(((uintptr_t)p + a - 1) & ~(uintptr_t)(a - 1));
}

extern "C" void kernel_launch(void* const* d_in, const int* in_sizes, int n_in,
                              void* d_out, int out_size, void* d_ws, size_t ws_size,
                              hipStream_t stream) {
  const float* x = (const float*)d_in[0];
  const float* edge_attr = (const float*)d_in[1];
  const float* gcn_w = (const float*)d_in[2];
  const float* gcn_b = (const float*)d_in[3];
  const float* ep_w = (const float*)d_in[4];
  const float* ep_b = (const float*)d_in[5];
  const float* gate_w = (const float*)d_in[6];
  const float* gate_b = (const float*)d_in[7];
  const float* n1_g = (const float*)d_in[8];
  const float* n1_b = (const float*)d_in[9];
  const float* in_w = (const float*)d_in[10];
  const float* in_b = (const float*)d_in[11];
  const float* out_w = (const float*)d_in[12];
  const float* out_b = (const float*)d_in[13];
  const float* tn_g = (const float*)d_in[14];
  const float* tn_b = (const float*)d_in[15];
  const float* m_w1 = (const float*)d_in[16];
  const float* m_b1 = (const float*)d_in[17];
  const float* m_w2 = (const float*)d_in[18];
  const float* m_b2 = (const float*)d_in[19];
  const float* fn_g = (const float*)d_in[20];
  const float* fn_b = (const float*)d_in[21];
  const int* eidx = (const int*)d_in[22];
  const int* src = eidx;
  const int* dst = eidx + EE;

  float* ws = (float*)d_ws;
  float* R1 = ws;
  float* R2 = R1 + (size_t)NN * 3 * CC;
  float* R3 = R2 + (size_t)NN * CC;
  float* R4 = R3 + (size_t)NN * CC;
  float* ew = R4 + (size_t)NN * CC;
  float* deg = ew + EE;
  float* dinv = deg + NN;
  int* ip = (int*)(dinv + NN);
  int* cnt_dst = ip;    ip += NN;
  int* start_dst = ip;  ip += NN + 1;
  int* cur_dst = ip;    ip += NN;
  int* cnt_src = ip;    ip += NN;
  int* start_src = ip;  ip += NN + 1;
  int* cur_src = ip;    ip += NN;
  int* elist_dst = ip;  ip += EE;
  int* elist_src = ip;  ip += EE;
  int* nid_src = ip;    ip += EE + 32;
  char* bp = alignp((char*)ip, 64);
  bf16_t* x2b = (bf16_t*)bp;          bp += (size_t)NN * CC * 2;
  bf16_t* gcn_wt = (bf16_t*)bp;       bp += (size_t)CC * CC * 2;
  bf16_t* gate_wt = (bf16_t*)bp;      bp += (size_t)CC * 2 * CC * 2;
  bf16_t* in_wt = (bf16_t*)bp;        bp += (size_t)3 * CC * CC * 2;
  bf16_t* out_wt = (bf16_t*)bp;       bp += (size_t)CC * CC * 2;
  bf16_t* m_w1t = (bf16_t*)bp;        bp += (size_t)2 * CC * CC * 2;
  bf16_t* m_w2t = (bf16_t*)bp;        bp += (size_t)CC * 2 * CC * 2;

  bf16_t* xb = (bf16_t*)R1;      // bf16(x)
  bf16_t* xcefb = (bf16_t*)R1;   // [x_conv | ef] bf16 N x 2C
  bf16_t* qkvb = (bf16_t*)R1;    // qkv bf16 N x 1536
  bf16_t* hb = (bf16_t*)R1;      // mlp hidden bf16 N x 2C
  bf16_t* xwb = (bf16_t*)R2;     // bf16 xw (GCN GEMM out)
  bf16_t* ob = (bf16_t*)R2;      // attn out bf16 (first half of R2)
  bf16_t* vt = ob + (size_t)NN * CC;  // V^T packed (second half of R2)
  bf16_t* x3b = (bf16_t*)R2;     // bf16(x3) (after ob dead)
  float* x2 = (float*)d_out;

  // --- edge prep ---
  init_kernel<<<(NN + 255) / 256, 256, 0, stream>>>(deg, cnt_dst, cnt_src, nid_src);
  edge_pass1<<<(EE + 255) / 256, 256, 0, stream>>>(edge_attr, src, dst, ew, deg,
                                                   cnt_dst, cnt_src);
  node_pass<<<(NN + 255) / 256, 256, 0, stream>>>(deg, dinv);
  exscan_kernel<<<1, 1024, 0, stream>>>(cnt_dst, start_dst, cur_dst, NN);
  exscan_kernel<<<1, 1024, 0, stream>>>(cnt_src, start_src, cur_src, NN);
  fill_kernel<<<(EE + 255) / 256, 256, 0, stream>>>(src, dst, cur_dst, cur_src,
                                                    elist_dst, elist_src, nid_src);

  // --- weight transposes ---
  wt_kernel<<<dim3(CC / 32, CC / 32), 256, 0, stream>>>(gcn_w, gcn_wt, CC, CC);
  wt_kernel<<<dim3(CC / 32, 2 * CC / 32), 256, 0, stream>>>(gate_w, gate_wt, 2 * CC, CC);
  wt_kernel<<<dim3(3 * CC / 32, CC / 32), 256, 0, stream>>>(in_w, in_wt, CC, 3 * CC);
  wt_kernel<<<dim3(CC / 32, CC / 32), 256, 0, stream>>>(out_w, out_wt, CC, CC);
  wt_kernel<<<dim3(2 * CC / 32, CC / 32), 256, 0, stream>>>(m_w1, m_w1t, CC, 2 * CC);
  wt_kernel<<<dim3(CC / 32, 2 * CC / 32), 256, 0, stream>>>(m_w2, m_w2t, 2 * CC, CC);

  // --- GCN conv ---
  cvt_bf16_kernel<<<(NN * CC / 4 + 255) / 256, 256, 0, stream>>>(x, xb, NN * CC / 4);
  dim3 gA(CC / 128, NN / 128);
  gemm_bf16_kernel<0, 1><<<gA, 256, 0, stream>>>(xb, gcn_wt, nullptr, xwb, NN, CC, CC);
  xconv_kernel<<<NN, 256, 0, stream>>>(xwb, ew, dinv, src, elist_dst, start_dst,
                                       gcn_b, R3, xcefb);
  ef_mfma_kernel<<<NN / 32, 512, 0, stream>>>(edge_attr, ep_w, ep_b, elist_src,
                                              nid_src, start_src, R4, xcefb);
  gemm_bf16_kernel<0, 0><<<gA, 256, 0, stream>>>(xcefb, gate_wt, nullptr, R2, NN, CC,
                                                 2 * CC);
  ln_gate_kernel<<<NN, 256, 0, stream>>>(R2, gate_b, R3, R4, n1_g, n1_b, x, x2, x2b);

  // --- MHA ---
  dim3 gQ(3 * CC / 128, NN / 128);
  gemm_bf16_kernel<0, 1><<<gQ, 256, 0, stream>>>(x2b, in_wt, in_b, qkvb, NN, 3 * CC, CC);
  vt_pack_kernel<<<BB * HH, 256, 0, stream>>>(qkvb, vt);
  attn_mfma_kernel<<<BB * HH, 256, 0, stream>>>(qkvb, vt, ob);
  gemm_bf16_kernel<0, 0><<<gA, 256, 0, stream>>>(ob, out_wt, out_b, R4, NN, CC, CC);
  ln_add_kernel<<<NN, 256, 0, stream>>>(x2, R4, tn_g, tn_b, R3, x3b);

  // --- MLP ---
  dim3 gH(2 * CC / 128, NN / 128);
  gemm_bf16_kernel<1, 1><<<gH, 256, 0, stream>>>(x3b, m_w1t, m_b1, hb, NN, 2 * CC, CC);
  gemm_bf16_kernel<0, 0><<<gA, 256, 0, stream>>>(hb, m_w2t, m_b2, R4, NN, CC, 2 * CC);
  ln_add_kernel<<<NN, 256, 0, stream>>>(R3, R4, fn_g, fn_b, (float*)d_out, nullptr);
}

// Round 6
// 664.942 us; speedup vs baseline: 1.2131x; 1.0189x over previous
//
#include <hip/hip_runtime.h>

#define NN 16384
#define CC 512
#define EE 524288
#define BB 64
#define HH 8
#define EFD 16

typedef __bf16 bf16_t;
typedef __bf16 bf16x4 __attribute__((ext_vector_type(4)));
typedef __bf16 bf16x8 __attribute__((ext_vector_type(8)));
typedef float f32x4v __attribute__((ext_vector_type(4)));

// ---------------- init / edge pre-pass ----------------

__global__ void init_kernel(float* deg, int* cnt_dst, int* cnt_src, int* nid_src) {
  int i = blockIdx.x * 256 + threadIdx.x;
  if (i < NN) { deg[i] = 1.0f; cnt_dst[i] = 0; cnt_src[i] = 0; }
  if (i < 32) nid_src[EE + i] = -1;  // pad for ef chunk tail
}

__global__ void edge_pass1(const float* __restrict__ ea, const int* __restrict__ src,
                           const int* __restrict__ dst, float* __restrict__ ew,
                           float* deg, int* cnt_dst, int* cnt_src) {
  int e = blockIdx.x * 256 + threadIdx.x;
  if (e >= EE) return;
  const float4* p = (const float4*)(ea + (size_t)e * EFD);
  float s = 0.f;
#pragma unroll
  for (int i = 0; i < 4; ++i) {
    float4 v = p[i];
    s += v.x * v.x + v.y * v.y + v.z * v.z + v.w * v.w;
  }
  float w = sqrtf(s);
  ew[e] = w;
  atomicAdd(&deg[dst[e]], w);
  atomicAdd(&cnt_dst[dst[e]], 1);
  atomicAdd(&cnt_src[src[e]], 1);
}

__global__ void node_pass(const float* __restrict__ deg, float* __restrict__ dinv) {
  int i = blockIdx.x * 256 + threadIdx.x;
  if (i >= NN) return;
  float d = deg[i];
  dinv[i] = d > 0.f ? rsqrtf(fmaxf(d, 1e-12f)) : 0.f;
}

// exclusive scan of n<=16384 ints, single block of 1024 threads (16/thread)
__global__ __launch_bounds__(1024) void exscan_kernel(const int* __restrict__ cnt,
                                                      int* __restrict__ start,
                                                      int* __restrict__ cur, int n) {
  __shared__ int sums[1024];
  int tid = threadIdx.x;
  int base = tid * 16;
  int loc[16];
  int s = 0;
#pragma unroll
  for (int k = 0; k < 16; ++k) {
    int idx = base + k;
    int v = (idx < n) ? cnt[idx] : 0;
    loc[k] = v;
    s += v;
  }
  sums[tid] = s;
  __syncthreads();
  for (int off = 1; off < 1024; off <<= 1) {
    int v = (tid >= off) ? sums[tid - off] : 0;
    __syncthreads();
    sums[tid] += v;
    __syncthreads();
  }
  int pre = (tid == 0) ? 0 : sums[tid - 1];
#pragma unroll
  for (int k = 0; k < 16; ++k) {
    int idx = base + k;
    if (idx < n) { start[idx] = pre; cur[idx] = pre; pre += loc[k]; }
  }
  if (tid == 1023) start[n] = pre;
}

__global__ void fill_kernel(const int* __restrict__ src, const int* __restrict__ dst,
                            int* cur_dst, int* cur_src, int* __restrict__ elist_dst,
                            int* __restrict__ elist_src, int* __restrict__ nid_src) {
  int e = blockIdx.x * 256 + threadIdx.x;
  if (e >= EE) return;
  int pd = atomicAdd(&cur_dst[dst[e]], 1);
  elist_dst[pd] = e;
  int s = src[e];
  int ps = atomicAdd(&cur_src[s], 1);
  elist_src[ps] = e;
  nid_src[ps] = s;
}

// ---------------- conversions ----------------

__global__ void cvt_bf16_kernel(const float* __restrict__ in, bf16_t* __restrict__ out,
                                int n4) {
  int i = blockIdx.x * 256 + threadIdx.x;
  if (i >= n4) return;
  float4 v = ((const float4*)in)[i];
  bf16x4 o;
  o[0] = (bf16_t)v.x; o[1] = (bf16_t)v.y; o[2] = (bf16_t)v.z; o[3] = (bf16_t)v.w;
  ((bf16x4*)out)[i] = o;
}

// W: f32 [K][N] row-major -> Wt: bf16 [N][K] row-major
__global__ __launch_bounds__(256) void wt_kernel(const float* __restrict__ W,
                                                 bf16_t* __restrict__ Wt, int K, int N) {
  __shared__ float tile[32][33];
  int bx = blockIdx.x * 32;  // N offset
  int by = blockIdx.y * 32;  // K offset
  int tx = threadIdx.x & 31, ty = threadIdx.x >> 5;  // ty 0..7
#pragma unroll
  for (int i = 0; i < 32; i += 8)
    tile[ty + i][tx] = W[(size_t)(by + ty + i) * N + bx + tx];
  __syncthreads();
#pragma unroll
  for (int i = 0; i < 32; i += 8)
    Wt[(size_t)(bx + ty + i) * K + by + tx] = (bf16_t)tile[tx][ty + i];
}

// ---------------- GCN conv gather (CSR by dst), bf16 xw ----------------
__global__ __launch_bounds__(256) void xconv_kernel(
    const bf16_t* __restrict__ xwb, const float* __restrict__ ew,
    const float* __restrict__ dinv, const int* __restrict__ src,
    const int* __restrict__ elist, const int* __restrict__ start,
    const float* __restrict__ gcn_b, float* __restrict__ xconv,
    bf16_t* __restrict__ xcb) {
  int i = blockIdx.x;
  int tid = threadIdx.x;
  int st = start[i], en = start[i + 1];
  float di = dinv[i];
  int c0 = tid * 2;
  __shared__ float2 scS[256];  // {coef, as_float(src_node)}
  union { unsigned u; struct { unsigned short lo, hi; } s; } pk;
  pk.u = *(const unsigned*)(xwb + (size_t)i * CC + c0);
  union { unsigned short us; bf16_t b; } c0v, c1v;
  c0v.us = pk.s.lo; c1v.us = pk.s.hi;
  float sc = di * di;
  float a0 = sc * (float)c0v.b + gcn_b[c0];
  float a1 = sc * (float)c1v.b + gcn_b[c0 + 1];
  for (int p0 = st; p0 < en; p0 += 256) {
    int m = min(256, en - p0);
    __syncthreads();
    if (tid < m) {
      int e = elist[p0 + tid];
      int sn = src[e];
      scS[tid] = make_float2(dinv[sn] * ew[e] * di, __int_as_float(sn));
    }
    __syncthreads();
    for (int j = 0; j < m; ++j) {
      float2 scv = scS[j];
      int sn = __float_as_int(scv.y);
      union { unsigned u; struct { unsigned short lo, hi; } s; } q;
      q.u = *(const unsigned*)(xwb + (size_t)sn * CC + c0);
      union { unsigned short us; bf16_t b; } v0, v1;
      v0.us = q.s.lo; v1.us = q.s.hi;
      a0 += scv.x * (float)v0.b;
      a1 += scv.x * (float)v1.b;
    }
  }
  *(float2*)(xconv + (size_t)i * CC + c0) = make_float2(a0, a1);
  xcb[(size_t)i * (2 * CC) + c0] = (bf16_t)a0;
  xcb[(size_t)i * (2 * CC) + c0 + 1] = (bf16_t)a1;
}

// ---------------- edge projection via double-MFMA (shuffle-free) ----------
// ef = S . relu(ea @ W + b) per 32-node block; S = 0/1 selection.
// K-order of GEMM2 permuted by pi(g*8+j) = g*4+(j&3)+16*(j>>2) so that each
// lane's GEMM1 D-frags concat directly into its GEMM2 B-frag (no shuffles).
__global__ __launch_bounds__(512) void ef_mfma_kernel(
    const float* __restrict__ ea, const float* __restrict__ ep_w,
    const float* __restrict__ ep_b, const int* __restrict__ elist,
    const int* __restrict__ nid, const int* __restrict__ start,
    float* __restrict__ ef, bf16_t* __restrict__ efb) {
  const int tid = threadIdx.x;
  const int lane = tid & 63;
  const int wv = tid >> 6;    // 0..7
  const int l15 = lane & 15;
  const int g = lane >> 4;    // 0..3
  const int n0 = blockIdx.x * 32;
  const int cbase = wv * 64;

  // W B-frags (loop-invariant): k=g*8+j; k<16 -> ep_w, k==16 -> bias (A has 1.0)
  bf16x8 wfr[4];
#pragma unroll
  for (int t = 0; t < 4; ++t) {
    bf16x8 f = {};
    int c = cbase + t * 16 + l15;
    if (g < 2) {
#pragma unroll
      for (int j = 0; j < 8; ++j) f[j] = (bf16_t)ep_w[(g * 8 + j) * CC + c];
    } else if (g == 2) {
      f[0] = (bf16_t)ep_b[c];
    }
    wfr[t] = f;
  }

  const int st = start[n0];
  const int en = start[n0 + 32];

  f32x4v eacc[2][4] = {};

  for (int cb = st; cb < en; cb += 32) {
    // ---- A-frags: ea rows for 32 edges (2 tiles of 16), K padded to 32 ----
    bf16x8 af[2];
#pragma unroll
    for (int mE = 0; mE < 2; ++mE) {
      int epos = cb + mE * 16 + l15;
      bool v = epos < en;
      bf16x8 f = {};
      if (g < 2) {
        if (v) {
          int eid = elist[epos];
          const f32x4v* p = (const f32x4v*)(ea + (size_t)eid * EFD + g * 8);
          f32x4v u0 = p[0], u1 = p[1];
#pragma unroll
          for (int r = 0; r < 4; ++r) {
            f[r] = (bf16_t)u0[r];
            f[4 + r] = (bf16_t)u1[r];
          }
        }
      } else if (g == 2) {
        if (v) f[0] = (bf16_t)1.0f;  // bias feature
      }
      af[mE] = f;
    }
    // ---- S-frags with permuted K: element j <-> edge cb + pi(g*8+j) ----
    // pi positions: j<4 -> g*4+j ; j>=4 -> 16+g*4+(j-4). Two int4 loads.
    int4 idlo = *(const int4*)(nid + cb + g * 4);
    int4 idhi = *(const int4*)(nid + cb + 16 + g * 4);
    bf16x8 sf[2];
#pragma unroll
    for (int mN = 0; mN < 2; ++mN) {
      int tgt = n0 + mN * 16 + l15;
      bf16x8 f;
      f[0] = (idlo.x == tgt) ? (bf16_t)1.0f : (bf16_t)0.0f;
      f[1] = (idlo.y == tgt) ? (bf16_t)1.0f : (bf16_t)0.0f;
      f[2] = (idlo.z == tgt) ? (bf16_t)1.0f : (bf16_t)0.0f;
      f[3] = (idlo.w == tgt) ? (bf16_t)1.0f : (bf16_t)0.0f;
      f[4] = (idhi.x == tgt) ? (bf16_t)1.0f : (bf16_t)0.0f;
      f[5] = (idhi.y == tgt) ? (bf16_t)1.0f : (bf16_t)0.0f;
      f[6] = (idhi.z == tgt) ? (bf16_t)1.0f : (bf16_t)0.0f;
      f[7] = (idhi.w == tgt) ? (bf16_t)1.0f : (bf16_t)0.0f;
      sf[mN] = f;
    }
    // ---- GEMM1 + relu + pack; GEMM2 B-frag = concat(D0, D1) ----
#pragma unroll
    for (int t = 0; t < 4; ++t) {
      f32x4v s0 = {}, s1 = {};
      s0 = __builtin_amdgcn_mfma_f32_16x16x32_bf16(af[0], wfr[t], s0, 0, 0, 0);
      s1 = __builtin_amdgcn_mfma_f32_16x16x32_bf16(af[1], wfr[t], s1, 0, 0, 0);
      union { bf16x8 v; bf16x4 h[2]; } pf;
#pragma unroll
      for (int r = 0; r < 4; ++r) {
        pf.h[0][r] = (bf16_t)fmaxf(s0[r], 0.f);
        pf.h[1][r] = (bf16_t)fmaxf(s1[r], 0.f);
      }
      eacc[0][t] =
          __builtin_amdgcn_mfma_f32_16x16x32_bf16(sf[0], pf.v, eacc[0][t], 0, 0, 0);
      eacc[1][t] =
          __builtin_amdgcn_mfma_f32_16x16x32_bf16(sf[1], pf.v, eacc[1][t], 0, 0, 0);
    }
  }
  // ---- epilogue: D[col=l15, node=mN*16+g*4+r] ----
#pragma unroll
  for (int mN = 0; mN < 2; ++mN) {
#pragma unroll
    for (int t = 0; t < 4; ++t) {
      int c = cbase + t * 16 + l15;
#pragma unroll
      for (int r = 0; r < 4; ++r) {
        int node = n0 + mN * 16 + g * 4 + r;
        float v = eacc[mN][t][r];
        ef[(size_t)node * CC + c] = v;
        efb[(size_t)node * (2 * CC) + CC + c] = (bf16_t)v;
      }
    }
  }
}

// ---------------- bf16 MFMA GEMM (m97 structure) ----------------
__device__ __forceinline__ void gl_lds16(const bf16_t* g, bf16_t* l) {
  __builtin_amdgcn_global_load_lds(
      (const __attribute__((address_space(1))) void*)g,
      (__attribute__((address_space(3))) void*)l, 16, 0, 0);
}

template <int ACT, int OUT>
__global__ __launch_bounds__(256) void gemm_bf16_kernel(
    const bf16_t* __restrict__ A, const bf16_t* __restrict__ Bt,
    const float* __restrict__ bias, void* __restrict__ Cout, int M, int N, int K) {
  __shared__ __align__(16) bf16_t Al[128 * 32];
  __shared__ __align__(16) bf16_t Bl[128 * 32];
  const int tid = threadIdx.x;
  const int lane = tid & 63;
  const int wave = tid >> 6;
  const int row0 = blockIdx.y * 128;
  const int col0 = blockIdx.x * 128;
  const int wm = (wave >> 1) * 64;
  const int wn = (wave & 1) * 64;
  f32x4v acc[4][4] = {};
  const bf16_t* aBase = A + (size_t)(row0 + (tid >> 2)) * K + (tid & 3) * 8;
  const bf16_t* bBase = Bt + (size_t)(col0 + (tid >> 2)) * K + (tid & 3) * 8;
  bf16_t* al0 = Al + wave * 512;
  bf16_t* al1 = Al + 2048 + wave * 512;
  bf16_t* bl0 = Bl + wave * 512;
  bf16_t* bl1 = Bl + 2048 + wave * 512;
  const int fr = lane & 15;
  const int fk = (lane >> 4) * 8;
  for (int k0 = 0; k0 < K; k0 += 32) {
    gl_lds16(aBase + k0, al0);
    gl_lds16(aBase + (size_t)64 * K + k0, al1);
    gl_lds16(bBase + k0, bl0);
    gl_lds16(bBase + (size_t)64 * K + k0, bl1);
    __syncthreads();
    bf16x8 af[4], bfv[4];
#pragma unroll
    for (int m = 0; m < 4; ++m)
      af[m] = *(const bf16x8*)(Al + (wm + m * 16 + fr) * 32 + fk);
#pragma unroll
    for (int n = 0; n < 4; ++n)
      bfv[n] = *(const bf16x8*)(Bl + (wn + n * 16 + fr) * 32 + fk);
#pragma unroll
    for (int m = 0; m < 4; ++m)
#pragma unroll
      for (int n = 0; n < 4; ++n)
        acc[m][n] =
            __builtin_amdgcn_mfma_f32_16x16x32_bf16(af[m], bfv[n], acc[m][n], 0, 0, 0);
    __syncthreads();
  }
  const int fq = (lane >> 4) * 4;
#pragma unroll
  for (int m = 0; m < 4; ++m) {
    int grb = row0 + wm + m * 16 + fq;
#pragma unroll
    for (int n = 0; n < 4; ++n) {
      int gc = col0 + wn + n * 16 + fr;
      float bv = bias ? bias[gc] : 0.f;
#pragma unroll
      for (int r = 0; r < 4; ++r) {
        float v = acc[m][n][r] + bv;
        if (ACT == 1) v = v / (1.f + __expf(-v));
        if (OUT == 0)
          ((float*)Cout)[(size_t)(grb + r) * N + gc] = v;
        else
          ((bf16_t*)Cout)[(size_t)(grb + r) * N + gc] = (bf16_t)v;
      }
    }
  }
}

// ---------------- layernorm fused kernels ----------------

__device__ inline void block_reduce2(float& s, float& q, float* red) {
#pragma unroll
  for (int off = 32; off >= 1; off >>= 1) {
    s += __shfl_xor(s, off, 64);
    q += __shfl_xor(q, off, 64);
  }
  int wid = threadIdx.x >> 6;
  if ((threadIdx.x & 63) == 0) { red[wid * 2] = s; red[wid * 2 + 1] = q; }
  __syncthreads();
  s = red[0] + red[2] + red[4] + red[6];
  q = red[1] + red[3] + red[5] + red[7];
}

__global__ __launch_bounds__(256) void ln_add_kernel(const float* __restrict__ A,
                                                     const float* __restrict__ Bb,
                                                     const float* __restrict__ g,
                                                     const float* __restrict__ be,
                                                     float* __restrict__ out,
                                                     bf16_t* __restrict__ bout) {
  int row = blockIdx.x, tid = threadIdx.x, c0 = tid * 2;
  __shared__ float red[8];
  float2 a = *(const float2*)(A + (size_t)row * CC + c0);
  float2 b = *(const float2*)(Bb + (size_t)row * CC + c0);
  float x0 = a.x + b.x, x1 = a.y + b.y;
  float s = x0 + x1, q = x0 * x0 + x1 * x1;
  block_reduce2(s, q, red);
  float mean = s * (1.f / CC);
  float var = q * (1.f / CC) - mean * mean;
  float rs = rsqrtf(var + 1e-5f);
  float o0 = (x0 - mean) * rs * g[c0] + be[c0];
  float o1 = (x1 - mean) * rs * g[c0 + 1] + be[c0 + 1];
  *(float2*)(out + (size_t)row * CC + c0) = make_float2(o0, o1);
  if (bout) {
    bout[(size_t)row * CC + c0] = (bf16_t)o0;
    bout[(size_t)row * CC + c0 + 1] = (bf16_t)o1;
  }
}

__global__ __launch_bounds__(256) void ln_gate_kernel(
    const float* __restrict__ gpre, const float* __restrict__ gate_b,
    const float* __restrict__ xc, const float* __restrict__ ef,
    const float* __restrict__ n1g, const float* __restrict__ n1b,
    const float* __restrict__ xin, float* __restrict__ x2, bf16_t* __restrict__ x2b) {
  int row = blockIdx.x, tid = threadIdx.x, c0 = tid * 2;
  __shared__ float red[8];
  float2 gp = *(const float2*)(gpre + (size_t)row * CC + c0);
  float2 xcv = *(const float2*)(xc + (size_t)row * CC + c0);
  float2 efv = *(const float2*)(ef + (size_t)row * CC + c0);
  float g0 = 1.f / (1.f + __expf(-(gp.x + gate_b[c0])));
  float g1 = 1.f / (1.f + __expf(-(gp.y + gate_b[c0 + 1])));
  float x0 = g0 * xcv.x + (1.f - g0) * efv.x;
  float x1 = g1 * xcv.y + (1.f - g1) * efv.y;
  float s = x0 + x1, q = x0 * x0 + x1 * x1;
  block_reduce2(s, q, red);
  float mean = s * (1.f / CC);
  float var = q * (1.f / CC) - mean * mean;
  float rs = rsqrtf(var + 1e-5f);
  float2 xi = *(const float2*)(xin + (size_t)row * CC + c0);
  float o0 = fmaxf((x0 - mean) * rs * n1g[c0] + n1b[c0], 0.f) + xi.x;
  float o1 = fmaxf((x1 - mean) * rs * n1g[c0 + 1] + n1b[c0 + 1], 0.f) + xi.y;
  *(float2*)(x2 + (size_t)row * CC + c0) = make_float2(o0, o1);
  x2b[(size_t)row * CC + c0] = (bf16_t)o0;
  x2b[(size_t)row * CC + c0 + 1] = (bf16_t)o1;
}

// ---------------- V^T pack (pre-swizzled + pi-permuted K for attn) ---------
// out position p holds V[k = (p & ~31) + pi(p & 31)]; pi(sl)=(sl>>3)*4+(sl&3)+16*((sl>>2)&1)
__global__ __launch_bounds__(256) void vt_pack_kernel(const bf16_t* __restrict__ qkvb,
                                                      bf16_t* __restrict__ vt) {
  int b = blockIdx.x >> 3, h = blockIdx.x & 7;
  int nb = b * 256;
  size_t voff = 1024 + (size_t)h * 64;
  char* out = (char*)(vt + (size_t)blockIdx.x * (64 * 256));
  __shared__ bf16_t tile[64][80];
  int tid = threadIdx.x;
  for (int kb = 0; kb < 4; ++kb) {
    __syncthreads();
#pragma unroll
    for (int p = 0; p < 2; ++p) {
      int k = p * 32 + (tid >> 3);
      int d8 = tid & 7;
      bf16x8 v = *(const bf16x8*)(qkvb + (size_t)(nb + kb * 64 + k) * 1536 + voff + d8 * 8);
      *(bf16x8*)(&tile[k][d8 * 8]) = v;
    }
    __syncthreads();
#pragma unroll
    for (int p = 0; p < 2; ++p) {
      int d = p * 32 + (tid >> 3);
      int k8 = tid & 7;
      bf16x8 v;
#pragma unroll
      for (int j = 0; j < 8; ++j) {
        int pos = k8 * 8 + j;               // local out position in 64-k tile
        int sl = pos & 31;
        int srck = (pos & 32) + ((sl >> 3) << 2) + (sl & 3) + (((sl >> 2) & 1) << 4);
        v[j] = tile[srck][d];
      }
      int byteoff = d * 512 + ((kb * 128 + k8 * 16) ^ ((d & 7) << 4));
      *(bf16x8*)(out + byteoff) = v;
    }
  }
}

// ---------------- MFMA attention (shuffle-free PV) ----------------
__global__ __launch_bounds__(256, 2) void attn_mfma_kernel(
    const bf16_t* __restrict__ qkvb, const bf16_t* __restrict__ vt,
    bf16_t* __restrict__ o) {
  const int b = blockIdx.x >> 3;
  const int h = blockIdx.x & 7;
  const int nb = b * 256;
  const int tid = threadIdx.x;
  const int lane = tid & 63;
  const int wv = tid >> 6;
  const int l15 = lane & 15;
  const int g = lane >> 4;
  const int swzk = (l15 & 7) << 4;
  __shared__ __align__(16) bf16_t Klds[256 * 64];
  __shared__ __align__(16) bf16_t Vtlds[64 * 256];
  const size_t qoff = (size_t)h * 64;
  const size_t koff = 512 + (size_t)h * 64;

  {
    const int dcol = 16 * ((tid & 7) ^ ((tid >> 3) & 7));
    const bf16_t* srcb = qkvb + koff + (dcol >> 1);
#pragma unroll
    for (int i = 0; i < 8; ++i) {
      int k = i * 32 + (tid >> 3);
      gl_lds16(srcb + (size_t)(nb + k) * 1536, Klds + ((i * 4096 + wv * 1024) >> 1));
    }
  }
  {
    const bf16_t* vsrc = vt + (size_t)blockIdx.x * (64 * 256);
#pragma unroll
    for (int i = 0; i < 8; ++i) {
      int base = i * 4096 + wv * 1024;
      gl_lds16(vsrc + ((base >> 1) + lane * 8), Vtlds + (base >> 1));
    }
  }

  bf16x8 qf[4][2];
#pragma unroll
  for (int n = 0; n < 4; ++n) {
    const bf16_t* qp = qkvb + (size_t)(nb + wv * 64 + 16 * n + l15) * 1536 + qoff + g * 8;
    qf[n][0] = *(const bf16x8*)(qp);
    qf[n][1] = *(const bf16x8*)(qp + 32);
  }

  __syncthreads();

  f32x4v oacc[4][4] = {};
  float mrun[4] = {-1e30f, -1e30f, -1e30f, -1e30f};
  float lrun[4] = {0.f, 0.f, 0.f, 0.f};

  for (int kc = 0; kc < 4; ++kc) {
    f32x4v sacc[4][4] = {};
    const int kb128 = (kc * 64 + l15) * 128;
#pragma unroll
    for (int m = 0; m < 4; ++m) {
      bf16x8 a0 = *(const bf16x8*)(Klds + ((kb128 + m * 2048 + ((g * 16) ^ swzk)) >> 1));
      bf16x8 a1 =
          *(const bf16x8*)(Klds + ((kb128 + m * 2048 + ((64 + g * 16) ^ swzk)) >> 1));
#pragma unroll
      for (int n = 0; n < 4; ++n) {
        sacc[m][n] = __builtin_amdgcn_mfma_f32_16x16x32_bf16(a0, qf[n][0], sacc[m][n], 0, 0, 0);
        sacc[m][n] = __builtin_amdgcn_mfma_f32_16x16x32_bf16(a1, qf[n][1], sacc[m][n], 0, 0, 0);
      }
    }
    uint2 pb[4][4];
#pragma unroll
    for (int n = 0; n < 4; ++n) {
      float mx = sacc[0][n][0];
#pragma unroll
      for (int m = 0; m < 4; ++m)
#pragma unroll
        for (int r = 0; r < 4; ++r) mx = fmaxf(mx, sacc[m][n][r]);
      mx = fmaxf(mx, __shfl_xor(mx, 16));
      mx = fmaxf(mx, __shfl_xor(mx, 32));
      float mnew = fmaxf(mrun[n], mx);
      float c = __expf((mrun[n] - mnew) * 0.125f);
      mrun[n] = mnew;
      float s = 0.f;
#pragma unroll
      for (int m = 0; m < 4; ++m) {
        float p0 = __expf((sacc[m][n][0] - mnew) * 0.125f);
        float p1 = __expf((sacc[m][n][1] - mnew) * 0.125f);
        float p2 = __expf((sacc[m][n][2] - mnew) * 0.125f);
        float p3 = __expf((sacc[m][n][3] - mnew) * 0.125f);
        s += (p0 + p1) + (p2 + p3);
        union { bf16x4 v; uint2 u; } cv;
        cv.v[0] = (bf16_t)p0; cv.v[1] = (bf16_t)p1;
        cv.v[2] = (bf16_t)p2; cv.v[3] = (bf16_t)p3;
        pb[m][n] = cv.u;
      }
      s += __shfl_xor(s, 16);
      s += __shfl_xor(s, 32);
      lrun[n] = lrun[n] * c + s;
#pragma unroll
      for (int m = 0; m < 4; ++m)
#pragma unroll
        for (int r = 0; r < 4; ++r) oacc[m][n][r] *= c;
    }
    // PV with pi-permuted K: B-frag = concat(pb[2h2], pb[2h2+1]) per lane
#pragma unroll
    for (int h2 = 0; h2 < 2; ++h2) {
      bf16x8 vf[4];
#pragma unroll
      for (int m = 0; m < 4; ++m)
        vf[m] = *(const bf16x8*)(Vtlds + (((16 * m + l15) * 512 +
                                          ((kc * 128 + h2 * 64 + g * 16) ^ swzk)) >> 1));
#pragma unroll
      for (int n = 0; n < 4; ++n) {
        union { uint2 u[2]; bf16x8 v; } pf;
        pf.u[0] = pb[2 * h2][n];
        pf.u[1] = pb[2 * h2 + 1][n];
#pragma unroll
        for (int m = 0; m < 4; ++m)
          oacc[m][n] =
              __builtin_amdgcn_mfma_f32_16x16x32_bf16(vf[m], pf.v, oacc[m][n], 0, 0, 0);
      }
    }
  }
  float inv[4];
#pragma unroll
  for (int n = 0; n < 4; ++n) inv[n] = 1.0f / lrun[n];
#pragma unroll
  for (int m = 0; m < 4; ++m)
#pragma unroll
    for (int n = 0; n < 4; ++n) {
      bf16x4 pk;
#pragma unroll
      for (int r = 0; r < 4; ++r) pk[r] = (bf16_t)(oacc[m][n][r] * inv[n]);
      *(bf16x4*)(o + (size_t)(nb + wv * 64 + 16 * n + l15) * 512 + h * 64 + 16 * m +
                 4 * g) = pk;
    }
}

// ---------------- launch ----------------

static inline char* alignp(char* p, size_t a) {
  return (char*)(((uintptr_t)p + a - 1) & ~(uintptr_t)(a - 1));
}

extern "C" void kernel_launch(void* const* d_in, const int* in_sizes, int n_in,
                              void* d_out, int out_size, void* d_ws, size_t ws_size,
                              hipStream_t stream) {
  const float* x = (const float*)d_in[0];
  const float* edge_attr = (const float*)d_in[1];
  const float* gcn_w = (const float*)d_in[2];
  const float* gcn_b = (const float*)d_in[3];
  const float* ep_w = (const float*)d_in[4];
  const float* ep_b = (const float*)d_in[5];
  const float* gate_w = (const float*)d_in[6];
  const float* gate_b = (const float*)d_in[7];
  const float* n1_g = (const float*)d_in[8];
  const float* n1_b = (const float*)d_in[9];
  const float* in_w = (const float*)d_in[10];
  const float* in_b = (const float*)d_in[11];
  const float* out_w = (const float*)d_in[12];
  const float* out_b = (const float*)d_in[13];
  const float* tn_g = (const float*)d_in[14];
  const float* tn_b = (const float*)d_in[15];
  const float* m_w1 = (const float*)d_in[16];
  const float* m_b1 = (const float*)d_in[17];
  const float* m_w2 = (const float*)d_in[18];
  const float* m_b2 = (const float*)d_in[19];
  const float* fn_g = (const float*)d_in[20];
  const float* fn_b = (const float*)d_in[21];
  const int* eidx = (const int*)d_in[22];
  const int* src = eidx;
  const int* dst = eidx + EE;

  float* ws = (float*)d_ws;
  float* R1 = ws;
  float* R2 = R1 + (size_t)NN * 3 * CC;
  float* R3 = R2 + (size_t)NN * CC;
  float* R4 = R3 + (size_t)NN * CC;
  float* ew = R4 + (size_t)NN * CC;
  float* deg = ew + EE;
  float* dinv = deg + NN;
  int* ip = (int*)(dinv + NN);
  int* cnt_dst = ip;    ip += NN;
  int* start_dst = ip;  ip += NN + 1;
  int* cur_dst = ip;    ip += NN;
  int* cnt_src = ip;    ip += NN;
  int* start_src = ip;  ip += NN + 1;
  int* cur_src = ip;    ip += NN;
  int* elist_dst = ip;  ip += EE;
  int* elist_src = ip;  ip += EE;
  int* nid_src = ip;    ip += EE + 32;
  char* bp = alignp((char*)ip, 64);
  bf16_t* x2b = (bf16_t*)bp;          bp += (size_t)NN * CC * 2;
  bf16_t* gcn_wt = (bf16_t*)bp;       bp += (size_t)CC * CC * 2;
  bf16_t* gate_wt = (bf16_t*)bp;      bp += (size_t)CC * 2 * CC * 2;
  bf16_t* in_wt = (bf16_t*)bp;        bp += (size_t)3 * CC * CC * 2;
  bf16_t* out_wt = (bf16_t*)bp;       bp += (size_t)CC * CC * 2;
  bf16_t* m_w1t = (bf16_t*)bp;        bp += (size_t)2 * CC * CC * 2;
  bf16_t* m_w2t = (bf16_t*)bp;        bp += (size_t)CC * 2 * CC * 2;

  bf16_t* xb = (bf16_t*)R1;      // bf16(x)
  bf16_t* xcefb = (bf16_t*)R1;   // [x_conv | ef] bf16 N x 2C
  bf16_t* qkvb = (bf16_t*)R1;    // qkv bf16 N x 1536
  bf16_t* hb = (bf16_t*)R1;      // mlp hidden bf16 N x 2C
  bf16_t* xwb = (bf16_t*)R2;     // bf16 xw (GCN GEMM out)
  bf16_t* ob = (bf16_t*)R2;      // attn out bf16 (first half of R2)
  bf16_t* vt = ob + (size_t)NN * CC;  // V^T packed (second half of R2)
  bf16_t* x3b = (bf16_t*)R2;     // bf16(x3) (after ob dead)
  float* x2 = (float*)d_out;

  // --- edge prep ---
  init_kernel<<<(NN + 255) / 256, 256, 0, stream>>>(deg, cnt_dst, cnt_src, nid_src);
  edge_pass1<<<(EE + 255) / 256, 256, 0, stream>>>(edge_attr, src, dst, ew, deg,
                                                   cnt_dst, cnt_src);
  node_pass<<<(NN + 255) / 256, 256, 0, stream>>>(deg, dinv);
  exscan_kernel<<<1, 1024, 0, stream>>>(cnt_dst, start_dst, cur_dst, NN);
  exscan_kernel<<<1, 1024, 0, stream>>>(cnt_src, start_src, cur_src, NN);
  fill_kernel<<<(EE + 255) / 256, 256, 0, stream>>>(src, dst, cur_dst, cur_src,
                                                    elist_dst, elist_src, nid_src);

  // --- weight transposes ---
  wt_kernel<<<dim3(CC / 32, CC / 32), 256, 0, stream>>>(gcn_w, gcn_wt, CC, CC);
  wt_kernel<<<dim3(CC / 32, 2 * CC / 32), 256, 0, stream>>>(gate_w, gate_wt, 2 * CC, CC);
  wt_kernel<<<dim3(3 * CC / 32, CC / 32), 256, 0, stream>>>(in_w, in_wt, CC, 3 * CC);
  wt_kernel<<<dim3(CC / 32, CC / 32), 256, 0, stream>>>(out_w, out_wt, CC, CC);
  wt_kernel<<<dim3(2 * CC / 32, CC / 32), 256, 0, stream>>>(m_w1, m_w1t, CC, 2 * CC);
  wt_kernel<<<dim3(CC / 32, 2 * CC / 32), 256, 0, stream>>>(m_w2, m_w2t, 2 * CC, CC);

  // --- GCN conv ---
  cvt_bf16_kernel<<<(NN * CC / 4 + 255) / 256, 256, 0, stream>>>(x, xb, NN * CC / 4);
  dim3 gA(CC / 128, NN / 128);
  gemm_bf16_kernel<0, 1><<<gA, 256, 0, stream>>>(xb, gcn_wt, nullptr, xwb, NN, CC, CC);
  xconv_kernel<<<NN, 256, 0, stream>>>(xwb, ew, dinv, src, elist_dst, start_dst,
                                       gcn_b, R3, xcefb);
  ef_mfma_kernel<<<NN / 32, 512, 0, stream>>>(edge_attr, ep_w, ep_b, elist_src,
                                              nid_src, start_src, R4, xcefb);
  gemm_bf16_kernel<0, 0><<<gA, 256, 0, stream>>>(xcefb, gate_wt, nullptr, R2, NN, CC,
                                                 2 * CC);
  ln_gate_kernel<<<NN, 256, 0, stream>>>(R2, gate_b, R3, R4, n1_g, n1_b, x, x2, x2b);

  // --- MHA ---
  dim3 gQ(3 * CC / 128, NN / 128);
  gemm_bf16_kernel<0, 1><<<gQ, 256, 0, stream>>>(x2b, in_wt, in_b, qkvb, NN, 3 * CC, CC);
  vt_pack_kernel<<<BB * HH, 256, 0, stream>>>(qkvb, vt);
  attn_mfma_kernel<<<BB * HH, 256, 0, stream>>>(qkvb, vt, ob);
  gemm_bf16_kernel<0, 0><<<gA, 256, 0, stream>>>(ob, out_wt, out_b, R4, NN, CC, CC);
  ln_add_kernel<<<NN, 256, 0, stream>>>(x2, R4, tn_g, tn_b, R3, x3b);

  // --- MLP ---
  dim3 gH(2 * CC / 128, NN / 128);
  gemm_bf16_kernel<1, 1><<<gH, 256, 0, stream>>>(x3b, m_w1t, m_b1, hb, NN, 2 * CC, CC);
  gemm_bf16_kernel<0, 0><<<gA, 256, 0, stream>>>(hb, m_w2t, m_b2, R4, NN, CC, 2 * CC);
  ln_add_kernel<<<NN, 256, 0, stream>>>(R3, R4, fn_g, fn_b, (float*)d_out, nullptr);
}

// Round 7
// 643.553 us; speedup vs baseline: 1.2535x; 1.0332x over previous
//
#include <hip/hip_runtime.h>

#define NN 16384
#define CC 512
#define EE 524288
#define BB 64
#define HH 8
#define EFD 16

typedef __bf16 bf16_t;
typedef __bf16 bf16x4 __attribute__((ext_vector_type(4)));
typedef __bf16 bf16x8 __attribute__((ext_vector_type(8)));
typedef float f32x4v __attribute__((ext_vector_type(4)));

// ---------------- init / edge pre-pass ----------------

__global__ void init_kernel(float* deg, int* cnt_dst, int* cnt_src, int* nid_src,
                            bf16_t* eacsr) {
  int i = blockIdx.x * 256 + threadIdx.x;
  if (i < NN) { deg[i] = 1.0f; cnt_dst[i] = 0; cnt_src[i] = 0; }
  if (i < 32) nid_src[EE + i] = -1;               // pad for ef chunk tail
  if (i < 256) ((int*)(eacsr + (size_t)EE * 16))[i] = 0;  // zero eacsr pad rows
}

__global__ void edge_pass1(const float* __restrict__ ea, const int* __restrict__ src,
                           const int* __restrict__ dst, float* __restrict__ ew,
                           float* deg, int* cnt_dst, int* cnt_src) {
  int e = blockIdx.x * 256 + threadIdx.x;
  if (e >= EE) return;
  const float4* p = (const float4*)(ea + (size_t)e * EFD);
  float s = 0.f;
#pragma unroll
  for (int i = 0; i < 4; ++i) {
    float4 v = p[i];
    s += v.x * v.x + v.y * v.y + v.z * v.z + v.w * v.w;
  }
  float w = sqrtf(s);
  ew[e] = w;
  atomicAdd(&deg[dst[e]], w);
  atomicAdd(&cnt_dst[dst[e]], 1);
  atomicAdd(&cnt_src[src[e]], 1);
}

__global__ void node_pass(const float* __restrict__ deg, float* __restrict__ dinv) {
  int i = blockIdx.x * 256 + threadIdx.x;
  if (i >= NN) return;
  float d = deg[i];
  dinv[i] = d > 0.f ? rsqrtf(fmaxf(d, 1e-12f)) : 0.f;
}

// exclusive scan of n<=16384 ints, single block of 1024 threads (16/thread)
__global__ __launch_bounds__(1024) void exscan_kernel(const int* __restrict__ cnt,
                                                      int* __restrict__ start,
                                                      int* __restrict__ cur, int n) {
  __shared__ int sums[1024];
  int tid = threadIdx.x;
  int base = tid * 16;
  int loc[16];
  int s = 0;
#pragma unroll
  for (int k = 0; k < 16; ++k) {
    int idx = base + k;
    int v = (idx < n) ? cnt[idx] : 0;
    loc[k] = v;
    s += v;
  }
  sums[tid] = s;
  __syncthreads();
  for (int off = 1; off < 1024; off <<= 1) {
    int v = (tid >= off) ? sums[tid - off] : 0;
    __syncthreads();
    sums[tid] += v;
    __syncthreads();
  }
  int pre = (tid == 0) ? 0 : sums[tid - 1];
#pragma unroll
  for (int k = 0; k < 16; ++k) {
    int idx = base + k;
    if (idx < n) { start[idx] = pre; cur[idx] = pre; pre += loc[k]; }
  }
  if (tid == 1023) start[n] = pre;
}

__global__ void fill_kernel(const int* __restrict__ src, const int* __restrict__ dst,
                            int* cur_dst, int* cur_src, int* __restrict__ elist_dst,
                            int* __restrict__ elist_src, int* __restrict__ nid_src) {
  int e = blockIdx.x * 256 + threadIdx.x;
  if (e >= EE) return;
  int pd = atomicAdd(&cur_dst[dst[e]], 1);
  elist_dst[pd] = e;
  int s = src[e];
  int ps = atomicAdd(&cur_src[s], 1);
  elist_src[ps] = e;
  nid_src[ps] = s;
}

// gather edge_attr rows into CSR order as bf16 (removes indirection from ef loop)
__global__ void ea_gather_kernel(const float* __restrict__ ea,
                                 const int* __restrict__ elist,
                                 bf16_t* __restrict__ eacsr) {
  int idx = blockIdx.x * 256 + threadIdx.x;
  if (idx >= EE * 2) return;
  int pos = idx >> 1, half = idx & 1;
  int e = elist[pos];
  const f32x4v* p = (const f32x4v*)(ea + (size_t)e * EFD + half * 8);
  f32x4v u0 = p[0], u1 = p[1];
  bf16x8 f;
#pragma unroll
  for (int r = 0; r < 4; ++r) {
    f[r] = (bf16_t)u0[r];
    f[4 + r] = (bf16_t)u1[r];
  }
  *(bf16x8*)(eacsr + (size_t)pos * 16 + half * 8) = f;
}

// ---------------- conversions ----------------

__global__ void cvt_bf16_kernel(const float* __restrict__ in, bf16_t* __restrict__ out,
                                int n4) {
  int i = blockIdx.x * 256 + threadIdx.x;
  if (i >= n4) return;
  float4 v = ((const float4*)in)[i];
  bf16x4 o;
  o[0] = (bf16_t)v.x; o[1] = (bf16_t)v.y; o[2] = (bf16_t)v.z; o[3] = (bf16_t)v.w;
  ((bf16x4*)out)[i] = o;
}

// W: f32 [K][N] row-major -> Wt: bf16 [N][K] row-major
__global__ __launch_bounds__(256) void wt_kernel(const float* __restrict__ W,
                                                 bf16_t* __restrict__ Wt, int K, int N) {
  __shared__ float tile[32][33];
  int bx = blockIdx.x * 32;  // N offset
  int by = blockIdx.y * 32;  // K offset
  int tx = threadIdx.x & 31, ty = threadIdx.x >> 5;  // ty 0..7
#pragma unroll
  for (int i = 0; i < 32; i += 8)
    tile[ty + i][tx] = W[(size_t)(by + ty + i) * N + bx + tx];
  __syncthreads();
#pragma unroll
  for (int i = 0; i < 32; i += 8)
    Wt[(size_t)(bx + ty + i) * K + by + tx] = (bf16_t)tile[tx][ty + i];
}

// ---------------- GCN conv gather (CSR by dst), bf16 xw ----------------
__global__ __launch_bounds__(256) void xconv_kernel(
    const bf16_t* __restrict__ xwb, const float* __restrict__ ew,
    const float* __restrict__ dinv, const int* __restrict__ src,
    const int* __restrict__ elist, const int* __restrict__ start,
    const float* __restrict__ gcn_b, float* __restrict__ xconv,
    bf16_t* __restrict__ xcb) {
  int i = blockIdx.x;
  int tid = threadIdx.x;
  int st = start[i], en = start[i + 1];
  float di = dinv[i];
  int c0 = tid * 2;
  __shared__ float2 scS[256];  // {coef, as_float(src_node)}
  union { unsigned u; struct { unsigned short lo, hi; } s; } pk;
  pk.u = *(const unsigned*)(xwb + (size_t)i * CC + c0);
  union { unsigned short us; bf16_t b; } c0v, c1v;
  c0v.us = pk.s.lo; c1v.us = pk.s.hi;
  float sc = di * di;
  float a0 = sc * (float)c0v.b + gcn_b[c0];
  float a1 = sc * (float)c1v.b + gcn_b[c0 + 1];
  for (int p0 = st; p0 < en; p0 += 256) {
    int m = min(256, en - p0);
    __syncthreads();
    if (tid < m) {
      int e = elist[p0 + tid];
      int sn = src[e];
      scS[tid] = make_float2(dinv[sn] * ew[e] * di, __int_as_float(sn));
    }
    __syncthreads();
    for (int j = 0; j < m; ++j) {
      float2 scv = scS[j];
      int sn = __float_as_int(scv.y);
      union { unsigned u; struct { unsigned short lo, hi; } s; } q;
      q.u = *(const unsigned*)(xwb + (size_t)sn * CC + c0);
      union { unsigned short us; bf16_t b; } v0, v1;
      v0.us = q.s.lo; v1.us = q.s.hi;
      a0 += scv.x * (float)v0.b;
      a1 += scv.x * (float)v1.b;
    }
  }
  *(float2*)(xconv + (size_t)i * CC + c0) = make_float2(a0, a1);
  xcb[(size_t)i * (2 * CC) + c0] = (bf16_t)a0;
  xcb[(size_t)i * (2 * CC) + c0 + 1] = (bf16_t)a1;
}

// ---------------- edge projection via double-MFMA v3 ----------------
// ef = S . relu(ea @ W + b); 4 waves x 16 nodes x 128 cols/wave.
// eacsr: CSR-ordered bf16 edge features (coalesced A-frag, no indirection).
// K-order of GEMM2 permuted by pi(g*8+j) = g*4+(j&3)+16*(j>>2) so each lane's
// GEMM1 D-frags concat directly into its GEMM2 B-frag (no cross-lane ops).
__global__ __launch_bounds__(256) void ef_mfma_kernel(
    const bf16_t* __restrict__ eacsr, const float* __restrict__ ep_w,
    const float* __restrict__ ep_b, const int* __restrict__ nid,
    const int* __restrict__ start, float* __restrict__ ef, bf16_t* __restrict__ efb) {
  const int tid = threadIdx.x;
  const int lane = tid & 63;
  const int wv = tid >> 6;      // 0..3
  const int l15 = lane & 15;
  const int g = lane >> 4;      // 0..3
  const int n0 = blockIdx.x * 16;
  const int cbase = wv * 128;

  // W B-frags (loop-invariant): k=g*8+j; k<16 -> ep_w, k==16 -> bias row
  bf16x8 wfr[8];
#pragma unroll
  for (int t = 0; t < 8; ++t) {
    bf16x8 f = {};
    int c = cbase + t * 16 + l15;
    if (g < 2) {
#pragma unroll
      for (int j = 0; j < 8; ++j) f[j] = (bf16_t)ep_w[(g * 8 + j) * CC + c];
    } else if (g == 2) {
      f[0] = (bf16_t)ep_b[c];
    }
    wfr[t] = f;
  }

  const int st = start[n0];
  const int en = start[n0 + 16];
  const int tgt = n0 + l15;

  f32x4v eacc[8] = {};

  for (int cb = st; cb < en; cb += 32) {
    // ---- A-frags: one coalesced 16B load each (K padded: k16=bias, rest 0)
    bf16x8 af[2];
#pragma unroll
    for (int mE = 0; mE < 2; ++mE) {
      bf16x8 f = {};
      if (g < 2) {
        f = *(const bf16x8*)(eacsr + (size_t)(cb + mE * 16 + l15) * 16 + g * 8);
      } else if (g == 2) {
        f[0] = (bf16_t)1.0f;  // bias feature (S=0 kills out-of-range rows)
      }
      af[mE] = f;
    }
    // ---- S-frag with permuted K: element j <-> edge cb + pi(g*8+j) ----
    int4 idlo = *(const int4*)(nid + cb + g * 4);
    int4 idhi = *(const int4*)(nid + cb + 16 + g * 4);
    bf16x8 sf;
    sf[0] = (idlo.x == tgt) ? (bf16_t)1.0f : (bf16_t)0.0f;
    sf[1] = (idlo.y == tgt) ? (bf16_t)1.0f : (bf16_t)0.0f;
    sf[2] = (idlo.z == tgt) ? (bf16_t)1.0f : (bf16_t)0.0f;
    sf[3] = (idlo.w == tgt) ? (bf16_t)1.0f : (bf16_t)0.0f;
    sf[4] = (idhi.x == tgt) ? (bf16_t)1.0f : (bf16_t)0.0f;
    sf[5] = (idhi.y == tgt) ? (bf16_t)1.0f : (bf16_t)0.0f;
    sf[6] = (idhi.z == tgt) ? (bf16_t)1.0f : (bf16_t)0.0f;
    sf[7] = (idhi.w == tgt) ? (bf16_t)1.0f : (bf16_t)0.0f;
    // ---- GEMM1 + relu + pack; GEMM2 B-frag = concat(D0, D1) ----
#pragma unroll
    for (int t = 0; t < 8; ++t) {
      f32x4v s0 = {}, s1 = {};
      s0 = __builtin_amdgcn_mfma_f32_16x16x32_bf16(af[0], wfr[t], s0, 0, 0, 0);
      s1 = __builtin_amdgcn_mfma_f32_16x16x32_bf16(af[1], wfr[t], s1, 0, 0, 0);
      union { bf16x8 v; bf16x4 h[2]; } pf;
#pragma unroll
      for (int r = 0; r < 4; ++r) {
        pf.h[0][r] = (bf16_t)fmaxf(s0[r], 0.f);
        pf.h[1][r] = (bf16_t)fmaxf(s1[r], 0.f);
      }
      eacc[t] = __builtin_amdgcn_mfma_f32_16x16x32_bf16(sf, pf.v, eacc[t], 0, 0, 0);
    }
  }
  // ---- epilogue: D[col=l15, node=g*4+r] ----
#pragma unroll
  for (int t = 0; t < 8; ++t) {
    int c = cbase + t * 16 + l15;
#pragma unroll
    for (int r = 0; r < 4; ++r) {
      int node = n0 + g * 4 + r;
      float v = eacc[t][r];
      ef[(size_t)node * CC + c] = v;
      efb[(size_t)node * (2 * CC) + CC + c] = (bf16_t)v;
    }
  }
}

// ---------------- bf16 MFMA GEMM (m97 structure) ----------------
__device__ __forceinline__ void gl_lds16(const bf16_t* g, bf16_t* l) {
  __builtin_amdgcn_global_load_lds(
      (const __attribute__((address_space(1))) void*)g,
      (__attribute__((address_space(3))) void*)l, 16, 0, 0);
}

template <int ACT, int OUT>
__global__ __launch_bounds__(256) void gemm_bf16_kernel(
    const bf16_t* __restrict__ A, const bf16_t* __restrict__ Bt,
    const float* __restrict__ bias, void* __restrict__ Cout, int M, int N, int K) {
  __shared__ __align__(16) bf16_t Al[128 * 32];
  __shared__ __align__(16) bf16_t Bl[128 * 32];
  const int tid = threadIdx.x;
  const int lane = tid & 63;
  const int wave = tid >> 6;
  const int row0 = blockIdx.y * 128;
  const int col0 = blockIdx.x * 128;
  const int wm = (wave >> 1) * 64;
  const int wn = (wave & 1) * 64;
  f32x4v acc[4][4] = {};
  const bf16_t* aBase = A + (size_t)(row0 + (tid >> 2)) * K + (tid & 3) * 8;
  const bf16_t* bBase = Bt + (size_t)(col0 + (tid >> 2)) * K + (tid & 3) * 8;
  bf16_t* al0 = Al + wave * 512;
  bf16_t* al1 = Al + 2048 + wave * 512;
  bf16_t* bl0 = Bl + wave * 512;
  bf16_t* bl1 = Bl + 2048 + wave * 512;
  const int fr = lane & 15;
  const int fk = (lane >> 4) * 8;
  for (int k0 = 0; k0 < K; k0 += 32) {
    gl_lds16(aBase + k0, al0);
    gl_lds16(aBase + (size_t)64 * K + k0, al1);
    gl_lds16(bBase + k0, bl0);
    gl_lds16(bBase + (size_t)64 * K + k0, bl1);
    __syncthreads();
    bf16x8 af[4], bfv[4];
#pragma unroll
    for (int m = 0; m < 4; ++m)
      af[m] = *(const bf16x8*)(Al + (wm + m * 16 + fr) * 32 + fk);
#pragma unroll
    for (int n = 0; n < 4; ++n)
      bfv[n] = *(const bf16x8*)(Bl + (wn + n * 16 + fr) * 32 + fk);
#pragma unroll
    for (int m = 0; m < 4; ++m)
#pragma unroll
      for (int n = 0; n < 4; ++n)
        acc[m][n] =
            __builtin_amdgcn_mfma_f32_16x16x32_bf16(af[m], bfv[n], acc[m][n], 0, 0, 0);
    __syncthreads();
  }
  const int fq = (lane >> 4) * 4;
#pragma unroll
  for (int m = 0; m < 4; ++m) {
    int grb = row0 + wm + m * 16 + fq;
#pragma unroll
    for (int n = 0; n < 4; ++n) {
      int gc = col0 + wn + n * 16 + fr;
      float bv = bias ? bias[gc] : 0.f;
#pragma unroll
      for (int r = 0; r < 4; ++r) {
        float v = acc[m][n][r] + bv;
        if (ACT == 1) v = v / (1.f + __expf(-v));
        if (OUT == 0)
          ((float*)Cout)[(size_t)(grb + r) * N + gc] = v;
        else
          ((bf16_t*)Cout)[(size_t)(grb + r) * N + gc] = (bf16_t)v;
      }
    }
  }
}

// ---------------- layernorm fused kernels ----------------

__device__ inline void block_reduce2(float& s, float& q, float* red) {
#pragma unroll
  for (int off = 32; off >= 1; off >>= 1) {
    s += __shfl_xor(s, off, 64);
    q += __shfl_xor(q, off, 64);
  }
  int wid = threadIdx.x >> 6;
  if ((threadIdx.x & 63) == 0) { red[wid * 2] = s; red[wid * 2 + 1] = q; }
  __syncthreads();
  s = red[0] + red[2] + red[4] + red[6];
  q = red[1] + red[3] + red[5] + red[7];
}

__global__ __launch_bounds__(256) void ln_add_kernel(const float* __restrict__ A,
                                                     const float* __restrict__ Bb,
                                                     const float* __restrict__ g,
                                                     const float* __restrict__ be,
                                                     float* __restrict__ out,
                                                     bf16_t* __restrict__ bout) {
  int row = blockIdx.x, tid = threadIdx.x, c0 = tid * 2;
  __shared__ float red[8];
  float2 a = *(const float2*)(A + (size_t)row * CC + c0);
  float2 b = *(const float2*)(Bb + (size_t)row * CC + c0);
  float x0 = a.x + b.x, x1 = a.y + b.y;
  float s = x0 + x1, q = x0 * x0 + x1 * x1;
  block_reduce2(s, q, red);
  float mean = s * (1.f / CC);
  float var = q * (1.f / CC) - mean * mean;
  float rs = rsqrtf(var + 1e-5f);
  float o0 = (x0 - mean) * rs * g[c0] + be[c0];
  float o1 = (x1 - mean) * rs * g[c0 + 1] + be[c0 + 1];
  *(float2*)(out + (size_t)row * CC + c0) = make_float2(o0, o1);
  if (bout) {
    bout[(size_t)row * CC + c0] = (bf16_t)o0;
    bout[(size_t)row * CC + c0 + 1] = (bf16_t)o1;
  }
}

__global__ __launch_bounds__(256) void ln_gate_kernel(
    const float* __restrict__ gpre, const float* __restrict__ gate_b,
    const float* __restrict__ xc, const float* __restrict__ ef,
    const float* __restrict__ n1g, const float* __restrict__ n1b,
    const float* __restrict__ xin, float* __restrict__ x2, bf16_t* __restrict__ x2b) {
  int row = blockIdx.x, tid = threadIdx.x, c0 = tid * 2;
  __shared__ float red[8];
  float2 gp = *(const float2*)(gpre + (size_t)row * CC + c0);
  float2 xcv = *(const float2*)(xc + (size_t)row * CC + c0);
  float2 efv = *(const float2*)(ef + (size_t)row * CC + c0);
  float g0 = 1.f / (1.f + __expf(-(gp.x + gate_b[c0])));
  float g1 = 1.f / (1.f + __expf(-(gp.y + gate_b[c0 + 1])));
  float x0 = g0 * xcv.x + (1.f - g0) * efv.x;
  float x1 = g1 * xcv.y + (1.f - g1) * efv.y;
  float s = x0 + x1, q = x0 * x0 + x1 * x1;
  block_reduce2(s, q, red);
  float mean = s * (1.f / CC);
  float var = q * (1.f / CC) - mean * mean;
  float rs = rsqrtf(var + 1e-5f);
  float2 xi = *(const float2*)(xin + (size_t)row * CC + c0);
  float o0 = fmaxf((x0 - mean) * rs * n1g[c0] + n1b[c0], 0.f) + xi.x;
  float o1 = fmaxf((x1 - mean) * rs * n1g[c0 + 1] + n1b[c0 + 1], 0.f) + xi.y;
  *(float2*)(x2 + (size_t)row * CC + c0) = make_float2(o0, o1);
  x2b[(size_t)row * CC + c0] = (bf16_t)o0;
  x2b[(size_t)row * CC + c0 + 1] = (bf16_t)o1;
}

// ---------------- V^T pack (pre-swizzled + pi-permuted K for attn) ---------
__global__ __launch_bounds__(256) void vt_pack_kernel(const bf16_t* __restrict__ qkvb,
                                                      bf16_t* __restrict__ vt) {
  int b = blockIdx.x >> 3, h = blockIdx.x & 7;
  int nb = b * 256;
  size_t voff = 1024 + (size_t)h * 64;
  char* out = (char*)(vt + (size_t)blockIdx.x * (64 * 256));
  __shared__ bf16_t tile[64][80];
  int tid = threadIdx.x;
  for (int kb = 0; kb < 4; ++kb) {
    __syncthreads();
#pragma unroll
    for (int p = 0; p < 2; ++p) {
      int k = p * 32 + (tid >> 3);
      int d8 = tid & 7;
      bf16x8 v = *(const bf16x8*)(qkvb + (size_t)(nb + kb * 64 + k) * 1536 + voff + d8 * 8);
      *(bf16x8*)(&tile[k][d8 * 8]) = v;
    }
    __syncthreads();
#pragma unroll
    for (int p = 0; p < 2; ++p) {
      int d = p * 32 + (tid >> 3);
      int k8 = tid & 7;
      bf16x8 v;
#pragma unroll
      for (int j = 0; j < 8; ++j) {
        int pos = k8 * 8 + j;
        int sl = pos & 31;
        int srck = (pos & 32) + ((sl >> 3) << 2) + (sl & 3) + (((sl >> 2) & 1) << 4);
        v[j] = tile[srck][d];
      }
      int byteoff = d * 512 + ((kb * 128 + k8 * 16) ^ ((d & 7) << 4));
      *(bf16x8*)(out + byteoff) = v;
    }
  }
}

// ---------------- MFMA attention (shuffle-free PV) ----------------
__global__ __launch_bounds__(256, 2) void attn_mfma_kernel(
    const bf16_t* __restrict__ qkvb, const bf16_t* __restrict__ vt,
    bf16_t* __restrict__ o) {
  const int b = blockIdx.x >> 3;
  const int h = blockIdx.x & 7;
  const int nb = b * 256;
  const int tid = threadIdx.x;
  const int lane = tid & 63;
  const int wv = tid >> 6;
  const int l15 = lane & 15;
  const int g = lane >> 4;
  const int swzk = (l15 & 7) << 4;
  __shared__ __align__(16) bf16_t Klds[256 * 64];
  __shared__ __align__(16) bf16_t Vtlds[64 * 256];
  const size_t qoff = (size_t)h * 64;
  const size_t koff = 512 + (size_t)h * 64;

  {
    const int dcol = 16 * ((tid & 7) ^ ((tid >> 3) & 7));
    const bf16_t* srcb = qkvb + koff + (dcol >> 1);
#pragma unroll
    for (int i = 0; i < 8; ++i) {
      int k = i * 32 + (tid >> 3);
      gl_lds16(srcb + (size_t)(nb + k) * 1536, Klds + ((i * 4096 + wv * 1024) >> 1));
    }
  }
  {
    const bf16_t* vsrc = vt + (size_t)blockIdx.x * (64 * 256);
#pragma unroll
    for (int i = 0; i < 8; ++i) {
      int base = i * 4096 + wv * 1024;
      gl_lds16(vsrc + ((base >> 1) + lane * 8), Vtlds + (base >> 1));
    }
  }

  bf16x8 qf[4][2];
#pragma unroll
  for (int n = 0; n < 4; ++n) {
    const bf16_t* qp = qkvb + (size_t)(nb + wv * 64 + 16 * n + l15) * 1536 + qoff + g * 8;
    qf[n][0] = *(const bf16x8*)(qp);
    qf[n][1] = *(const bf16x8*)(qp + 32);
  }

  __syncthreads();

  f32x4v oacc[4][4] = {};
  float mrun[4] = {-1e30f, -1e30f, -1e30f, -1e30f};
  float lrun[4] = {0.f, 0.f, 0.f, 0.f};

  for (int kc = 0; kc < 4; ++kc) {
    f32x4v sacc[4][4] = {};
    const int kb128 = (kc * 64 + l15) * 128;
#pragma unroll
    for (int m = 0; m < 4; ++m) {
      bf16x8 a0 = *(const bf16x8*)(Klds + ((kb128 + m * 2048 + ((g * 16) ^ swzk)) >> 1));
      bf16x8 a1 =
          *(const bf16x8*)(Klds + ((kb128 + m * 2048 + ((64 + g * 16) ^ swzk)) >> 1));
#pragma unroll
      for (int n = 0; n < 4; ++n) {
        sacc[m][n] = __builtin_amdgcn_mfma_f32_16x16x32_bf16(a0, qf[n][0], sacc[m][n], 0, 0, 0);
        sacc[m][n] = __builtin_amdgcn_mfma_f32_16x16x32_bf16(a1, qf[n][1], sacc[m][n], 0, 0, 0);
      }
    }
    uint2 pb[4][4];
#pragma unroll
    for (int n = 0; n < 4; ++n) {
      float mx = sacc[0][n][0];
#pragma unroll
      for (int m = 0; m < 4; ++m)
#pragma unroll
        for (int r = 0; r < 4; ++r) mx = fmaxf(mx, sacc[m][n][r]);
      mx = fmaxf(mx, __shfl_xor(mx, 16));
      mx = fmaxf(mx, __shfl_xor(mx, 32));
      float mnew = fmaxf(mrun[n], mx);
      float c = __expf((mrun[n] - mnew) * 0.125f);
      mrun[n] = mnew;
      float s = 0.f;
#pragma unroll
      for (int m = 0; m < 4; ++m) {
        float p0 = __expf((sacc[m][n][0] - mnew) * 0.125f);
        float p1 = __expf((sacc[m][n][1] - mnew) * 0.125f);
        float p2 = __expf((sacc[m][n][2] - mnew) * 0.125f);
        float p3 = __expf((sacc[m][n][3] - mnew) * 0.125f);
        s += (p0 + p1) + (p2 + p3);
        union { bf16x4 v; uint2 u; } cv;
        cv.v[0] = (bf16_t)p0; cv.v[1] = (bf16_t)p1;
        cv.v[2] = (bf16_t)p2; cv.v[3] = (bf16_t)p3;
        pb[m][n] = cv.u;
      }
      s += __shfl_xor(s, 16);
      s += __shfl_xor(s, 32);
      lrun[n] = lrun[n] * c + s;
#pragma unroll
      for (int m = 0; m < 4; ++m)
#pragma unroll
        for (int r = 0; r < 4; ++r) oacc[m][n][r] *= c;
    }
#pragma unroll
    for (int h2 = 0; h2 < 2; ++h2) {
      bf16x8 vf[4];
#pragma unroll
      for (int m = 0; m < 4; ++m)
        vf[m] = *(const bf16x8*)(Vtlds + (((16 * m + l15) * 512 +
                                          ((kc * 128 + h2 * 64 + g * 16) ^ swzk)) >> 1));
#pragma unroll
      for (int n = 0; n < 4; ++n) {
        union { uint2 u[2]; bf16x8 v; } pf;
        pf.u[0] = pb[2 * h2][n];
        pf.u[1] = pb[2 * h2 + 1][n];
#pragma unroll
        for (int m = 0; m < 4; ++m)
          oacc[m][n] =
              __builtin_amdgcn_mfma_f32_16x16x32_bf16(vf[m], pf.v, oacc[m][n], 0, 0, 0);
      }
    }
  }
  float inv[4];
#pragma unroll
  for (int n = 0; n < 4; ++n) inv[n] = 1.0f / lrun[n];
#pragma unroll
  for (int m = 0; m < 4; ++m)
#pragma unroll
    for (int n = 0; n < 4; ++n) {
      bf16x4 pk;
#pragma unroll
      for (int r = 0; r < 4; ++r) pk[r] = (bf16_t)(oacc[m][n][r] * inv[n]);
      *(bf16x4*)(o + (size_t)(nb + wv * 64 + 16 * n + l15) * 512 + h * 64 + 16 * m +
                 4 * g) = pk;
    }
}

// ---------------- launch ----------------

static inline char* alignp(char* p, size_t a) {
  return (char*)(((uintptr_t)p + a - 1) & ~(uintptr_t)(a - 1));
}

extern "C" void kernel_launch(void* const* d_in, const int* in_sizes, int n_in,
                              void* d_out, int out_size, void* d_ws, size_t ws_size,
                              hipStream_t stream) {
  const float* x = (const float*)d_in[0];
  const float* edge_attr = (const float*)d_in[1];
  const float* gcn_w = (const float*)d_in[2];
  const float* gcn_b = (const float*)d_in[3];
  const float* ep_w = (const float*)d_in[4];
  const float* ep_b = (const float*)d_in[5];
  const float* gate_w = (const float*)d_in[6];
  const float* gate_b = (const float*)d_in[7];
  const float* n1_g = (const float*)d_in[8];
  const float* n1_b = (const float*)d_in[9];
  const float* in_w = (const float*)d_in[10];
  const float* in_b = (const float*)d_in[11];
  const float* out_w = (const float*)d_in[12];
  const float* out_b = (const float*)d_in[13];
  const float* tn_g = (const float*)d_in[14];
  const float* tn_b = (const float*)d_in[15];
  const float* m_w1 = (const float*)d_in[16];
  const float* m_b1 = (const float*)d_in[17];
  const float* m_w2 = (const float*)d_in[18];
  const float* m_b2 = (const float*)d_in[19];
  const float* fn_g = (const float*)d_in[20];
  const float* fn_b = (const float*)d_in[21];
  const int* eidx = (const int*)d_in[22];
  const int* src = eidx;
  const int* dst = eidx + EE;

  float* ws = (float*)d_ws;
  float* R1 = ws;
  float* R2 = R1 + (size_t)NN * 3 * CC;
  float* R3 = R2 + (size_t)NN * CC;
  float* R4 = R3 + (size_t)NN * CC;
  float* ew = R4 + (size_t)NN * CC;
  float* deg = ew + EE;
  float* dinv = deg + NN;
  int* ip = (int*)(dinv + NN);
  int* cnt_dst = ip;    ip += NN;
  int* start_dst = ip;  ip += NN + 1;
  int* cur_dst = ip;    ip += NN;
  int* cnt_src = ip;    ip += NN;
  int* start_src = ip;  ip += NN + 1;
  int* cur_src = ip;    ip += NN;
  int* elist_dst = ip;  ip += EE;
  int* elist_src = ip;  ip += EE;
  int* nid_src = ip;    ip += EE + 32;
  char* bp = alignp((char*)ip, 64);
  bf16_t* x2b = (bf16_t*)bp;          bp += (size_t)NN * CC * 2;
  bf16_t* gcn_wt = (bf16_t*)bp;       bp += (size_t)CC * CC * 2;
  bf16_t* gate_wt = (bf16_t*)bp;      bp += (size_t)CC * 2 * CC * 2;
  bf16_t* in_wt = (bf16_t*)bp;        bp += (size_t)3 * CC * CC * 2;
  bf16_t* out_wt = (bf16_t*)bp;       bp += (size_t)CC * CC * 2;
  bf16_t* m_w1t = (bf16_t*)bp;        bp += (size_t)2 * CC * CC * 2;
  bf16_t* m_w2t = (bf16_t*)bp;        bp += (size_t)CC * 2 * CC * 2;

  bf16_t* xb = (bf16_t*)R1;      // bf16(x)
  bf16_t* xcefb = (bf16_t*)R1;   // [x_conv | ef] bf16 N x 2C (first 32MB of R1)
  bf16_t* qkvb = (bf16_t*)R1;    // qkv bf16 N x 1536 (first 48MB of R1)
  bf16_t* hb = (bf16_t*)R1;      // mlp hidden bf16 N x 2C
  // eacsr lives at R1 + 64MB (coexists with xb/xcefb/qkvb, all < 48MB)
  bf16_t* eacsr = (bf16_t*)((char*)R1 + (size_t)64 * 1024 * 1024);
  bf16_t* xwb = (bf16_t*)R2;     // bf16 xw (GCN GEMM out)
  bf16_t* ob = (bf16_t*)R2;      // attn out bf16 (first half of R2)
  bf16_t* vt = ob + (size_t)NN * CC;  // V^T packed (second half of R2)
  bf16_t* x3b = (bf16_t*)R2;     // bf16(x3) (after ob dead)
  float* x2 = (float*)d_out;

  // --- edge prep ---
  init_kernel<<<(NN + 255) / 256, 256, 0, stream>>>(deg, cnt_dst, cnt_src, nid_src,
                                                    eacsr);
  edge_pass1<<<(EE + 255) / 256, 256, 0, stream>>>(edge_attr, src, dst, ew, deg,
                                                   cnt_dst, cnt_src);
  node_pass<<<(NN + 255) / 256, 256, 0, stream>>>(deg, dinv);
  exscan_kernel<<<1, 1024, 0, stream>>>(cnt_dst, start_dst, cur_dst, NN);
  exscan_kernel<<<1, 1024, 0, stream>>>(cnt_src, start_src, cur_src, NN);
  fill_kernel<<<(EE + 255) / 256, 256, 0, stream>>>(src, dst, cur_dst, cur_src,
                                                    elist_dst, elist_src, nid_src);
  ea_gather_kernel<<<(EE * 2 + 255) / 256, 256, 0, stream>>>(edge_attr, elist_src,
                                                             eacsr);

  // --- weight transposes ---
  wt_kernel<<<dim3(CC / 32, CC / 32), 256, 0, stream>>>(gcn_w, gcn_wt, CC, CC);
  wt_kernel<<<dim3(CC / 32, 2 * CC / 32), 256, 0, stream>>>(gate_w, gate_wt, 2 * CC, CC);
  wt_kernel<<<dim3(3 * CC / 32, CC / 32), 256, 0, stream>>>(in_w, in_wt, CC, 3 * CC);
  wt_kernel<<<dim3(CC / 32, CC / 32), 256, 0, stream>>>(out_w, out_wt, CC, CC);
  wt_kernel<<<dim3(2 * CC / 32, CC / 32), 256, 0, stream>>>(m_w1, m_w1t, CC, 2 * CC);
  wt_kernel<<<dim3(CC / 32, 2 * CC / 32), 256, 0, stream>>>(m_w2, m_w2t, 2 * CC, CC);

  // --- GCN conv ---
  cvt_bf16_kernel<<<(NN * CC / 4 + 255) / 256, 256, 0, stream>>>(x, xb, NN * CC / 4);
  dim3 gA(CC / 128, NN / 128);
  gemm_bf16_kernel<0, 1><<<gA, 256, 0, stream>>>(xb, gcn_wt, nullptr, xwb, NN, CC, CC);
  xconv_kernel<<<NN, 256, 0, stream>>>(xwb, ew, dinv, src, elist_dst, start_dst,
                                       gcn_b, R3, xcefb);
  ef_mfma_kernel<<<NN / 16, 256, 0, stream>>>(eacsr, ep_w, ep_b, nid_src, start_src,
                                              R4, xcefb);
  gemm_bf16_kernel<0, 0><<<gA, 256, 0, stream>>>(xcefb, gate_wt, nullptr, R2, NN, CC,
                                                 2 * CC);
  ln_gate_kernel<<<NN, 256, 0, stream>>>(R2, gate_b, R3, R4, n1_g, n1_b, x, x2, x2b);

  // --- MHA ---
  dim3 gQ(3 * CC / 128, NN / 128);
  gemm_bf16_kernel<0, 1><<<gQ, 256, 0, stream>>>(x2b, in_wt, in_b, qkvb, NN, 3 * CC, CC);
  vt_pack_kernel<<<BB * HH, 256, 0, stream>>>(qkvb, vt);
  attn_mfma_kernel<<<BB * HH, 256, 0, stream>>>(qkvb, vt, ob);
  gemm_bf16_kernel<0, 0><<<gA, 256, 0, stream>>>(ob, out_wt, out_b, R4, NN, CC, CC);
  ln_add_kernel<<<NN, 256, 0, stream>>>(x2, R4, tn_g, tn_b, R3, x3b);

  // --- MLP ---
  dim3 gH(2 * CC / 128, NN / 128);
  gemm_bf16_kernel<1, 1><<<gH, 256, 0, stream>>>(x3b, m_w1t, m_b1, hb, NN, 2 * CC, CC);
  gemm_bf16_kernel<0, 0><<<gA, 256, 0, stream>>>(hb, m_w2t, m_b2, R4, NN, CC, 2 * CC);
  ln_add_kernel<<<NN, 256, 0, stream>>>(R3, R4, fn_g, fn_b, (float*)d_out, nullptr);
}

// Round 8
// 587.667 us; speedup vs baseline: 1.3727x; 1.0951x over previous
//
#include <hip/hip_runtime.h>

#define NN 16384
#define CC 512
#define EE 524288
#define BB 64
#define HH 8
#define EFD 16
#define GEMAXE 10240

typedef __bf16 bf16_t;
typedef __bf16 bf16x4 __attribute__((ext_vector_type(4)));
typedef __bf16 bf16x8 __attribute__((ext_vector_type(8)));
typedef float f32x4v __attribute__((ext_vector_type(4)));

// ---------------- init / edge pre-pass ----------------

__global__ void init_kernel(float* deg, int* ghist, int* nid_src, bf16_t* eacsr) {
  int i = blockIdx.x * 256 + threadIdx.x;
  if (i < NN) deg[i] = 1.0f;
  if (i < 64) ghist[i] = 0;
  if (i < 32) nid_src[EE + i] = -1;               // pad for ef chunk tail
  if (i < 256) ((int*)(eacsr + (size_t)EE * 16))[i] = 0;  // zero eacsr pad rows
}

// ew, weighted deg, per-graph histogram (LDS-aggregated)
__global__ __launch_bounds__(256) void edge_pass1(const float* __restrict__ ea,
                                                  const int* __restrict__ src,
                                                  const int* __restrict__ dst,
                                                  float* __restrict__ ew, float* deg,
                                                  int* ghist) {
  __shared__ int h[64];
  int tid = threadIdx.x;
  if (tid < 64) h[tid] = 0;
  __syncthreads();
  int e = blockIdx.x * 256 + tid;  // EE % 256 == 0
  const float4* p = (const float4*)(ea + (size_t)e * EFD);
  float s = 0.f;
#pragma unroll
  for (int i = 0; i < 4; ++i) {
    float4 v = p[i];
    s += v.x * v.x + v.y * v.y + v.z * v.z + v.w * v.w;
  }
  float w = sqrtf(s);
  ew[e] = w;
  int d = dst[e];
  atomicAdd(&deg[d], w);
  atomicAdd(&h[d >> 8], 1);
  __syncthreads();
  if (tid < 64 && h[tid]) atomicAdd(&ghist[tid], h[tid]);
}

__global__ void node_pass(const float* __restrict__ deg, float* __restrict__ dinv) {
  int i = blockIdx.x * 256 + threadIdx.x;
  if (i >= NN) return;
  float d = deg[i];
  dinv[i] = d > 0.f ? rsqrtf(fmaxf(d, 1e-12f)) : 0.f;
}

__global__ void gexscan_kernel(const int* __restrict__ ghist, int* __restrict__ gstart,
                               int* __restrict__ gcur) {
  if (threadIdx.x == 0) {
    int s = 0;
    for (int g = 0; g < 64; ++g) { gstart[g] = s; gcur[g] = s; s += ghist[g]; }
    gstart[64] = s;
  }
}

// bucket edges by graph with block-aggregated offsets (coalesced-ish writes)
__global__ __launch_bounds__(256) void graph_scatter_kernel(const int* __restrict__ dst,
                                                            int* gcur,
                                                            int* __restrict__ glist) {
  __shared__ int h[64], base[64], h2[64];
  int tid = threadIdx.x;
  if (tid < 64) { h[tid] = 0; h2[tid] = 0; }
  __syncthreads();
  int e0 = blockIdx.x * 2048;
  int gloc[8];
#pragma unroll
  for (int k = 0; k < 8; ++k) {
    gloc[k] = dst[e0 + k * 256 + tid] >> 8;
    atomicAdd(&h[gloc[k]], 1);
  }
  __syncthreads();
  if (tid < 64) base[tid] = h[tid] ? atomicAdd(&gcur[tid], h[tid]) : 0;
  __syncthreads();
#pragma unroll
  for (int k = 0; k < 8; ++k) {
    int g = gloc[k];
    int p = atomicAdd(&h2[g], 1);
    glist[base[g] + p] = e0 + k * 256 + tid;
  }
}

// per-graph LDS counting sort by local node: emits src-CSR (elist+nid) and
// dst-CSR packed {dinv[src]*ew, src} records, plus both start arrays.
__global__ __launch_bounds__(1024) void graph_sort_kernel(
    const int* __restrict__ glist, const int* __restrict__ gstart,
    const int* __restrict__ src, const int* __restrict__ dstar,
    const float* __restrict__ ew, const float* __restrict__ dinv,
    int* __restrict__ elist_src, int* __restrict__ nid_src,
    int* __restrict__ start_src, float2* __restrict__ dstrec,
    int* __restrict__ start_dst) {
  __shared__ int lbuf[GEMAXE];
  __shared__ int h[256], hex[256], h2[256];
  const int g = blockIdx.x;
  const int tid = threadIdx.x;
  const int gs = gstart[g];
  const int cnt = gstart[g + 1] - gs;
  // ---------------- SRC pass ----------------
  if (tid < 256) { h[tid] = 0; h2[tid] = 0; }
  __syncthreads();
  for (int i = tid; i < cnt; i += 1024) atomicAdd(&h[src[glist[gs + i]] & 255], 1);
  __syncthreads();
  int myc = (tid < 256) ? h[tid] : 0;
  for (int off = 1; off < 256; off <<= 1) {
    int v = (tid < 256 && tid >= off) ? h[tid - off] : 0;
    __syncthreads();
    if (tid < 256) h[tid] += v;
    __syncthreads();
  }
  if (tid < 256) {
    hex[tid] = h[tid] - myc;
    start_src[g * 256 + tid] = gs + hex[tid];
  }
  if (g == 63 && tid == 0) start_src[NN] = EE;
  __syncthreads();
  for (int i = tid; i < cnt; i += 1024) {
    int e = glist[gs + i];
    int ls = src[e] & 255;
    int p = hex[ls] + atomicAdd(&h2[ls], 1);
    lbuf[p] = (ls << 19) | e;
  }
  __syncthreads();
  for (int i = tid; i < cnt; i += 1024) {
    int w = lbuf[i];
    elist_src[gs + i] = w & 0x7FFFF;
    nid_src[gs + i] = g * 256 + (w >> 19);
  }
  __syncthreads();
  // ---------------- DST pass ----------------
  if (tid < 256) { h[tid] = 0; h2[tid] = 0; }
  __syncthreads();
  for (int i = tid; i < cnt; i += 1024) atomicAdd(&h[dstar[glist[gs + i]] & 255], 1);
  __syncthreads();
  int myc2 = (tid < 256) ? h[tid] : 0;
  for (int off = 1; off < 256; off <<= 1) {
    int v = (tid < 256 && tid >= off) ? h[tid - off] : 0;
    __syncthreads();
    if (tid < 256) h[tid] += v;
    __syncthreads();
  }
  if (tid < 256) {
    hex[tid] = h[tid] - myc2;
    start_dst[g * 256 + tid] = gs + hex[tid];
  }
  if (g == 63 && tid == 0) start_dst[NN] = EE;
  __syncthreads();
  for (int i = tid; i < cnt; i += 1024) {
    int e = glist[gs + i];
    int ld = dstar[e] & 255;
    int p = hex[ld] + atomicAdd(&h2[ld], 1);
    lbuf[p] = e;
  }
  __syncthreads();
  for (int i = tid; i < cnt; i += 1024) {
    int e = lbuf[i];
    int s = src[e];
    dstrec[gs + i] = make_float2(dinv[s] * ew[e], __int_as_float(s));
  }
}

// gather edge_attr rows into CSR order as bf16
__global__ void ea_gather_kernel(const float* __restrict__ ea,
                                 const int* __restrict__ elist,
                                 bf16_t* __restrict__ eacsr) {
  int idx = blockIdx.x * 256 + threadIdx.x;
  if (idx >= EE * 2) return;
  int pos = idx >> 1, half = idx & 1;
  int e = elist[pos];
  const f32x4v* p = (const f32x4v*)(ea + (size_t)e * EFD + half * 8);
  f32x4v u0 = p[0], u1 = p[1];
  bf16x8 f;
#pragma unroll
  for (int r = 0; r < 4; ++r) {
    f[r] = (bf16_t)u0[r];
    f[4 + r] = (bf16_t)u1[r];
  }
  *(bf16x8*)(eacsr + (size_t)pos * 16 + half * 8) = f;
}

// ---------------- conversions ----------------

__global__ void cvt_bf16_kernel(const float* __restrict__ in, bf16_t* __restrict__ out,
                                int n4) {
  int i = blockIdx.x * 256 + threadIdx.x;
  if (i >= n4) return;
  float4 v = ((const float4*)in)[i];
  bf16x4 o;
  o[0] = (bf16_t)v.x; o[1] = (bf16_t)v.y; o[2] = (bf16_t)v.z; o[3] = (bf16_t)v.w;
  ((bf16x4*)out)[i] = o;
}

// W: f32 [K][N] row-major -> Wt: bf16 [N][K] row-major
__global__ __launch_bounds__(256) void wt_kernel(const float* __restrict__ W,
                                                 bf16_t* __restrict__ Wt, int K, int N) {
  __shared__ float tile[32][33];
  int bx = blockIdx.x * 32;
  int by = blockIdx.y * 32;
  int tx = threadIdx.x & 31, ty = threadIdx.x >> 5;
#pragma unroll
  for (int i = 0; i < 32; i += 8)
    tile[ty + i][tx] = W[(size_t)(by + ty + i) * N + bx + tx];
  __syncthreads();
#pragma unroll
  for (int i = 0; i < 32; i += 8)
    Wt[(size_t)(bx + ty + i) * K + by + tx] = (bf16_t)tile[tx][ty + i];
}

// ---------------- GCN conv gather (CSR by dst, packed records) -------------
__global__ __launch_bounds__(256) void xconv_kernel(
    const bf16_t* __restrict__ xwb, const float* __restrict__ dinv,
    const float2* __restrict__ dstrec, const int* __restrict__ start,
    const float* __restrict__ gcn_b, float* __restrict__ xconv,
    bf16_t* __restrict__ xcb) {
  int i = blockIdx.x;
  int tid = threadIdx.x;
  int st = start[i], en = start[i + 1];
  float di = dinv[i];
  int c0 = tid * 2;
  __shared__ float2 scS[256];  // {coef (incl di), as_float(src_node)}
  union { unsigned u; struct { unsigned short lo, hi; } s; } pk;
  pk.u = *(const unsigned*)(xwb + (size_t)i * CC + c0);
  union { unsigned short us; bf16_t b; } c0v, c1v;
  c0v.us = pk.s.lo; c1v.us = pk.s.hi;
  float sc = di * di;
  float a0 = sc * (float)c0v.b + gcn_b[c0];
  float a1 = sc * (float)c1v.b + gcn_b[c0 + 1];
  for (int p0 = st; p0 < en; p0 += 256) {
    int m = min(256, en - p0);
    __syncthreads();
    if (tid < m) {
      float2 r = dstrec[p0 + tid];
      scS[tid] = make_float2(r.x * di, r.y);
    }
    __syncthreads();
    for (int j = 0; j < m; ++j) {
      float2 scv = scS[j];
      int sn = __float_as_int(scv.y);
      union { unsigned u; struct { unsigned short lo, hi; } s; } q;
      q.u = *(const unsigned*)(xwb + (size_t)sn * CC + c0);
      union { unsigned short us; bf16_t b; } v0, v1;
      v0.us = q.s.lo; v1.us = q.s.hi;
      a0 += scv.x * (float)v0.b;
      a1 += scv.x * (float)v1.b;
    }
  }
  *(float2*)(xconv + (size_t)i * CC + c0) = make_float2(a0, a1);
  xcb[(size_t)i * (2 * CC) + c0] = (bf16_t)a0;
  xcb[(size_t)i * (2 * CC) + c0 + 1] = (bf16_t)a1;
}

// ---------------- edge projection via double-MFMA v3 ----------------
__global__ __launch_bounds__(256) void ef_mfma_kernel(
    const bf16_t* __restrict__ eacsr, const float* __restrict__ ep_w,
    const float* __restrict__ ep_b, const int* __restrict__ nid,
    const int* __restrict__ start, float* __restrict__ ef, bf16_t* __restrict__ efb) {
  const int tid = threadIdx.x;
  const int lane = tid & 63;
  const int wv = tid >> 6;
  const int l15 = lane & 15;
  const int g = lane >> 4;
  const int n0 = blockIdx.x * 16;
  const int cbase = wv * 128;

  bf16x8 wfr[8];
#pragma unroll
  for (int t = 0; t < 8; ++t) {
    bf16x8 f = {};
    int c = cbase + t * 16 + l15;
    if (g < 2) {
#pragma unroll
      for (int j = 0; j < 8; ++j) f[j] = (bf16_t)ep_w[(g * 8 + j) * CC + c];
    } else if (g == 2) {
      f[0] = (bf16_t)ep_b[c];
    }
    wfr[t] = f;
  }

  const int st = start[n0];
  const int en = start[n0 + 16];
  const int tgt = n0 + l15;

  f32x4v eacc[8] = {};

  for (int cb = st; cb < en; cb += 32) {
    bf16x8 af[2];
#pragma unroll
    for (int mE = 0; mE < 2; ++mE) {
      bf16x8 f = {};
      if (g < 2) {
        f = *(const bf16x8*)(eacsr + (size_t)(cb + mE * 16 + l15) * 16 + g * 8);
      } else if (g == 2) {
        f[0] = (bf16_t)1.0f;
      }
      af[mE] = f;
    }
    int4 idlo = *(const int4*)(nid + cb + g * 4);
    int4 idhi = *(const int4*)(nid + cb + 16 + g * 4);
    bf16x8 sf;
    sf[0] = (idlo.x == tgt) ? (bf16_t)1.0f : (bf16_t)0.0f;
    sf[1] = (idlo.y == tgt) ? (bf16_t)1.0f : (bf16_t)0.0f;
    sf[2] = (idlo.z == tgt) ? (bf16_t)1.0f : (bf16_t)0.0f;
    sf[3] = (idlo.w == tgt) ? (bf16_t)1.0f : (bf16_t)0.0f;
    sf[4] = (idhi.x == tgt) ? (bf16_t)1.0f : (bf16_t)0.0f;
    sf[5] = (idhi.y == tgt) ? (bf16_t)1.0f : (bf16_t)0.0f;
    sf[6] = (idhi.z == tgt) ? (bf16_t)1.0f : (bf16_t)0.0f;
    sf[7] = (idhi.w == tgt) ? (bf16_t)1.0f : (bf16_t)0.0f;
#pragma unroll
    for (int t = 0; t < 8; ++t) {
      f32x4v s0 = {}, s1 = {};
      s0 = __builtin_amdgcn_mfma_f32_16x16x32_bf16(af[0], wfr[t], s0, 0, 0, 0);
      s1 = __builtin_amdgcn_mfma_f32_16x16x32_bf16(af[1], wfr[t], s1, 0, 0, 0);
      union { bf16x8 v; bf16x4 h[2]; } pf;
#pragma unroll
      for (int r = 0; r < 4; ++r) {
        pf.h[0][r] = (bf16_t)fmaxf(s0[r], 0.f);
        pf.h[1][r] = (bf16_t)fmaxf(s1[r], 0.f);
      }
      eacc[t] = __builtin_amdgcn_mfma_f32_16x16x32_bf16(sf, pf.v, eacc[t], 0, 0, 0);
    }
  }
#pragma unroll
  for (int t = 0; t < 8; ++t) {
    int c = cbase + t * 16 + l15;
#pragma unroll
    for (int r = 0; r < 4; ++r) {
      int node = n0 + g * 4 + r;
      float v = eacc[t][r];
      ef[(size_t)node * CC + c] = v;
      efb[(size_t)node * (2 * CC) + CC + c] = (bf16_t)v;
    }
  }
}

// ---------------- bf16 MFMA GEMM (m97 structure) ----------------
__device__ __forceinline__ void gl_lds16(const bf16_t* g, bf16_t* l) {
  __builtin_amdgcn_global_load_lds(
      (const __attribute__((address_space(1))) void*)g,
      (__attribute__((address_space(3))) void*)l, 16, 0, 0);
}

template <int ACT, int OUT>
__global__ __launch_bounds__(256) void gemm_bf16_kernel(
    const bf16_t* __restrict__ A, const bf16_t* __restrict__ Bt,
    const float* __restrict__ bias, void* __restrict__ Cout, int M, int N, int K) {
  __shared__ __align__(16) bf16_t Al[128 * 32];
  __shared__ __align__(16) bf16_t Bl[128 * 32];
  const int tid = threadIdx.x;
  const int lane = tid & 63;
  const int wave = tid >> 6;
  const int row0 = blockIdx.y * 128;
  const int col0 = blockIdx.x * 128;
  const int wm = (wave >> 1) * 64;
  const int wn = (wave & 1) * 64;
  f32x4v acc[4][4] = {};
  const bf16_t* aBase = A + (size_t)(row0 + (tid >> 2)) * K + (tid & 3) * 8;
  const bf16_t* bBase = Bt + (size_t)(col0 + (tid >> 2)) * K + (tid & 3) * 8;
  bf16_t* al0 = Al + wave * 512;
  bf16_t* al1 = Al + 2048 + wave * 512;
  bf16_t* bl0 = Bl + wave * 512;
  bf16_t* bl1 = Bl + 2048 + wave * 512;
  const int fr = lane & 15;
  const int fk = (lane >> 4) * 8;
  for (int k0 = 0; k0 < K; k0 += 32) {
    gl_lds16(aBase + k0, al0);
    gl_lds16(aBase + (size_t)64 * K + k0, al1);
    gl_lds16(bBase + k0, bl0);
    gl_lds16(bBase + (size_t)64 * K + k0, bl1);
    __syncthreads();
    bf16x8 af[4], bfv[4];
#pragma unroll
    for (int m = 0; m < 4; ++m)
      af[m] = *(const bf16x8*)(Al + (wm + m * 16 + fr) * 32 + fk);
#pragma unroll
    for (int n = 0; n < 4; ++n)
      bfv[n] = *(const bf16x8*)(Bl + (wn + n * 16 + fr) * 32 + fk);
#pragma unroll
    for (int m = 0; m < 4; ++m)
#pragma unroll
      for (int n = 0; n < 4; ++n)
        acc[m][n] =
            __builtin_amdgcn_mfma_f32_16x16x32_bf16(af[m], bfv[n], acc[m][n], 0, 0, 0);
    __syncthreads();
  }
  const int fq = (lane >> 4) * 4;
#pragma unroll
  for (int m = 0; m < 4; ++m) {
    int grb = row0 + wm + m * 16 + fq;
#pragma unroll
    for (int n = 0; n < 4; ++n) {
      int gc = col0 + wn + n * 16 + fr;
      float bv = bias ? bias[gc] : 0.f;
#pragma unroll
      for (int r = 0; r < 4; ++r) {
        float v = acc[m][n][r] + bv;
        if (ACT == 1) v = v / (1.f + __expf(-v));
        if (OUT == 0)
          ((float*)Cout)[(size_t)(grb + r) * N + gc] = v;
        else
          ((bf16_t*)Cout)[(size_t)(grb + r) * N + gc] = (bf16_t)v;
      }
    }
  }
}

// ---------------- layernorm fused kernels ----------------

__device__ inline void block_reduce2(float& s, float& q, float* red) {
#pragma unroll
  for (int off = 32; off >= 1; off >>= 1) {
    s += __shfl_xor(s, off, 64);
    q += __shfl_xor(q, off, 64);
  }
  int wid = threadIdx.x >> 6;
  if ((threadIdx.x & 63) == 0) { red[wid * 2] = s; red[wid * 2 + 1] = q; }
  __syncthreads();
  s = red[0] + red[2] + red[4] + red[6];
  q = red[1] + red[3] + red[5] + red[7];
}

__global__ __launch_bounds__(256) void ln_add_kernel(const float* __restrict__ A,
                                                     const float* __restrict__ Bb,
                                                     const float* __restrict__ g,
                                                     const float* __restrict__ be,
                                                     float* __restrict__ out,
                                                     bf16_t* __restrict__ bout) {
  int row = blockIdx.x, tid = threadIdx.x, c0 = tid * 2;
  __shared__ float red[8];
  float2 a = *(const float2*)(A + (size_t)row * CC + c0);
  float2 b = *(const float2*)(Bb + (size_t)row * CC + c0);
  float x0 = a.x + b.x, x1 = a.y + b.y;
  float s = x0 + x1, q = x0 * x0 + x1 * x1;
  block_reduce2(s, q, red);
  float mean = s * (1.f / CC);
  float var = q * (1.f / CC) - mean * mean;
  float rs = rsqrtf(var + 1e-5f);
  float o0 = (x0 - mean) * rs * g[c0] + be[c0];
  float o1 = (x1 - mean) * rs * g[c0 + 1] + be[c0 + 1];
  *(float2*)(out + (size_t)row * CC + c0) = make_float2(o0, o1);
  if (bout) {
    bout[(size_t)row * CC + c0] = (bf16_t)o0;
    bout[(size_t)row * CC + c0 + 1] = (bf16_t)o1;
  }
}

__global__ __launch_bounds__(256) void ln_gate_kernel(
    const float* __restrict__ gpre, const float* __restrict__ gate_b,
    const float* __restrict__ xc, const float* __restrict__ ef,
    const float* __restrict__ n1g, const float* __restrict__ n1b,
    const float* __restrict__ xin, float* __restrict__ x2, bf16_t* __restrict__ x2b) {
  int row = blockIdx.x, tid = threadIdx.x, c0 = tid * 2;
  __shared__ float red[8];
  float2 gp = *(const float2*)(gpre + (size_t)row * CC + c0);
  float2 xcv = *(const float2*)(xc + (size_t)row * CC + c0);
  float2 efv = *(const float2*)(ef + (size_t)row * CC + c0);
  float g0 = 1.f / (1.f + __expf(-(gp.x + gate_b[c0])));
  float g1 = 1.f / (1.f + __expf(-(gp.y + gate_b[c0 + 1])));
  float x0 = g0 * xcv.x + (1.f - g0) * efv.x;
  float x1 = g1 * xcv.y + (1.f - g1) * efv.y;
  float s = x0 + x1, q = x0 * x0 + x1 * x1;
  block_reduce2(s, q, red);
  float mean = s * (1.f / CC);
  float var = q * (1.f / CC) - mean * mean;
  float rs = rsqrtf(var + 1e-5f);
  float2 xi = *(const float2*)(xin + (size_t)row * CC + c0);
  float o0 = fmaxf((x0 - mean) * rs * n1g[c0] + n1b[c0], 0.f) + xi.x;
  float o1 = fmaxf((x1 - mean) * rs * n1g[c0 + 1] + n1b[c0 + 1], 0.f) + xi.y;
  *(float2*)(x2 + (size_t)row * CC + c0) = make_float2(o0, o1);
  x2b[(size_t)row * CC + c0] = (bf16_t)o0;
  x2b[(size_t)row * CC + c0 + 1] = (bf16_t)o1;
}

// ---------------- V^T pack (pre-swizzled + pi-permuted K for attn) ---------
__global__ __launch_bounds__(256) void vt_pack_kernel(const bf16_t* __restrict__ qkvb,
                                                      bf16_t* __restrict__ vt) {
  int b = blockIdx.x >> 3, h = blockIdx.x & 7;
  int nb = b * 256;
  size_t voff = 1024 + (size_t)h * 64;
  char* out = (char*)(vt + (size_t)blockIdx.x * (64 * 256));
  __shared__ bf16_t tile[64][80];
  int tid = threadIdx.x;
  for (int kb = 0; kb < 4; ++kb) {
    __syncthreads();
#pragma unroll
    for (int p = 0; p < 2; ++p) {
      int k = p * 32 + (tid >> 3);
      int d8 = tid & 7;
      bf16x8 v = *(const bf16x8*)(qkvb + (size_t)(nb + kb * 64 + k) * 1536 + voff + d8 * 8);
      *(bf16x8*)(&tile[k][d8 * 8]) = v;
    }
    __syncthreads();
#pragma unroll
    for (int p = 0; p < 2; ++p) {
      int d = p * 32 + (tid >> 3);
      int k8 = tid & 7;
      bf16x8 v;
#pragma unroll
      for (int j = 0; j < 8; ++j) {
        int pos = k8 * 8 + j;
        int sl = pos & 31;
        int srck = (pos & 32) + ((sl >> 3) << 2) + (sl & 3) + (((sl >> 2) & 1) << 4);
        v[j] = tile[srck][d];
      }
      int byteoff = d * 512 + ((kb * 128 + k8 * 16) ^ ((d & 7) << 4));
      *(bf16x8*)(out + byteoff) = v;
    }
  }
}

// ---------------- MFMA attention (shuffle-free PV) ----------------
__global__ __launch_bounds__(256, 2) void attn_mfma_kernel(
    const bf16_t* __restrict__ qkvb, const bf16_t* __restrict__ vt,
    bf16_t* __restrict__ o) {
  const int b = blockIdx.x >> 3;
  const int h = blockIdx.x & 7;
  const int nb = b * 256;
  const int tid = threadIdx.x;
  const int lane = tid & 63;
  const int wv = tid >> 6;
  const int l15 = lane & 15;
  const int g = lane >> 4;
  const int swzk = (l15 & 7) << 4;
  __shared__ __align__(16) bf16_t Klds[256 * 64];
  __shared__ __align__(16) bf16_t Vtlds[64 * 256];
  const size_t qoff = (size_t)h * 64;
  const size_t koff = 512 + (size_t)h * 64;

  {
    const int dcol = 16 * ((tid & 7) ^ ((tid >> 3) & 7));
    const bf16_t* srcb = qkvb + koff + (dcol >> 1);
#pragma unroll
    for (int i = 0; i < 8; ++i) {
      int k = i * 32 + (tid >> 3);
      gl_lds16(srcb + (size_t)(nb + k) * 1536, Klds + ((i * 4096 + wv * 1024) >> 1));
    }
  }
  {
    const bf16_t* vsrc = vt + (size_t)blockIdx.x * (64 * 256);
#pragma unroll
    for (int i = 0; i < 8; ++i) {
      int base = i * 4096 + wv * 1024;
      gl_lds16(vsrc + ((base >> 1) + lane * 8), Vtlds + (base >> 1));
    }
  }

  bf16x8 qf[4][2];
#pragma unroll
  for (int n = 0; n < 4; ++n) {
    const bf16_t* qp = qkvb + (size_t)(nb + wv * 64 + 16 * n + l15) * 1536 + qoff + g * 8;
    qf[n][0] = *(const bf16x8*)(qp);
    qf[n][1] = *(const bf16x8*)(qp + 32);
  }

  __syncthreads();

  f32x4v oacc[4][4] = {};
  float mrun[4] = {-1e30f, -1e30f, -1e30f, -1e30f};
  float lrun[4] = {0.f, 0.f, 0.f, 0.f};

  for (int kc = 0; kc < 4; ++kc) {
    f32x4v sacc[4][4] = {};
    const int kb128 = (kc * 64 + l15) * 128;
#pragma unroll
    for (int m = 0; m < 4; ++m) {
      bf16x8 a0 = *(const bf16x8*)(Klds + ((kb128 + m * 2048 + ((g * 16) ^ swzk)) >> 1));
      bf16x8 a1 =
          *(const bf16x8*)(Klds + ((kb128 + m * 2048 + ((64 + g * 16) ^ swzk)) >> 1));
#pragma unroll
      for (int n = 0; n < 4; ++n) {
        sacc[m][n] = __builtin_amdgcn_mfma_f32_16x16x32_bf16(a0, qf[n][0], sacc[m][n], 0, 0, 0);
        sacc[m][n] = __builtin_amdgcn_mfma_f32_16x16x32_bf16(a1, qf[n][1], sacc[m][n], 0, 0, 0);
      }
    }
    uint2 pb[4][4];
#pragma unroll
    for (int n = 0; n < 4; ++n) {
      float mx = sacc[0][n][0];
#pragma unroll
      for (int m = 0; m < 4; ++m)
#pragma unroll
        for (int r = 0; r < 4; ++r) mx = fmaxf(mx, sacc[m][n][r]);
      mx = fmaxf(mx, __shfl_xor(mx, 16));
      mx = fmaxf(mx, __shfl_xor(mx, 32));
      float mnew = fmaxf(mrun[n], mx);
      float c = __expf((mrun[n] - mnew) * 0.125f);
      mrun[n] = mnew;
      float s = 0.f;
#pragma unroll
      for (int m = 0; m < 4; ++m) {
        float p0 = __expf((sacc[m][n][0] - mnew) * 0.125f);
        float p1 = __expf((sacc[m][n][1] - mnew) * 0.125f);
        float p2 = __expf((sacc[m][n][2] - mnew) * 0.125f);
        float p3 = __expf((sacc[m][n][3] - mnew) * 0.125f);
        s += (p0 + p1) + (p2 + p3);
        union { bf16x4 v; uint2 u; } cv;
        cv.v[0] = (bf16_t)p0; cv.v[1] = (bf16_t)p1;
        cv.v[2] = (bf16_t)p2; cv.v[3] = (bf16_t)p3;
        pb[m][n] = cv.u;
      }
      s += __shfl_xor(s, 16);
      s += __shfl_xor(s, 32);
      lrun[n] = lrun[n] * c + s;
#pragma unroll
      for (int m = 0; m < 4; ++m)
#pragma unroll
        for (int r = 0; r < 4; ++r) oacc[m][n][r] *= c;
    }
#pragma unroll
    for (int h2 = 0; h2 < 2; ++h2) {
      bf16x8 vf[4];
#pragma unroll
      for (int m = 0; m < 4; ++m)
        vf[m] = *(const bf16x8*)(Vtlds + (((16 * m + l15) * 512 +
                                          ((kc * 128 + h2 * 64 + g * 16) ^ swzk)) >> 1));
#pragma unroll
      for (int n = 0; n < 4; ++n) {
        union { uint2 u[2]; bf16x8 v; } pf;
        pf.u[0] = pb[2 * h2][n];
        pf.u[1] = pb[2 * h2 + 1][n];
#pragma unroll
        for (int m = 0; m < 4; ++m)
          oacc[m][n] =
              __builtin_amdgcn_mfma_f32_16x16x32_bf16(vf[m], pf.v, oacc[m][n], 0, 0, 0);
      }
    }
  }
  float inv[4];
#pragma unroll
  for (int n = 0; n < 4; ++n) inv[n] = 1.0f / lrun[n];
#pragma unroll
  for (int m = 0; m < 4; ++m)
#pragma unroll
    for (int n = 0; n < 4; ++n) {
      bf16x4 pk;
#pragma unroll
      for (int r = 0; r < 4; ++r) pk[r] = (bf16_t)(oacc[m][n][r] * inv[n]);
      *(bf16x4*)(o + (size_t)(nb + wv * 64 + 16 * n + l15) * 512 + h * 64 + 16 * m +
                 4 * g) = pk;
    }
}

// ---------------- launch ----------------

static inline char* alignp(char* p, size_t a) {
  return (char*)(((uintptr_t)p + a - 1) & ~(uintptr_t)(a - 1));
}

extern "C" void kernel_launch(void* const* d_in, const int* in_sizes, int n_in,
                              void* d_out, int out_size, void* d_ws, size_t ws_size,
                              hipStream_t stream) {
  const float* x = (const float*)d_in[0];
  const float* edge_attr = (const float*)d_in[1];
  const float* gcn_w = (const float*)d_in[2];
  const float* gcn_b = (const float*)d_in[3];
  const float* ep_w = (const float*)d_in[4];
  const float* ep_b = (const float*)d_in[5];
  const float* gate_w = (const float*)d_in[6];
  const float* gate_b = (const float*)d_in[7];
  const float* n1_g = (const float*)d_in[8];
  const float* n1_b = (const float*)d_in[9];
  const float* in_w = (const float*)d_in[10];
  const float* in_b = (const float*)d_in[11];
  const float* out_w = (const float*)d_in[12];
  const float* out_b = (const float*)d_in[13];
  const float* tn_g = (const float*)d_in[14];
  const float* tn_b = (const float*)d_in[15];
  const float* m_w1 = (const float*)d_in[16];
  const float* m_b1 = (const float*)d_in[17];
  const float* m_w2 = (const float*)d_in[18];
  const float* m_b2 = (const float*)d_in[19];
  const float* fn_g = (const float*)d_in[20];
  const float* fn_b = (const float*)d_in[21];
  const int* eidx = (const int*)d_in[22];
  const int* src = eidx;
  const int* dst = eidx + EE;

  float* ws = (float*)d_ws;
  float* R1 = ws;
  float* R2 = R1 + (size_t)NN * 3 * CC;
  float* R3 = R2 + (size_t)NN * CC;
  float* R4 = R3 + (size_t)NN * CC;
  float* ew = R4 + (size_t)NN * CC;
  float* deg = ew + EE;
  float* dinv = deg + NN;
  int* ip = (int*)(dinv + NN);
  int* ghist = ip;      ip += 64;
  int* gstart = ip;     ip += 65;
  int* gcur = ip;       ip += 64;
  int* glist = ip;      ip += EE;
  int* elist_src = ip;  ip += EE;
  int* nid_src = ip;    ip += EE + 32;
  int* start_src = ip;  ip += NN + 1;
  int* start_dst = ip;  ip += NN + 1;
  char* bp = alignp((char*)ip, 64);
  float2* dstrec = (float2*)bp;       bp += (size_t)EE * 8;
  bf16_t* x2b = (bf16_t*)bp;          bp += (size_t)NN * CC * 2;
  bf16_t* gcn_wt = (bf16_t*)bp;       bp += (size_t)CC * CC * 2;
  bf16_t* gate_wt = (bf16_t*)bp;      bp += (size_t)CC * 2 * CC * 2;
  bf16_t* in_wt = (bf16_t*)bp;        bp += (size_t)3 * CC * CC * 2;
  bf16_t* out_wt = (bf16_t*)bp;       bp += (size_t)CC * CC * 2;
  bf16_t* m_w1t = (bf16_t*)bp;        bp += (size_t)2 * CC * CC * 2;
  bf16_t* m_w2t = (bf16_t*)bp;        bp += (size_t)CC * 2 * CC * 2;

  bf16_t* xb = (bf16_t*)R1;      // bf16(x)
  bf16_t* xcefb = (bf16_t*)R1;   // [x_conv | ef] bf16 N x 2C
  bf16_t* qkvb = (bf16_t*)R1;    // qkv bf16 N x 1536 (first 48MB of R1)
  bf16_t* hb = (bf16_t*)R1;      // mlp hidden bf16 N x 2C
  bf16_t* eacsr = (bf16_t*)((char*)R1 + (size_t)64 * 1024 * 1024);  // 16.8MB at R1+64MB
  bf16_t* xwb = (bf16_t*)R2;     // bf16 xw (GCN GEMM out)
  bf16_t* ob = (bf16_t*)R2;      // attn out bf16 (first half of R2)
  bf16_t* vt = ob + (size_t)NN * CC;  // V^T packed (second half of R2)
  bf16_t* x3b = (bf16_t*)R2;     // bf16(x3) (after ob dead)
  float* x2 = (float*)d_out;

  // --- edge prep: two-level counting sort (coalesced) ---
  init_kernel<<<(NN + 255) / 256, 256, 0, stream>>>(deg, ghist, nid_src, eacsr);
  edge_pass1<<<EE / 256, 256, 0, stream>>>(edge_attr, src, dst, ew, deg, ghist);
  node_pass<<<(NN + 255) / 256, 256, 0, stream>>>(deg, dinv);
  gexscan_kernel<<<1, 64, 0, stream>>>(ghist, gstart, gcur);
  graph_scatter_kernel<<<EE / 2048, 256, 0, stream>>>(dst, gcur, glist);
  graph_sort_kernel<<<BB, 1024, 0, stream>>>(glist, gstart, src, dst, ew, dinv,
                                             elist_src, nid_src, start_src, dstrec,
                                             start_dst);
  ea_gather_kernel<<<(EE * 2 + 255) / 256, 256, 0, stream>>>(edge_attr, elist_src,
                                                             eacsr);

  // --- weight transposes ---
  wt_kernel<<<dim3(CC / 32, CC / 32), 256, 0, stream>>>(gcn_w, gcn_wt, CC, CC);
  wt_kernel<<<dim3(CC / 32, 2 * CC / 32), 256, 0, stream>>>(gate_w, gate_wt, 2 * CC, CC);
  wt_kernel<<<dim3(3 * CC / 32, CC / 32), 256, 0, stream>>>(in_w, in_wt, CC, 3 * CC);
  wt_kernel<<<dim3(CC / 32, CC / 32), 256, 0, stream>>>(out_w, out_wt, CC, CC);
  wt_kernel<<<dim3(2 * CC / 32, CC / 32), 256, 0, stream>>>(m_w1, m_w1t, CC, 2 * CC);
  wt_kernel<<<dim3(CC / 32, 2 * CC / 32), 256, 0, stream>>>(m_w2, m_w2t, 2 * CC, CC);

  // --- GCN conv ---
  cvt_bf16_kernel<<<(NN * CC / 4 + 255) / 256, 256, 0, stream>>>(x, xb, NN * CC / 4);
  dim3 gA(CC / 128, NN / 128);
  gemm_bf16_kernel<0, 1><<<gA, 256, 0, stream>>>(xb, gcn_wt, nullptr, xwb, NN, CC, CC);
  xconv_kernel<<<NN, 256, 0, stream>>>(xwb, dinv, dstrec, start_dst, gcn_b, R3, xcefb);
  ef_mfma_kernel<<<NN / 16, 256, 0, stream>>>(eacsr, ep_w, ep_b, nid_src, start_src,
                                              R4, xcefb);
  gemm_bf16_kernel<0, 0><<<gA, 256, 0, stream>>>(xcefb, gate_wt, nullptr, R2, NN, CC,
                                                 2 * CC);
  ln_gate_kernel<<<NN, 256, 0, stream>>>(R2, gate_b, R3, R4, n1_g, n1_b, x, x2, x2b);

  // --- MHA ---
  dim3 gQ(3 * CC / 128, NN / 128);
  gemm_bf16_kernel<0, 1><<<gQ, 256, 0, stream>>>(x2b, in_wt, in_b, qkvb, NN, 3 * CC, CC);
  vt_pack_kernel<<<BB * HH, 256, 0, stream>>>(qkvb, vt);
  attn_mfma_kernel<<<BB * HH, 256, 0, stream>>>(qkvb, vt, ob);
  gemm_bf16_kernel<0, 0><<<gA, 256, 0, stream>>>(ob, out_wt, out_b, R4, NN, CC, CC);
  ln_add_kernel<<<NN, 256, 0, stream>>>(x2, R4, tn_g, tn_b, R3, x3b);

  // --- MLP ---
  dim3 gH(2 * CC / 128, NN / 128);
  gemm_bf16_kernel<1, 1><<<gH, 256, 0, stream>>>(x3b, m_w1t, m_b1, hb, NN, 2 * CC, CC);
  gemm_bf16_kernel<0, 0><<<gA, 256, 0, stream>>>(hb, m_w2t, m_b2, R4, NN, CC, 2 * CC);
  ln_add_kernel<<<NN, 256, 0, stream>>>(R3, R4, fn_g, fn_b, (float*)d_out, nullptr);
}

// Round 9
// 569.499 us; speedup vs baseline: 1.4164x; 1.0319x over previous
//
#include <hip/hip_runtime.h>

#define NN 16384
#define CC 512
#define EE 524288
#define BB 64
#define HH 8
#define EFD 16
#define GEMAXE 10240

typedef __bf16 bf16_t;
typedef __bf16 bf16x4 __attribute__((ext_vector_type(4)));
typedef __bf16 bf16x8 __attribute__((ext_vector_type(8)));
typedef float f32x4v __attribute__((ext_vector_type(4)));

// ---------------- init / edge pre-pass ----------------

__global__ void init_kernel(int* ghist, int* nid_src, bf16_t* eacsr) {
  int i = threadIdx.x;
  if (i < 64) ghist[i] = 0;
  if (i < 32) nid_src[EE + i] = -1;               // pad for ef chunk tail
  ((int*)(eacsr + (size_t)EE * 16))[i] = 0;       // zero eacsr pad rows (256 ints)
}

// ew + per-graph histogram (LDS-aggregated). NO scattered atomics.
__global__ __launch_bounds__(256) void edge_pass1(const float* __restrict__ ea,
                                                  const int* __restrict__ dst,
                                                  float* __restrict__ ew, int* ghist) {
  __shared__ int h[64];
  int tid = threadIdx.x;
  if (tid < 64) h[tid] = 0;
  __syncthreads();
  int e = blockIdx.x * 256 + tid;  // EE % 256 == 0
  const float4* p = (const float4*)(ea + (size_t)e * EFD);
  float s = 0.f;
#pragma unroll
  for (int i = 0; i < 4; ++i) {
    float4 v = p[i];
    s += v.x * v.x + v.y * v.y + v.z * v.z + v.w * v.w;
  }
  ew[e] = sqrtf(s);
  atomicAdd(&h[dst[e] >> 8], 1);
  __syncthreads();
  if (tid < 64 && h[tid]) atomicAdd(&ghist[tid], h[tid]);
}

__global__ void gexscan_kernel(const int* __restrict__ ghist, int* __restrict__ gstart,
                               int* __restrict__ gcur) {
  if (threadIdx.x == 0) {
    int s = 0;
    for (int g = 0; g < 64; ++g) { gstart[g] = s; gcur[g] = s; s += ghist[g]; }
    gstart[64] = s;
  }
}

// bucket edges by graph with block-aggregated offsets (coalesced-ish writes)
__global__ __launch_bounds__(256) void graph_scatter_kernel(const int* __restrict__ dst,
                                                            int* gcur,
                                                            int* __restrict__ glist) {
  __shared__ int h[64], base[64], h2[64];
  int tid = threadIdx.x;
  if (tid < 64) { h[tid] = 0; h2[tid] = 0; }
  __syncthreads();
  int e0 = blockIdx.x * 2048;
  int gloc[8];
#pragma unroll
  for (int k = 0; k < 8; ++k) {
    gloc[k] = dst[e0 + k * 256 + tid] >> 8;
    atomicAdd(&h[gloc[k]], 1);
  }
  __syncthreads();
  if (tid < 64) base[tid] = h[tid] ? atomicAdd(&gcur[tid], h[tid]) : 0;
  __syncthreads();
#pragma unroll
  for (int k = 0; k < 8; ++k) {
    int g = gloc[k];
    int p = atomicAdd(&h2[g], 1);
    glist[base[g] + p] = e0 + k * 256 + tid;
  }
}

// per-graph LDS counting sort by local node. DST pass first: sorts, computes
// deg/dinv per node in-LDS (deg = 1 + sum ew over segment), emits dstrec and
// start_dst, writes global dinv. Then SRC pass emits elist/nid/start_src.
__global__ __launch_bounds__(1024) void graph_sort_kernel(
    const int* __restrict__ glist, const int* __restrict__ gstart,
    const int* __restrict__ src, const int* __restrict__ dstar,
    const float* __restrict__ ew, int* __restrict__ elist_src,
    int* __restrict__ nid_src, int* __restrict__ start_src,
    float2* __restrict__ dstrec, int* __restrict__ start_dst,
    float* __restrict__ dinv) {
  __shared__ int lbuf[GEMAXE];
  __shared__ int h[256], hex[256], h2[256];
  __shared__ float fdinv[256];
  const int g = blockIdx.x;
  const int tid = threadIdx.x;
  const int gs = gstart[g];
  const int cnt = gstart[g + 1] - gs;
  // ---------------- DST pass ----------------
  if (tid < 256) { h[tid] = 0; h2[tid] = 0; }
  __syncthreads();
  for (int i = tid; i < cnt; i += 1024) atomicAdd(&h[dstar[glist[gs + i]] & 255], 1);
  __syncthreads();
  int mycD = (tid < 256) ? h[tid] : 0;
  for (int off = 1; off < 256; off <<= 1) {
    int v = (tid < 256 && tid >= off) ? h[tid - off] : 0;
    __syncthreads();
    if (tid < 256) h[tid] += v;
    __syncthreads();
  }
  if (tid < 256) {
    hex[tid] = h[tid] - mycD;
    start_dst[g * 256 + tid] = gs + hex[tid];
  }
  if (g == 63 && tid == 0) start_dst[NN] = EE;
  __syncthreads();
  for (int i = tid; i < cnt; i += 1024) {
    int e = glist[gs + i];
    int ld = dstar[e] & 255;
    int p = hex[ld] + atomicAdd(&h2[ld], 1);
    lbuf[p] = e;
  }
  __syncthreads();
  // deg/dinv per local node (deg = 1 + segment sum of ew)
  if (tid < 256) {
    float dg = 1.0f;
    int s0 = hex[tid], e0 = s0 + mycD;
    for (int i = s0; i < e0; ++i) dg += ew[lbuf[i]];
    float dv = rsqrtf(fmaxf(dg, 1e-12f));
    fdinv[tid] = dv;
    dinv[g * 256 + tid] = dv;
  }
  __syncthreads();
  for (int i = tid; i < cnt; i += 1024) {
    int e = lbuf[i];
    int s = src[e];
    dstrec[gs + i] = make_float2(fdinv[s & 255] * ew[e], __int_as_float(s));
  }
  __syncthreads();
  // ---------------- SRC pass ----------------
  if (tid < 256) { h[tid] = 0; h2[tid] = 0; }
  __syncthreads();
  for (int i = tid; i < cnt; i += 1024) atomicAdd(&h[src[glist[gs + i]] & 255], 1);
  __syncthreads();
  int mycS = (tid < 256) ? h[tid] : 0;
  for (int off = 1; off < 256; off <<= 1) {
    int v = (tid < 256 && tid >= off) ? h[tid - off] : 0;
    __syncthreads();
    if (tid < 256) h[tid] += v;
    __syncthreads();
  }
  if (tid < 256) {
    hex[tid] = h[tid] - mycS;
    start_src[g * 256 + tid] = gs + hex[tid];
  }
  if (g == 63 && tid == 0) start_src[NN] = EE;
  __syncthreads();
  for (int i = tid; i < cnt; i += 1024) {
    int e = glist[gs + i];
    int ls = src[e] & 255;
    int p = hex[ls] + atomicAdd(&h2[ls], 1);
    lbuf[p] = (ls << 19) | e;
  }
  __syncthreads();
  for (int i = tid; i < cnt; i += 1024) {
    int w = lbuf[i];
    elist_src[gs + i] = w & 0x7FFFF;
    nid_src[gs + i] = g * 256 + (w >> 19);
  }
}

// gather edge_attr rows into CSR order as bf16
__global__ void ea_gather_kernel(const float* __restrict__ ea,
                                 const int* __restrict__ elist,
                                 bf16_t* __restrict__ eacsr) {
  int idx = blockIdx.x * 256 + threadIdx.x;
  if (idx >= EE * 2) return;
  int pos = idx >> 1, half = idx & 1;
  int e = elist[pos];
  const f32x4v* p = (const f32x4v*)(ea + (size_t)e * EFD + half * 8);
  f32x4v u0 = p[0], u1 = p[1];
  bf16x8 f;
#pragma unroll
  for (int r = 0; r < 4; ++r) {
    f[r] = (bf16_t)u0[r];
    f[4 + r] = (bf16_t)u1[r];
  }
  *(bf16x8*)(eacsr + (size_t)pos * 16 + half * 8) = f;
}

// ---------------- conversions ----------------

__global__ void cvt_bf16_kernel(const float* __restrict__ in, bf16_t* __restrict__ out,
                                int n4) {
  int i = blockIdx.x * 256 + threadIdx.x;
  if (i >= n4) return;
  float4 v = ((const float4*)in)[i];
  bf16x4 o;
  o[0] = (bf16_t)v.x; o[1] = (bf16_t)v.y; o[2] = (bf16_t)v.z; o[3] = (bf16_t)v.w;
  ((bf16x4*)out)[i] = o;
}

// W: f32 [K][N] row-major -> Wt: bf16 [N][K] row-major
__global__ __launch_bounds__(256) void wt_kernel(const float* __restrict__ W,
                                                 bf16_t* __restrict__ Wt, int K, int N) {
  __shared__ float tile[32][33];
  int bx = blockIdx.x * 32;
  int by = blockIdx.y * 32;
  int tx = threadIdx.x & 31, ty = threadIdx.x >> 5;
#pragma unroll
  for (int i = 0; i < 32; i += 8)
    tile[ty + i][tx] = W[(size_t)(by + ty + i) * N + bx + tx];
  __syncthreads();
#pragma unroll
  for (int i = 0; i < 32; i += 8)
    Wt[(size_t)(bx + ty + i) * K + by + tx] = (bf16_t)tile[tx][ty + i];
}

// ---------------- GCN conv gather (CSR by dst, packed records) -------------
__global__ __launch_bounds__(256) void xconv_kernel(
    const bf16_t* __restrict__ xwb, const float* __restrict__ dinv,
    const float2* __restrict__ dstrec, const int* __restrict__ start,
    const float* __restrict__ gcn_b, float* __restrict__ xconv,
    bf16_t* __restrict__ xcb) {
  int i = blockIdx.x;
  int tid = threadIdx.x;
  int st = start[i], en = start[i + 1];
  float di = dinv[i];
  int c0 = tid * 2;
  __shared__ float2 scS[256];  // {coef (incl di), as_float(src_node)}
  union { unsigned u; struct { unsigned short lo, hi; } s; } pk;
  pk.u = *(const unsigned*)(xwb + (size_t)i * CC + c0);
  union { unsigned short us; bf16_t b; } c0v, c1v;
  c0v.us = pk.s.lo; c1v.us = pk.s.hi;
  float sc = di * di;
  float a0 = sc * (float)c0v.b + gcn_b[c0];
  float a1 = sc * (float)c1v.b + gcn_b[c0 + 1];
  for (int p0 = st; p0 < en; p0 += 256) {
    int m = min(256, en - p0);
    __syncthreads();
    if (tid < m) {
      float2 r = dstrec[p0 + tid];
      scS[tid] = make_float2(r.x * di, r.y);
    }
    __syncthreads();
    for (int j = 0; j < m; ++j) {
      float2 scv = scS[j];
      int sn = __float_as_int(scv.y);
      union { unsigned u; struct { unsigned short lo, hi; } s; } q;
      q.u = *(const unsigned*)(xwb + (size_t)sn * CC + c0);
      union { unsigned short us; bf16_t b; } v0, v1;
      v0.us = q.s.lo; v1.us = q.s.hi;
      a0 += scv.x * (float)v0.b;
      a1 += scv.x * (float)v1.b;
    }
  }
  *(float2*)(xconv + (size_t)i * CC + c0) = make_float2(a0, a1);
  xcb[(size_t)i * (2 * CC) + c0] = (bf16_t)a0;
  xcb[(size_t)i * (2 * CC) + c0 + 1] = (bf16_t)a1;
}

// ---------------- edge projection via double-MFMA v3 ----------------
__global__ __launch_bounds__(256) void ef_mfma_kernel(
    const bf16_t* __restrict__ eacsr, const float* __restrict__ ep_w,
    const float* __restrict__ ep_b, const int* __restrict__ nid,
    const int* __restrict__ start, float* __restrict__ ef, bf16_t* __restrict__ efb) {
  const int tid = threadIdx.x;
  const int lane = tid & 63;
  const int wv = tid >> 6;
  const int l15 = lane & 15;
  const int g = lane >> 4;
  const int n0 = blockIdx.x * 16;
  const int cbase = wv * 128;

  bf16x8 wfr[8];
#pragma unroll
  for (int t = 0; t < 8; ++t) {
    bf16x8 f = {};
    int c = cbase + t * 16 + l15;
    if (g < 2) {
#pragma unroll
      for (int j = 0; j < 8; ++j) f[j] = (bf16_t)ep_w[(g * 8 + j) * CC + c];
    } else if (g == 2) {
      f[0] = (bf16_t)ep_b[c];
    }
    wfr[t] = f;
  }

  const int st = start[n0];
  const int en = start[n0 + 16];
  const int tgt = n0 + l15;

  f32x4v eacc[8] = {};

  for (int cb = st; cb < en; cb += 32) {
    bf16x8 af[2];
#pragma unroll
    for (int mE = 0; mE < 2; ++mE) {
      bf16x8 f = {};
      if (g < 2) {
        f = *(const bf16x8*)(eacsr + (size_t)(cb + mE * 16 + l15) * 16 + g * 8);
      } else if (g == 2) {
        f[0] = (bf16_t)1.0f;
      }
      af[mE] = f;
    }
    int4 idlo = *(const int4*)(nid + cb + g * 4);
    int4 idhi = *(const int4*)(nid + cb + 16 + g * 4);
    bf16x8 sf;
    sf[0] = (idlo.x == tgt) ? (bf16_t)1.0f : (bf16_t)0.0f;
    sf[1] = (idlo.y == tgt) ? (bf16_t)1.0f : (bf16_t)0.0f;
    sf[2] = (idlo.z == tgt) ? (bf16_t)1.0f : (bf16_t)0.0f;
    sf[3] = (idlo.w == tgt) ? (bf16_t)1.0f : (bf16_t)0.0f;
    sf[4] = (idhi.x == tgt) ? (bf16_t)1.0f : (bf16_t)0.0f;
    sf[5] = (idhi.y == tgt) ? (bf16_t)1.0f : (bf16_t)0.0f;
    sf[6] = (idhi.z == tgt) ? (bf16_t)1.0f : (bf16_t)0.0f;
    sf[7] = (idhi.w == tgt) ? (bf16_t)1.0f : (bf16_t)0.0f;
#pragma unroll
    for (int t = 0; t < 8; ++t) {
      f32x4v s0 = {}, s1 = {};
      s0 = __builtin_amdgcn_mfma_f32_16x16x32_bf16(af[0], wfr[t], s0, 0, 0, 0);
      s1 = __builtin_amdgcn_mfma_f32_16x16x32_bf16(af[1], wfr[t], s1, 0, 0, 0);
      union { bf16x8 v; bf16x4 h[2]; } pf;
#pragma unroll
      for (int r = 0; r < 4; ++r) {
        pf.h[0][r] = (bf16_t)fmaxf(s0[r], 0.f);
        pf.h[1][r] = (bf16_t)fmaxf(s1[r], 0.f);
      }
      eacc[t] = __builtin_amdgcn_mfma_f32_16x16x32_bf16(sf, pf.v, eacc[t], 0, 0, 0);
    }
  }
#pragma unroll
  for (int t = 0; t < 8; ++t) {
    int c = cbase + t * 16 + l15;
#pragma unroll
    for (int r = 0; r < 4; ++r) {
      int node = n0 + g * 4 + r;
      float v = eacc[t][r];
      ef[(size_t)node * CC + c] = v;
      efb[(size_t)node * (2 * CC) + CC + c] = (bf16_t)v;
    }
  }
}

// ---------------- bf16 MFMA GEMM (m97 structure) ----------------
__device__ __forceinline__ void gl_lds16(const bf16_t* g, bf16_t* l) {
  __builtin_amdgcn_global_load_lds(
      (const __attribute__((address_space(1))) void*)g,
      (__attribute__((address_space(3))) void*)l, 16, 0, 0);
}

template <int ACT, int OUT>
__global__ __launch_bounds__(256) void gemm_bf16_kernel(
    const bf16_t* __restrict__ A, const bf16_t* __restrict__ Bt,
    const float* __restrict__ bias, void* __restrict__ Cout, int M, int N, int K) {
  __shared__ __align__(16) bf16_t Al[128 * 32];
  __shared__ __align__(16) bf16_t Bl[128 * 32];
  const int tid = threadIdx.x;
  const int lane = tid & 63;
  const int wave = tid >> 6;
  const int row0 = blockIdx.y * 128;
  const int col0 = blockIdx.x * 128;
  const int wm = (wave >> 1) * 64;
  const int wn = (wave & 1) * 64;
  f32x4v acc[4][4] = {};
  const bf16_t* aBase = A + (size_t)(row0 + (tid >> 2)) * K + (tid & 3) * 8;
  const bf16_t* bBase = Bt + (size_t)(col0 + (tid >> 2)) * K + (tid & 3) * 8;
  bf16_t* al0 = Al + wave * 512;
  bf16_t* al1 = Al + 2048 + wave * 512;
  bf16_t* bl0 = Bl + wave * 512;
  bf16_t* bl1 = Bl + 2048 + wave * 512;
  const int fr = lane & 15;
  const int fk = (lane >> 4) * 8;
  for (int k0 = 0; k0 < K; k0 += 32) {
    gl_lds16(aBase + k0, al0);
    gl_lds16(aBase + (size_t)64 * K + k0, al1);
    gl_lds16(bBase + k0, bl0);
    gl_lds16(bBase + (size_t)64 * K + k0, bl1);
    __syncthreads();
    bf16x8 af[4], bfv[4];
#pragma unroll
    for (int m = 0; m < 4; ++m)
      af[m] = *(const bf16x8*)(Al + (wm + m * 16 + fr) * 32 + fk);
#pragma unroll
    for (int n = 0; n < 4; ++n)
      bfv[n] = *(const bf16x8*)(Bl + (wn + n * 16 + fr) * 32 + fk);
#pragma unroll
    for (int m = 0; m < 4; ++m)
#pragma unroll
      for (int n = 0; n < 4; ++n)
        acc[m][n] =
            __builtin_amdgcn_mfma_f32_16x16x32_bf16(af[m], bfv[n], acc[m][n], 0, 0, 0);
    __syncthreads();
  }
  const int fq = (lane >> 4) * 4;
#pragma unroll
  for (int m = 0; m < 4; ++m) {
    int grb = row0 + wm + m * 16 + fq;
#pragma unroll
    for (int n = 0; n < 4; ++n) {
      int gc = col0 + wn + n * 16 + fr;
      float bv = bias ? bias[gc] : 0.f;
#pragma unroll
      for (int r = 0; r < 4; ++r) {
        float v = acc[m][n][r] + bv;
        if (ACT == 1) v = v / (1.f + __expf(-v));
        if (OUT == 0)
          ((float*)Cout)[(size_t)(grb + r) * N + gc] = v;
        else
          ((bf16_t*)Cout)[(size_t)(grb + r) * N + gc] = (bf16_t)v;
      }
    }
  }
}

// ---------------- layernorm fused kernels ----------------

__device__ inline void block_reduce2(float& s, float& q, float* red) {
#pragma unroll
  for (int off = 32; off >= 1; off >>= 1) {
    s += __shfl_xor(s, off, 64);
    q += __shfl_xor(q, off, 64);
  }
  int wid = threadIdx.x >> 6;
  if ((threadIdx.x & 63) == 0) { red[wid * 2] = s; red[wid * 2 + 1] = q; }
  __syncthreads();
  s = red[0] + red[2] + red[4] + red[6];
  q = red[1] + red[3] + red[5] + red[7];
}

__global__ __launch_bounds__(256) void ln_add_kernel(const float* __restrict__ A,
                                                     const float* __restrict__ Bb,
                                                     const float* __restrict__ g,
                                                     const float* __restrict__ be,
                                                     float* __restrict__ out,
                                                     bf16_t* __restrict__ bout) {
  int row = blockIdx.x, tid = threadIdx.x, c0 = tid * 2;
  __shared__ float red[8];
  float2 a = *(const float2*)(A + (size_t)row * CC + c0);
  float2 b = *(const float2*)(Bb + (size_t)row * CC + c0);
  float x0 = a.x + b.x, x1 = a.y + b.y;
  float s = x0 + x1, q = x0 * x0 + x1 * x1;
  block_reduce2(s, q, red);
  float mean = s * (1.f / CC);
  float var = q * (1.f / CC) - mean * mean;
  float rs = rsqrtf(var + 1e-5f);
  float o0 = (x0 - mean) * rs * g[c0] + be[c0];
  float o1 = (x1 - mean) * rs * g[c0 + 1] + be[c0 + 1];
  *(float2*)(out + (size_t)row * CC + c0) = make_float2(o0, o1);
  if (bout) {
    bout[(size_t)row * CC + c0] = (bf16_t)o0;
    bout[(size_t)row * CC + c0 + 1] = (bf16_t)o1;
  }
}

__global__ __launch_bounds__(256) void ln_gate_kernel(
    const float* __restrict__ gpre, const float* __restrict__ gate_b,
    const float* __restrict__ xc, const float* __restrict__ ef,
    const float* __restrict__ n1g, const float* __restrict__ n1b,
    const float* __restrict__ xin, float* __restrict__ x2, bf16_t* __restrict__ x2b) {
  int row = blockIdx.x, tid = threadIdx.x, c0 = tid * 2;
  __shared__ float red[8];
  float2 gp = *(const float2*)(gpre + (size_t)row * CC + c0);
  float2 xcv = *(const float2*)(xc + (size_t)row * CC + c0);
  float2 efv = *(const float2*)(ef + (size_t)row * CC + c0);
  float g0 = 1.f / (1.f + __expf(-(gp.x + gate_b[c0])));
  float g1 = 1.f / (1.f + __expf(-(gp.y + gate_b[c0 + 1])));
  float x0 = g0 * xcv.x + (1.f - g0) * efv.x;
  float x1 = g1 * xcv.y + (1.f - g1) * efv.y;
  float s = x0 + x1, q = x0 * x0 + x1 * x1;
  block_reduce2(s, q, red);
  float mean = s * (1.f / CC);
  float var = q * (1.f / CC) - mean * mean;
  float rs = rsqrtf(var + 1e-5f);
  float2 xi = *(const float2*)(xin + (size_t)row * CC + c0);
  float o0 = fmaxf((x0 - mean) * rs * n1g[c0] + n1b[c0], 0.f) + xi.x;
  float o1 = fmaxf((x1 - mean) * rs * n1g[c0 + 1] + n1b[c0 + 1], 0.f) + xi.y;
  *(float2*)(x2 + (size_t)row * CC + c0) = make_float2(o0, o1);
  x2b[(size_t)row * CC + c0] = (bf16_t)o0;
  x2b[(size_t)row * CC + c0 + 1] = (bf16_t)o1;
}

// ---------------- V^T pack (pre-swizzled + pi-permuted K for attn) ---------
__global__ __launch_bounds__(256) void vt_pack_kernel(const bf16_t* __restrict__ qkvb,
                                                      bf16_t* __restrict__ vt) {
  int b = blockIdx.x >> 3, h = blockIdx.x & 7;
  int nb = b * 256;
  size_t voff = 1024 + (size_t)h * 64;
  char* out = (char*)(vt + (size_t)blockIdx.x * (64 * 256));
  __shared__ bf16_t tile[64][80];
  int tid = threadIdx.x;
  for (int kb = 0; kb < 4; ++kb) {
    __syncthreads();
#pragma unroll
    for (int p = 0; p < 2; ++p) {
      int k = p * 32 + (tid >> 3);
      int d8 = tid & 7;
      bf16x8 v = *(const bf16x8*)(qkvb + (size_t)(nb + kb * 64 + k) * 1536 + voff + d8 * 8);
      *(bf16x8*)(&tile[k][d8 * 8]) = v;
    }
    __syncthreads();
#pragma unroll
    for (int p = 0; p < 2; ++p) {
      int d = p * 32 + (tid >> 3);
      int k8 = tid & 7;
      bf16x8 v;
#pragma unroll
      for (int j = 0; j < 8; ++j) {
        int pos = k8 * 8 + j;
        int sl = pos & 31;
        int srck = (pos & 32) + ((sl >> 3) << 2) + (sl & 3) + (((sl >> 2) & 1) << 4);
        v[j] = tile[srck][d];
      }
      int byteoff = d * 512 + ((kb * 128 + k8 * 16) ^ ((d & 7) << 4));
      *(bf16x8*)(out + byteoff) = v;
    }
  }
}

// ---------------- MFMA attention (shuffle-free PV) ----------------
__global__ __launch_bounds__(256, 2) void attn_mfma_kernel(
    const bf16_t* __restrict__ qkvb, const bf16_t* __restrict__ vt,
    bf16_t* __restrict__ o) {
  const int b = blockIdx.x >> 3;
  const int h = blockIdx.x & 7;
  const int nb = b * 256;
  const int tid = threadIdx.x;
  const int lane = tid & 63;
  const int wv = tid >> 6;
  const int l15 = lane & 15;
  const int g = lane >> 4;
  const int swzk = (l15 & 7) << 4;
  __shared__ __align__(16) bf16_t Klds[256 * 64];
  __shared__ __align__(16) bf16_t Vtlds[64 * 256];
  const size_t qoff = (size_t)h * 64;
  const size_t koff = 512 + (size_t)h * 64;

  {
    const int dcol = 16 * ((tid & 7) ^ ((tid >> 3) & 7));
    const bf16_t* srcb = qkvb + koff + (dcol >> 1);
#pragma unroll
    for (int i = 0; i < 8; ++i) {
      int k = i * 32 + (tid >> 3);
      gl_lds16(srcb + (size_t)(nb + k) * 1536, Klds + ((i * 4096 + wv * 1024) >> 1));
    }
  }
  {
    const bf16_t* vsrc = vt + (size_t)blockIdx.x * (64 * 256);
#pragma unroll
    for (int i = 0; i < 8; ++i) {
      int base = i * 4096 + wv * 1024;
      gl_lds16(vsrc + ((base >> 1) + lane * 8), Vtlds + (base >> 1));
    }
  }

  bf16x8 qf[4][2];
#pragma unroll
  for (int n = 0; n < 4; ++n) {
    const bf16_t* qp = qkvb + (size_t)(nb + wv * 64 + 16 * n + l15) * 1536 + qoff + g * 8;
    qf[n][0] = *(const bf16x8*)(qp);
    qf[n][1] = *(const bf16x8*)(qp + 32);
  }

  __syncthreads();

  f32x4v oacc[4][4] = {};
  float mrun[4] = {-1e30f, -1e30f, -1e30f, -1e30f};
  float lrun[4] = {0.f, 0.f, 0.f, 0.f};

  for (int kc = 0; kc < 4; ++kc) {
    f32x4v sacc[4][4] = {};
    const int kb128 = (kc * 64 + l15) * 128;
#pragma unroll
    for (int m = 0; m < 4; ++m) {
      bf16x8 a0 = *(const bf16x8*)(Klds + ((kb128 + m * 2048 + ((g * 16) ^ swzk)) >> 1));
      bf16x8 a1 =
          *(const bf16x8*)(Klds + ((kb128 + m * 2048 + ((64 + g * 16) ^ swzk)) >> 1));
#pragma unroll
      for (int n = 0; n < 4; ++n) {
        sacc[m][n] = __builtin_amdgcn_mfma_f32_16x16x32_bf16(a0, qf[n][0], sacc[m][n], 0, 0, 0);
        sacc[m][n] = __builtin_amdgcn_mfma_f32_16x16x32_bf16(a1, qf[n][1], sacc[m][n], 0, 0, 0);
      }
    }
    uint2 pb[4][4];
#pragma unroll
    for (int n = 0; n < 4; ++n) {
      float mx = sacc[0][n][0];
#pragma unroll
      for (int m = 0; m < 4; ++m)
#pragma unroll
        for (int r = 0; r < 4; ++r) mx = fmaxf(mx, sacc[m][n][r]);
      mx = fmaxf(mx, __shfl_xor(mx, 16));
      mx = fmaxf(mx, __shfl_xor(mx, 32));
      float mnew = fmaxf(mrun[n], mx);
      float c = __expf((mrun[n] - mnew) * 0.125f);
      mrun[n] = mnew;
      float s = 0.f;
#pragma unroll
      for (int m = 0; m < 4; ++m) {
        float p0 = __expf((sacc[m][n][0] - mnew) * 0.125f);
        float p1 = __expf((sacc[m][n][1] - mnew) * 0.125f);
        float p2 = __expf((sacc[m][n][2] - mnew) * 0.125f);
        float p3 = __expf((sacc[m][n][3] - mnew) * 0.125f);
        s += (p0 + p1) + (p2 + p3);
        union { bf16x4 v; uint2 u; } cv;
        cv.v[0] = (bf16_t)p0; cv.v[1] = (bf16_t)p1;
        cv.v[2] = (bf16_t)p2; cv.v[3] = (bf16_t)p3;
        pb[m][n] = cv.u;
      }
      s += __shfl_xor(s, 16);
      s += __shfl_xor(s, 32);
      lrun[n] = lrun[n] * c + s;
#pragma unroll
      for (int m = 0; m < 4; ++m)
#pragma unroll
        for (int r = 0; r < 4; ++r) oacc[m][n][r] *= c;
    }
#pragma unroll
    for (int h2 = 0; h2 < 2; ++h2) {
      bf16x8 vf[4];
#pragma unroll
      for (int m = 0; m < 4; ++m)
        vf[m] = *(const bf16x8*)(Vtlds + (((16 * m + l15) * 512 +
                                          ((kc * 128 + h2 * 64 + g * 16) ^ swzk)) >> 1));
#pragma unroll
      for (int n = 0; n < 4; ++n) {
        union { uint2 u[2]; bf16x8 v; } pf;
        pf.u[0] = pb[2 * h2][n];
        pf.u[1] = pb[2 * h2 + 1][n];
#pragma unroll
        for (int m = 0; m < 4; ++m)
          oacc[m][n] =
              __builtin_amdgcn_mfma_f32_16x16x32_bf16(vf[m], pf.v, oacc[m][n], 0, 0, 0);
      }
    }
  }
  float inv[4];
#pragma unroll
  for (int n = 0; n < 4; ++n) inv[n] = 1.0f / lrun[n];
#pragma unroll
  for (int m = 0; m < 4; ++m)
#pragma unroll
    for (int n = 0; n < 4; ++n) {
      bf16x4 pk;
#pragma unroll
      for (int r = 0; r < 4; ++r) pk[r] = (bf16_t)(oacc[m][n][r] * inv[n]);
      *(bf16x4*)(o + (size_t)(nb + wv * 64 + 16 * n + l15) * 512 + h * 64 + 16 * m +
                 4 * g) = pk;
    }
}

// ---------------- launch ----------------

static inline char* alignp(char* p, size_t a) {
  return (char*)(((uintptr_t)p + a - 1) & ~(uintptr_t)(a - 1));
}

extern "C" void kernel_launch(void* const* d_in, const int* in_sizes, int n_in,
                              void* d_out, int out_size, void* d_ws, size_t ws_size,
                              hipStream_t stream) {
  const float* x = (const float*)d_in[0];
  const float* edge_attr = (const float*)d_in[1];
  const float* gcn_w = (const float*)d_in[2];
  const float* gcn_b = (const float*)d_in[3];
  const float* ep_w = (const float*)d_in[4];
  const float* ep_b = (const float*)d_in[5];
  const float* gate_w = (const float*)d_in[6];
  const float* gate_b = (const float*)d_in[7];
  const float* n1_g = (const float*)d_in[8];
  const float* n1_b = (const float*)d_in[9];
  const float* in_w = (const float*)d_in[10];
  const float* in_b = (const float*)d_in[11];
  const float* out_w = (const float*)d_in[12];
  const float* out_b = (const float*)d_in[13];
  const float* tn_g = (const float*)d_in[14];
  const float* tn_b = (const float*)d_in[15];
  const float* m_w1 = (const float*)d_in[16];
  const float* m_b1 = (const float*)d_in[17];
  const float* m_w2 = (const float*)d_in[18];
  const float* m_b2 = (const float*)d_in[19];
  const float* fn_g = (const float*)d_in[20];
  const float* fn_b = (const float*)d_in[21];
  const int* eidx = (const int*)d_in[22];
  const int* src = eidx;
  const int* dst = eidx + EE;

  float* ws = (float*)d_ws;
  float* R1 = ws;
  float* R2 = R1 + (size_t)NN * 3 * CC;
  float* R3 = R2 + (size_t)NN * CC;
  float* R4 = R3 + (size_t)NN * CC;
  float* ew = R4 + (size_t)NN * CC;
  float* dinv = ew + EE;
  int* ip = (int*)(dinv + NN);
  int* ghist = ip;      ip += 64;
  int* gstart = ip;     ip += 65;
  int* gcur = ip;       ip += 64;
  int* glist = ip;      ip += EE;
  int* elist_src = ip;  ip += EE;
  int* nid_src = ip;    ip += EE + 32;
  int* start_src = ip;  ip += NN + 1;
  int* start_dst = ip;  ip += NN + 1;
  char* bp = alignp((char*)ip, 64);
  float2* dstrec = (float2*)bp;       bp += (size_t)EE * 8;
  bf16_t* x2b = (bf16_t*)bp;          bp += (size_t)NN * CC * 2;
  bf16_t* gcn_wt = (bf16_t*)bp;       bp += (size_t)CC * CC * 2;
  bf16_t* gate_wt = (bf16_t*)bp;      bp += (size_t)CC * 2 * CC * 2;
  bf16_t* in_wt = (bf16_t*)bp;        bp += (size_t)3 * CC * CC * 2;
  bf16_t* out_wt = (bf16_t*)bp;       bp += (size_t)CC * CC * 2;
  bf16_t* m_w1t = (bf16_t*)bp;        bp += (size_t)2 * CC * CC * 2;
  bf16_t* m_w2t = (bf16_t*)bp;        bp += (size_t)CC * 2 * CC * 2;

  bf16_t* xb = (bf16_t*)R1;      // bf16(x)
  bf16_t* xcefb = (bf16_t*)R1;   // [x_conv | ef] bf16 N x 2C
  bf16_t* qkvb = (bf16_t*)R1;    // qkv bf16 N x 1536 (first 48MB of R1)
  bf16_t* hb = (bf16_t*)R1;      // mlp hidden bf16 N x 2C
  bf16_t* eacsr = (bf16_t*)((char*)R1 + (size_t)64 * 1024 * 1024);  // 16.8MB at R1+64MB
  bf16_t* xwb = (bf16_t*)R2;     // bf16 xw (GCN GEMM out)
  bf16_t* ob = (bf16_t*)R2;      // attn out bf16 (first half of R2)
  bf16_t* vt = ob + (size_t)NN * CC;  // V^T packed (second half of R2)
  bf16_t* x3b = (bf16_t*)R2;     // bf16(x3) (after ob dead)
  float* x2 = (float*)d_out;

  // --- edge prep: two-level counting sort; deg folded into the sort ---
  init_kernel<<<1, 256, 0, stream>>>(ghist, nid_src, eacsr);
  edge_pass1<<<EE / 256, 256, 0, stream>>>(edge_attr, dst, ew, ghist);
  gexscan_kernel<<<1, 64, 0, stream>>>(ghist, gstart, gcur);
  graph_scatter_kernel<<<EE / 2048, 256, 0, stream>>>(dst, gcur, glist);
  graph_sort_kernel<<<BB, 1024, 0, stream>>>(glist, gstart, src, dst, ew, elist_src,
                                             nid_src, start_src, dstrec, start_dst,
                                             dinv);
  ea_gather_kernel<<<(EE * 2 + 255) / 256, 256, 0, stream>>>(edge_attr, elist_src,
                                                             eacsr);

  // --- weight transposes ---
  wt_kernel<<<dim3(CC / 32, CC / 32), 256, 0, stream>>>(gcn_w, gcn_wt, CC, CC);
  wt_kernel<<<dim3(CC / 32, 2 * CC / 32), 256, 0, stream>>>(gate_w, gate_wt, 2 * CC, CC);
  wt_kernel<<<dim3(3 * CC / 32, CC / 32), 256, 0, stream>>>(in_w, in_wt, CC, 3 * CC);
  wt_kernel<<<dim3(CC / 32, CC / 32), 256, 0, stream>>>(out_w, out_wt, CC, CC);
  wt_kernel<<<dim3(2 * CC / 32, CC / 32), 256, 0, stream>>>(m_w1, m_w1t, CC, 2 * CC);
  wt_kernel<<<dim3(CC / 32, 2 * CC / 32), 256, 0, stream>>>(m_w2, m_w2t, 2 * CC, CC);

  // --- GCN conv ---
  cvt_bf16_kernel<<<(NN * CC / 4 + 255) / 256, 256, 0, stream>>>(x, xb, NN * CC / 4);
  dim3 gA(CC / 128, NN / 128);
  gemm_bf16_kernel<0, 1><<<gA, 256, 0, stream>>>(xb, gcn_wt, nullptr, xwb, NN, CC, CC);
  xconv_kernel<<<NN, 256, 0, stream>>>(xwb, dinv, dstrec, start_dst, gcn_b, R3, xcefb);
  ef_mfma_kernel<<<NN / 16, 256, 0, stream>>>(eacsr, ep_w, ep_b, nid_src, start_src,
                                              R4, xcefb);
  gemm_bf16_kernel<0, 0><<<gA, 256, 0, stream>>>(xcefb, gate_wt, nullptr, R2, NN, CC,
                                                 2 * CC);
  ln_gate_kernel<<<NN, 256, 0, stream>>>(R2, gate_b, R3, R4, n1_g, n1_b, x, x2, x2b);

  // --- MHA ---
  dim3 gQ(3 * CC / 128, NN / 128);
  gemm_bf16_kernel<0, 1><<<gQ, 256, 0, stream>>>(x2b, in_wt, in_b, qkvb, NN, 3 * CC, CC);
  vt_pack_kernel<<<BB * HH, 256, 0, stream>>>(qkvb, vt);
  attn_mfma_kernel<<<BB * HH, 256, 0, stream>>>(qkvb, vt, ob);
  gemm_bf16_kernel<0, 0><<<gA, 256, 0, stream>>>(ob, out_wt, out_b, R4, NN, CC, CC);
  ln_add_kernel<<<NN, 256, 0, stream>>>(x2, R4, tn_g, tn_b, R3, x3b);

  // --- MLP ---
  dim3 gH(2 * CC / 128, NN / 128);
  gemm_bf16_kernel<1, 1><<<gH, 256, 0, stream>>>(x3b, m_w1t, m_b1, hb, NN, 2 * CC, CC);
  gemm_bf16_kernel<0, 0><<<gA, 256, 0, stream>>>(hb, m_w2t, m_b2, R4, NN, CC, 2 * CC);
  ln_add_kernel<<<NN, 256, 0, stream>>>(R3, R4, fn_g, fn_b, (float*)d_out, nullptr);
}

// Round 10
// 528.963 us; speedup vs baseline: 1.5250x; 1.0766x over previous
//
#include <hip/hip_runtime.h>

#define NN 16384
#define CC 512
#define EE 524288
#define BB 64
#define HH 8
#define EFD 16
#define GEMAXE 10240

typedef __bf16 bf16_t;
typedef __bf16 bf16x4 __attribute__((ext_vector_type(4)));
typedef __bf16 bf16x8 __attribute__((ext_vector_type(8)));
typedef float f32x4v __attribute__((ext_vector_type(4)));

// ---------------- init / edge pre-pass ----------------

__global__ void init_kernel(int* ghist, int* nid_src, bf16_t* eacsr) {
  int i = threadIdx.x;
  if (i < 64) ghist[i] = 0;
  if (i < 32) nid_src[EE + i] = -1;               // pad for ef chunk tail
  ((int*)(eacsr + (size_t)EE * 16))[i] = 0;       // zero eacsr pad rows (256 ints)
}

// ew + per-graph histogram (LDS-aggregated). NO scattered atomics.
__global__ __launch_bounds__(256) void edge_pass1(const float* __restrict__ ea,
                                                  const int* __restrict__ dst,
                                                  float* __restrict__ ew, int* ghist) {
  __shared__ int h[64];
  int tid = threadIdx.x;
  if (tid < 64) h[tid] = 0;
  __syncthreads();
  int e = blockIdx.x * 256 + tid;  // EE % 256 == 0
  const float4* p = (const float4*)(ea + (size_t)e * EFD);
  float s = 0.f;
#pragma unroll
  for (int i = 0; i < 4; ++i) {
    float4 v = p[i];
    s += v.x * v.x + v.y * v.y + v.z * v.z + v.w * v.w;
  }
  ew[e] = sqrtf(s);
  atomicAdd(&h[dst[e] >> 8], 1);
  __syncthreads();
  if (tid < 64 && h[tid]) atomicAdd(&ghist[tid], h[tid]);
}

__global__ void gexscan_kernel(const int* __restrict__ ghist, int* __restrict__ gstart,
                               int* __restrict__ gcur) {
  if (threadIdx.x == 0) {
    int s = 0;
    for (int g = 0; g < 64; ++g) { gstart[g] = s; gcur[g] = s; s += ghist[g]; }
    gstart[64] = s;
  }
}

// bucket edges by graph with block-aggregated offsets; emit packed records
// grec = {e | ls<<19, ld} and f32 ewg so the sort never random-gathers.
__global__ __launch_bounds__(256) void graph_scatter_kernel(
    const int* __restrict__ src, const int* __restrict__ dst,
    const float* __restrict__ ew, int* gcur, int2* __restrict__ grec,
    float* __restrict__ ewg) {
  __shared__ int h[64], base[64], h2[64];
  int tid = threadIdx.x;
  if (tid < 64) { h[tid] = 0; h2[tid] = 0; }
  __syncthreads();
  int e0 = blockIdx.x * 2048;
  int gloc[8];
#pragma unroll
  for (int k = 0; k < 8; ++k) {
    gloc[k] = dst[e0 + k * 256 + tid] >> 8;
    atomicAdd(&h[gloc[k]], 1);
  }
  __syncthreads();
  if (tid < 64) base[tid] = h[tid] ? atomicAdd(&gcur[tid], h[tid]) : 0;
  __syncthreads();
#pragma unroll
  for (int k = 0; k < 8; ++k) {
    int e = e0 + k * 256 + tid;
    int g = gloc[k];
    int p = atomicAdd(&h2[g], 1);
    int pos = base[g] + p;
    int ls = src[e] & 255;
    int ld = dst[e] & 255;
    grec[pos] = make_int2(e | (ls << 19), ld);
    ewg[pos] = ew[e];
  }
}

// per-graph LDS counting sort, 128 blocks: blockIdx<64 -> DST pass (dstrec,
// start_dst, dinv), else SRC pass (elist_src, nid_src, start_src).
__global__ __launch_bounds__(1024) void graph_sort2_kernel(
    const int2* __restrict__ grec, const float* __restrict__ ewg,
    const int* __restrict__ gstart, int* __restrict__ elist_src,
    int* __restrict__ nid_src, int* __restrict__ start_src,
    float2* __restrict__ dstrec, int* __restrict__ start_dst,
    float* __restrict__ dinv) {
  __shared__ int lbuf[GEMAXE];
  __shared__ unsigned short sl[GEMAXE];  // DST: ls | ld<<8
  __shared__ float ewl[GEMAXE];          // DST: f32 ew ; SRC: int scratch
  __shared__ int h[256], hx[256], h2[256];
  __shared__ float fdinv[256];
  const int g = blockIdx.x & 63;
  const int tid = threadIdx.x;
  const int gs = gstart[g];
  const int cnt = gstart[g + 1] - gs;
  if (tid < 256) { h[tid] = 0; h2[tid] = 0; }
  __syncthreads();
  if (blockIdx.x < 64) {
    // ---------------- DST pass ----------------
    for (int i = tid; i < cnt; i += 1024) {
      int2 r = grec[gs + i];
      int ld = r.y;
      sl[i] = (unsigned short)(((r.x >> 19) & 255) | (ld << 8));
      ewl[i] = ewg[gs + i];
      atomicAdd(&h[ld], 1);
    }
    __syncthreads();
    int myc = (tid < 256) ? h[tid] : 0;
    for (int off = 1; off < 256; off <<= 1) {
      int v = (tid < 256 && tid >= off) ? h[tid - off] : 0;
      __syncthreads();
      if (tid < 256) h[tid] += v;
      __syncthreads();
    }
    if (tid < 256) {
      hx[tid] = h[tid] - myc;
      start_dst[g * 256 + tid] = gs + hx[tid];
    }
    if (g == 63 && tid == 0) start_dst[NN] = EE;
    __syncthreads();
    for (int i = tid; i < cnt; i += 1024) {
      int ld = sl[i] >> 8;
      int p = hx[ld] + atomicAdd(&h2[ld], 1);
      lbuf[p] = i;
    }
    __syncthreads();
    if (tid < 256) {
      float dg = 1.0f;
      int s0 = hx[tid], e0 = s0 + myc;
      for (int i = s0; i < e0; ++i) dg += ewl[lbuf[i]];
      float dv = rsqrtf(fmaxf(dg, 1e-12f));
      fdinv[tid] = dv;
      dinv[g * 256 + tid] = dv;
    }
    __syncthreads();
    for (int p = tid; p < cnt; p += 1024) {
      int i = lbuf[p];
      int ls = sl[i] & 255;
      dstrec[gs + p] = make_float2(fdinv[ls] * ewl[i], __int_as_float(g * 256 + ls));
    }
  } else {
    // ---------------- SRC pass ----------------
    int* wb = (int*)ewl;
    for (int i = tid; i < cnt; i += 1024) {
      int w = grec[gs + i].x;  // (ls<<19) | e
      wb[i] = w;
      atomicAdd(&h[w >> 19], 1);
    }
    __syncthreads();
    int myc = (tid < 256) ? h[tid] : 0;
    for (int off = 1; off < 256; off <<= 1) {
      int v = (tid < 256 && tid >= off) ? h[tid - off] : 0;
      __syncthreads();
      if (tid < 256) h[tid] += v;
      __syncthreads();
    }
    if (tid < 256) {
      hx[tid] = h[tid] - myc;
      start_src[g * 256 + tid] = gs + hx[tid];
    }
    if (g == 63 && tid == 0) start_src[NN] = EE;
    __syncthreads();
    for (int i = tid; i < cnt; i += 1024) {
      int w = wb[i];
      int ls = w >> 19;
      int p = hx[ls] + atomicAdd(&h2[ls], 1);
      lbuf[p] = w;
    }
    __syncthreads();
    for (int p = tid; p < cnt; p += 1024) {
      int w = lbuf[p];
      elist_src[gs + p] = w & 0x7FFFF;
      nid_src[gs + p] = g * 256 + (w >> 19);
    }
  }
}

// gather edge_attr rows into CSR order as bf16
__global__ void ea_gather_kernel(const float* __restrict__ ea,
                                 const int* __restrict__ elist,
                                 bf16_t* __restrict__ eacsr) {
  int idx = blockIdx.x * 256 + threadIdx.x;
  if (idx >= EE * 2) return;
  int pos = idx >> 1, half = idx & 1;
  int e = elist[pos];
  const f32x4v* p = (const f32x4v*)(ea + (size_t)e * EFD + half * 8);
  f32x4v u0 = p[0], u1 = p[1];
  bf16x8 f;
#pragma unroll
  for (int r = 0; r < 4; ++r) {
    f[r] = (bf16_t)u0[r];
    f[4 + r] = (bf16_t)u1[r];
  }
  *(bf16x8*)(eacsr + (size_t)pos * 16 + half * 8) = f;
}

// ---------------- conversions ----------------

__global__ void cvt_bf16_kernel(const float* __restrict__ in, bf16_t* __restrict__ out,
                                int n4) {
  int i = blockIdx.x * 256 + threadIdx.x;
  if (i >= n4) return;
  float4 v = ((const float4*)in)[i];
  bf16x4 o;
  o[0] = (bf16_t)v.x; o[1] = (bf16_t)v.y; o[2] = (bf16_t)v.z; o[3] = (bf16_t)v.w;
  ((bf16x4*)out)[i] = o;
}

// W: f32 [K][N] row-major -> Wt: bf16 [N][K] row-major
__global__ __launch_bounds__(256) void wt_kernel(const float* __restrict__ W,
                                                 bf16_t* __restrict__ Wt, int K, int N) {
  __shared__ float tile[32][33];
  int bx = blockIdx.x * 32;
  int by = blockIdx.y * 32;
  int tx = threadIdx.x & 31, ty = threadIdx.x >> 5;
#pragma unroll
  for (int i = 0; i < 32; i += 8)
    tile[ty + i][tx] = W[(size_t)(by + ty + i) * N + bx + tx];
  __syncthreads();
#pragma unroll
  for (int i = 0; i < 32; i += 8)
    Wt[(size_t)(bx + ty + i) * K + by + tx] = (bf16_t)tile[tx][ty + i];
}

// ---------------- GCN conv gather (CSR by dst, packed records) -------------
__global__ __launch_bounds__(256) void xconv_kernel(
    const bf16_t* __restrict__ xwb, const float* __restrict__ dinv,
    const float2* __restrict__ dstrec, const int* __restrict__ start,
    const float* __restrict__ gcn_b, float* __restrict__ xconv,
    bf16_t* __restrict__ xcb) {
  int i = blockIdx.x;
  int tid = threadIdx.x;
  int st = start[i], en = start[i + 1];
  float di = dinv[i];
  int c0 = tid * 2;
  __shared__ float2 scS[256];  // {coef (incl di), as_float(src_node)}
  union { unsigned u; struct { unsigned short lo, hi; } s; } pk;
  pk.u = *(const unsigned*)(xwb + (size_t)i * CC + c0);
  union { unsigned short us; bf16_t b; } c0v, c1v;
  c0v.us = pk.s.lo; c1v.us = pk.s.hi;
  float sc = di * di;
  float a0 = sc * (float)c0v.b + gcn_b[c0];
  float a1 = sc * (float)c1v.b + gcn_b[c0 + 1];
  for (int p0 = st; p0 < en; p0 += 256) {
    int m = min(256, en - p0);
    __syncthreads();
    if (tid < m) {
      float2 r = dstrec[p0 + tid];
      scS[tid] = make_float2(r.x * di, r.y);
    }
    __syncthreads();
    for (int j = 0; j < m; ++j) {
      float2 scv = scS[j];
      int sn = __float_as_int(scv.y);
      union { unsigned u; struct { unsigned short lo, hi; } s; } q;
      q.u = *(const unsigned*)(xwb + (size_t)sn * CC + c0);
      union { unsigned short us; bf16_t b; } v0, v1;
      v0.us = q.s.lo; v1.us = q.s.hi;
      a0 += scv.x * (float)v0.b;
      a1 += scv.x * (float)v1.b;
    }
  }
  *(float2*)(xconv + (size_t)i * CC + c0) = make_float2(a0, a1);
  xcb[(size_t)i * (2 * CC) + c0] = (bf16_t)a0;
  xcb[(size_t)i * (2 * CC) + c0 + 1] = (bf16_t)a1;
}

// ---------------- edge projection via double-MFMA v3 ----------------
__global__ __launch_bounds__(256) void ef_mfma_kernel(
    const bf16_t* __restrict__ eacsr, const float* __restrict__ ep_w,
    const float* __restrict__ ep_b, const int* __restrict__ nid,
    const int* __restrict__ start, float* __restrict__ ef, bf16_t* __restrict__ efb) {
  const int tid = threadIdx.x;
  const int lane = tid & 63;
  const int wv = tid >> 6;
  const int l15 = lane & 15;
  const int g = lane >> 4;
  const int n0 = blockIdx.x * 16;
  const int cbase = wv * 128;

  bf16x8 wfr[8];
#pragma unroll
  for (int t = 0; t < 8; ++t) {
    bf16x8 f = {};
    int c = cbase + t * 16 + l15;
    if (g < 2) {
#pragma unroll
      for (int j = 0; j < 8; ++j) f[j] = (bf16_t)ep_w[(g * 8 + j) * CC + c];
    } else if (g == 2) {
      f[0] = (bf16_t)ep_b[c];
    }
    wfr[t] = f;
  }

  const int st = start[n0];
  const int en = start[n0 + 16];
  const int tgt = n0 + l15;

  f32x4v eacc[8] = {};

  for (int cb = st; cb < en; cb += 32) {
    bf16x8 af[2];
#pragma unroll
    for (int mE = 0; mE < 2; ++mE) {
      bf16x8 f = {};
      if (g < 2) {
        f = *(const bf16x8*)(eacsr + (size_t)(cb + mE * 16 + l15) * 16 + g * 8);
      } else if (g == 2) {
        f[0] = (bf16_t)1.0f;
      }
      af[mE] = f;
    }
    int4 idlo = *(const int4*)(nid + cb + g * 4);
    int4 idhi = *(const int4*)(nid + cb + 16 + g * 4);
    bf16x8 sf;
    sf[0] = (idlo.x == tgt) ? (bf16_t)1.0f : (bf16_t)0.0f;
    sf[1] = (idlo.y == tgt) ? (bf16_t)1.0f : (bf16_t)0.0f;
    sf[2] = (idlo.z == tgt) ? (bf16_t)1.0f : (bf16_t)0.0f;
    sf[3] = (idlo.w == tgt) ? (bf16_t)1.0f : (bf16_t)0.0f;
    sf[4] = (idhi.x == tgt) ? (bf16_t)1.0f : (bf16_t)0.0f;
    sf[5] = (idhi.y == tgt) ? (bf16_t)1.0f : (bf16_t)0.0f;
    sf[6] = (idhi.z == tgt) ? (bf16_t)1.0f : (bf16_t)0.0f;
    sf[7] = (idhi.w == tgt) ? (bf16_t)1.0f : (bf16_t)0.0f;
#pragma unroll
    for (int t = 0; t < 8; ++t) {
      f32x4v s0 = {}, s1 = {};
      s0 = __builtin_amdgcn_mfma_f32_16x16x32_bf16(af[0], wfr[t], s0, 0, 0, 0);
      s1 = __builtin_amdgcn_mfma_f32_16x16x32_bf16(af[1], wfr[t], s1, 0, 0, 0);
      union { bf16x8 v; bf16x4 h[2]; } pf;
#pragma unroll
      for (int r = 0; r < 4; ++r) {
        pf.h[0][r] = (bf16_t)fmaxf(s0[r], 0.f);
        pf.h[1][r] = (bf16_t)fmaxf(s1[r], 0.f);
      }
      eacc[t] = __builtin_amdgcn_mfma_f32_16x16x32_bf16(sf, pf.v, eacc[t], 0, 0, 0);
    }
  }
#pragma unroll
  for (int t = 0; t < 8; ++t) {
    int c = cbase + t * 16 + l15;
#pragma unroll
    for (int r = 0; r < 4; ++r) {
      int node = n0 + g * 4 + r;
      float v = eacc[t][r];
      ef[(size_t)node * CC + c] = v;
      efb[(size_t)node * (2 * CC) + CC + c] = (bf16_t)v;
    }
  }
}

// ---------------- bf16 MFMA GEMM (m97 structure) ----------------
__device__ __forceinline__ void gl_lds16(const bf16_t* g, bf16_t* l) {
  __builtin_amdgcn_global_load_lds(
      (const __attribute__((address_space(1))) void*)g,
      (__attribute__((address_space(3))) void*)l, 16, 0, 0);
}

template <int ACT, int OUT>
__global__ __launch_bounds__(256) void gemm_bf16_kernel(
    const bf16_t* __restrict__ A, const bf16_t* __restrict__ Bt,
    const float* __restrict__ bias, void* __restrict__ Cout, int M, int N, int K) {
  __shared__ __align__(16) bf16_t Al[128 * 32];
  __shared__ __align__(16) bf16_t Bl[128 * 32];
  const int tid = threadIdx.x;
  const int lane = tid & 63;
  const int wave = tid >> 6;
  const int row0 = blockIdx.y * 128;
  const int col0 = blockIdx.x * 128;
  const int wm = (wave >> 1) * 64;
  const int wn = (wave & 1) * 64;
  f32x4v acc[4][4] = {};
  const bf16_t* aBase = A + (size_t)(row0 + (tid >> 2)) * K + (tid & 3) * 8;
  const bf16_t* bBase = Bt + (size_t)(col0 + (tid >> 2)) * K + (tid & 3) * 8;
  bf16_t* al0 = Al + wave * 512;
  bf16_t* al1 = Al + 2048 + wave * 512;
  bf16_t* bl0 = Bl + wave * 512;
  bf16_t* bl1 = Bl + 2048 + wave * 512;
  const int fr = lane & 15;
  const int fk = (lane >> 4) * 8;
  for (int k0 = 0; k0 < K; k0 += 32) {
    gl_lds16(aBase + k0, al0);
    gl_lds16(aBase + (size_t)64 * K + k0, al1);
    gl_lds16(bBase + k0, bl0);
    gl_lds16(bBase + (size_t)64 * K + k0, bl1);
    __syncthreads();
    bf16x8 af[4], bfv[4];
#pragma unroll
    for (int m = 0; m < 4; ++m)
      af[m] = *(const bf16x8*)(Al + (wm + m * 16 + fr) * 32 + fk);
#pragma unroll
    for (int n = 0; n < 4; ++n)
      bfv[n] = *(const bf16x8*)(Bl + (wn + n * 16 + fr) * 32 + fk);
#pragma unroll
    for (int m = 0; m < 4; ++m)
#pragma unroll
      for (int n = 0; n < 4; ++n)
        acc[m][n] =
            __builtin_amdgcn_mfma_f32_16x16x32_bf16(af[m], bfv[n], acc[m][n], 0, 0, 0);
    __syncthreads();
  }
  const int fq = (lane >> 4) * 4;
#pragma unroll
  for (int m = 0; m < 4; ++m) {
    int grb = row0 + wm + m * 16 + fq;
#pragma unroll
    for (int n = 0; n < 4; ++n) {
      int gc = col0 + wn + n * 16 + fr;
      float bv = bias ? bias[gc] : 0.f;
#pragma unroll
      for (int r = 0; r < 4; ++r) {
        float v = acc[m][n][r] + bv;
        if (ACT == 1) v = v / (1.f + __expf(-v));
        if (OUT == 0)
          ((float*)Cout)[(size_t)(grb + r) * N + gc] = v;
        else
          ((bf16_t*)Cout)[(size_t)(grb + r) * N + gc] = (bf16_t)v;
      }
    }
  }
}

// ---------------- layernorm fused kernels ----------------

__device__ inline void block_reduce2(float& s, float& q, float* red) {
#pragma unroll
  for (int off = 32; off >= 1; off >>= 1) {
    s += __shfl_xor(s, off, 64);
    q += __shfl_xor(q, off, 64);
  }
  int wid = threadIdx.x >> 6;
  if ((threadIdx.x & 63) == 0) { red[wid * 2] = s; red[wid * 2 + 1] = q; }
  __syncthreads();
  s = red[0] + red[2] + red[4] + red[6];
  q = red[1] + red[3] + red[5] + red[7];
}

__global__ __launch_bounds__(256) void ln_add_kernel(const float* __restrict__ A,
                                                     const float* __restrict__ Bb,
                                                     const float* __restrict__ g,
                                                     const float* __restrict__ be,
                                                     float* __restrict__ out,
                                                     bf16_t* __restrict__ bout) {
  int row = blockIdx.x, tid = threadIdx.x, c0 = tid * 2;
  __shared__ float red[8];
  float2 a = *(const float2*)(A + (size_t)row * CC + c0);
  float2 b = *(const float2*)(Bb + (size_t)row * CC + c0);
  float x0 = a.x + b.x, x1 = a.y + b.y;
  float s = x0 + x1, q = x0 * x0 + x1 * x1;
  block_reduce2(s, q, red);
  float mean = s * (1.f / CC);
  float var = q * (1.f / CC) - mean * mean;
  float rs = rsqrtf(var + 1e-5f);
  float o0 = (x0 - mean) * rs * g[c0] + be[c0];
  float o1 = (x1 - mean) * rs * g[c0 + 1] + be[c0 + 1];
  *(float2*)(out + (size_t)row * CC + c0) = make_float2(o0, o1);
  if (bout) {
    bout[(size_t)row * CC + c0] = (bf16_t)o0;
    bout[(size_t)row * CC + c0 + 1] = (bf16_t)o1;
  }
}

__global__ __launch_bounds__(256) void ln_gate_kernel(
    const float* __restrict__ gpre, const float* __restrict__ gate_b,
    const float* __restrict__ xc, const float* __restrict__ ef,
    const float* __restrict__ n1g, const float* __restrict__ n1b,
    const float* __restrict__ xin, float* __restrict__ x2, bf16_t* __restrict__ x2b) {
  int row = blockIdx.x, tid = threadIdx.x, c0 = tid * 2;
  __shared__ float red[8];
  float2 gp = *(const float2*)(gpre + (size_t)row * CC + c0);
  float2 xcv = *(const float2*)(xc + (size_t)row * CC + c0);
  float2 efv = *(const float2*)(ef + (size_t)row * CC + c0);
  float g0 = 1.f / (1.f + __expf(-(gp.x + gate_b[c0])));
  float g1 = 1.f / (1.f + __expf(-(gp.y + gate_b[c0 + 1])));
  float x0 = g0 * xcv.x + (1.f - g0) * efv.x;
  float x1 = g1 * xcv.y + (1.f - g1) * efv.y;
  float s = x0 + x1, q = x0 * x0 + x1 * x1;
  block_reduce2(s, q, red);
  float mean = s * (1.f / CC);
  float var = q * (1.f / CC) - mean * mean;
  float rs = rsqrtf(var + 1e-5f);
  float2 xi = *(const float2*)(xin + (size_t)row * CC + c0);
  float o0 = fmaxf((x0 - mean) * rs * n1g[c0] + n1b[c0], 0.f) + xi.x;
  float o1 = fmaxf((x1 - mean) * rs * n1g[c0 + 1] + n1b[c0 + 1], 0.f) + xi.y;
  *(float2*)(x2 + (size_t)row * CC + c0) = make_float2(o0, o1);
  x2b[(size_t)row * CC + c0] = (bf16_t)o0;
  x2b[(size_t)row * CC + c0 + 1] = (bf16_t)o1;
}

// ---------------- V^T pack (pre-swizzled + pi-permuted K for attn) ---------
__global__ __launch_bounds__(256) void vt_pack_kernel(const bf16_t* __restrict__ qkvb,
                                                      bf16_t* __restrict__ vt) {
  int b = blockIdx.x >> 3, h = blockIdx.x & 7;
  int nb = b * 256;
  size_t voff = 1024 + (size_t)h * 64;
  char* out = (char*)(vt + (size_t)blockIdx.x * (64 * 256));
  __shared__ bf16_t tile[64][80];
  int tid = threadIdx.x;
  for (int kb = 0; kb < 4; ++kb) {
    __syncthreads();
#pragma unroll
    for (int p = 0; p < 2; ++p) {
      int k = p * 32 + (tid >> 3);
      int d8 = tid & 7;
      bf16x8 v = *(const bf16x8*)(qkvb + (size_t)(nb + kb * 64 + k) * 1536 + voff + d8 * 8);
      *(bf16x8*)(&tile[k][d8 * 8]) = v;
    }
    __syncthreads();
#pragma unroll
    for (int p = 0; p < 2; ++p) {
      int d = p * 32 + (tid >> 3);
      int k8 = tid & 7;
      bf16x8 v;
#pragma unroll
      for (int j = 0; j < 8; ++j) {
        int pos = k8 * 8 + j;
        int sl = pos & 31;
        int srck = (pos & 32) + ((sl >> 3) << 2) + (sl & 3) + (((sl >> 2) & 1) << 4);
        v[j] = tile[srck][d];
      }
      int byteoff = d * 512 + ((kb * 128 + k8 * 16) ^ ((d & 7) << 4));
      *(bf16x8*)(out + byteoff) = v;
    }
  }
}

// ---------------- MFMA attention (shuffle-free PV) ----------------
__global__ __launch_bounds__(256, 2) void attn_mfma_kernel(
    const bf16_t* __restrict__ qkvb, const bf16_t* __restrict__ vt,
    bf16_t* __restrict__ o) {
  const int b = blockIdx.x >> 3;
  const int h = blockIdx.x & 7;
  const int nb = b * 256;
  const int tid = threadIdx.x;
  const int lane = tid & 63;
  const int wv = tid >> 6;
  const int l15 = lane & 15;
  const int g = lane >> 4;
  const int swzk = (l15 & 7) << 4;
  __shared__ __align__(16) bf16_t Klds[256 * 64];
  __shared__ __align__(16) bf16_t Vtlds[64 * 256];
  const size_t qoff = (size_t)h * 64;
  const size_t koff = 512 + (size_t)h * 64;

  {
    const int dcol = 16 * ((tid & 7) ^ ((tid >> 3) & 7));
    const bf16_t* srcb = qkvb + koff + (dcol >> 1);
#pragma unroll
    for (int i = 0; i < 8; ++i) {
      int k = i * 32 + (tid >> 3);
      gl_lds16(srcb + (size_t)(nb + k) * 1536, Klds + ((i * 4096 + wv * 1024) >> 1));
    }
  }
  {
    const bf16_t* vsrc = vt + (size_t)blockIdx.x * (64 * 256);
#pragma unroll
    for (int i = 0; i < 8; ++i) {
      int base = i * 4096 + wv * 1024;
      gl_lds16(vsrc + ((base >> 1) + lane * 8), Vtlds + (base >> 1));
    }
  }

  bf16x8 qf[4][2];
#pragma unroll
  for (int n = 0; n < 4; ++n) {
    const bf16_t* qp = qkvb + (size_t)(nb + wv * 64 + 16 * n + l15) * 1536 + qoff + g * 8;
    qf[n][0] = *(const bf16x8*)(qp);
    qf[n][1] = *(const bf16x8*)(qp + 32);
  }

  __syncthreads();

  f32x4v oacc[4][4] = {};
  float mrun[4] = {-1e30f, -1e30f, -1e30f, -1e30f};
  float lrun[4] = {0.f, 0.f, 0.f, 0.f};

  for (int kc = 0; kc < 4; ++kc) {
    f32x4v sacc[4][4] = {};
    const int kb128 = (kc * 64 + l15) * 128;
#pragma unroll
    for (int m = 0; m < 4; ++m) {
      bf16x8 a0 = *(const bf16x8*)(Klds + ((kb128 + m * 2048 + ((g * 16) ^ swzk)) >> 1));
      bf16x8 a1 =
          *(const bf16x8*)(Klds + ((kb128 + m * 2048 + ((64 + g * 16) ^ swzk)) >> 1));
#pragma unroll
      for (int n = 0; n < 4; ++n) {
        sacc[m][n] = __builtin_amdgcn_mfma_f32_16x16x32_bf16(a0, qf[n][0], sacc[m][n], 0, 0, 0);
        sacc[m][n] = __builtin_amdgcn_mfma_f32_16x16x32_bf16(a1, qf[n][1], sacc[m][n], 0, 0, 0);
      }
    }
    uint2 pb[4][4];
#pragma unroll
    for (int n = 0; n < 4; ++n) {
      float mx = sacc[0][n][0];
#pragma unroll
      for (int m = 0; m < 4; ++m)
#pragma unroll
        for (int r = 0; r < 4; ++r) mx = fmaxf(mx, sacc[m][n][r]);
      mx = fmaxf(mx, __shfl_xor(mx, 16));
      mx = fmaxf(mx, __shfl_xor(mx, 32));
      float mnew = fmaxf(mrun[n], mx);
      float c = __expf((mrun[n] - mnew) * 0.125f);
      mrun[n] = mnew;
      float s = 0.f;
#pragma unroll
      for (int m = 0; m < 4; ++m) {
        float p0 = __expf((sacc[m][n][0] - mnew) * 0.125f);
        float p1 = __expf((sacc[m][n][1] - mnew) * 0.125f);
        float p2 = __expf((sacc[m][n][2] - mnew) * 0.125f);
        float p3 = __expf((sacc[m][n][3] - mnew) * 0.125f);
        s += (p0 + p1) + (p2 + p3);
        union { bf16x4 v; uint2 u; } cv;
        cv.v[0] = (bf16_t)p0; cv.v[1] = (bf16_t)p1;
        cv.v[2] = (bf16_t)p2; cv.v[3] = (bf16_t)p3;
        pb[m][n] = cv.u;
      }
      s += __shfl_xor(s, 16);
      s += __shfl_xor(s, 32);
      lrun[n] = lrun[n] * c + s;
#pragma unroll
      for (int m = 0; m < 4; ++m)
#pragma unroll
        for (int r = 0; r < 4; ++r) oacc[m][n][r] *= c;
    }
#pragma unroll
    for (int h2 = 0; h2 < 2; ++h2) {
      bf16x8 vf[4];
#pragma unroll
      for (int m = 0; m < 4; ++m)
        vf[m] = *(const bf16x8*)(Vtlds + (((16 * m + l15) * 512 +
                                          ((kc * 128 + h2 * 64 + g * 16) ^ swzk)) >> 1));
#pragma unroll
      for (int n = 0; n < 4; ++n) {
        union { uint2 u[2]; bf16x8 v; } pf;
        pf.u[0] = pb[2 * h2][n];
        pf.u[1] = pb[2 * h2 + 1][n];
#pragma unroll
        for (int m = 0; m < 4; ++m)
          oacc[m][n] =
              __builtin_amdgcn_mfma_f32_16x16x32_bf16(vf[m], pf.v, oacc[m][n], 0, 0, 0);
      }
    }
  }
  float inv[4];
#pragma unroll
  for (int n = 0; n < 4; ++n) inv[n] = 1.0f / lrun[n];
#pragma unroll
  for (int m = 0; m < 4; ++m)
#pragma unroll
    for (int n = 0; n < 4; ++n) {
      bf16x4 pk;
#pragma unroll
      for (int r = 0; r < 4; ++r) pk[r] = (bf16_t)(oacc[m][n][r] * inv[n]);
      *(bf16x4*)(o + (size_t)(nb + wv * 64 + 16 * n + l15) * 512 + h * 64 + 16 * m +
                 4 * g) = pk;
    }
}

// ---------------- launch ----------------

static inline char* alignp(char* p, size_t a) {
  return (char*)(((uintptr_t)p + a - 1) & ~(uintptr_t)(a - 1));
}

extern "C" void kernel_launch(void* const* d_in, const int* in_sizes, int n_in,
                              void* d_out, int out_size, void* d_ws, size_t ws_size,
                              hipStream_t stream) {
  const float* x = (const float*)d_in[0];
  const float* edge_attr = (const float*)d_in[1];
  const float* gcn_w = (const float*)d_in[2];
  const float* gcn_b = (const float*)d_in[3];
  const float* ep_w = (const float*)d_in[4];
  const float* ep_b = (const float*)d_in[5];
  const float* gate_w = (const float*)d_in[6];
  const float* gate_b = (const float*)d_in[7];
  const float* n1_g = (const float*)d_in[8];
  const float* n1_b = (const float*)d_in[9];
  const float* in_w = (const float*)d_in[10];
  const float* in_b = (const float*)d_in[11];
  const float* out_w = (const float*)d_in[12];
  const float* out_b = (const float*)d_in[13];
  const float* tn_g = (const float*)d_in[14];
  const float* tn_b = (const float*)d_in[15];
  const float* m_w1 = (const float*)d_in[16];
  const float* m_b1 = (const float*)d_in[17];
  const float* m_w2 = (const float*)d_in[18];
  const float* m_b2 = (const float*)d_in[19];
  const float* fn_g = (const float*)d_in[20];
  const float* fn_b = (const float*)d_in[21];
  const int* eidx = (const int*)d_in[22];
  const int* src = eidx;
  const int* dst = eidx + EE;

  float* ws = (float*)d_ws;
  float* R1 = ws;
  float* R2 = R1 + (size_t)NN * 3 * CC;
  float* R3 = R2 + (size_t)NN * CC;
  float* R4 = R3 + (size_t)NN * CC;
  float* ew = R4 + (size_t)NN * CC;
  float* dinv = ew + EE;
  int* ip = (int*)(dinv + NN);
  int* ghist = ip;      ip += 64;
  int* gstart = ip;     ip += 65;
  int* gcur = ip;       ip += 64;
  int* elist_src = ip;  ip += EE;
  int* nid_src = ip;    ip += EE + 32;
  int* start_src = ip;  ip += NN + 1;
  int* start_dst = ip;  ip += NN + 1;
  char* bp = alignp((char*)ip, 64);
  int2* grec = (int2*)bp;             bp += (size_t)EE * 8;
  float* ewg = (float*)bp;            bp += (size_t)EE * 4;
  float2* dstrec = (float2*)bp;       bp += (size_t)EE * 8;
  bf16_t* x2b = (bf16_t*)bp;          bp += (size_t)NN * CC * 2;
  bf16_t* gcn_wt = (bf16_t*)bp;       bp += (size_t)CC * CC * 2;
  bf16_t* gate_wt = (bf16_t*)bp;      bp += (size_t)CC * 2 * CC * 2;
  bf16_t* in_wt = (bf16_t*)bp;        bp += (size_t)3 * CC * CC * 2;
  bf16_t* out_wt = (bf16_t*)bp;       bp += (size_t)CC * CC * 2;
  bf16_t* m_w1t = (bf16_t*)bp;        bp += (size_t)2 * CC * CC * 2;
  bf16_t* m_w2t = (bf16_t*)bp;        bp += (size_t)CC * 2 * CC * 2;

  bf16_t* xb = (bf16_t*)R1;      // bf16(x)
  bf16_t* xcefb = (bf16_t*)R1;   // [x_conv | ef] bf16 N x 2C
  bf16_t* qkvb = (bf16_t*)R1;    // qkv bf16 N x 1536 (first 48MB of R1)
  bf16_t* hb = (bf16_t*)R1;      // mlp hidden bf16 N x 2C
  bf16_t* eacsr = (bf16_t*)((char*)R1 + (size_t)64 * 1024 * 1024);  // 16.8MB at R1+64MB
  bf16_t* xwb = (bf16_t*)R2;     // bf16 xw (GCN GEMM out)
  bf16_t* ob = (bf16_t*)R2;      // attn out bf16 (first half of R2)
  bf16_t* vt = ob + (size_t)NN * CC;  // V^T packed (second half of R2)
  bf16_t* x3b = (bf16_t*)R2;     // bf16(x3) (after ob dead)
  float* x2 = (float*)d_out;

  // --- edge prep: two-level counting sort, 2-pass parallel ---
  init_kernel<<<1, 256, 0, stream>>>(ghist, nid_src, eacsr);
  edge_pass1<<<EE / 256, 256, 0, stream>>>(edge_attr, dst, ew, ghist);
  gexscan_kernel<<<1, 64, 0, stream>>>(ghist, gstart, gcur);
  graph_scatter_kernel<<<EE / 2048, 256, 0, stream>>>(src, dst, ew, gcur, grec, ewg);
  graph_sort2_kernel<<<128, 1024, 0, stream>>>(grec, ewg, gstart, elist_src, nid_src,
                                               start_src, dstrec, start_dst, dinv);
  ea_gather_kernel<<<(EE * 2 + 255) / 256, 256, 0, stream>>>(edge_attr, elist_src,
                                                             eacsr);

  // --- weight transposes ---
  wt_kernel<<<dim3(CC / 32, CC / 32), 256, 0, stream>>>(gcn_w, gcn_wt, CC, CC);
  wt_kernel<<<dim3(CC / 32, 2 * CC / 32), 256, 0, stream>>>(gate_w, gate_wt, 2 * CC, CC);
  wt_kernel<<<dim3(3 * CC / 32, CC / 32), 256, 0, stream>>>(in_w, in_wt, CC, 3 * CC);
  wt_kernel<<<dim3(CC / 32, CC / 32), 256, 0, stream>>>(out_w, out_wt, CC, CC);
  wt_kernel<<<dim3(2 * CC / 32, CC / 32), 256, 0, stream>>>(m_w1, m_w1t, CC, 2 * CC);
  wt_kernel<<<dim3(CC / 32, 2 * CC / 32), 256, 0, stream>>>(m_w2, m_w2t, 2 * CC, CC);

  // --- GCN conv ---
  cvt_bf16_kernel<<<(NN * CC / 4 + 255) / 256, 256, 0, stream>>>(x, xb, NN * CC / 4);
  dim3 gA(CC / 128, NN / 128);
  gemm_bf16_kernel<0, 1><<<gA, 256, 0, stream>>>(xb, gcn_wt, nullptr, xwb, NN, CC, CC);
  xconv_kernel<<<NN, 256, 0, stream>>>(xwb, dinv, dstrec, start_dst, gcn_b, R3, xcefb);
  ef_mfma_kernel<<<NN / 16, 256, 0, stream>>>(eacsr, ep_w, ep_b, nid_src, start_src,
                                              R4, xcefb);
  gemm_bf16_kernel<0, 0><<<gA, 256, 0, stream>>>(xcefb, gate_wt, nullptr, R2, NN, CC,
                                                 2 * CC);
  ln_gate_kernel<<<NN, 256, 0, stream>>>(R2, gate_b, R3, R4, n1_g, n1_b, x, x2, x2b);

  // --- MHA ---
  dim3 gQ(3 * CC / 128, NN / 128);
  gemm_bf16_kernel<0, 1><<<gQ, 256, 0, stream>>>(x2b, in_wt, in_b, qkvb, NN, 3 * CC, CC);
  vt_pack_kernel<<<BB * HH, 256, 0, stream>>>(qkvb, vt);
  attn_mfma_kernel<<<BB * HH, 256, 0, stream>>>(qkvb, vt, ob);
  gemm_bf16_kernel<0, 0><<<gA, 256, 0, stream>>>(ob, out_wt, out_b, R4, NN, CC, CC);
  ln_add_kernel<<<NN, 256, 0, stream>>>(x2, R4, tn_g, tn_b, R3, x3b);

  // --- MLP ---
  dim3 gH(2 * CC / 128, NN / 128);
  gemm_bf16_kernel<1, 1><<<gH, 256, 0, stream>>>(x3b, m_w1t, m_b1, hb, NN, 2 * CC, CC);
  gemm_bf16_kernel<0, 0><<<gA, 256, 0, stream>>>(hb, m_w2t, m_b2, R4, NN, CC, 2 * CC);
  ln_add_kernel<<<NN, 256, 0, stream>>>(R3, R4, fn_g, fn_b, (float*)d_out, nullptr);
}

// Round 12
// 485.927 us; speedup vs baseline: 1.6601x; 1.0886x over previous
//
#include <hip/hip_runtime.h>

#define NN 16384
#define CC 512
#define EE 524288
#define BB 64
#define HH 8
#define EFD 16
#define GEMAXE 10240

typedef __bf16 bf16_t;
typedef __bf16 bf16x4 __attribute__((ext_vector_type(4)));
typedef __bf16 bf16x8 __attribute__((ext_vector_type(8)));
typedef float f32x4v __attribute__((ext_vector_type(4)));

__device__ __forceinline__ float2 ldb2(const bf16_t* p) {
  unsigned w = *(const unsigned*)p;
  return make_float2(__uint_as_float(w << 16), __uint_as_float(w & 0xFFFF0000u));
}

// ---------------- init / edge pre-pass ----------------

__global__ void init_kernel(int* ghist, int* nid_src, bf16_t* eacsr) {
  int i = threadIdx.x;
  if (i < 64) ghist[i] = 0;
  if (i < 32) nid_src[EE + i] = -1;               // pad for ef chunk tail
  ((int*)(eacsr + (size_t)EE * 16))[i] = 0;       // zero eacsr pad rows (256 ints)
}

// ew + per-graph histogram (LDS-aggregated). NO scattered atomics.
__global__ __launch_bounds__(256) void edge_pass1(const float* __restrict__ ea,
                                                  const int* __restrict__ dst,
                                                  float* __restrict__ ew, int* ghist) {
  __shared__ int h[64];
  int tid = threadIdx.x;
  if (tid < 64) h[tid] = 0;
  __syncthreads();
  int e = blockIdx.x * 256 + tid;  // EE % 256 == 0
  const float4* p = (const float4*)(ea + (size_t)e * EFD);
  float s = 0.f;
#pragma unroll
  for (int i = 0; i < 4; ++i) {
    float4 v = p[i];
    s += v.x * v.x + v.y * v.y + v.z * v.z + v.w * v.w;
  }
  ew[e] = sqrtf(s);
  atomicAdd(&h[dst[e] >> 8], 1);
  __syncthreads();
  if (tid < 64 && h[tid]) atomicAdd(&ghist[tid], h[tid]);
}

__global__ void gexscan_kernel(const int* __restrict__ ghist, int* __restrict__ gstart,
                               int* __restrict__ gcur) {
  if (threadIdx.x == 0) {
    int s = 0;
    for (int g = 0; g < 64; ++g) { gstart[g] = s; gcur[g] = s; s += ghist[g]; }
    gstart[64] = s;
  }
}

// bucket edges by graph with block-aggregated offsets; emit packed records
__global__ __launch_bounds__(256) void graph_scatter_kernel(
    const int* __restrict__ src, const int* __restrict__ dst,
    const float* __restrict__ ew, int* gcur, int2* __restrict__ grec,
    float* __restrict__ ewg) {
  __shared__ int h[64], base[64], h2[64];
  int tid = threadIdx.x;
  if (tid < 64) { h[tid] = 0; h2[tid] = 0; }
  __syncthreads();
  int e0 = blockIdx.x * 2048;
  int gloc[8];
#pragma unroll
  for (int k = 0; k < 8; ++k) {
    gloc[k] = dst[e0 + k * 256 + tid] >> 8;
    atomicAdd(&h[gloc[k]], 1);
  }
  __syncthreads();
  if (tid < 64) base[tid] = h[tid] ? atomicAdd(&gcur[tid], h[tid]) : 0;
  __syncthreads();
#pragma unroll
  for (int k = 0; k < 8; ++k) {
    int e = e0 + k * 256 + tid;
    int g = gloc[k];
    int p = atomicAdd(&h2[g], 1);
    int pos = base[g] + p;
    int ls = src[e] & 255;
    int ld = dst[e] & 255;
    grec[pos] = make_int2(e | (ls << 19), ld);
    ewg[pos] = ew[e];
  }
}

// per-graph LDS counting sort, 128 blocks: blockIdx<64 -> DST pass, else SRC.
__global__ __launch_bounds__(1024) void graph_sort2_kernel(
    const int2* __restrict__ grec, const float* __restrict__ ewg,
    const int* __restrict__ gstart, int* __restrict__ elist_src,
    int* __restrict__ nid_src, int* __restrict__ start_src,
    float2* __restrict__ dstrec, int* __restrict__ start_dst,
    float* __restrict__ dinv) {
  __shared__ int lbuf[GEMAXE];
  __shared__ unsigned short sl[GEMAXE];
  __shared__ float ewl[GEMAXE];
  __shared__ int h[256], hx[256], h2[256];
  __shared__ float fdinv[256];
  const int g = blockIdx.x & 63;
  const int tid = threadIdx.x;
  const int gs = gstart[g];
  const int cnt = gstart[g + 1] - gs;
  if (tid < 256) { h[tid] = 0; h2[tid] = 0; }
  __syncthreads();
  if (blockIdx.x < 64) {
    for (int i = tid; i < cnt; i += 1024) {
      int2 r = grec[gs + i];
      int ld = r.y;
      sl[i] = (unsigned short)(((r.x >> 19) & 255) | (ld << 8));
      ewl[i] = ewg[gs + i];
      atomicAdd(&h[ld], 1);
    }
    __syncthreads();
    int myc = (tid < 256) ? h[tid] : 0;
    for (int off = 1; off < 256; off <<= 1) {
      int v = (tid < 256 && tid >= off) ? h[tid - off] : 0;
      __syncthreads();
      if (tid < 256) h[tid] += v;
      __syncthreads();
    }
    if (tid < 256) {
      hx[tid] = h[tid] - myc;
      start_dst[g * 256 + tid] = gs + hx[tid];
    }
    if (g == 63 && tid == 0) start_dst[NN] = EE;
    __syncthreads();
    for (int i = tid; i < cnt; i += 1024) {
      int ld = sl[i] >> 8;
      int p = hx[ld] + atomicAdd(&h2[ld], 1);
      lbuf[p] = i;
    }
    __syncthreads();
    if (tid < 256) {
      float dg = 1.0f;
      int s0 = hx[tid], e0 = s0 + myc;
      for (int i = s0; i < e0; ++i) dg += ewl[lbuf[i]];
      float dv = rsqrtf(fmaxf(dg, 1e-12f));
      fdinv[tid] = dv;
      dinv[g * 256 + tid] = dv;
    }
    __syncthreads();
    for (int p = tid; p < cnt; p += 1024) {
      int i = lbuf[p];
      int ls = sl[i] & 255;
      dstrec[gs + p] = make_float2(fdinv[ls] * ewl[i], __int_as_float(g * 256 + ls));
    }
  } else {
    int* wb = (int*)ewl;
    for (int i = tid; i < cnt; i += 1024) {
      int w = grec[gs + i].x;
      wb[i] = w;
      atomicAdd(&h[w >> 19], 1);
    }
    __syncthreads();
    int myc = (tid < 256) ? h[tid] : 0;
    for (int off = 1; off < 256; off <<= 1) {
      int v = (tid < 256 && tid >= off) ? h[tid - off] : 0;
      __syncthreads();
      if (tid < 256) h[tid] += v;
      __syncthreads();
    }
    if (tid < 256) {
      hx[tid] = h[tid] - myc;
      start_src[g * 256 + tid] = gs + hx[tid];
    }
    if (g == 63 && tid == 0) start_src[NN] = EE;
    __syncthreads();
    for (int i = tid; i < cnt; i += 1024) {
      int w = wb[i];
      int ls = w >> 19;
      int p = hx[ls] + atomicAdd(&h2[ls], 1);
      lbuf[p] = w;
    }
    __syncthreads();
    for (int p = tid; p < cnt; p += 1024) {
      int w = lbuf[p];
      elist_src[gs + p] = w & 0x7FFFF;
      nid_src[gs + p] = g * 256 + (w >> 19);
    }
  }
}

// gather edge_attr rows into CSR order as bf16
__global__ void ea_gather_kernel(const float* __restrict__ ea,
                                 const int* __restrict__ elist,
                                 bf16_t* __restrict__ eacsr) {
  int idx = blockIdx.x * 256 + threadIdx.x;
  if (idx >= EE * 2) return;
  int pos = idx >> 1, half = idx & 1;
  int e = elist[pos];
  const f32x4v* p = (const f32x4v*)(ea + (size_t)e * EFD + half * 8);
  f32x4v u0 = p[0], u1 = p[1];
  bf16x8 f;
#pragma unroll
  for (int r = 0; r < 4; ++r) {
    f[r] = (bf16_t)u0[r];
    f[4 + r] = (bf16_t)u1[r];
  }
  *(bf16x8*)(eacsr + (size_t)pos * 16 + half * 8) = f;
}

// ---------------- conversions ----------------

__global__ void cvt_bf16_kernel(const float* __restrict__ in, bf16_t* __restrict__ out,
                                int n4) {
  int i = blockIdx.x * 256 + threadIdx.x;
  if (i >= n4) return;
  float4 v = ((const float4*)in)[i];
  bf16x4 o;
  o[0] = (bf16_t)v.x; o[1] = (bf16_t)v.y; o[2] = (bf16_t)v.z; o[3] = (bf16_t)v.w;
  ((bf16x4*)out)[i] = o;
}

// W: f32 [K][N] row-major -> Wt: bf16 [N][K] row-major
__global__ __launch_bounds__(256) void wt_kernel(const float* __restrict__ W,
                                                 bf16_t* __restrict__ Wt, int K, int N) {
  __shared__ float tile[32][33];
  int bx = blockIdx.x * 32;
  int by = blockIdx.y * 32;
  int tx = threadIdx.x & 31, ty = threadIdx.x >> 5;
#pragma unroll
  for (int i = 0; i < 32; i += 8)
    tile[ty + i][tx] = W[(size_t)(by + ty + i) * N + bx + tx];
  __syncthreads();
#pragma unroll
  for (int i = 0; i < 32; i += 8)
    Wt[(size_t)(bx + ty + i) * K + by + tx] = (bf16_t)tile[tx][ty + i];
}

// ---------------- GCN conv gather (CSR by dst, packed records) -------------
// writes ONLY bf16 into xcefb first half
__global__ __launch_bounds__(256) void xconv_kernel(
    const bf16_t* __restrict__ xwb, const float* __restrict__ dinv,
    const float2* __restrict__ dstrec, const int* __restrict__ start,
    const float* __restrict__ gcn_b, bf16_t* __restrict__ xcb) {
  int i = blockIdx.x;
  int tid = threadIdx.x;
  int st = start[i], en = start[i + 1];
  float di = dinv[i];
  int c0 = tid * 2;
  __shared__ float2 scS[256];
  float2 xv = ldb2(xwb + (size_t)i * CC + c0);
  float sc = di * di;
  float a0 = sc * xv.x + gcn_b[c0];
  float a1 = sc * xv.y + gcn_b[c0 + 1];
  for (int p0 = st; p0 < en; p0 += 256) {
    int m = min(256, en - p0);
    __syncthreads();
    if (tid < m) {
      float2 r = dstrec[p0 + tid];
      scS[tid] = make_float2(r.x * di, r.y);
    }
    __syncthreads();
    for (int j = 0; j < m; ++j) {
      float2 scv = scS[j];
      int sn = __float_as_int(scv.y);
      float2 v = ldb2(xwb + (size_t)sn * CC + c0);
      a0 += scv.x * v.x;
      a1 += scv.x * v.y;
    }
  }
  xcb[(size_t)i * (2 * CC) + c0] = (bf16_t)a0;
  xcb[(size_t)i * (2 * CC) + c0 + 1] = (bf16_t)a1;
}

// ---------------- edge projection via double-MFMA (bf16-only output) -------
__global__ __launch_bounds__(256) void ef_mfma_kernel(
    const bf16_t* __restrict__ eacsr, const float* __restrict__ ep_w,
    const float* __restrict__ ep_b, const int* __restrict__ nid,
    const int* __restrict__ start, bf16_t* __restrict__ efb) {
  const int tid = threadIdx.x;
  const int lane = tid & 63;
  const int wv = tid >> 6;
  const int l15 = lane & 15;
  const int g = lane >> 4;
  const int n0 = blockIdx.x * 16;
  const int cbase = wv * 128;

  bf16x8 wfr[8];
#pragma unroll
  for (int t = 0; t < 8; ++t) {
    bf16x8 f = {};
    int c = cbase + t * 16 + l15;
    if (g < 2) {
#pragma unroll
      for (int j = 0; j < 8; ++j) f[j] = (bf16_t)ep_w[(g * 8 + j) * CC + c];
    } else if (g == 2) {
      f[0] = (bf16_t)ep_b[c];
    }
    wfr[t] = f;
  }

  const int st = start[n0];
  const int en = start[n0 + 16];
  const int tgt = n0 + l15;

  f32x4v eacc[8] = {};

  for (int cb = st; cb < en; cb += 32) {
    bf16x8 af[2];
#pragma unroll
    for (int mE = 0; mE < 2; ++mE) {
      bf16x8 f = {};
      if (g < 2) {
        f = *(const bf16x8*)(eacsr + (size_t)(cb + mE * 16 + l15) * 16 + g * 8);
      } else if (g == 2) {
        f[0] = (bf16_t)1.0f;
      }
      af[mE] = f;
    }
    int4 idlo = *(const int4*)(nid + cb + g * 4);
    int4 idhi = *(const int4*)(nid + cb + 16 + g * 4);
    bf16x8 sf;
    sf[0] = (idlo.x == tgt) ? (bf16_t)1.0f : (bf16_t)0.0f;
    sf[1] = (idlo.y == tgt) ? (bf16_t)1.0f : (bf16_t)0.0f;
    sf[2] = (idlo.z == tgt) ? (bf16_t)1.0f : (bf16_t)0.0f;
    sf[3] = (idlo.w == tgt) ? (bf16_t)1.0f : (bf16_t)0.0f;
    sf[4] = (idhi.x == tgt) ? (bf16_t)1.0f : (bf16_t)0.0f;
    sf[5] = (idhi.y == tgt) ? (bf16_t)1.0f : (bf16_t)0.0f;
    sf[6] = (idhi.z == tgt) ? (bf16_t)1.0f : (bf16_t)0.0f;
    sf[7] = (idhi.w == tgt) ? (bf16_t)1.0f : (bf16_t)0.0f;
#pragma unroll
    for (int t = 0; t < 8; ++t) {
      f32x4v s0 = {}, s1 = {};
      s0 = __builtin_amdgcn_mfma_f32_16x16x32_bf16(af[0], wfr[t], s0, 0, 0, 0);
      s1 = __builtin_amdgcn_mfma_f32_16x16x32_bf16(af[1], wfr[t], s1, 0, 0, 0);
      union { bf16x8 v; bf16x4 h[2]; } pf;
#pragma unroll
      for (int r = 0; r < 4; ++r) {
        pf.h[0][r] = (bf16_t)fmaxf(s0[r], 0.f);
        pf.h[1][r] = (bf16_t)fmaxf(s1[r], 0.f);
      }
      eacc[t] = __builtin_amdgcn_mfma_f32_16x16x32_bf16(sf, pf.v, eacc[t], 0, 0, 0);
    }
  }
#pragma unroll
  for (int t = 0; t < 8; ++t) {
    int c = cbase + t * 16 + l15;
#pragma unroll
    for (int r = 0; r < 4; ++r) {
      int node = n0 + g * 4 + r;
      efb[(size_t)node * (2 * CC) + CC + c] = (bf16_t)eacc[t][r];
    }
  }
}

// ---------------- bf16 MFMA GEMM (m97 structure) ----------------
__device__ __forceinline__ void gl_lds16(const bf16_t* g, bf16_t* l) {
  __builtin_amdgcn_global_load_lds(
      (const __attribute__((address_space(1))) void*)g,
      (__attribute__((address_space(3))) void*)l, 16, 0, 0);
}

template <int ACT, int OUT>
__global__ __launch_bounds__(256) void gemm_bf16_kernel(
    const bf16_t* __restrict__ A, const bf16_t* __restrict__ Bt,
    const float* __restrict__ bias, void* __restrict__ Cout, int M, int N, int K) {
  __shared__ __align__(16) bf16_t Al[128 * 32];
  __shared__ __align__(16) bf16_t Bl[128 * 32];
  const int tid = threadIdx.x;
  const int lane = tid & 63;
  const int wave = tid >> 6;
  const int row0 = blockIdx.y * 128;
  const int col0 = blockIdx.x * 128;
  const int wm = (wave >> 1) * 64;
  const int wn = (wave & 1) * 64;
  f32x4v acc[4][4] = {};
  const bf16_t* aBase = A + (size_t)(row0 + (tid >> 2)) * K + (tid & 3) * 8;
  const bf16_t* bBase = Bt + (size_t)(col0 + (tid >> 2)) * K + (tid & 3) * 8;
  bf16_t* al0 = Al + wave * 512;
  bf16_t* al1 = Al + 2048 + wave * 512;
  bf16_t* bl0 = Bl + wave * 512;
  bf16_t* bl1 = Bl + 2048 + wave * 512;
  const int fr = lane & 15;
  const int fk = (lane >> 4) * 8;
  for (int k0 = 0; k0 < K; k0 += 32) {
    gl_lds16(aBase + k0, al0);
    gl_lds16(aBase + (size_t)64 * K + k0, al1);
    gl_lds16(bBase + k0, bl0);
    gl_lds16(bBase + (size_t)64 * K + k0, bl1);
    __syncthreads();
    bf16x8 af[4], bfv[4];
#pragma unroll
    for (int m = 0; m < 4; ++m)
      af[m] = *(const bf16x8*)(Al + (wm + m * 16 + fr) * 32 + fk);
#pragma unroll
    for (int n = 0; n < 4; ++n)
      bfv[n] = *(const bf16x8*)(Bl + (wn + n * 16 + fr) * 32 + fk);
#pragma unroll
    for (int m = 0; m < 4; ++m)
#pragma unroll
      for (int n = 0; n < 4; ++n)
        acc[m][n] =
            __builtin_amdgcn_mfma_f32_16x16x32_bf16(af[m], bfv[n], acc[m][n], 0, 0, 0);
    __syncthreads();
  }
  const int fq = (lane >> 4) * 4;
#pragma unroll
  for (int m = 0; m < 4; ++m) {
    int grb = row0 + wm + m * 16 + fq;
#pragma unroll
    for (int n = 0; n < 4; ++n) {
      int gc = col0 + wn + n * 16 + fr;
      float bv = bias ? bias[gc] : 0.f;
#pragma unroll
      for (int r = 0; r < 4; ++r) {
        float v = acc[m][n][r] + bv;
        if (ACT == 1) v = v / (1.f + __expf(-v));
        if (OUT == 0)
          ((float*)Cout)[(size_t)(grb + r) * N + gc] = v;
        else
          ((bf16_t*)Cout)[(size_t)(grb + r) * N + gc] = (bf16_t)v;
      }
    }
  }
}

// ---------------- layernorm fused kernels ----------------

__device__ inline void block_reduce2(float& s, float& q, float* red) {
#pragma unroll
  for (int off = 32; off >= 1; off >>= 1) {
    s += __shfl_xor(s, off, 64);
    q += __shfl_xor(q, off, 64);
  }
  int wid = threadIdx.x >> 6;
  if ((threadIdx.x & 63) == 0) { red[wid * 2] = s; red[wid * 2 + 1] = q; }
  __syncthreads();
  s = red[0] + red[2] + red[4] + red[6];
  q = red[1] + red[3] + red[5] + red[7];
}

// out = LN(A + B) * g + be ; IA/IB: 1 = bf16 input; WF: 1 = f32 out, else bf16
template <int IA, int IB, int WF>
__global__ __launch_bounds__(256) void ln_addT_kernel(
    const void* __restrict__ A, const void* __restrict__ Bv,
    const float* __restrict__ g, const float* __restrict__ be,
    float* __restrict__ outf, bf16_t* __restrict__ outb) {
  int row = blockIdx.x, tid = threadIdx.x, c0 = tid * 2;
  __shared__ float red[8];
  float2 a = IA ? ldb2((const bf16_t*)A + (size_t)row * CC + c0)
                : *(const float2*)((const float*)A + (size_t)row * CC + c0);
  float2 b = IB ? ldb2((const bf16_t*)Bv + (size_t)row * CC + c0)
                : *(const float2*)((const float*)Bv + (size_t)row * CC + c0);
  float x0 = a.x + b.x, x1 = a.y + b.y;
  float s = x0 + x1, q = x0 * x0 + x1 * x1;
  block_reduce2(s, q, red);
  float mean = s * (1.f / CC);
  float var = q * (1.f / CC) - mean * mean;
  float rs = rsqrtf(var + 1e-5f);
  float o0 = (x0 - mean) * rs * g[c0] + be[c0];
  float o1 = (x1 - mean) * rs * g[c0 + 1] + be[c0 + 1];
  if (WF) {
    *(float2*)(outf + (size_t)row * CC + c0) = make_float2(o0, o1);
  } else {
    outb[(size_t)row * CC + c0] = (bf16_t)o0;
    outb[(size_t)row * CC + c0 + 1] = (bf16_t)o1;
  }
}

// gate+mix+LN+relu+residual; bf16 inputs (gpre, xc|ef), f32 x residual; bf16 out
__global__ __launch_bounds__(256) void ln_gate_kernel(
    const bf16_t* __restrict__ gpreb, const float* __restrict__ gate_b,
    const bf16_t* __restrict__ xcef, const float* __restrict__ n1g,
    const float* __restrict__ n1b, const float* __restrict__ xin,
    bf16_t* __restrict__ x2b) {
  int row = blockIdx.x, tid = threadIdx.x, c0 = tid * 2;
  __shared__ float red[8];
  float2 gp = ldb2(gpreb + (size_t)row * CC + c0);
  float2 xcv = ldb2(xcef + (size_t)row * (2 * CC) + c0);
  float2 efv = ldb2(xcef + (size_t)row * (2 * CC) + CC + c0);
  float g0 = 1.f / (1.f + __expf(-(gp.x + gate_b[c0])));
  float g1 = 1.f / (1.f + __expf(-(gp.y + gate_b[c0 + 1])));
  float x0 = g0 * xcv.x + (1.f - g0) * efv.x;
  float x1 = g1 * xcv.y + (1.f - g1) * efv.y;
  float s = x0 + x1, q = x0 * x0 + x1 * x1;
  block_reduce2(s, q, red);
  float mean = s * (1.f / CC);
  float var = q * (1.f / CC) - mean * mean;
  float rs = rsqrtf(var + 1e-5f);
  float2 xi = *(const float2*)(xin + (size_t)row * CC + c0);
  float o0 = fmaxf((x0 - mean) * rs * n1g[c0] + n1b[c0], 0.f) + xi.x;
  float o1 = fmaxf((x1 - mean) * rs * n1g[c0 + 1] + n1b[c0 + 1], 0.f) + xi.y;
  x2b[(size_t)row * CC + c0] = (bf16_t)o0;
  x2b[(size_t)row * CC + c0 + 1] = (bf16_t)o1;
}

// ---------------- V^T pack (pre-swizzled + pi-permuted K for attn) ---------
__global__ __launch_bounds__(256) void vt_pack_kernel(const bf16_t* __restrict__ qkvb,
                                                      bf16_t* __restrict__ vt) {
  int b = blockIdx.x >> 3, h = blockIdx.x & 7;
  int nb = b * 256;
  size_t voff = 1024 + (size_t)h * 64;
  char* out = (char*)(vt + (size_t)blockIdx.x * (64 * 256));
  __shared__ bf16_t tile[64][80];
  int tid = threadIdx.x;
  for (int kb = 0; kb < 4; ++kb) {
    __syncthreads();
#pragma unroll
    for (int p = 0; p < 2; ++p) {
      int k = p * 32 + (tid >> 3);
      int d8 = tid & 7;
      bf16x8 v = *(const bf16x8*)(qkvb + (size_t)(nb + kb * 64 + k) * 1536 + voff + d8 * 8);
      *(bf16x8*)(&tile[k][d8 * 8]) = v;
    }
    __syncthreads();
#pragma unroll
    for (int p = 0; p < 2; ++p) {
      int d = p * 32 + (tid >> 3);
      int k8 = tid & 7;
      bf16x8 v;
#pragma unroll
      for (int j = 0; j < 8; ++j) {
        int pos = k8 * 8 + j;
        int sl = pos & 31;
        int srck = (pos & 32) + ((sl >> 3) << 2) + (sl & 3) + (((sl >> 2) & 1) << 4);
        v[j] = tile[srck][d];
      }
      int byteoff = d * 512 + ((kb * 128 + k8 * 16) ^ ((d & 7) << 4));
      *(bf16x8*)(out + byteoff) = v;
    }
  }
}

// ---------------- MFMA attention (shuffle-free PV) ----------------
__global__ __launch_bounds__(256, 2) void attn_mfma_kernel(
    const bf16_t* __restrict__ qkvb, const bf16_t* __restrict__ vt,
    bf16_t* __restrict__ o) {
  const int b = blockIdx.x >> 3;
  const int h = blockIdx.x & 7;
  const int nb = b * 256;
  const int tid = threadIdx.x;
  const int lane = tid & 63;
  const int wv = tid >> 6;
  const int l15 = lane & 15;
  const int g = lane >> 4;
  const int swzk = (l15 & 7) << 4;
  __shared__ __align__(16) bf16_t Klds[256 * 64];
  __shared__ __align__(16) bf16_t Vtlds[64 * 256];
  const size_t qoff = (size_t)h * 64;
  const size_t koff = 512 + (size_t)h * 64;

  {
    const int dcol = 16 * ((tid & 7) ^ ((tid >> 3) & 7));
    const bf16_t* srcb = qkvb + koff + (dcol >> 1);
#pragma unroll
    for (int i = 0; i < 8; ++i) {
      int k = i * 32 + (tid >> 3);
      gl_lds16(srcb + (size_t)(nb + k) * 1536, Klds + ((i * 4096 + wv * 1024) >> 1));
    }
  }
  {
    const bf16_t* vsrc = vt + (size_t)blockIdx.x * (64 * 256);
#pragma unroll
    for (int i = 0; i < 8; ++i) {
      int base = i * 4096 + wv * 1024;
      gl_lds16(vsrc + ((base >> 1) + lane * 8), Vtlds + (base >> 1));
    }
  }

  bf16x8 qf[4][2];
#pragma unroll
  for (int n = 0; n < 4; ++n) {
    const bf16_t* qp = qkvb + (size_t)(nb + wv * 64 + 16 * n + l15) * 1536 + qoff + g * 8;
    qf[n][0] = *(const bf16x8*)(qp);
    qf[n][1] = *(const bf16x8*)(qp + 32);
  }

  __syncthreads();

  f32x4v oacc[4][4] = {};
  float mrun[4] = {-1e30f, -1e30f, -1e30f, -1e30f};
  float lrun[4] = {0.f, 0.f, 0.f, 0.f};

  for (int kc = 0; kc < 4; ++kc) {
    f32x4v sacc[4][4] = {};
    const int kb128 = (kc * 64 + l15) * 128;
#pragma unroll
    for (int m = 0; m < 4; ++m) {
      bf16x8 a0 = *(const bf16x8*)(Klds + ((kb128 + m * 2048 + ((g * 16) ^ swzk)) >> 1));
      bf16x8 a1 =
          *(const bf16x8*)(Klds + ((kb128 + m * 2048 + ((64 + g * 16) ^ swzk)) >> 1));
#pragma unroll
      for (int n = 0; n < 4; ++n) {
        sacc[m][n] = __builtin_amdgcn_mfma_f32_16x16x32_bf16(a0, qf[n][0], sacc[m][n], 0, 0, 0);
        sacc[m][n] = __builtin_amdgcn_mfma_f32_16x16x32_bf16(a1, qf[n][1], sacc[m][n], 0, 0, 0);
      }
    }
    uint2 pb[4][4];
#pragma unroll
    for (int n = 0; n < 4; ++n) {
      float mx = sacc[0][n][0];
#pragma unroll
      for (int m = 0; m < 4; ++m)
#pragma unroll
        for (int r = 0; r < 4; ++r) mx = fmaxf(mx, sacc[m][n][r]);
      mx = fmaxf(mx, __shfl_xor(mx, 16));
      mx = fmaxf(mx, __shfl_xor(mx, 32));
      float mnew = fmaxf(mrun[n], mx);
      float c = __expf((mrun[n] - mnew) * 0.125f);
      mrun[n] = mnew;
      float s = 0.f;
#pragma unroll
      for (int m = 0; m < 4; ++m) {
        float p0 = __expf((sacc[m][n][0] - mnew) * 0.125f);
        float p1 = __expf((sacc[m][n][1] - mnew) * 0.125f);
        float p2 = __expf((sacc[m][n][2] - mnew) * 0.125f);
        float p3 = __expf((sacc[m][n][3] - mnew) * 0.125f);
        s += (p0 + p1) + (p2 + p3);
        union { bf16x4 v; uint2 u; } cv;
        cv.v[0] = (bf16_t)p0; cv.v[1] = (bf16_t)p1;
        cv.v[2] = (bf16_t)p2; cv.v[3] = (bf16_t)p3;
        pb[m][n] = cv.u;
      }
      s += __shfl_xor(s, 16);
      s += __shfl_xor(s, 32);
      lrun[n] = lrun[n] * c + s;
#pragma unroll
      for (int m = 0; m < 4; ++m)
#pragma unroll
        for (int r = 0; r < 4; ++r) oacc[m][n][r] *= c;
    }
#pragma unroll
    for (int h2 = 0; h2 < 2; ++h2) {
      bf16x8 vf[4];
#pragma unroll
      for (int m = 0; m < 4; ++m)
        vf[m] = *(const bf16x8*)(Vtlds + (((16 * m + l15) * 512 +
                                          ((kc * 128 + h2 * 64 + g * 16) ^ swzk)) >> 1));
#pragma unroll
      for (int n = 0; n < 4; ++n) {
        union { uint2 u[2]; bf16x8 v; } pf;
        pf.u[0] = pb[2 * h2][n];
        pf.u[1] = pb[2 * h2 + 1][n];
#pragma unroll
        for (int m = 0; m < 4; ++m)
          oacc[m][n] =
              __builtin_amdgcn_mfma_f32_16x16x32_bf16(vf[m], pf.v, oacc[m][n], 0, 0, 0);
      }
    }
  }
  float inv[4];
#pragma unroll
  for (int n = 0; n < 4; ++n) inv[n] = 1.0f / lrun[n];
#pragma unroll
  for (int m = 0; m < 4; ++m)
#pragma unroll
    for (int n = 0; n < 4; ++n) {
      bf16x4 pk;
#pragma unroll
      for (int r = 0; r < 4; ++r) pk[r] = (bf16_t)(oacc[m][n][r] * inv[n]);
      *(bf16x4*)(o + (size_t)(nb + wv * 64 + 16 * n + l15) * 512 + h * 64 + 16 * m +
                 4 * g) = pk;
    }
}

// ---------------- launch ----------------

static inline char* alignp(char* p, size_t a) {
  return (char*)(((uintptr_t)p + a - 1) & ~(uintptr_t)(a - 1));
}

extern "C" void kernel_launch(void* const* d_in, const int* in_sizes, int n_in,
                              void* d_out, int out_size, void* d_ws, size_t ws_size,
                              hipStream_t stream) {
  const float* x = (const float*)d_in[0];
  const float* edge_attr = (const float*)d_in[1];
  const float* gcn_w = (const float*)d_in[2];
  const float* gcn_b = (const float*)d_in[3];
  const float* ep_w = (const float*)d_in[4];
  const float* ep_b = (const float*)d_in[5];
  const float* gate_w = (const float*)d_in[6];
  const float* gate_b = (const float*)d_in[7];
  const float* n1_g = (const float*)d_in[8];
  const float* n1_b = (const float*)d_in[9];
  const float* in_w = (const float*)d_in[10];
  const float* in_b = (const float*)d_in[11];
  const float* out_w = (const float*)d_in[12];
  const float* out_b = (const float*)d_in[13];
  const float* tn_g = (const float*)d_in[14];
  const float* tn_b = (const float*)d_in[15];
  const float* m_w1 = (const float*)d_in[16];
  const float* m_b1 = (const float*)d_in[17];
  const float* m_w2 = (const float*)d_in[18];
  const float* m_b2 = (const float*)d_in[19];
  const float* fn_g = (const float*)d_in[20];
  const float* fn_b = (const float*)d_in[21];
  const int* eidx = (const int*)d_in[22];
  const int* src = eidx;
  const int* dst = eidx + EE;

  float* ws = (float*)d_ws;
  float* R1 = ws;
  float* R2 = R1 + (size_t)NN * 3 * CC;
  float* R3 = R2 + (size_t)NN * CC;
  float* R4 = R3 + (size_t)NN * CC;
  float* ew = R4 + (size_t)NN * CC;
  float* dinv = ew + EE;
  int* ip = (int*)(dinv + NN);
  int* ghist = ip;      ip += 64;
  int* gstart = ip;     ip += 65;
  int* gcur = ip;       ip += 64;
  int* elist_src = ip;  ip += EE;
  int* nid_src = ip;    ip += EE + 32;
  int* start_src = ip;  ip += NN + 1;
  int* start_dst = ip;  ip += NN + 1;
  char* bp = alignp((char*)ip, 64);
  int2* grec = (int2*)bp;             bp += (size_t)EE * 8;
  float* ewg = (float*)bp;            bp += (size_t)EE * 4;
  float2* dstrec = (float2*)bp;       bp += (size_t)EE * 8;
  bf16_t* x2b = (bf16_t*)bp;          bp += (size_t)NN * CC * 2;
  bf16_t* gcn_wt = (bf16_t*)bp;       bp += (size_t)CC * CC * 2;
  bf16_t* gate_wt = (bf16_t*)bp;      bp += (size_t)CC * 2 * CC * 2;
  bf16_t* in_wt = (bf16_t*)bp;        bp += (size_t)3 * CC * CC * 2;
  bf16_t* out_wt = (bf16_t*)bp;       bp += (size_t)CC * CC * 2;
  bf16_t* m_w1t = (bf16_t*)bp;        bp += (size_t)2 * CC * CC * 2;
  bf16_t* m_w2t = (bf16_t*)bp;        bp += (size_t)CC * 2 * CC * 2;

  bf16_t* xb = (bf16_t*)R1;      // bf16(x)
  bf16_t* xcefb = (bf16_t*)R1;   // [x_conv | ef] bf16 N x 2C
  bf16_t* qkvb = (bf16_t*)R1;    // qkv bf16 N x 1536
  bf16_t* hb = (bf16_t*)R1;      // mlp hidden bf16 N x 2C
  bf16_t* eacsr = (bf16_t*)((char*)R1 + (size_t)64 * 1024 * 1024);  // 16.8MB
  bf16_t* xwb = (bf16_t*)R2;     // bf16 xw (GCN GEMM out)
  bf16_t* gpreb = (bf16_t*)R2;   // gate pre-act bf16 (after xwb dead)
  bf16_t* ob = (bf16_t*)R2;      // attn out bf16 (first half of R2)
  bf16_t* vt = ob + (size_t)NN * CC;  // V^T packed (second half of R2)
  bf16_t* x3b = (bf16_t*)R2;     // bf16(x3) (after ob dead)
  bf16_t* oprjb = (bf16_t*)R4;   // out-proj bf16
  float* yf = R4;                // mlp2 f32 out (after oprjb dead)

  // --- edge prep ---
  init_kernel<<<1, 256, 0, stream>>>(ghist, nid_src, eacsr);
  edge_pass1<<<EE / 256, 256, 0, stream>>>(edge_attr, dst, ew, ghist);
  gexscan_kernel<<<1, 64, 0, stream>>>(ghist, gstart, gcur);
  graph_scatter_kernel<<<EE / 2048, 256, 0, stream>>>(src, dst, ew, gcur, grec, ewg);
  graph_sort2_kernel<<<128, 1024, 0, stream>>>(grec, ewg, gstart, elist_src, nid_src,
                                               start_src, dstrec, start_dst, dinv);
  ea_gather_kernel<<<(EE * 2 + 255) / 256, 256, 0, stream>>>(edge_attr, elist_src,
                                                             eacsr);

  // --- weight transposes ---
  wt_kernel<<<dim3(CC / 32, CC / 32), 256, 0, stream>>>(gcn_w, gcn_wt, CC, CC);
  wt_kernel<<<dim3(CC / 32, 2 * CC / 32), 256, 0, stream>>>(gate_w, gate_wt, 2 * CC, CC);
  wt_kernel<<<dim3(3 * CC / 32, CC / 32), 256, 0, stream>>>(in_w, in_wt, CC, 3 * CC);
  wt_kernel<<<dim3(CC / 32, CC / 32), 256, 0, stream>>>(out_w, out_wt, CC, CC);
  wt_kernel<<<dim3(2 * CC / 32, CC / 32), 256, 0, stream>>>(m_w1, m_w1t, CC, 2 * CC);
  wt_kernel<<<dim3(CC / 32, 2 * CC / 32), 256, 0, stream>>>(m_w2, m_w2t, 2 * CC, CC);

  // --- GCN conv ---
  cvt_bf16_kernel<<<(NN * CC / 4 + 255) / 256, 256, 0, stream>>>(x, xb, NN * CC / 4);
  dim3 gA(CC / 128, NN / 128);
  gemm_bf16_kernel<0, 1><<<gA, 256, 0, stream>>>(xb, gcn_wt, nullptr, xwb, NN, CC, CC);
  xconv_kernel<<<NN, 256, 0, stream>>>(xwb, dinv, dstrec, start_dst, gcn_b, xcefb);
  ef_mfma_kernel<<<NN / 16, 256, 0, stream>>>(eacsr, ep_w, ep_b, nid_src, start_src,
                                              xcefb);
  gemm_bf16_kernel<0, 1><<<gA, 256, 0, stream>>>(xcefb, gate_wt, nullptr, gpreb, NN,
                                                 CC, 2 * CC);
  ln_gate_kernel<<<NN, 256, 0, stream>>>(gpreb, gate_b, xcefb, n1_g, n1_b, x, x2b);

  // --- MHA ---
  dim3 gQ(3 * CC / 128, NN / 128);
  gemm_bf16_kernel<0, 1><<<gQ, 256, 0, stream>>>(x2b, in_wt, in_b, qkvb, NN, 3 * CC, CC);
  vt_pack_kernel<<<BB * HH, 256, 0, stream>>>(qkvb, vt);
  attn_mfma_kernel<<<BB * HH, 256, 0, stream>>>(qkvb, vt, ob);
  gemm_bf16_kernel<0, 1><<<gA, 256, 0, stream>>>(ob, out_wt, out_b, oprjb, NN, CC, CC);
  ln_addT_kernel<1, 1, 0><<<NN, 256, 0, stream>>>(x2b, oprjb, tn_g, tn_b, nullptr, x3b);

  // --- MLP ---
  dim3 gH(2 * CC / 128, NN / 128);
  gemm_bf16_kernel<1, 1><<<gH, 256, 0, stream>>>(x3b, m_w1t, m_b1, hb, NN, 2 * CC, CC);
  gemm_bf16_kernel<0, 0><<<gA, 256, 0, stream>>>(hb, m_w2t, m_b2, yf, NN, CC, 2 * CC);
  ln_addT_kernel<1, 0, 1><<<NN, 256, 0, stream>>>(x3b, yf, fn_g, fn_b, (float*)d_out,
                                                  nullptr);
}

// Round 13
// 472.913 us; speedup vs baseline: 1.7057x; 1.0275x over previous
//
#include <hip/hip_runtime.h>

#define NN 16384
#define CC 512
#define EE 524288
#define BB 64
#define HH 8
#define EFD 16
#define GEMAXE 10240

typedef __bf16 bf16_t;
typedef __bf16 bf16x4 __attribute__((ext_vector_type(4)));
typedef __bf16 bf16x8 __attribute__((ext_vector_type(8)));
typedef float f32x4v __attribute__((ext_vector_type(4)));

__device__ __forceinline__ float2 ldb2(const bf16_t* p) {
  unsigned w = *(const unsigned*)p;
  return make_float2(__uint_as_float(w << 16), __uint_as_float(w & 0xFFFF0000u));
}

// ---------------- init / edge pre-pass ----------------

__global__ void init_kernel(int* ghist, int* nid_src, bf16_t* eacsr) {
  int i = threadIdx.x;
  if (i < 64) ghist[i] = 0;
  if (i < 32) nid_src[EE + i] = -1;               // pad for ef chunk tail
  ((int*)(eacsr + (size_t)EE * 16))[i] = 0;       // zero eacsr pad rows (256 ints)
}

// ew + per-graph histogram (LDS-aggregated). NO scattered atomics.
__global__ __launch_bounds__(256) void edge_pass1(const float* __restrict__ ea,
                                                  const int* __restrict__ dst,
                                                  float* __restrict__ ew, int* ghist) {
  __shared__ int h[64];
  int tid = threadIdx.x;
  if (tid < 64) h[tid] = 0;
  __syncthreads();
  int e = blockIdx.x * 256 + tid;  // EE % 256 == 0
  const float4* p = (const float4*)(ea + (size_t)e * EFD);
  float s = 0.f;
#pragma unroll
  for (int i = 0; i < 4; ++i) {
    float4 v = p[i];
    s += v.x * v.x + v.y * v.y + v.z * v.z + v.w * v.w;
  }
  ew[e] = sqrtf(s);
  atomicAdd(&h[dst[e] >> 8], 1);
  __syncthreads();
  if (tid < 64 && h[tid]) atomicAdd(&ghist[tid], h[tid]);
}

__global__ void gexscan_kernel(const int* __restrict__ ghist, int* __restrict__ gstart,
                               int* __restrict__ gcur) {
  if (threadIdx.x == 0) {
    int s = 0;
    for (int g = 0; g < 64; ++g) { gstart[g] = s; gcur[g] = s; s += ghist[g]; }
    gstart[64] = s;
  }
}

// bucket edges by graph with block-aggregated offsets; emit packed records
__global__ __launch_bounds__(256) void graph_scatter_kernel(
    const int* __restrict__ src, const int* __restrict__ dst,
    const float* __restrict__ ew, int* gcur, int2* __restrict__ grec,
    float* __restrict__ ewg) {
  __shared__ int h[64], base[64], h2[64];
  int tid = threadIdx.x;
  if (tid < 64) { h[tid] = 0; h2[tid] = 0; }
  __syncthreads();
  int e0 = blockIdx.x * 2048;
  int gloc[8];
#pragma unroll
  for (int k = 0; k < 8; ++k) {
    gloc[k] = dst[e0 + k * 256 + tid] >> 8;
    atomicAdd(&h[gloc[k]], 1);
  }
  __syncthreads();
  if (tid < 64) base[tid] = h[tid] ? atomicAdd(&gcur[tid], h[tid]) : 0;
  __syncthreads();
#pragma unroll
  for (int k = 0; k < 8; ++k) {
    int e = e0 + k * 256 + tid;
    int g = gloc[k];
    int p = atomicAdd(&h2[g], 1);
    int pos = base[g] + p;
    int ls = src[e] & 255;
    int ld = dst[e] & 255;
    grec[pos] = make_int2(e | (ls << 19), ld);
    ewg[pos] = ew[e];
  }
}

// per-graph LDS counting sort, 128 blocks: blockIdx<64 -> DST pass, else SRC.
// DST pass emits full-coef records {dinv[s]*ew*dinv[d], ls} + start_dst + dinv.
__global__ __launch_bounds__(1024) void graph_sort2_kernel(
    const int2* __restrict__ grec, const float* __restrict__ ewg,
    const int* __restrict__ gstart, int* __restrict__ elist_src,
    int* __restrict__ nid_src, int* __restrict__ start_src,
    float2* __restrict__ dstrec, int* __restrict__ start_dst,
    float* __restrict__ dinv) {
  __shared__ int lbuf[GEMAXE];
  __shared__ unsigned short sl[GEMAXE];
  __shared__ float ewl[GEMAXE];
  __shared__ int h[256], hx[256], h2[256];
  __shared__ float fdinv[256];
  const int g = blockIdx.x & 63;
  const int tid = threadIdx.x;
  const int gs = gstart[g];
  const int cnt = gstart[g + 1] - gs;
  if (tid < 256) { h[tid] = 0; h2[tid] = 0; }
  __syncthreads();
  if (blockIdx.x < 64) {
    for (int i = tid; i < cnt; i += 1024) {
      int2 r = grec[gs + i];
      int ld = r.y;
      sl[i] = (unsigned short)(((r.x >> 19) & 255) | (ld << 8));
      ewl[i] = ewg[gs + i];
      atomicAdd(&h[ld], 1);
    }
    __syncthreads();
    int myc = (tid < 256) ? h[tid] : 0;
    for (int off = 1; off < 256; off <<= 1) {
      int v = (tid < 256 && tid >= off) ? h[tid - off] : 0;
      __syncthreads();
      if (tid < 256) h[tid] += v;
      __syncthreads();
    }
    if (tid < 256) {
      hx[tid] = h[tid] - myc;
      start_dst[g * 256 + tid] = gs + hx[tid];
    }
    if (g == 63 && tid == 0) start_dst[NN] = EE;
    __syncthreads();
    for (int i = tid; i < cnt; i += 1024) {
      int ld = sl[i] >> 8;
      int p = hx[ld] + atomicAdd(&h2[ld], 1);
      lbuf[p] = i;
    }
    __syncthreads();
    if (tid < 256) {
      float dg = 1.0f;
      int s0 = hx[tid], e0 = s0 + myc;
      for (int i = s0; i < e0; ++i) dg += ewl[lbuf[i]];
      float dv = rsqrtf(fmaxf(dg, 1e-12f));
      fdinv[tid] = dv;
      dinv[g * 256 + tid] = dv;
    }
    __syncthreads();
    for (int p = tid; p < cnt; p += 1024) {
      int i = lbuf[p];
      int ls = sl[i] & 255;
      int ld = sl[i] >> 8;
      dstrec[gs + p] =
          make_float2(fdinv[ls] * ewl[i] * fdinv[ld], __int_as_float(ls));
    }
  } else {
    int* wb = (int*)ewl;
    for (int i = tid; i < cnt; i += 1024) {
      int w = grec[gs + i].x;
      wb[i] = w;
      atomicAdd(&h[w >> 19], 1);
    }
    __syncthreads();
    int myc = (tid < 256) ? h[tid] : 0;
    for (int off = 1; off < 256; off <<= 1) {
      int v = (tid < 256 && tid >= off) ? h[tid - off] : 0;
      __syncthreads();
      if (tid < 256) h[tid] += v;
      __syncthreads();
    }
    if (tid < 256) {
      hx[tid] = h[tid] - myc;
      start_src[g * 256 + tid] = gs + hx[tid];
    }
    if (g == 63 && tid == 0) start_src[NN] = EE;
    __syncthreads();
    for (int i = tid; i < cnt; i += 1024) {
      int w = wb[i];
      int ls = w >> 19;
      int p = hx[ls] + atomicAdd(&h2[ls], 1);
      lbuf[p] = w;
    }
    __syncthreads();
    for (int p = tid; p < cnt; p += 1024) {
      int w = lbuf[p];
      elist_src[gs + p] = w & 0x7FFFF;
      nid_src[gs + p] = g * 256 + (w >> 19);
    }
  }
}

// gather edge_attr rows into CSR order as bf16
__global__ void ea_gather_kernel(const float* __restrict__ ea,
                                 const int* __restrict__ elist,
                                 bf16_t* __restrict__ eacsr) {
  int idx = blockIdx.x * 256 + threadIdx.x;
  if (idx >= EE * 2) return;
  int pos = idx >> 1, half = idx & 1;
  int e = elist[pos];
  const f32x4v* p = (const f32x4v*)(ea + (size_t)e * EFD + half * 8);
  f32x4v u0 = p[0], u1 = p[1];
  bf16x8 f;
#pragma unroll
  for (int r = 0; r < 4; ++r) {
    f[r] = (bf16_t)u0[r];
    f[4 + r] = (bf16_t)u1[r];
  }
  *(bf16x8*)(eacsr + (size_t)pos * 16 + half * 8) = f;
}

// ---------------- dense per-graph adjacency build ----------------
// An[16384][256] bf16: An[g*256+i][j] = sum coef(e: dst=i,src=j) + diag dinv^2
__global__ __launch_bounds__(256) void an_build_kernel(
    const float2* __restrict__ dstrec, const int* __restrict__ start_dst,
    const float* __restrict__ dinv, bf16_t* __restrict__ An) {
  __shared__ float AnS[128][256];  // 128 KB
  const int g = blockIdx.x >> 1, h = blockIdx.x & 1;
  const int tid = threadIdx.x;
  float4* az = (float4*)&AnS[0][0];
  for (int i = tid; i < 128 * 256 / 4; i += 256)
    az[i] = make_float4(0.f, 0.f, 0.f, 0.f);
  __syncthreads();
  const int nbase = g * 256 + h * 128;
  if (tid < 128) {
    int node = nbase + tid;
    int st = start_dst[node], en = start_dst[node + 1];
    float* row = AnS[tid];
    for (int p = st; p < en; ++p) {
      float2 r = dstrec[p];
      row[__float_as_int(r.y)] += r.x;
    }
    float dv = dinv[node];
    row[h * 128 + tid] += dv * dv;
  }
  __syncthreads();
  bf16_t* out = An + (size_t)nbase * 256;
  const float* s0 = &AnS[0][0];
  for (int i = tid; i < 128 * 256 / 8; i += 256) {
    bf16x8 v;
#pragma unroll
    for (int r = 0; r < 8; ++r) v[r] = (bf16_t)s0[i * 8 + r];
    *(bf16x8*)(out + i * 8) = v;
  }
}

// ---------------- conversions ----------------

__global__ void cvt_bf16_kernel(const float* __restrict__ in, bf16_t* __restrict__ out,
                                int n4) {
  int i = blockIdx.x * 256 + threadIdx.x;
  if (i >= n4) return;
  float4 v = ((const float4*)in)[i];
  bf16x4 o;
  o[0] = (bf16_t)v.x; o[1] = (bf16_t)v.y; o[2] = (bf16_t)v.z; o[3] = (bf16_t)v.w;
  ((bf16x4*)out)[i] = o;
}

// W: f32 [K][N] row-major -> Wt: bf16 [N][K] row-major
__global__ __launch_bounds__(256) void wt_kernel(const float* __restrict__ W,
                                                 bf16_t* __restrict__ Wt, int K, int N) {
  __shared__ float tile[32][33];
  int bx = blockIdx.x * 32;
  int by = blockIdx.y * 32;
  int tx = threadIdx.x & 31, ty = threadIdx.x >> 5;
#pragma unroll
  for (int i = 0; i < 32; i += 8)
    tile[ty + i][tx] = W[(size_t)(by + ty + i) * N + bx + tx];
  __syncthreads();
#pragma unroll
  for (int i = 0; i < 32; i += 8)
    Wt[(size_t)(bx + ty + i) * K + by + tx] = (bf16_t)tile[tx][ty + i];
}

// ---------------- edge projection via double-MFMA (8 waves x 64 cols) ------
__global__ __launch_bounds__(512) void ef_mfma_kernel(
    const bf16_t* __restrict__ eacsr, const float* __restrict__ ep_w,
    const float* __restrict__ ep_b, const int* __restrict__ nid,
    const int* __restrict__ start, bf16_t* __restrict__ efb) {
  const int tid = threadIdx.x;
  const int lane = tid & 63;
  const int wv = tid >> 6;      // 0..7
  const int l15 = lane & 15;
  const int g = lane >> 4;
  const int n0 = blockIdx.x * 16;
  const int cbase = wv * 64;

  bf16x8 wfr[4];
#pragma unroll
  for (int t = 0; t < 4; ++t) {
    bf16x8 f = {};
    int c = cbase + t * 16 + l15;
    if (g < 2) {
#pragma unroll
      for (int j = 0; j < 8; ++j) f[j] = (bf16_t)ep_w[(g * 8 + j) * CC + c];
    } else if (g == 2) {
      f[0] = (bf16_t)ep_b[c];
    }
    wfr[t] = f;
  }

  const int st = start[n0];
  const int en = start[n0 + 16];
  const int tgt = n0 + l15;

  f32x4v eacc[4] = {};

  for (int cb = st; cb < en; cb += 32) {
    bf16x8 af[2];
#pragma unroll
    for (int mE = 0; mE < 2; ++mE) {
      bf16x8 f = {};
      if (g < 2) {
        f = *(const bf16x8*)(eacsr + (size_t)(cb + mE * 16 + l15) * 16 + g * 8);
      } else if (g == 2) {
        f[0] = (bf16_t)1.0f;
      }
      af[mE] = f;
    }
    int4 idlo = *(const int4*)(nid + cb + g * 4);
    int4 idhi = *(const int4*)(nid + cb + 16 + g * 4);
    bf16x8 sf;
    sf[0] = (idlo.x == tgt) ? (bf16_t)1.0f : (bf16_t)0.0f;
    sf[1] = (idlo.y == tgt) ? (bf16_t)1.0f : (bf16_t)0.0f;
    sf[2] = (idlo.z == tgt) ? (bf16_t)1.0f : (bf16_t)0.0f;
    sf[3] = (idlo.w == tgt) ? (bf16_t)1.0f : (bf16_t)0.0f;
    sf[4] = (idhi.x == tgt) ? (bf16_t)1.0f : (bf16_t)0.0f;
    sf[5] = (idhi.y == tgt) ? (bf16_t)1.0f : (bf16_t)0.0f;
    sf[6] = (idhi.z == tgt) ? (bf16_t)1.0f : (bf16_t)0.0f;
    sf[7] = (idhi.w == tgt) ? (bf16_t)1.0f : (bf16_t)0.0f;
#pragma unroll
    for (int t = 0; t < 4; ++t) {
      f32x4v s0 = {}, s1 = {};
      s0 = __builtin_amdgcn_mfma_f32_16x16x32_bf16(af[0], wfr[t], s0, 0, 0, 0);
      s1 = __builtin_amdgcn_mfma_f32_16x16x32_bf16(af[1], wfr[t], s1, 0, 0, 0);
      union { bf16x8 v; bf16x4 h[2]; } pf;
#pragma unroll
      for (int r = 0; r < 4; ++r) {
        pf.h[0][r] = (bf16_t)fmaxf(s0[r], 0.f);
        pf.h[1][r] = (bf16_t)fmaxf(s1[r], 0.f);
      }
      eacc[t] = __builtin_amdgcn_mfma_f32_16x16x32_bf16(sf, pf.v, eacc[t], 0, 0, 0);
    }
  }
#pragma unroll
  for (int t = 0; t < 4; ++t) {
    int c = cbase + t * 16 + l15;
#pragma unroll
    for (int r = 0; r < 4; ++r) {
      int node = n0 + g * 4 + r;
      efb[(size_t)node * (2 * CC) + CC + c] = (bf16_t)eacc[t][r];
    }
  }
}

// ---------------- bf16 MFMA GEMM (m97 structure) ----------------
__device__ __forceinline__ void gl_lds16(const bf16_t* g, bf16_t* l) {
  __builtin_amdgcn_global_load_lds(
      (const __attribute__((address_space(1))) void*)g,
      (__attribute__((address_space(3))) void*)l, 16, 0, 0);
}

template <int ACT, int OUT>
__global__ __launch_bounds__(256) void gemm_bf16_kernel(
    const bf16_t* __restrict__ A, const bf16_t* __restrict__ Bt,
    const float* __restrict__ bias, void* __restrict__ Cout, int M, int N, int K) {
  __shared__ __align__(16) bf16_t Al[128 * 32];
  __shared__ __align__(16) bf16_t Bl[128 * 32];
  const int tid = threadIdx.x;
  const int lane = tid & 63;
  const int wave = tid >> 6;
  const int row0 = blockIdx.y * 128;
  const int col0 = blockIdx.x * 128;
  const int wm = (wave >> 1) * 64;
  const int wn = (wave & 1) * 64;
  f32x4v acc[4][4] = {};
  const bf16_t* aBase = A + (size_t)(row0 + (tid >> 2)) * K + (tid & 3) * 8;
  const bf16_t* bBase = Bt + (size_t)(col0 + (tid >> 2)) * K + (tid & 3) * 8;
  bf16_t* al0 = Al + wave * 512;
  bf16_t* al1 = Al + 2048 + wave * 512;
  bf16_t* bl0 = Bl + wave * 512;
  bf16_t* bl1 = Bl + 2048 + wave * 512;
  const int fr = lane & 15;
  const int fk = (lane >> 4) * 8;
  for (int k0 = 0; k0 < K; k0 += 32) {
    gl_lds16(aBase + k0, al0);
    gl_lds16(aBase + (size_t)64 * K + k0, al1);
    gl_lds16(bBase + k0, bl0);
    gl_lds16(bBase + (size_t)64 * K + k0, bl1);
    __syncthreads();
    bf16x8 af[4], bfv[4];
#pragma unroll
    for (int m = 0; m < 4; ++m)
      af[m] = *(const bf16x8*)(Al + (wm + m * 16 + fr) * 32 + fk);
#pragma unroll
    for (int n = 0; n < 4; ++n)
      bfv[n] = *(const bf16x8*)(Bl + (wn + n * 16 + fr) * 32 + fk);
#pragma unroll
    for (int m = 0; m < 4; ++m)
#pragma unroll
      for (int n = 0; n < 4; ++n)
        acc[m][n] =
            __builtin_amdgcn_mfma_f32_16x16x32_bf16(af[m], bfv[n], acc[m][n], 0, 0, 0);
    __syncthreads();
  }
  const int fq = (lane >> 4) * 4;
#pragma unroll
  for (int m = 0; m < 4; ++m) {
    int grb = row0 + wm + m * 16 + fq;
#pragma unroll
    for (int n = 0; n < 4; ++n) {
      int gc = col0 + wn + n * 16 + fr;
      float bv = bias ? bias[gc] : 0.f;
#pragma unroll
      for (int r = 0; r < 4; ++r) {
        float v = acc[m][n][r] + bv;
        if (ACT == 1) v = v / (1.f + __expf(-v));
        if (OUT == 0)
          ((float*)Cout)[(size_t)(grb + r) * N + gc] = v;
        else
          ((bf16_t*)Cout)[(size_t)(grb + r) * N + gc] = (bf16_t)v;
      }
    }
  }
}

// ---------------- block-diagonal An GEMM: xcef[:, :512] = An_g @ xw_g + b --
// An [16384][256] bf16; xwT [512][16384] bf16 (chan-major); out bf16 ldC=1024
__global__ __launch_bounds__(256) void an_gemm_kernel(
    const bf16_t* __restrict__ An, const bf16_t* __restrict__ xwT,
    const float* __restrict__ bias, bf16_t* __restrict__ outb) {
  __shared__ __align__(16) bf16_t Al[128 * 32];
  __shared__ __align__(16) bf16_t Bl[128 * 32];
  const int tid = threadIdx.x;
  const int lane = tid & 63;
  const int wave = tid >> 6;
  const int row0 = blockIdx.y * 128;  // node rows
  const int col0 = blockIdx.x * 128;  // chan cols
  const int g = row0 >> 8;
  f32x4v acc[4][4] = {};
  const bf16_t* aBase = An + (size_t)(row0 + (tid >> 2)) * 256 + (tid & 3) * 8;
  const bf16_t* bBase =
      xwT + (size_t)(col0 + (tid >> 2)) * NN + g * 256 + (tid & 3) * 8;
  bf16_t* al0 = Al + wave * 512;
  bf16_t* al1 = Al + 2048 + wave * 512;
  bf16_t* bl0 = Bl + wave * 512;
  bf16_t* bl1 = Bl + 2048 + wave * 512;
  const int wm = (wave >> 1) * 64;
  const int wn = (wave & 1) * 64;
  const int fr = lane & 15;
  const int fk = (lane >> 4) * 8;
  for (int k0 = 0; k0 < 256; k0 += 32) {
    gl_lds16(aBase + k0, al0);
    gl_lds16(aBase + (size_t)64 * 256 + k0, al1);
    gl_lds16(bBase + k0, bl0);
    gl_lds16(bBase + (size_t)64 * NN + k0, bl1);
    __syncthreads();
    bf16x8 af[4], bfv[4];
#pragma unroll
    for (int m = 0; m < 4; ++m)
      af[m] = *(const bf16x8*)(Al + (wm + m * 16 + fr) * 32 + fk);
#pragma unroll
    for (int n = 0; n < 4; ++n)
      bfv[n] = *(const bf16x8*)(Bl + (wn + n * 16 + fr) * 32 + fk);
#pragma unroll
    for (int m = 0; m < 4; ++m)
#pragma unroll
      for (int n = 0; n < 4; ++n)
        acc[m][n] =
            __builtin_amdgcn_mfma_f32_16x16x32_bf16(af[m], bfv[n], acc[m][n], 0, 0, 0);
    __syncthreads();
  }
  const int fq = (lane >> 4) * 4;
#pragma unroll
  for (int m = 0; m < 4; ++m) {
    int grb = row0 + wm + m * 16 + fq;
#pragma unroll
    for (int n = 0; n < 4; ++n) {
      int gc = col0 + wn + n * 16 + fr;
      float bv = bias[gc];
#pragma unroll
      for (int r = 0; r < 4; ++r)
        outb[(size_t)(grb + r) * (2 * CC) + gc] = (bf16_t)(acc[m][n][r] + bv);
    }
  }
}

// ---------------- layernorm fused kernels ----------------

__device__ inline void block_reduce2(float& s, float& q, float* red) {
#pragma unroll
  for (int off = 32; off >= 1; off >>= 1) {
    s += __shfl_xor(s, off, 64);
    q += __shfl_xor(q, off, 64);
  }
  int wid = threadIdx.x >> 6;
  if ((threadIdx.x & 63) == 0) { red[wid * 2] = s; red[wid * 2 + 1] = q; }
  __syncthreads();
  s = red[0] + red[2] + red[4] + red[6];
  q = red[1] + red[3] + red[5] + red[7];
}

// out = LN(A + B) * g + be ; IA/IB: 1 = bf16 input; WF: 1 = f32 out, else bf16
template <int IA, int IB, int WF>
__global__ __launch_bounds__(256) void ln_addT_kernel(
    const void* __restrict__ A, const void* __restrict__ Bv,
    const float* __restrict__ g, const float* __restrict__ be,
    float* __restrict__ outf, bf16_t* __restrict__ outb) {
  int row = blockIdx.x, tid = threadIdx.x, c0 = tid * 2;
  __shared__ float red[8];
  float2 a = IA ? ldb2((const bf16_t*)A + (size_t)row * CC + c0)
                : *(const float2*)((const float*)A + (size_t)row * CC + c0);
  float2 b = IB ? ldb2((const bf16_t*)Bv + (size_t)row * CC + c0)
                : *(const float2*)((const float*)Bv + (size_t)row * CC + c0);
  float x0 = a.x + b.x, x1 = a.y + b.y;
  float s = x0 + x1, q = x0 * x0 + x1 * x1;
  block_reduce2(s, q, red);
  float mean = s * (1.f / CC);
  float var = q * (1.f / CC) - mean * mean;
  float rs = rsqrtf(var + 1e-5f);
  float o0 = (x0 - mean) * rs * g[c0] + be[c0];
  float o1 = (x1 - mean) * rs * g[c0 + 1] + be[c0 + 1];
  if (WF) {
    *(float2*)(outf + (size_t)row * CC + c0) = make_float2(o0, o1);
  } else {
    outb[(size_t)row * CC + c0] = (bf16_t)o0;
    outb[(size_t)row * CC + c0 + 1] = (bf16_t)o1;
  }
}

// gate+mix+LN+relu+residual; bf16 inputs (gpre, xc|ef), f32 x residual; bf16 out
__global__ __launch_bounds__(256) void ln_gate_kernel(
    const bf16_t* __restrict__ gpreb, const float* __restrict__ gate_b,
    const bf16_t* __restrict__ xcef, const float* __restrict__ n1g,
    const float* __restrict__ n1b, const float* __restrict__ xin,
    bf16_t* __restrict__ x2b) {
  int row = blockIdx.x, tid = threadIdx.x, c0 = tid * 2;
  __shared__ float red[8];
  float2 gp = ldb2(gpreb + (size_t)row * CC + c0);
  float2 xcv = ldb2(xcef + (size_t)row * (2 * CC) + c0);
  float2 efv = ldb2(xcef + (size_t)row * (2 * CC) + CC + c0);
  float g0 = 1.f / (1.f + __expf(-(gp.x + gate_b[c0])));
  float g1 = 1.f / (1.f + __expf(-(gp.y + gate_b[c0 + 1])));
  float x0 = g0 * xcv.x + (1.f - g0) * efv.x;
  float x1 = g1 * xcv.y + (1.f - g1) * efv.y;
  float s = x0 + x1, q = x0 * x0 + x1 * x1;
  block_reduce2(s, q, red);
  float mean = s * (1.f / CC);
  float var = q * (1.f / CC) - mean * mean;
  float rs = rsqrtf(var + 1e-5f);
  float2 xi = *(const float2*)(xin + (size_t)row * CC + c0);
  float o0 = fmaxf((x0 - mean) * rs * n1g[c0] + n1b[c0], 0.f) + xi.x;
  float o1 = fmaxf((x1 - mean) * rs * n1g[c0 + 1] + n1b[c0 + 1], 0.f) + xi.y;
  x2b[(size_t)row * CC + c0] = (bf16_t)o0;
  x2b[(size_t)row * CC + c0 + 1] = (bf16_t)o1;
}

// ---------------- V^T pack (pre-swizzled + pi-permuted K for attn) ---------
__global__ __launch_bounds__(256) void vt_pack_kernel(const bf16_t* __restrict__ qkvb,
                                                      bf16_t* __restrict__ vt) {
  int b = blockIdx.x >> 3, h = blockIdx.x & 7;
  int nb = b * 256;
  size_t voff = 1024 + (size_t)h * 64;
  char* out = (char*)(vt + (size_t)blockIdx.x * (64 * 256));
  __shared__ bf16_t tile[64][80];
  int tid = threadIdx.x;
  for (int kb = 0; kb < 4; ++kb) {
    __syncthreads();
#pragma unroll
    for (int p = 0; p < 2; ++p) {
      int k = p * 32 + (tid >> 3);
      int d8 = tid & 7;
      bf16x8 v = *(const bf16x8*)(qkvb + (size_t)(nb + kb * 64 + k) * 1536 + voff + d8 * 8);
      *(bf16x8*)(&tile[k][d8 * 8]) = v;
    }
    __syncthreads();
#pragma unroll
    for (int p = 0; p < 2; ++p) {
      int d = p * 32 + (tid >> 3);
      int k8 = tid & 7;
      bf16x8 v;
#pragma unroll
      for (int j = 0; j < 8; ++j) {
        int pos = k8 * 8 + j;
        int sl = pos & 31;
        int srck = (pos & 32) + ((sl >> 3) << 2) + (sl & 3) + (((sl >> 2) & 1) << 4);
        v[j] = tile[srck][d];
      }
      int byteoff = d * 512 + ((kb * 128 + k8 * 16) ^ ((d & 7) << 4));
      *(bf16x8*)(out + byteoff) = v;
    }
  }
}

// ---------------- MFMA attention (shuffle-free PV) ----------------
__global__ __launch_bounds__(256, 2) void attn_mfma_kernel(
    const bf16_t* __restrict__ qkvb, const bf16_t* __restrict__ vt,
    bf16_t* __restrict__ o) {
  const int b = blockIdx.x >> 3;
  const int h = blockIdx.x & 7;
  const int nb = b * 256;
  const int tid = threadIdx.x;
  const int lane = tid & 63;
  const int wv = tid >> 6;
  const int l15 = lane & 15;
  const int g = lane >> 4;
  const int swzk = (l15 & 7) << 4;
  __shared__ __align__(16) bf16_t Klds[256 * 64];
  __shared__ __align__(16) bf16_t Vtlds[64 * 256];
  const size_t qoff = (size_t)h * 64;
  const size_t koff = 512 + (size_t)h * 64;

  {
    const int dcol = 16 * ((tid & 7) ^ ((tid >> 3) & 7));
    const bf16_t* srcb = qkvb + koff + (dcol >> 1);
#pragma unroll
    for (int i = 0; i < 8; ++i) {
      int k = i * 32 + (tid >> 3);
      gl_lds16(srcb + (size_t)(nb + k) * 1536, Klds + ((i * 4096 + wv * 1024) >> 1));
    }
  }
  {
    const bf16_t* vsrc = vt + (size_t)blockIdx.x * (64 * 256);
#pragma unroll
    for (int i = 0; i < 8; ++i) {
      int base = i * 4096 + wv * 1024;
      gl_lds16(vsrc + ((base >> 1) + lane * 8), Vtlds + (base >> 1));
    }
  }

  bf16x8 qf[4][2];
#pragma unroll
  for (int n = 0; n < 4; ++n) {
    const bf16_t* qp = qkvb + (size_t)(nb + wv * 64 + 16 * n + l15) * 1536 + qoff + g * 8;
    qf[n][0] = *(const bf16x8*)(qp);
    qf[n][1] = *(const bf16x8*)(qp + 32);
  }

  __syncthreads();

  f32x4v oacc[4][4] = {};
  float mrun[4] = {-1e30f, -1e30f, -1e30f, -1e30f};
  float lrun[4] = {0.f, 0.f, 0.f, 0.f};

  for (int kc = 0; kc < 4; ++kc) {
    f32x4v sacc[4][4] = {};
    const int kb128 = (kc * 64 + l15) * 128;
#pragma unroll
    for (int m = 0; m < 4; ++m) {
      bf16x8 a0 = *(const bf16x8*)(Klds + ((kb128 + m * 2048 + ((g * 16) ^ swzk)) >> 1));
      bf16x8 a1 =
          *(const bf16x8*)(Klds + ((kb128 + m * 2048 + ((64 + g * 16) ^ swzk)) >> 1));
#pragma unroll
      for (int n = 0; n < 4; ++n) {
        sacc[m][n] = __builtin_amdgcn_mfma_f32_16x16x32_bf16(a0, qf[n][0], sacc[m][n], 0, 0, 0);
        sacc[m][n] = __builtin_amdgcn_mfma_f32_16x16x32_bf16(a1, qf[n][1], sacc[m][n], 0, 0, 0);
      }
    }
    uint2 pb[4][4];
#pragma unroll
    for (int n = 0; n < 4; ++n) {
      float mx = sacc[0][n][0];
#pragma unroll
      for (int m = 0; m < 4; ++m)
#pragma unroll
        for (int r = 0; r < 4; ++r) mx = fmaxf(mx, sacc[m][n][r]);
      mx = fmaxf(mx, __shfl_xor(mx, 16));
      mx = fmaxf(mx, __shfl_xor(mx, 32));
      float mnew = fmaxf(mrun[n], mx);
      float c = __expf((mrun[n] - mnew) * 0.125f);
      mrun[n] = mnew;
      float s = 0.f;
#pragma unroll
      for (int m = 0; m < 4; ++m) {
        float p0 = __expf((sacc[m][n][0] - mnew) * 0.125f);
        float p1 = __expf((sacc[m][n][1] - mnew) * 0.125f);
        float p2 = __expf((sacc[m][n][2] - mnew) * 0.125f);
        float p3 = __expf((sacc[m][n][3] - mnew) * 0.125f);
        s += (p0 + p1) + (p2 + p3);
        union { bf16x4 v; uint2 u; } cv;
        cv.v[0] = (bf16_t)p0; cv.v[1] = (bf16_t)p1;
        cv.v[2] = (bf16_t)p2; cv.v[3] = (bf16_t)p3;
        pb[m][n] = cv.u;
      }
      s += __shfl_xor(s, 16);
      s += __shfl_xor(s, 32);
      lrun[n] = lrun[n] * c + s;
#pragma unroll
      for (int m = 0; m < 4; ++m)
#pragma unroll
        for (int r = 0; r < 4; ++r) oacc[m][n][r] *= c;
    }
#pragma unroll
    for (int h2 = 0; h2 < 2; ++h2) {
      bf16x8 vf[4];
#pragma unroll
      for (int m = 0; m < 4; ++m)
        vf[m] = *(const bf16x8*)(Vtlds + (((16 * m + l15) * 512 +
                                          ((kc * 128 + h2 * 64 + g * 16) ^ swzk)) >> 1));
#pragma unroll
      for (int n = 0; n < 4; ++n) {
        union { uint2 u[2]; bf16x8 v; } pf;
        pf.u[0] = pb[2 * h2][n];
        pf.u[1] = pb[2 * h2 + 1][n];
#pragma unroll
        for (int m = 0; m < 4; ++m)
          oacc[m][n] =
              __builtin_amdgcn_mfma_f32_16x16x32_bf16(vf[m], pf.v, oacc[m][n], 0, 0, 0);
      }
    }
  }
  float inv[4];
#pragma unroll
  for (int n = 0; n < 4; ++n) inv[n] = 1.0f / lrun[n];
#pragma unroll
  for (int m = 0; m < 4; ++m)
#pragma unroll
    for (int n = 0; n < 4; ++n) {
      bf16x4 pk;
#pragma unroll
      for (int r = 0; r < 4; ++r) pk[r] = (bf16_t)(oacc[m][n][r] * inv[n]);
      *(bf16x4*)(o + (size_t)(nb + wv * 64 + 16 * n + l15) * 512 + h * 64 + 16 * m +
                 4 * g) = pk;
    }
}

// ---------------- launch ----------------

static inline char* alignp(char* p, size_t a) {
  return (char*)(((uintptr_t)p + a - 1) & ~(uintptr_t)(a - 1));
}

extern "C" void kernel_launch(void* const* d_in, const int* in_sizes, int n_in,
                              void* d_out, int out_size, void* d_ws, size_t ws_size,
                              hipStream_t stream) {
  const float* x = (const float*)d_in[0];
  const float* edge_attr = (const float*)d_in[1];
  const float* gcn_w = (const float*)d_in[2];
  const float* gcn_b = (const float*)d_in[3];
  const float* ep_w = (const float*)d_in[4];
  const float* ep_b = (const float*)d_in[5];
  const float* gate_w = (const float*)d_in[6];
  const float* gate_b = (const float*)d_in[7];
  const float* n1_g = (const float*)d_in[8];
  const float* n1_b = (const float*)d_in[9];
  const float* in_w = (const float*)d_in[10];
  const float* in_b = (const float*)d_in[11];
  const float* out_w = (const float*)d_in[12];
  const float* out_b = (const float*)d_in[13];
  const float* tn_g = (const float*)d_in[14];
  const float* tn_b = (const float*)d_in[15];
  const float* m_w1 = (const float*)d_in[16];
  const float* m_b1 = (const float*)d_in[17];
  const float* m_w2 = (const float*)d_in[18];
  const float* m_b2 = (const float*)d_in[19];
  const float* fn_g = (const float*)d_in[20];
  const float* fn_b = (const float*)d_in[21];
  const int* eidx = (const int*)d_in[22];
  const int* src = eidx;
  const int* dst = eidx + EE;

  float* ws = (float*)d_ws;
  float* R1 = ws;
  float* R2 = R1 + (size_t)NN * 3 * CC;
  float* R3 = R2 + (size_t)NN * CC;
  float* R4 = R3 + (size_t)NN * CC;
  float* ew = R4 + (size_t)NN * CC;
  float* dinv = ew + EE;
  int* ip = (int*)(dinv + NN);
  int* ghist = ip;      ip += 64;
  int* gstart = ip;     ip += 65;
  int* gcur = ip;       ip += 64;
  int* elist_src = ip;  ip += EE;
  int* nid_src = ip;    ip += EE + 32;
  int* start_src = ip;  ip += NN + 1;
  int* start_dst = ip;  ip += NN + 1;
  char* bp = alignp((char*)ip, 64);
  int2* grec = (int2*)bp;             bp += (size_t)EE * 8;
  float* ewg = (float*)bp;            bp += (size_t)EE * 4;
  float2* dstrec = (float2*)bp;       bp += (size_t)EE * 8;
  bf16_t* x2b = (bf16_t*)bp;          bp += (size_t)NN * CC * 2;
  bf16_t* gcn_wt = (bf16_t*)bp;       bp += (size_t)CC * CC * 2;
  bf16_t* gate_wt = (bf16_t*)bp;      bp += (size_t)CC * 2 * CC * 2;
  bf16_t* in_wt = (bf16_t*)bp;        bp += (size_t)3 * CC * CC * 2;
  bf16_t* out_wt = (bf16_t*)bp;       bp += (size_t)CC * CC * 2;
  bf16_t* m_w1t = (bf16_t*)bp;        bp += (size_t)2 * CC * CC * 2;
  bf16_t* m_w2t = (bf16_t*)bp;        bp += (size_t)CC * 2 * CC * 2;

  bf16_t* xb = (bf16_t*)R1;      // bf16(x)
  bf16_t* xcefb = (bf16_t*)R1;   // [x_conv | ef] bf16 N x 2C
  bf16_t* qkvb = (bf16_t*)R1;    // qkv bf16 N x 1536
  bf16_t* hb = (bf16_t*)R1;      // mlp hidden bf16 N x 2C
  bf16_t* eacsr = (bf16_t*)((char*)R1 + (size_t)64 * 1024 * 1024);  // 16.8MB
  bf16_t* xwT = (bf16_t*)R2;     // (x@gcn_w)^T bf16 [512][16384]
  bf16_t* gpreb = (bf16_t*)R2;   // gate pre-act bf16 (after xwT dead)
  bf16_t* ob = (bf16_t*)R2;      // attn out bf16 (first half of R2)
  bf16_t* vt = ob + (size_t)NN * CC;  // V^T packed (second half of R2)
  bf16_t* x3b = (bf16_t*)R2;     // bf16(x3) (after ob dead)
  bf16_t* AnFull = (bf16_t*)R3;  // dense adjacency bf16 [16384][256] (8MB)
  bf16_t* oprjb = (bf16_t*)R4;   // out-proj bf16
  float* yf = R4;                // mlp2 f32 out (after oprjb dead)

  // --- edge prep ---
  init_kernel<<<1, 256, 0, stream>>>(ghist, nid_src, eacsr);
  edge_pass1<<<EE / 256, 256, 0, stream>>>(edge_attr, dst, ew, ghist);
  gexscan_kernel<<<1, 64, 0, stream>>>(ghist, gstart, gcur);
  graph_scatter_kernel<<<EE / 2048, 256, 0, stream>>>(src, dst, ew, gcur, grec, ewg);
  graph_sort2_kernel<<<128, 1024, 0, stream>>>(grec, ewg, gstart, elist_src, nid_src,
                                               start_src, dstrec, start_dst, dinv);
  ea_gather_kernel<<<(EE * 2 + 255) / 256, 256, 0, stream>>>(edge_attr, elist_src,
                                                             eacsr);
  an_build_kernel<<<128, 256, 0, stream>>>(dstrec, start_dst, dinv, AnFull);

  // --- weight transposes ---
  wt_kernel<<<dim3(CC / 32, CC / 32), 256, 0, stream>>>(gcn_w, gcn_wt, CC, CC);
  wt_kernel<<<dim3(CC / 32, 2 * CC / 32), 256, 0, stream>>>(gate_w, gate_wt, 2 * CC, CC);
  wt_kernel<<<dim3(3 * CC / 32, CC / 32), 256, 0, stream>>>(in_w, in_wt, CC, 3 * CC);
  wt_kernel<<<dim3(CC / 32, CC / 32), 256, 0, stream>>>(out_w, out_wt, CC, CC);
  wt_kernel<<<dim3(2 * CC / 32, CC / 32), 256, 0, stream>>>(m_w1, m_w1t, CC, 2 * CC);
  wt_kernel<<<dim3(CC / 32, 2 * CC / 32), 256, 0, stream>>>(m_w2, m_w2t, 2 * CC, CC);

  // --- GCN conv: xwT = (x @ gcn_w)^T via flipped GEMM, then dense An GEMM ---
  cvt_bf16_kernel<<<(NN * CC / 4 + 255) / 256, 256, 0, stream>>>(x, xb, NN * CC / 4);
  gemm_bf16_kernel<0, 1><<<dim3(NN / 128, CC / 128), 256, 0, stream>>>(
      gcn_wt, xb, nullptr, xwT, CC, NN, CC);
  an_gemm_kernel<<<dim3(CC / 128, NN / 128), 256, 0, stream>>>(AnFull, xwT, gcn_b,
                                                               xcefb);
  ef_mfma_kernel<<<NN / 16, 512, 0, stream>>>(eacsr, ep_w, ep_b, nid_src, start_src,
                                              xcefb);
  dim3 gA(CC / 128, NN / 128);
  gemm_bf16_kernel<0, 1><<<gA, 256, 0, stream>>>(xcefb, gate_wt, nullptr, gpreb, NN,
                                                 CC, 2 * CC);
  ln_gate_kernel<<<NN, 256, 0, stream>>>(gpreb, gate_b, xcefb, n1_g, n1_b, x, x2b);

  // --- MHA ---
  dim3 gQ(3 * CC / 128, NN / 128);
  gemm_bf16_kernel<0, 1><<<gQ, 256, 0, stream>>>(x2b, in_wt, in_b, qkvb, NN, 3 * CC, CC);
  vt_pack_kernel<<<BB * HH, 256, 0, stream>>>(qkvb, vt);
  attn_mfma_kernel<<<BB * HH, 256, 0, stream>>>(qkvb, vt, ob);
  gemm_bf16_kernel<0, 1><<<gA, 256, 0, stream>>>(ob, out_wt, out_b, oprjb, NN, CC, CC);
  ln_addT_kernel<1, 1, 0><<<NN, 256, 0, stream>>>(x2b, oprjb, tn_g, tn_b, nullptr, x3b);

  // --- MLP ---
  dim3 gH(2 * CC / 128, NN / 128);
  gemm_bf16_kernel<1, 1><<<gH, 256, 0, stream>>>(x3b, m_w1t, m_b1, hb, NN, 2 * CC, CC);
  gemm_bf16_kernel<0, 0><<<gA, 256, 0, stream>>>(hb, m_w2t, m_b2, yf, NN, CC, 2 * CC);
  ln_addT_kernel<1, 0, 1><<<NN, 256, 0, stream>>>(x3b, yf, fn_g, fn_b, (float*)d_out,
                                                  nullptr);
}

// Round 14
// 458.031 us; speedup vs baseline: 1.7612x; 1.0325x over previous
//
#include <hip/hip_runtime.h>

#define NN 16384
#define CC 512
#define EE 524288
#define BB 64
#define HH 8
#define EFD 16
#define GEMAXE 10240

typedef __bf16 bf16_t;
typedef __bf16 bf16x4 __attribute__((ext_vector_type(4)));
typedef __bf16 bf16x8 __attribute__((ext_vector_type(8)));
typedef float f32x4v __attribute__((ext_vector_type(4)));

__device__ __forceinline__ float2 ldb2(const bf16_t* p) {
  unsigned w = *(const unsigned*)p;
  return make_float2(__uint_as_float(w << 16), __uint_as_float(w & 0xFFFF0000u));
}

// XCD-aware chunked swizzle (nwg % 8 == 0 for all our grids)
__device__ __forceinline__ int2 xcd_swizzle() {
  int nwg = gridDim.x * gridDim.y;
  int bid = blockIdx.y * gridDim.x + blockIdx.x;
  int wg = (bid & 7) * (nwg >> 3) + (bid >> 3);
  return make_int2(wg % gridDim.x, wg / gridDim.x);
}

// ---------------- init / edge pre-pass ----------------

__global__ void init_kernel(int* ghist, int* nid_src, bf16_t* eacsr) {
  int i = threadIdx.x;
  if (i < 64) ghist[i] = 0;
  if (i < 32) nid_src[EE + i] = -1;               // pad for ef chunk tail
  ((int*)(eacsr + (size_t)EE * 16))[i] = 0;       // zero eacsr pad rows (256 ints)
}

// ew + per-graph histogram (LDS-aggregated). NO scattered atomics.
__global__ __launch_bounds__(256) void edge_pass1(const float* __restrict__ ea,
                                                  const int* __restrict__ dst,
                                                  float* __restrict__ ew, int* ghist) {
  __shared__ int h[64];
  int tid = threadIdx.x;
  if (tid < 64) h[tid] = 0;
  __syncthreads();
  int e = blockIdx.x * 256 + tid;  // EE % 256 == 0
  const float4* p = (const float4*)(ea + (size_t)e * EFD);
  float s = 0.f;
#pragma unroll
  for (int i = 0; i < 4; ++i) {
    float4 v = p[i];
    s += v.x * v.x + v.y * v.y + v.z * v.z + v.w * v.w;
  }
  ew[e] = sqrtf(s);
  atomicAdd(&h[dst[e] >> 8], 1);
  __syncthreads();
  if (tid < 64 && h[tid]) atomicAdd(&ghist[tid], h[tid]);
}

__global__ void gexscan_kernel(const int* __restrict__ ghist, int* __restrict__ gstart,
                               int* __restrict__ gcur) {
  if (threadIdx.x == 0) {
    int s = 0;
    for (int g = 0; g < 64; ++g) { gstart[g] = s; gcur[g] = s; s += ghist[g]; }
    gstart[64] = s;
  }
}

// bucket edges by graph with block-aggregated offsets; emit packed records
__global__ __launch_bounds__(256) void graph_scatter_kernel(
    const int* __restrict__ src, const int* __restrict__ dst,
    const float* __restrict__ ew, int* gcur, int2* __restrict__ grec,
    float* __restrict__ ewg) {
  __shared__ int h[64], base[64], h2[64];
  int tid = threadIdx.x;
  if (tid < 64) { h[tid] = 0; h2[tid] = 0; }
  __syncthreads();
  int e0 = blockIdx.x * 2048;
  int gloc[8];
#pragma unroll
  for (int k = 0; k < 8; ++k) {
    gloc[k] = dst[e0 + k * 256 + tid] >> 8;
    atomicAdd(&h[gloc[k]], 1);
  }
  __syncthreads();
  if (tid < 64) base[tid] = h[tid] ? atomicAdd(&gcur[tid], h[tid]) : 0;
  __syncthreads();
#pragma unroll
  for (int k = 0; k < 8; ++k) {
    int e = e0 + k * 256 + tid;
    int g = gloc[k];
    int p = atomicAdd(&h2[g], 1);
    int pos = base[g] + p;
    int ls = src[e] & 255;
    int ld = dst[e] & 255;
    grec[pos] = make_int2(e | (ls << 19), ld);
    ewg[pos] = ew[e];
  }
}

// per-graph LDS counting sort, 128 blocks: blockIdx<64 -> DST pass, else SRC.
// DST pass emits full-coef records {dinv[s]*ew*dinv[d], ls} + start_dst + dinv.
__global__ __launch_bounds__(1024) void graph_sort2_kernel(
    const int2* __restrict__ grec, const float* __restrict__ ewg,
    const int* __restrict__ gstart, int* __restrict__ elist_src,
    int* __restrict__ nid_src, int* __restrict__ start_src,
    float2* __restrict__ dstrec, int* __restrict__ start_dst,
    float* __restrict__ dinv) {
  __shared__ int lbuf[GEMAXE];
  __shared__ unsigned short sl[GEMAXE];
  __shared__ float ewl[GEMAXE];
  __shared__ int h[256], hx[256], h2[256];
  __shared__ float fdinv[256];
  const int g = blockIdx.x & 63;
  const int tid = threadIdx.x;
  const int gs = gstart[g];
  const int cnt = gstart[g + 1] - gs;
  if (tid < 256) { h[tid] = 0; h2[tid] = 0; }
  __syncthreads();
  if (blockIdx.x < 64) {
    for (int i = tid; i < cnt; i += 1024) {
      int2 r = grec[gs + i];
      int ld = r.y;
      sl[i] = (unsigned short)(((r.x >> 19) & 255) | (ld << 8));
      ewl[i] = ewg[gs + i];
      atomicAdd(&h[ld], 1);
    }
    __syncthreads();
    int myc = (tid < 256) ? h[tid] : 0;
    for (int off = 1; off < 256; off <<= 1) {
      int v = (tid < 256 && tid >= off) ? h[tid - off] : 0;
      __syncthreads();
      if (tid < 256) h[tid] += v;
      __syncthreads();
    }
    if (tid < 256) {
      hx[tid] = h[tid] - myc;
      start_dst[g * 256 + tid] = gs + hx[tid];
    }
    if (g == 63 && tid == 0) start_dst[NN] = EE;
    __syncthreads();
    for (int i = tid; i < cnt; i += 1024) {
      int ld = sl[i] >> 8;
      int p = hx[ld] + atomicAdd(&h2[ld], 1);
      lbuf[p] = i;
    }
    __syncthreads();
    if (tid < 256) {
      float dg = 1.0f;
      int s0 = hx[tid], e0 = s0 + myc;
      for (int i = s0; i < e0; ++i) dg += ewl[lbuf[i]];
      float dv = rsqrtf(fmaxf(dg, 1e-12f));
      fdinv[tid] = dv;
      dinv[g * 256 + tid] = dv;
    }
    __syncthreads();
    for (int p = tid; p < cnt; p += 1024) {
      int i = lbuf[p];
      int ls = sl[i] & 255;
      int ld = sl[i] >> 8;
      dstrec[gs + p] =
          make_float2(fdinv[ls] * ewl[i] * fdinv[ld], __int_as_float(ls));
    }
  } else {
    int* wb = (int*)ewl;
    for (int i = tid; i < cnt; i += 1024) {
      int w = grec[gs + i].x;
      wb[i] = w;
      atomicAdd(&h[w >> 19], 1);
    }
    __syncthreads();
    int myc = (tid < 256) ? h[tid] : 0;
    for (int off = 1; off < 256; off <<= 1) {
      int v = (tid < 256 && tid >= off) ? h[tid - off] : 0;
      __syncthreads();
      if (tid < 256) h[tid] += v;
      __syncthreads();
    }
    if (tid < 256) {
      hx[tid] = h[tid] - myc;
      start_src[g * 256 + tid] = gs + hx[tid];
    }
    if (g == 63 && tid == 0) start_src[NN] = EE;
    __syncthreads();
    for (int i = tid; i < cnt; i += 1024) {
      int w = wb[i];
      int ls = w >> 19;
      int p = hx[ls] + atomicAdd(&h2[ls], 1);
      lbuf[p] = w;
    }
    __syncthreads();
    for (int p = tid; p < cnt; p += 1024) {
      int w = lbuf[p];
      elist_src[gs + p] = w & 0x7FFFF;
      nid_src[gs + p] = g * 256 + (w >> 19);
    }
  }
}

// gather edge_attr rows into CSR order as bf16
__global__ void ea_gather_kernel(const float* __restrict__ ea,
                                 const int* __restrict__ elist,
                                 bf16_t* __restrict__ eacsr) {
  int idx = blockIdx.x * 256 + threadIdx.x;
  if (idx >= EE * 2) return;
  int pos = idx >> 1, half = idx & 1;
  int e = elist[pos];
  const f32x4v* p = (const f32x4v*)(ea + (size_t)e * EFD + half * 8);
  f32x4v u0 = p[0], u1 = p[1];
  bf16x8 f;
#pragma unroll
  for (int r = 0; r < 4; ++r) {
    f[r] = (bf16_t)u0[r];
    f[4 + r] = (bf16_t)u1[r];
  }
  *(bf16x8*)(eacsr + (size_t)pos * 16 + half * 8) = f;
}

// ---------------- dense per-graph adjacency build ----------------
__global__ __launch_bounds__(256) void an_build_kernel(
    const float2* __restrict__ dstrec, const int* __restrict__ start_dst,
    const float* __restrict__ dinv, bf16_t* __restrict__ An) {
  __shared__ float AnS[128][256];  // 128 KB
  const int g = blockIdx.x >> 1, h = blockIdx.x & 1;
  const int tid = threadIdx.x;
  float4* az = (float4*)&AnS[0][0];
  for (int i = tid; i < 128 * 256 / 4; i += 256)
    az[i] = make_float4(0.f, 0.f, 0.f, 0.f);
  __syncthreads();
  const int nbase = g * 256 + h * 128;
  if (tid < 128) {
    int node = nbase + tid;
    int st = start_dst[node], en = start_dst[node + 1];
    float* row = AnS[tid];
    for (int p = st; p < en; ++p) {
      float2 r = dstrec[p];
      row[__float_as_int(r.y)] += r.x;
    }
    float dv = dinv[node];
    row[h * 128 + tid] += dv * dv;
  }
  __syncthreads();
  bf16_t* out = An + (size_t)nbase * 256;
  const float* s0 = &AnS[0][0];
  for (int i = tid; i < 128 * 256 / 8; i += 256) {
    bf16x8 v;
#pragma unroll
    for (int r = 0; r < 8; ++r) v[r] = (bf16_t)s0[i * 8 + r];
    *(bf16x8*)(out + i * 8) = v;
  }
}

// ---------------- conversions ----------------

__global__ void cvt_bf16_kernel(const float* __restrict__ in, bf16_t* __restrict__ out,
                                int n4) {
  int i = blockIdx.x * 256 + threadIdx.x;
  if (i >= n4) return;
  float4 v = ((const float4*)in)[i];
  bf16x4 o;
  o[0] = (bf16_t)v.x; o[1] = (bf16_t)v.y; o[2] = (bf16_t)v.z; o[3] = (bf16_t)v.w;
  ((bf16x4*)out)[i] = o;
}

// W: f32 [K][N] row-major -> Wt: bf16 [N][K] row-major
__global__ __launch_bounds__(256) void wt_kernel(const float* __restrict__ W,
                                                 bf16_t* __restrict__ Wt, int K, int N) {
  __shared__ float tile[32][33];
  int bx = blockIdx.x * 32;
  int by = blockIdx.y * 32;
  int tx = threadIdx.x & 31, ty = threadIdx.x >> 5;
#pragma unroll
  for (int i = 0; i < 32; i += 8)
    tile[ty + i][tx] = W[(size_t)(by + ty + i) * N + bx + tx];
  __syncthreads();
#pragma unroll
  for (int i = 0; i < 32; i += 8)
    Wt[(size_t)(bx + ty + i) * K + by + tx] = (bf16_t)tile[tx][ty + i];
}

// ---------------- edge projection via double-MFMA (8 waves x 64 cols) ------
__global__ __launch_bounds__(512) void ef_mfma_kernel(
    const bf16_t* __restrict__ eacsr, const float* __restrict__ ep_w,
    const float* __restrict__ ep_b, const int* __restrict__ nid,
    const int* __restrict__ start, bf16_t* __restrict__ efb) {
  const int tid = threadIdx.x;
  const int lane = tid & 63;
  const int wv = tid >> 6;      // 0..7
  const int l15 = lane & 15;
  const int g = lane >> 4;
  const int n0 = blockIdx.x * 16;
  const int cbase = wv * 64;

  bf16x8 wfr[4];
#pragma unroll
  for (int t = 0; t < 4; ++t) {
    bf16x8 f = {};
    int c = cbase + t * 16 + l15;
    if (g < 2) {
#pragma unroll
      for (int j = 0; j < 8; ++j) f[j] = (bf16_t)ep_w[(g * 8 + j) * CC + c];
    } else if (g == 2) {
      f[0] = (bf16_t)ep_b[c];
    }
    wfr[t] = f;
  }

  const int st = start[n0];
  const int en = start[n0 + 16];
  const int tgt = n0 + l15;

  f32x4v eacc[4] = {};

  for (int cb = st; cb < en; cb += 32) {
    bf16x8 af[2];
#pragma unroll
    for (int mE = 0; mE < 2; ++mE) {
      bf16x8 f = {};
      if (g < 2) {
        f = *(const bf16x8*)(eacsr + (size_t)(cb + mE * 16 + l15) * 16 + g * 8);
      } else if (g == 2) {
        f[0] = (bf16_t)1.0f;
      }
      af[mE] = f;
    }
    int4 idlo = *(const int4*)(nid + cb + g * 4);
    int4 idhi = *(const int4*)(nid + cb + 16 + g * 4);
    bf16x8 sf;
    sf[0] = (idlo.x == tgt) ? (bf16_t)1.0f : (bf16_t)0.0f;
    sf[1] = (idlo.y == tgt) ? (bf16_t)1.0f : (bf16_t)0.0f;
    sf[2] = (idlo.z == tgt) ? (bf16_t)1.0f : (bf16_t)0.0f;
    sf[3] = (idlo.w == tgt) ? (bf16_t)1.0f : (bf16_t)0.0f;
    sf[4] = (idhi.x == tgt) ? (bf16_t)1.0f : (bf16_t)0.0f;
    sf[5] = (idhi.y == tgt) ? (bf16_t)1.0f : (bf16_t)0.0f;
    sf[6] = (idhi.z == tgt) ? (bf16_t)1.0f : (bf16_t)0.0f;
    sf[7] = (idhi.w == tgt) ? (bf16_t)1.0f : (bf16_t)0.0f;
#pragma unroll
    for (int t = 0; t < 4; ++t) {
      f32x4v s0 = {}, s1 = {};
      s0 = __builtin_amdgcn_mfma_f32_16x16x32_bf16(af[0], wfr[t], s0, 0, 0, 0);
      s1 = __builtin_amdgcn_mfma_f32_16x16x32_bf16(af[1], wfr[t], s1, 0, 0, 0);
      union { bf16x8 v; bf16x4 h[2]; } pf;
#pragma unroll
      for (int r = 0; r < 4; ++r) {
        pf.h[0][r] = (bf16_t)fmaxf(s0[r], 0.f);
        pf.h[1][r] = (bf16_t)fmaxf(s1[r], 0.f);
      }
      eacc[t] = __builtin_amdgcn_mfma_f32_16x16x32_bf16(sf, pf.v, eacc[t], 0, 0, 0);
    }
  }
#pragma unroll
  for (int t = 0; t < 4; ++t) {
    int c = cbase + t * 16 + l15;
#pragma unroll
    for (int r = 0; r < 4; ++r) {
      int node = n0 + g * 4 + r;
      efb[(size_t)node * (2 * CC) + CC + c] = (bf16_t)eacc[t][r];
    }
  }
}

// ---------------- bf16 MFMA GEMM (m97 structure + XCD swizzle) ----------------
__device__ __forceinline__ void gl_lds16(const bf16_t* g, bf16_t* l) {
  __builtin_amdgcn_global_load_lds(
      (const __attribute__((address_space(1))) void*)g,
      (__attribute__((address_space(3))) void*)l, 16, 0, 0);
}

template <int ACT, int OUT>
__global__ __launch_bounds__(256) void gemm_bf16_kernel(
    const bf16_t* __restrict__ A, const bf16_t* __restrict__ Bt,
    const float* __restrict__ bias, void* __restrict__ Cout, int M, int N, int K) {
  __shared__ __align__(16) bf16_t Al[128 * 32];
  __shared__ __align__(16) bf16_t Bl[128 * 32];
  const int tid = threadIdx.x;
  const int lane = tid & 63;
  const int wave = tid >> 6;
  int2 sw = xcd_swizzle();
  const int row0 = sw.y * 128;
  const int col0 = sw.x * 128;
  const int wm = (wave >> 1) * 64;
  const int wn = (wave & 1) * 64;
  f32x4v acc[4][4] = {};
  const bf16_t* aBase = A + (size_t)(row0 + (tid >> 2)) * K + (tid & 3) * 8;
  const bf16_t* bBase = Bt + (size_t)(col0 + (tid >> 2)) * K + (tid & 3) * 8;
  bf16_t* al0 = Al + wave * 512;
  bf16_t* al1 = Al + 2048 + wave * 512;
  bf16_t* bl0 = Bl + wave * 512;
  bf16_t* bl1 = Bl + 2048 + wave * 512;
  const int fr = lane & 15;
  const int fk = (lane >> 4) * 8;
  for (int k0 = 0; k0 < K; k0 += 32) {
    gl_lds16(aBase + k0, al0);
    gl_lds16(aBase + (size_t)64 * K + k0, al1);
    gl_lds16(bBase + k0, bl0);
    gl_lds16(bBase + (size_t)64 * K + k0, bl1);
    __syncthreads();
    bf16x8 af[4], bfv[4];
#pragma unroll
    for (int m = 0; m < 4; ++m)
      af[m] = *(const bf16x8*)(Al + (wm + m * 16 + fr) * 32 + fk);
#pragma unroll
    for (int n = 0; n < 4; ++n)
      bfv[n] = *(const bf16x8*)(Bl + (wn + n * 16 + fr) * 32 + fk);
#pragma unroll
    for (int m = 0; m < 4; ++m)
#pragma unroll
      for (int n = 0; n < 4; ++n)
        acc[m][n] =
            __builtin_amdgcn_mfma_f32_16x16x32_bf16(af[m], bfv[n], acc[m][n], 0, 0, 0);
    __syncthreads();
  }
  const int fq = (lane >> 4) * 4;
#pragma unroll
  for (int m = 0; m < 4; ++m) {
    int grb = row0 + wm + m * 16 + fq;
#pragma unroll
    for (int n = 0; n < 4; ++n) {
      int gc = col0 + wn + n * 16 + fr;
      float bv = bias ? bias[gc] : 0.f;
#pragma unroll
      for (int r = 0; r < 4; ++r) {
        float v = acc[m][n][r] + bv;
        if (ACT == 1) v = v / (1.f + __expf(-v));
        if (OUT == 0)
          ((float*)Cout)[(size_t)(grb + r) * N + gc] = v;
        else
          ((bf16_t*)Cout)[(size_t)(grb + r) * N + gc] = (bf16_t)v;
      }
    }
  }
}

// ---------------- block-diagonal An GEMM (XCD swizzle) ----------------
__global__ __launch_bounds__(256) void an_gemm_kernel(
    const bf16_t* __restrict__ An, const bf16_t* __restrict__ xwT,
    const float* __restrict__ bias, bf16_t* __restrict__ outb) {
  __shared__ __align__(16) bf16_t Al[128 * 32];
  __shared__ __align__(16) bf16_t Bl[128 * 32];
  const int tid = threadIdx.x;
  const int lane = tid & 63;
  const int wave = tid >> 6;
  int2 sw = xcd_swizzle();
  const int row0 = sw.y * 128;  // node rows
  const int col0 = sw.x * 128;  // chan cols
  const int g = row0 >> 8;
  f32x4v acc[4][4] = {};
  const bf16_t* aBase = An + (size_t)(row0 + (tid >> 2)) * 256 + (tid & 3) * 8;
  const bf16_t* bBase =
      xwT + (size_t)(col0 + (tid >> 2)) * NN + g * 256 + (tid & 3) * 8;
  bf16_t* al0 = Al + wave * 512;
  bf16_t* al1 = Al + 2048 + wave * 512;
  bf16_t* bl0 = Bl + wave * 512;
  bf16_t* bl1 = Bl + 2048 + wave * 512;
  const int wm = (wave >> 1) * 64;
  const int wn = (wave & 1) * 64;
  const int fr = lane & 15;
  const int fk = (lane >> 4) * 8;
  for (int k0 = 0; k0 < 256; k0 += 32) {
    gl_lds16(aBase + k0, al0);
    gl_lds16(aBase + (size_t)64 * 256 + k0, al1);
    gl_lds16(bBase + k0, bl0);
    gl_lds16(bBase + (size_t)64 * NN + k0, bl1);
    __syncthreads();
    bf16x8 af[4], bfv[4];
#pragma unroll
    for (int m = 0; m < 4; ++m)
      af[m] = *(const bf16x8*)(Al + (wm + m * 16 + fr) * 32 + fk);
#pragma unroll
    for (int n = 0; n < 4; ++n)
      bfv[n] = *(const bf16x8*)(Bl + (wn + n * 16 + fr) * 32 + fk);
#pragma unroll
    for (int m = 0; m < 4; ++m)
#pragma unroll
      for (int n = 0; n < 4; ++n)
        acc[m][n] =
            __builtin_amdgcn_mfma_f32_16x16x32_bf16(af[m], bfv[n], acc[m][n], 0, 0, 0);
    __syncthreads();
  }
  const int fq = (lane >> 4) * 4;
#pragma unroll
  for (int m = 0; m < 4; ++m) {
    int grb = row0 + wm + m * 16 + fq;
#pragma unroll
    for (int n = 0; n < 4; ++n) {
      int gc = col0 + wn + n * 16 + fr;
      float bv = bias[gc];
#pragma unroll
      for (int r = 0; r < 4; ++r)
        outb[(size_t)(grb + r) * (2 * CC) + gc] = (bf16_t)(acc[m][n][r] + bv);
    }
  }
}

// ---------------- layernorm fused kernels ----------------

__device__ inline void block_reduce2(float& s, float& q, float* red) {
#pragma unroll
  for (int off = 32; off >= 1; off >>= 1) {
    s += __shfl_xor(s, off, 64);
    q += __shfl_xor(q, off, 64);
  }
  int wid = threadIdx.x >> 6;
  if ((threadIdx.x & 63) == 0) { red[wid * 2] = s; red[wid * 2 + 1] = q; }
  __syncthreads();
  s = red[0] + red[2] + red[4] + red[6];
  q = red[1] + red[3] + red[5] + red[7];
}

// out = LN(A + B) * g + be ; IA/IB: 1 = bf16 input; WF: 1 = f32 out, else bf16
template <int IA, int IB, int WF>
__global__ __launch_bounds__(256) void ln_addT_kernel(
    const void* __restrict__ A, const void* __restrict__ Bv,
    const float* __restrict__ g, const float* __restrict__ be,
    float* __restrict__ outf, bf16_t* __restrict__ outb) {
  int row = blockIdx.x, tid = threadIdx.x, c0 = tid * 2;
  __shared__ float red[8];
  float2 a = IA ? ldb2((const bf16_t*)A + (size_t)row * CC + c0)
                : *(const float2*)((const float*)A + (size_t)row * CC + c0);
  float2 b = IB ? ldb2((const bf16_t*)Bv + (size_t)row * CC + c0)
                : *(const float2*)((const float*)Bv + (size_t)row * CC + c0);
  float x0 = a.x + b.x, x1 = a.y + b.y;
  float s = x0 + x1, q = x0 * x0 + x1 * x1;
  block_reduce2(s, q, red);
  float mean = s * (1.f / CC);
  float var = q * (1.f / CC) - mean * mean;
  float rs = rsqrtf(var + 1e-5f);
  float o0 = (x0 - mean) * rs * g[c0] + be[c0];
  float o1 = (x1 - mean) * rs * g[c0 + 1] + be[c0 + 1];
  if (WF) {
    *(float2*)(outf + (size_t)row * CC + c0) = make_float2(o0, o1);
  } else {
    outb[(size_t)row * CC + c0] = (bf16_t)o0;
    outb[(size_t)row * CC + c0 + 1] = (bf16_t)o1;
  }
}

// gate+mix+LN+relu+residual; bf16 inputs (gpre, xc|ef), f32 x residual; bf16 out
__global__ __launch_bounds__(256) void ln_gate_kernel(
    const bf16_t* __restrict__ gpreb, const float* __restrict__ gate_b,
    const bf16_t* __restrict__ xcef, const float* __restrict__ n1g,
    const float* __restrict__ n1b, const float* __restrict__ xin,
    bf16_t* __restrict__ x2b) {
  int row = blockIdx.x, tid = threadIdx.x, c0 = tid * 2;
  __shared__ float red[8];
  float2 gp = ldb2(gpreb + (size_t)row * CC + c0);
  float2 xcv = ldb2(xcef + (size_t)row * (2 * CC) + c0);
  float2 efv = ldb2(xcef + (size_t)row * (2 * CC) + CC + c0);
  float g0 = 1.f / (1.f + __expf(-(gp.x + gate_b[c0])));
  float g1 = 1.f / (1.f + __expf(-(gp.y + gate_b[c0 + 1])));
  float x0 = g0 * xcv.x + (1.f - g0) * efv.x;
  float x1 = g1 * xcv.y + (1.f - g1) * efv.y;
  float s = x0 + x1, q = x0 * x0 + x1 * x1;
  block_reduce2(s, q, red);
  float mean = s * (1.f / CC);
  float var = q * (1.f / CC) - mean * mean;
  float rs = rsqrtf(var + 1e-5f);
  float2 xi = *(const float2*)(xin + (size_t)row * CC + c0);
  float o0 = fmaxf((x0 - mean) * rs * n1g[c0] + n1b[c0], 0.f) + xi.x;
  float o1 = fmaxf((x1 - mean) * rs * n1g[c0 + 1] + n1b[c0 + 1], 0.f) + xi.y;
  x2b[(size_t)row * CC + c0] = (bf16_t)o0;
  x2b[(size_t)row * CC + c0 + 1] = (bf16_t)o1;
}

// ---------------- V^T pack (pre-swizzled + pi-permuted K for attn) ---------
__global__ __launch_bounds__(256) void vt_pack_kernel(const bf16_t* __restrict__ qkvb,
                                                      bf16_t* __restrict__ vt) {
  int b = blockIdx.x >> 3, h = blockIdx.x & 7;
  int nb = b * 256;
  size_t voff = 1024 + (size_t)h * 64;
  char* out = (char*)(vt + (size_t)blockIdx.x * (64 * 256));
  __shared__ bf16_t tile[64][80];
  int tid = threadIdx.x;
  for (int kb = 0; kb < 4; ++kb) {
    __syncthreads();
#pragma unroll
    for (int p = 0; p < 2; ++p) {
      int k = p * 32 + (tid >> 3);
      int d8 = tid & 7;
      bf16x8 v = *(const bf16x8*)(qkvb + (size_t)(nb + kb * 64 + k) * 1536 + voff + d8 * 8);
      *(bf16x8*)(&tile[k][d8 * 8]) = v;
    }
    __syncthreads();
#pragma unroll
    for (int p = 0; p < 2; ++p) {
      int d = p * 32 + (tid >> 3);
      int k8 = tid & 7;
      bf16x8 v;
#pragma unroll
      for (int j = 0; j < 8; ++j) {
        int pos = k8 * 8 + j;
        int sl = pos & 31;
        int srck = (pos & 32) + ((sl >> 3) << 2) + (sl & 3) + (((sl >> 2) & 1) << 4);
        v[j] = tile[srck][d];
      }
      int byteoff = d * 512 + ((kb * 128 + k8 * 16) ^ ((d & 7) << 4));
      *(bf16x8*)(out + byteoff) = v;
    }
  }
}

// ---------------- MFMA attention (shuffle-free PV) ----------------
__global__ __launch_bounds__(256, 2) void attn_mfma_kernel(
    const bf16_t* __restrict__ qkvb, const bf16_t* __restrict__ vt,
    bf16_t* __restrict__ o) {
  const int b = blockIdx.x >> 3;
  const int h = blockIdx.x & 7;
  const int nb = b * 256;
  const int tid = threadIdx.x;
  const int lane = tid & 63;
  const int wv = tid >> 6;
  const int l15 = lane & 15;
  const int g = lane >> 4;
  const int swzk = (l15 & 7) << 4;
  __shared__ __align__(16) bf16_t Klds[256 * 64];
  __shared__ __align__(16) bf16_t Vtlds[64 * 256];
  const size_t qoff = (size_t)h * 64;
  const size_t koff = 512 + (size_t)h * 64;

  {
    const int dcol = 16 * ((tid & 7) ^ ((tid >> 3) & 7));
    const bf16_t* srcb = qkvb + koff + (dcol >> 1);
#pragma unroll
    for (int i = 0; i < 8; ++i) {
      int k = i * 32 + (tid >> 3);
      gl_lds16(srcb + (size_t)(nb + k) * 1536, Klds + ((i * 4096 + wv * 1024) >> 1));
    }
  }
  {
    const bf16_t* vsrc = vt + (size_t)blockIdx.x * (64 * 256);
#pragma unroll
    for (int i = 0; i < 8; ++i) {
      int base = i * 4096 + wv * 1024;
      gl_lds16(vsrc + ((base >> 1) + lane * 8), Vtlds + (base >> 1));
    }
  }

  bf16x8 qf[4][2];
#pragma unroll
  for (int n = 0; n < 4; ++n) {
    const bf16_t* qp = qkvb + (size_t)(nb + wv * 64 + 16 * n + l15) * 1536 + qoff + g * 8;
    qf[n][0] = *(const bf16x8*)(qp);
    qf[n][1] = *(const bf16x8*)(qp + 32);
  }

  __syncthreads();

  f32x4v oacc[4][4] = {};
  float mrun[4] = {-1e30f, -1e30f, -1e30f, -1e30f};
  float lrun[4] = {0.f, 0.f, 0.f, 0.f};

  for (int kc = 0; kc < 4; ++kc) {
    f32x4v sacc[4][4] = {};
    const int kb128 = (kc * 64 + l15) * 128;
#pragma unroll
    for (int m = 0; m < 4; ++m) {
      bf16x8 a0 = *(const bf16x8*)(Klds + ((kb128 + m * 2048 + ((g * 16) ^ swzk)) >> 1));
      bf16x8 a1 =
          *(const bf16x8*)(Klds + ((kb128 + m * 2048 + ((64 + g * 16) ^ swzk)) >> 1));
#pragma unroll
      for (int n = 0; n < 4; ++n) {
        sacc[m][n] = __builtin_amdgcn_mfma_f32_16x16x32_bf16(a0, qf[n][0], sacc[m][n], 0, 0, 0);
        sacc[m][n] = __builtin_amdgcn_mfma_f32_16x16x32_bf16(a1, qf[n][1], sacc[m][n], 0, 0, 0);
      }
    }
    uint2 pb[4][4];
#pragma unroll
    for (int n = 0; n < 4; ++n) {
      float mx = sacc[0][n][0];
#pragma unroll
      for (int m = 0; m < 4; ++m)
#pragma unroll
        for (int r = 0; r < 4; ++r) mx = fmaxf(mx, sacc[m][n][r]);
      mx = fmaxf(mx, __shfl_xor(mx, 16));
      mx = fmaxf(mx, __shfl_xor(mx, 32));
      float mnew = fmaxf(mrun[n], mx);
      float c = __expf((mrun[n] - mnew) * 0.125f);
      mrun[n] = mnew;
      float s = 0.f;
#pragma unroll
      for (int m = 0; m < 4; ++m) {
        float p0 = __expf((sacc[m][n][0] - mnew) * 0.125f);
        float p1 = __expf((sacc[m][n][1] - mnew) * 0.125f);
        float p2 = __expf((sacc[m][n][2] - mnew) * 0.125f);
        float p3 = __expf((sacc[m][n][3] - mnew) * 0.125f);
        s += (p0 + p1) + (p2 + p3);
        union { bf16x4 v; uint2 u; } cv;
        cv.v[0] = (bf16_t)p0; cv.v[1] = (bf16_t)p1;
        cv.v[2] = (bf16_t)p2; cv.v[3] = (bf16_t)p3;
        pb[m][n] = cv.u;
      }
      s += __shfl_xor(s, 16);
      s += __shfl_xor(s, 32);
      lrun[n] = lrun[n] * c + s;
#pragma unroll
      for (int m = 0; m < 4; ++m)
#pragma unroll
        for (int r = 0; r < 4; ++r) oacc[m][n][r] *= c;
    }
#pragma unroll
    for (int h2 = 0; h2 < 2; ++h2) {
      bf16x8 vf[4];
#pragma unroll
      for (int m = 0; m < 4; ++m)
        vf[m] = *(const bf16x8*)(Vtlds + (((16 * m + l15) * 512 +
                                          ((kc * 128 + h2 * 64 + g * 16) ^ swzk)) >> 1));
#pragma unroll
      for (int n = 0; n < 4; ++n) {
        union { uint2 u[2]; bf16x8 v; } pf;
        pf.u[0] = pb[2 * h2][n];
        pf.u[1] = pb[2 * h2 + 1][n];
#pragma unroll
        for (int m = 0; m < 4; ++m)
          oacc[m][n] =
              __builtin_amdgcn_mfma_f32_16x16x32_bf16(vf[m], pf.v, oacc[m][n], 0, 0, 0);
      }
    }
  }
  float inv[4];
#pragma unroll
  for (int n = 0; n < 4; ++n) inv[n] = 1.0f / lrun[n];
#pragma unroll
  for (int m = 0; m < 4; ++m)
#pragma unroll
    for (int n = 0; n < 4; ++n) {
      bf16x4 pk;
#pragma unroll
      for (int r = 0; r < 4; ++r) pk[r] = (bf16_t)(oacc[m][n][r] * inv[n]);
      *(bf16x4*)(o + (size_t)(nb + wv * 64 + 16 * n + l15) * 512 + h * 64 + 16 * m +
                 4 * g) = pk;
    }
}

// ---------------- launch ----------------

static inline char* alignp(char* p, size_t a) {
  return (char*)(((uintptr_t)p + a - 1) & ~(uintptr_t)(a - 1));
}

extern "C" void kernel_launch(void* const* d_in, const int* in_sizes, int n_in,
                              void* d_out, int out_size, void* d_ws, size_t ws_size,
                              hipStream_t stream) {
  const float* x = (const float*)d_in[0];
  const float* edge_attr = (const float*)d_in[1];
  const float* gcn_w = (const float*)d_in[2];
  const float* gcn_b = (const float*)d_in[3];
  const float* ep_w = (const float*)d_in[4];
  const float* ep_b = (const float*)d_in[5];
  const float* gate_w = (const float*)d_in[6];
  const float* gate_b = (const float*)d_in[7];
  const float* n1_g = (const float*)d_in[8];
  const float* n1_b = (const float*)d_in[9];
  const float* in_w = (const float*)d_in[10];
  const float* in_b = (const float*)d_in[11];
  const float* out_w = (const float*)d_in[12];
  const float* out_b = (const float*)d_in[13];
  const float* tn_g = (const float*)d_in[14];
  const float* tn_b = (const float*)d_in[15];
  const float* m_w1 = (const float*)d_in[16];
  const float* m_b1 = (const float*)d_in[17];
  const float* m_w2 = (const float*)d_in[18];
  const float* m_b2 = (const float*)d_in[19];
  const float* fn_g = (const float*)d_in[20];
  const float* fn_b = (const float*)d_in[21];
  const int* eidx = (const int*)d_in[22];
  const int* src = eidx;
  const int* dst = eidx + EE;

  float* ws = (float*)d_ws;
  float* R1 = ws;
  float* R2 = R1 + (size_t)NN * 3 * CC;
  float* R3 = R2 + (size_t)NN * CC;
  float* R4 = R3 + (size_t)NN * CC;
  float* ew = R4 + (size_t)NN * CC;
  float* dinv = ew + EE;
  int* ip = (int*)(dinv + NN);
  int* ghist = ip;      ip += 64;
  int* gstart = ip;     ip += 65;
  int* gcur = ip;       ip += 64;
  int* elist_src = ip;  ip += EE;
  int* nid_src = ip;    ip += EE + 32;
  int* start_src = ip;  ip += NN + 1;
  int* start_dst = ip;  ip += NN + 1;
  char* bp = alignp((char*)ip, 64);
  int2* grec = (int2*)bp;             bp += (size_t)EE * 8;
  float* ewg = (float*)bp;            bp += (size_t)EE * 4;
  float2* dstrec = (float2*)bp;       bp += (size_t)EE * 8;
  bf16_t* x2b = (bf16_t*)bp;          bp += (size_t)NN * CC * 2;
  bf16_t* gcn_wt = (bf16_t*)bp;       bp += (size_t)CC * CC * 2;
  bf16_t* gate_wt = (bf16_t*)bp;      bp += (size_t)CC * 2 * CC * 2;
  bf16_t* in_wt = (bf16_t*)bp;        bp += (size_t)3 * CC * CC * 2;
  bf16_t* out_wt = (bf16_t*)bp;       bp += (size_t)CC * CC * 2;
  bf16_t* m_w1t = (bf16_t*)bp;        bp += (size_t)2 * CC * CC * 2;
  bf16_t* m_w2t = (bf16_t*)bp;        bp += (size_t)CC * 2 * CC * 2;

  bf16_t* xb = (bf16_t*)R1;      // bf16(x)
  bf16_t* xcefb = (bf16_t*)R1;   // [x_conv | ef] bf16 N x 2C
  bf16_t* qkvb = (bf16_t*)R1;    // qkv bf16 N x 1536
  bf16_t* hb = (bf16_t*)R1;      // mlp hidden bf16 N x 2C
  bf16_t* eacsr = (bf16_t*)((char*)R1 + (size_t)64 * 1024 * 1024);  // 16.8MB
  bf16_t* xwT = (bf16_t*)R2;     // (x@gcn_w)^T bf16 [512][16384]
  bf16_t* gpreb = (bf16_t*)R2;   // gate pre-act bf16 (after xwT dead)
  bf16_t* ob = (bf16_t*)R2;      // attn out bf16 (first half of R2)
  bf16_t* vt = ob + (size_t)NN * CC;  // V^T packed (second half of R2)
  bf16_t* x3b = (bf16_t*)R2;     // bf16(x3) (after ob dead)
  bf16_t* AnFull = (bf16_t*)R3;  // dense adjacency bf16 [16384][256] (8MB)
  bf16_t* oprjb = (bf16_t*)R4;   // out-proj bf16
  float* yf = R4;                // mlp2 f32 out (after oprjb dead)

  // --- edge prep ---
  init_kernel<<<1, 256, 0, stream>>>(ghist, nid_src, eacsr);
  edge_pass1<<<EE / 256, 256, 0, stream>>>(edge_attr, dst, ew, ghist);
  gexscan_kernel<<<1, 64, 0, stream>>>(ghist, gstart, gcur);
  graph_scatter_kernel<<<EE / 2048, 256, 0, stream>>>(src, dst, ew, gcur, grec, ewg);
  graph_sort2_kernel<<<128, 1024, 0, stream>>>(grec, ewg, gstart, elist_src, nid_src,
                                               start_src, dstrec, start_dst, dinv);
  ea_gather_kernel<<<(EE * 2 + 255) / 256, 256, 0, stream>>>(edge_attr, elist_src,
                                                             eacsr);
  an_build_kernel<<<128, 256, 0, stream>>>(dstrec, start_dst, dinv, AnFull);

  // --- weight transposes ---
  wt_kernel<<<dim3(CC / 32, CC / 32), 256, 0, stream>>>(gcn_w, gcn_wt, CC, CC);
  wt_kernel<<<dim3(CC / 32, 2 * CC / 32), 256, 0, stream>>>(gate_w, gate_wt, 2 * CC, CC);
  wt_kernel<<<dim3(3 * CC / 32, CC / 32), 256, 0, stream>>>(in_w, in_wt, CC, 3 * CC);
  wt_kernel<<<dim3(CC / 32, CC / 32), 256, 0, stream>>>(out_w, out_wt, CC, CC);
  wt_kernel<<<dim3(2 * CC / 32, CC / 32), 256, 0, stream>>>(m_w1, m_w1t, CC, 2 * CC);
  wt_kernel<<<dim3(CC / 32, 2 * CC / 32), 256, 0, stream>>>(m_w2, m_w2t, 2 * CC, CC);

  // --- GCN conv: xwT = (x @ gcn_w)^T via flipped GEMM, then dense An GEMM ---
  cvt_bf16_kernel<<<(NN * CC / 4 + 255) / 256, 256, 0, stream>>>(x, xb, NN * CC / 4);
  gemm_bf16_kernel<0, 1><<<dim3(NN / 128, CC / 128), 256, 0, stream>>>(
      gcn_wt, xb, nullptr, xwT, CC, NN, CC);
  an_gemm_kernel<<<dim3(CC / 128, NN / 128), 256, 0, stream>>>(AnFull, xwT, gcn_b,
                                                               xcefb);
  ef_mfma_kernel<<<NN / 16, 512, 0, stream>>>(eacsr, ep_w, ep_b, nid_src, start_src,
                                              xcefb);
  dim3 gA(CC / 128, NN / 128);
  gemm_bf16_kernel<0, 1><<<gA, 256, 0, stream>>>(xcefb, gate_wt, nullptr, gpreb, NN,
                                                 CC, 2 * CC);
  ln_gate_kernel<<<NN, 256, 0, stream>>>(gpreb, gate_b, xcefb, n1_g, n1_b, x, x2b);

  // --- MHA ---
  dim3 gQ(3 * CC / 128, NN / 128);
  gemm_bf16_kernel<0, 1><<<gQ, 256, 0, stream>>>(x2b, in_wt, in_b, qkvb, NN, 3 * CC, CC);
  vt_pack_kernel<<<BB * HH, 256, 0, stream>>>(qkvb, vt);
  attn_mfma_kernel<<<BB * HH, 256, 0, stream>>>(qkvb, vt, ob);
  gemm_bf16_kernel<0, 1><<<gA, 256, 0, stream>>>(ob, out_wt, out_b, oprjb, NN, CC, CC);
  ln_addT_kernel<1, 1, 0><<<NN, 256, 0, stream>>>(x2b, oprjb, tn_g, tn_b, nullptr, x3b);

  // --- MLP ---
  dim3 gH(2 * CC / 128, NN / 128);
  gemm_bf16_kernel<1, 1><<<gH, 256, 0, stream>>>(x3b, m_w1t, m_b1, hb, NN, 2 * CC, CC);
  gemm_bf16_kernel<0, 0><<<gA, 256, 0, stream>>>(hb, m_w2t, m_b2, yf, NN, CC, 2 * CC);
  ln_addT_kernel<1, 0, 1><<<NN, 256, 0, stream>>>(x3b, yf, fn_g, fn_b, (float*)d_out,
                                                  nullptr);
}

// Round 15
// 442.918 us; speedup vs baseline: 1.8212x; 1.0341x over previous
//
#include <hip/hip_runtime.h>

#define NN 16384
#define CC 512
#define EE 524288
#define BB 64
#define HH 8
#define EFD 16
#define GEMAXE 10240

typedef __bf16 bf16_t;
typedef __bf16 bf16x4 __attribute__((ext_vector_type(4)));
typedef __bf16 bf16x8 __attribute__((ext_vector_type(8)));
typedef float f32x4v __attribute__((ext_vector_type(4)));

__device__ __forceinline__ float2 ldb2(const bf16_t* p) {
  unsigned w = *(const unsigned*)p;
  return make_float2(__uint_as_float(w << 16), __uint_as_float(w & 0xFFFF0000u));
}

// XCD-aware chunked swizzle (nwg % 8 == 0 for all our grids)
__device__ __forceinline__ int2 xcd_swizzle() {
  int nwg = gridDim.x * gridDim.y;
  int bid = blockIdx.y * gridDim.x + blockIdx.x;
  int wg = (bid & 7) * (nwg >> 3) + (bid >> 3);
  return make_int2(wg % gridDim.x, wg / gridDim.x);
}

// ---------------- init / edge pre-pass ----------------

__global__ void init_kernel(int* ghist, int* nid_src, bf16_t* eacsr) {
  int i = threadIdx.x;
  if (i < 64) ghist[i] = 0;
  if (i < 32) nid_src[EE + i] = -1;               // pad for ef chunk tail
  ((int*)(eacsr + (size_t)EE * 16))[i] = 0;       // zero eacsr pad rows (256 ints)
}

// per-graph histogram only (LDS-aggregated)
__global__ __launch_bounds__(256) void edge_pass1(const int* __restrict__ dst,
                                                  int* ghist) {
  __shared__ int h[64];
  int tid = threadIdx.x;
  if (tid < 64) h[tid] = 0;
  __syncthreads();
  int e = blockIdx.x * 256 + tid;  // EE % 256 == 0
  atomicAdd(&h[dst[e] >> 8], 1);
  __syncthreads();
  if (tid < 64 && h[tid]) atomicAdd(&ghist[tid], h[tid]);
}

__global__ void gexscan_kernel(const int* __restrict__ ghist, int* __restrict__ gstart,
                               int* __restrict__ gcur) {
  if (threadIdx.x == 0) {
    int s = 0;
    for (int g = 0; g < 64; ++g) { gstart[g] = s; gcur[g] = s; s += ghist[g]; }
    gstart[64] = s;
  }
}

// bucket edges by graph with block-aggregated offsets; emit packed records.
// ew computed inline from ea (single pass over edge_attr).
__global__ __launch_bounds__(256) void graph_scatter_kernel(
    const int* __restrict__ src, const int* __restrict__ dst,
    const float* __restrict__ ea, int* gcur, int2* __restrict__ grec,
    float* __restrict__ ewg) {
  __shared__ int h[64], base[64], h2[64];
  int tid = threadIdx.x;
  if (tid < 64) { h[tid] = 0; h2[tid] = 0; }
  __syncthreads();
  int e0 = blockIdx.x * 2048;
  int gloc[8];
#pragma unroll
  for (int k = 0; k < 8; ++k) {
    gloc[k] = dst[e0 + k * 256 + tid] >> 8;
    atomicAdd(&h[gloc[k]], 1);
  }
  __syncthreads();
  if (tid < 64) base[tid] = h[tid] ? atomicAdd(&gcur[tid], h[tid]) : 0;
  __syncthreads();
#pragma unroll
  for (int k = 0; k < 8; ++k) {
    int e = e0 + k * 256 + tid;
    int g = gloc[k];
    int p = atomicAdd(&h2[g], 1);
    int pos = base[g] + p;
    int ls = src[e] & 255;
    int ld = dst[e] & 255;
    grec[pos] = make_int2(e | (ls << 19), ld);
    const float4* pa = (const float4*)(ea + (size_t)e * EFD);
    float s = 0.f;
#pragma unroll
    for (int q = 0; q < 4; ++q) {
      float4 v = pa[q];
      s += v.x * v.x + v.y * v.y + v.z * v.z + v.w * v.w;
    }
    ewg[pos] = sqrtf(s);
  }
}

// per-graph LDS counting sort, 128 blocks: blockIdx<64 -> DST pass, else SRC.
// DST pass emits full-coef records {dinv[s]*ew*dinv[d], ls} + start_dst + dinv.
__global__ __launch_bounds__(1024) void graph_sort2_kernel(
    const int2* __restrict__ grec, const float* __restrict__ ewg,
    const int* __restrict__ gstart, int* __restrict__ elist_src,
    int* __restrict__ nid_src, int* __restrict__ start_src,
    float2* __restrict__ dstrec, int* __restrict__ start_dst,
    float* __restrict__ dinv) {
  __shared__ int lbuf[GEMAXE];
  __shared__ unsigned short sl[GEMAXE];
  __shared__ float ewl[GEMAXE];
  __shared__ int h[256], hx[256], h2[256];
  __shared__ float fdinv[256];
  const int g = blockIdx.x & 63;
  const int tid = threadIdx.x;
  const int gs = gstart[g];
  const int cnt = gstart[g + 1] - gs;
  if (tid < 256) { h[tid] = 0; h2[tid] = 0; }
  __syncthreads();
  if (blockIdx.x < 64) {
    for (int i = tid; i < cnt; i += 1024) {
      int2 r = grec[gs + i];
      int ld = r.y;
      sl[i] = (unsigned short)(((r.x >> 19) & 255) | (ld << 8));
      ewl[i] = ewg[gs + i];
      atomicAdd(&h[ld], 1);
    }
    __syncthreads();
    int myc = (tid < 256) ? h[tid] : 0;
    for (int off = 1; off < 256; off <<= 1) {
      int v = (tid < 256 && tid >= off) ? h[tid - off] : 0;
      __syncthreads();
      if (tid < 256) h[tid] += v;
      __syncthreads();
    }
    if (tid < 256) {
      hx[tid] = h[tid] - myc;
      start_dst[g * 256 + tid] = gs + hx[tid];
    }
    if (g == 63 && tid == 0) start_dst[NN] = EE;
    __syncthreads();
    for (int i = tid; i < cnt; i += 1024) {
      int ld = sl[i] >> 8;
      int p = hx[ld] + atomicAdd(&h2[ld], 1);
      lbuf[p] = i;
    }
    __syncthreads();
    if (tid < 256) {
      float dg = 1.0f;
      int s0 = hx[tid], e0 = s0 + myc;
      for (int i = s0; i < e0; ++i) dg += ewl[lbuf[i]];
      float dv = rsqrtf(fmaxf(dg, 1e-12f));
      fdinv[tid] = dv;
      dinv[g * 256 + tid] = dv;
    }
    __syncthreads();
    for (int p = tid; p < cnt; p += 1024) {
      int i = lbuf[p];
      int ls = sl[i] & 255;
      int ld = sl[i] >> 8;
      dstrec[gs + p] =
          make_float2(fdinv[ls] * ewl[i] * fdinv[ld], __int_as_float(ls));
    }
  } else {
    int* wb = (int*)ewl;
    for (int i = tid; i < cnt; i += 1024) {
      int w = grec[gs + i].x;
      wb[i] = w;
      atomicAdd(&h[w >> 19], 1);
    }
    __syncthreads();
    int myc = (tid < 256) ? h[tid] : 0;
    for (int off = 1; off < 256; off <<= 1) {
      int v = (tid < 256 && tid >= off) ? h[tid - off] : 0;
      __syncthreads();
      if (tid < 256) h[tid] += v;
      __syncthreads();
    }
    if (tid < 256) {
      hx[tid] = h[tid] - myc;
      start_src[g * 256 + tid] = gs + hx[tid];
    }
    if (g == 63 && tid == 0) start_src[NN] = EE;
    __syncthreads();
    for (int i = tid; i < cnt; i += 1024) {
      int w = wb[i];
      int ls = w >> 19;
      int p = hx[ls] + atomicAdd(&h2[ls], 1);
      lbuf[p] = w;
    }
    __syncthreads();
    for (int p = tid; p < cnt; p += 1024) {
      int w = lbuf[p];
      elist_src[gs + p] = w & 0x7FFFF;
      nid_src[gs + p] = g * 256 + (w >> 19);
    }
  }
}

// gather edge_attr rows into CSR order as bf16
__global__ void ea_gather_kernel(const float* __restrict__ ea,
                                 const int* __restrict__ elist,
                                 bf16_t* __restrict__ eacsr) {
  int idx = blockIdx.x * 256 + threadIdx.x;
  if (idx >= EE * 2) return;
  int pos = idx >> 1, half = idx & 1;
  int e = elist[pos];
  const f32x4v* p = (const f32x4v*)(ea + (size_t)e * EFD + half * 8);
  f32x4v u0 = p[0], u1 = p[1];
  bf16x8 f;
#pragma unroll
  for (int r = 0; r < 4; ++r) {
    f[r] = (bf16_t)u0[r];
    f[4 + r] = (bf16_t)u1[r];
  }
  *(bf16x8*)(eacsr + (size_t)pos * 16 + half * 8) = f;
}

// ---------------- dense per-graph adjacency build ----------------
__global__ __launch_bounds__(256) void an_build_kernel(
    const float2* __restrict__ dstrec, const int* __restrict__ start_dst,
    const float* __restrict__ dinv, bf16_t* __restrict__ An) {
  __shared__ float AnS[128][256];  // 128 KB
  const int g = blockIdx.x >> 1, h = blockIdx.x & 1;
  const int tid = threadIdx.x;
  float4* az = (float4*)&AnS[0][0];
  for (int i = tid; i < 128 * 256 / 4; i += 256)
    az[i] = make_float4(0.f, 0.f, 0.f, 0.f);
  __syncthreads();
  const int nbase = g * 256 + h * 128;
  if (tid < 128) {
    int node = nbase + tid;
    int st = start_dst[node], en = start_dst[node + 1];
    float* row = AnS[tid];
    for (int p = st; p < en; ++p) {
      float2 r = dstrec[p];
      row[__float_as_int(r.y)] += r.x;
    }
    float dv = dinv[node];
    row[h * 128 + tid] += dv * dv;
  }
  __syncthreads();
  bf16_t* out = An + (size_t)nbase * 256;
  const float* s0 = &AnS[0][0];
  for (int i = tid; i < 128 * 256 / 8; i += 256) {
    bf16x8 v;
#pragma unroll
    for (int r = 0; r < 8; ++r) v[r] = (bf16_t)s0[i * 8 + r];
    *(bf16x8*)(out + i * 8) = v;
  }
}

// ---------------- conversions ----------------

__global__ void cvt_bf16_kernel(const float* __restrict__ in, bf16_t* __restrict__ out,
                                int n4) {
  int i = blockIdx.x * 256 + threadIdx.x;
  if (i >= n4) return;
  float4 v = ((const float4*)in)[i];
  bf16x4 o;
  o[0] = (bf16_t)v.x; o[1] = (bf16_t)v.y; o[2] = (bf16_t)v.z; o[3] = (bf16_t)v.w;
  ((bf16x4*)out)[i] = o;
}

// W: f32 [K][N] row-major -> Wt: bf16 [N][K] row-major
__global__ __launch_bounds__(256) void wt_kernel(const float* __restrict__ W,
                                                 bf16_t* __restrict__ Wt, int K, int N) {
  __shared__ float tile[32][33];
  int bx = blockIdx.x * 32;
  int by = blockIdx.y * 32;
  int tx = threadIdx.x & 31, ty = threadIdx.x >> 5;
#pragma unroll
  for (int i = 0; i < 32; i += 8)
    tile[ty + i][tx] = W[(size_t)(by + ty + i) * N + bx + tx];
  __syncthreads();
#pragma unroll
  for (int i = 0; i < 32; i += 8)
    Wt[(size_t)(bx + ty + i) * K + by + tx] = (bf16_t)tile[tx][ty + i];
}

// ---------------- edge projection via double-MFMA (8 waves x 64 cols) ------
__global__ __launch_bounds__(512) void ef_mfma_kernel(
    const bf16_t* __restrict__ eacsr, const float* __restrict__ ep_w,
    const float* __restrict__ ep_b, const int* __restrict__ nid,
    const int* __restrict__ start, bf16_t* __restrict__ efb) {
  const int tid = threadIdx.x;
  const int lane = tid & 63;
  const int wv = tid >> 6;      // 0..7
  const int l15 = lane & 15;
  const int g = lane >> 4;
  const int n0 = blockIdx.x * 16;
  const int cbase = wv * 64;

  bf16x8 wfr[4];
#pragma unroll
  for (int t = 0; t < 4; ++t) {
    bf16x8 f = {};
    int c = cbase + t * 16 + l15;
    if (g < 2) {
#pragma unroll
      for (int j = 0; j < 8; ++j) f[j] = (bf16_t)ep_w[(g * 8 + j) * CC + c];
    } else if (g == 2) {
      f[0] = (bf16_t)ep_b[c];
    }
    wfr[t] = f;
  }

  const int st = start[n0];
  const int en = start[n0 + 16];
  const int tgt = n0 + l15;

  f32x4v eacc[4] = {};

  for (int cb = st; cb < en; cb += 32) {
    bf16x8 af[2];
#pragma unroll
    for (int mE = 0; mE < 2; ++mE) {
      bf16x8 f = {};
      if (g < 2) {
        f = *(const bf16x8*)(eacsr + (size_t)(cb + mE * 16 + l15) * 16 + g * 8);
      } else if (g == 2) {
        f[0] = (bf16_t)1.0f;
      }
      af[mE] = f;
    }
    int4 idlo = *(const int4*)(nid + cb + g * 4);
    int4 idhi = *(const int4*)(nid + cb + 16 + g * 4);
    bf16x8 sf;
    sf[0] = (idlo.x == tgt) ? (bf16_t)1.0f : (bf16_t)0.0f;
    sf[1] = (idlo.y == tgt) ? (bf16_t)1.0f : (bf16_t)0.0f;
    sf[2] = (idlo.z == tgt) ? (bf16_t)1.0f : (bf16_t)0.0f;
    sf[3] = (idlo.w == tgt) ? (bf16_t)1.0f : (bf16_t)0.0f;
    sf[4] = (idhi.x == tgt) ? (bf16_t)1.0f : (bf16_t)0.0f;
    sf[5] = (idhi.y == tgt) ? (bf16_t)1.0f : (bf16_t)0.0f;
    sf[6] = (idhi.z == tgt) ? (bf16_t)1.0f : (bf16_t)0.0f;
    sf[7] = (idhi.w == tgt) ? (bf16_t)1.0f : (bf16_t)0.0f;
#pragma unroll
    for (int t = 0; t < 4; ++t) {
      f32x4v s0 = {}, s1 = {};
      s0 = __builtin_amdgcn_mfma_f32_16x16x32_bf16(af[0], wfr[t], s0, 0, 0, 0);
      s1 = __builtin_amdgcn_mfma_f32_16x16x32_bf16(af[1], wfr[t], s1, 0, 0, 0);
      union { bf16x8 v; bf16x4 h[2]; } pf;
#pragma unroll
      for (int r = 0; r < 4; ++r) {
        pf.h[0][r] = (bf16_t)fmaxf(s0[r], 0.f);
        pf.h[1][r] = (bf16_t)fmaxf(s1[r], 0.f);
      }
      eacc[t] = __builtin_amdgcn_mfma_f32_16x16x32_bf16(sf, pf.v, eacc[t], 0, 0, 0);
    }
  }
#pragma unroll
  for (int t = 0; t < 4; ++t) {
    int c = cbase + t * 16 + l15;
#pragma unroll
    for (int r = 0; r < 4; ++r) {
      int node = n0 + g * 4 + r;
      efb[(size_t)node * (2 * CC) + CC + c] = (bf16_t)eacc[t][r];
    }
  }
}

// ---------------- bf16 MFMA GEMM: BK=64, swizzled LDS, XCD swizzle ---------
__device__ __forceinline__ void gl_lds16(const bf16_t* g, bf16_t* l) {
  __builtin_amdgcn_global_load_lds(
      (const __attribute__((address_space(1))) void*)g,
      (__attribute__((address_space(3))) void*)l, 16, 0, 0);
}

// LDS [128][64] bf16 (128B rows), content swizzled: LDS slot sl of row r holds
// global k-slot sl^(r&7). Write: linear dest, pre-swizzled global source.
// Read: slot q at LDS slot q^(r&7). Conflict-free ds_read_b128 (2 lanes/bank).
template <int ACT, int OUT>
__global__ __launch_bounds__(256) void gemm_bf16_kernel(
    const bf16_t* __restrict__ A, const bf16_t* __restrict__ Bt,
    const float* __restrict__ bias, void* __restrict__ Cout, int M, int N, int K) {
  __shared__ __align__(16) bf16_t Al[128 * 64];
  __shared__ __align__(16) bf16_t Bl[128 * 64];
  const int tid = threadIdx.x;
  const int lane = tid & 63;
  const int wave = tid >> 6;
  int2 sw = xcd_swizzle();
  const int row0 = sw.y * 128;
  const int col0 = sw.x * 128;
  const int wm = (wave >> 1) * 64;
  const int wn = (wave & 1) * 64;
  f32x4v acc[4][4] = {};
  // staging: issue i covers rows i*32 + wave*8 + (lane>>3); slot = lane&7
  const int srow = wave * 8 + (lane >> 3);
  const int sslot = (lane & 7) ^ (lane >> 3);
  const bf16_t* aBase = A + (size_t)(row0 + srow) * K + sslot * 8;
  const bf16_t* bBase = Bt + (size_t)(col0 + srow) * K + sslot * 8;
  const int fr = lane & 15;
  const int g = lane >> 4;
  const int f7 = fr & 7;
  for (int k0 = 0; k0 < K; k0 += 64) {
#pragma unroll
    for (int i = 0; i < 4; ++i)
      gl_lds16(aBase + (size_t)(i * 32) * K + k0, Al + i * 2048 + wave * 512);
#pragma unroll
    for (int i = 0; i < 4; ++i)
      gl_lds16(bBase + (size_t)(i * 32) * K + k0, Bl + i * 2048 + wave * 512);
    __syncthreads();
#pragma unroll
    for (int s = 0; s < 2; ++s) {
      const int sl = ((s * 4 + g) ^ f7) * 8;
      bf16x8 af[4], bfv[4];
#pragma unroll
      for (int m = 0; m < 4; ++m)
        af[m] = *(const bf16x8*)(Al + (wm + m * 16 + fr) * 64 + sl);
#pragma unroll
      for (int n = 0; n < 4; ++n)
        bfv[n] = *(const bf16x8*)(Bl + (wn + n * 16 + fr) * 64 + sl);
#pragma unroll
      for (int m = 0; m < 4; ++m)
#pragma unroll
        for (int n = 0; n < 4; ++n)
          acc[m][n] = __builtin_amdgcn_mfma_f32_16x16x32_bf16(af[m], bfv[n],
                                                              acc[m][n], 0, 0, 0);
    }
    __syncthreads();
  }
  const int fq = (lane >> 4) * 4;
#pragma unroll
  for (int m = 0; m < 4; ++m) {
    int grb = row0 + wm + m * 16 + fq;
#pragma unroll
    for (int n = 0; n < 4; ++n) {
      int gc = col0 + wn + n * 16 + fr;
      float bv = bias ? bias[gc] : 0.f;
#pragma unroll
      for (int r = 0; r < 4; ++r) {
        float v = acc[m][n][r] + bv;
        if (ACT == 1) v = v / (1.f + __expf(-v));
        if (OUT == 0)
          ((float*)Cout)[(size_t)(grb + r) * N + gc] = v;
        else
          ((bf16_t*)Cout)[(size_t)(grb + r) * N + gc] = (bf16_t)v;
      }
    }
  }
}

// ---------------- block-diagonal An GEMM (BK=64, swizzled, XCD) ------------
__global__ __launch_bounds__(256) void an_gemm_kernel(
    const bf16_t* __restrict__ An, const bf16_t* __restrict__ xwT,
    const float* __restrict__ bias, bf16_t* __restrict__ outb) {
  __shared__ __align__(16) bf16_t Al[128 * 64];
  __shared__ __align__(16) bf16_t Bl[128 * 64];
  const int tid = threadIdx.x;
  const int lane = tid & 63;
  const int wave = tid >> 6;
  int2 sw = xcd_swizzle();
  const int row0 = sw.y * 128;  // node rows
  const int col0 = sw.x * 128;  // chan cols
  const int gr = row0 >> 8;     // graph
  f32x4v acc[4][4] = {};
  const int srow = wave * 8 + (lane >> 3);
  const int sslot = (lane & 7) ^ (lane >> 3);
  const bf16_t* aBase = An + (size_t)(row0 + srow) * 256 + sslot * 8;
  const bf16_t* bBase = xwT + (size_t)(col0 + srow) * NN + gr * 256 + sslot * 8;
  const int wm = (wave >> 1) * 64;
  const int wn = (wave & 1) * 64;
  const int fr = lane & 15;
  const int g = lane >> 4;
  const int f7 = fr & 7;
  for (int k0 = 0; k0 < 256; k0 += 64) {
#pragma unroll
    for (int i = 0; i < 4; ++i)
      gl_lds16(aBase + (size_t)(i * 32) * 256 + k0, Al + i * 2048 + wave * 512);
#pragma unroll
    for (int i = 0; i < 4; ++i)
      gl_lds16(bBase + (size_t)(i * 32) * NN + k0, Bl + i * 2048 + wave * 512);
    __syncthreads();
#pragma unroll
    for (int s = 0; s < 2; ++s) {
      const int sl = ((s * 4 + g) ^ f7) * 8;
      bf16x8 af[4], bfv[4];
#pragma unroll
      for (int m = 0; m < 4; ++m)
        af[m] = *(const bf16x8*)(Al + (wm + m * 16 + fr) * 64 + sl);
#pragma unroll
      for (int n = 0; n < 4; ++n)
        bfv[n] = *(const bf16x8*)(Bl + (wn + n * 16 + fr) * 64 + sl);
#pragma unroll
      for (int m = 0; m < 4; ++m)
#pragma unroll
        for (int n = 0; n < 4; ++n)
          acc[m][n] = __builtin_amdgcn_mfma_f32_16x16x32_bf16(af[m], bfv[n],
                                                              acc[m][n], 0, 0, 0);
    }
    __syncthreads();
  }
  const int fq = (lane >> 4) * 4;
#pragma unroll
  for (int m = 0; m < 4; ++m) {
    int grb = row0 + wm + m * 16 + fq;
#pragma unroll
    for (int n = 0; n < 4; ++n) {
      int gc = col0 + wn + n * 16 + fr;
      float bv = bias[gc];
#pragma unroll
      for (int r = 0; r < 4; ++r)
        outb[(size_t)(grb + r) * (2 * CC) + gc] = (bf16_t)(acc[m][n][r] + bv);
    }
  }
}

// ---------------- layernorm fused kernels ----------------

__device__ inline void block_reduce2(float& s, float& q, float* red) {
#pragma unroll
  for (int off = 32; off >= 1; off >>= 1) {
    s += __shfl_xor(s, off, 64);
    q += __shfl_xor(q, off, 64);
  }
  int wid = threadIdx.x >> 6;
  if ((threadIdx.x & 63) == 0) { red[wid * 2] = s; red[wid * 2 + 1] = q; }
  __syncthreads();
  s = red[0] + red[2] + red[4] + red[6];
  q = red[1] + red[3] + red[5] + red[7];
}

// out = LN(A + B) * g + be ; IA/IB: 1 = bf16 input; WF: 1 = f32 out, else bf16
template <int IA, int IB, int WF>
__global__ __launch_bounds__(256) void ln_addT_kernel(
    const void* __restrict__ A, const void* __restrict__ Bv,
    const float* __restrict__ g, const float* __restrict__ be,
    float* __restrict__ outf, bf16_t* __restrict__ outb) {
  int row = blockIdx.x, tid = threadIdx.x, c0 = tid * 2;
  __shared__ float red[8];
  float2 a = IA ? ldb2((const bf16_t*)A + (size_t)row * CC + c0)
                : *(const float2*)((const float*)A + (size_t)row * CC + c0);
  float2 b = IB ? ldb2((const bf16_t*)Bv + (size_t)row * CC + c0)
                : *(const float2*)((const float*)Bv + (size_t)row * CC + c0);
  float x0 = a.x + b.x, x1 = a.y + b.y;
  float s = x0 + x1, q = x0 * x0 + x1 * x1;
  block_reduce2(s, q, red);
  float mean = s * (1.f / CC);
  float var = q * (1.f / CC) - mean * mean;
  float rs = rsqrtf(var + 1e-5f);
  float o0 = (x0 - mean) * rs * g[c0] + be[c0];
  float o1 = (x1 - mean) * rs * g[c0 + 1] + be[c0 + 1];
  if (WF) {
    *(float2*)(outf + (size_t)row * CC + c0) = make_float2(o0, o1);
  } else {
    outb[(size_t)row * CC + c0] = (bf16_t)o0;
    outb[(size_t)row * CC + c0 + 1] = (bf16_t)o1;
  }
}

// gate+mix+LN+relu+residual; bf16 inputs (gpre, xc|ef), f32 x residual; bf16 out
__global__ __launch_bounds__(256) void ln_gate_kernel(
    const bf16_t* __restrict__ gpreb, const float* __restrict__ gate_b,
    const bf16_t* __restrict__ xcef, const float* __restrict__ n1g,
    const float* __restrict__ n1b, const float* __restrict__ xin,
    bf16_t* __restrict__ x2b) {
  int row = blockIdx.x, tid = threadIdx.x, c0 = tid * 2;
  __shared__ float red[8];
  float2 gp = ldb2(gpreb + (size_t)row * CC + c0);
  float2 xcv = ldb2(xcef + (size_t)row * (2 * CC) + c0);
  float2 efv = ldb2(xcef + (size_t)row * (2 * CC) + CC + c0);
  float g0 = 1.f / (1.f + __expf(-(gp.x + gate_b[c0])));
  float g1 = 1.f / (1.f + __expf(-(gp.y + gate_b[c0 + 1])));
  float x0 = g0 * xcv.x + (1.f - g0) * efv.x;
  float x1 = g1 * xcv.y + (1.f - g1) * efv.y;
  float s = x0 + x1, q = x0 * x0 + x1 * x1;
  block_reduce2(s, q, red);
  float mean = s * (1.f / CC);
  float var = q * (1.f / CC) - mean * mean;
  float rs = rsqrtf(var + 1e-5f);
  float2 xi = *(const float2*)(xin + (size_t)row * CC + c0);
  float o0 = fmaxf((x0 - mean) * rs * n1g[c0] + n1b[c0], 0.f) + xi.x;
  float o1 = fmaxf((x1 - mean) * rs * n1g[c0 + 1] + n1b[c0 + 1], 0.f) + xi.y;
  x2b[(size_t)row * CC + c0] = (bf16_t)o0;
  x2b[(size_t)row * CC + c0 + 1] = (bf16_t)o1;
}

// ---------------- V^T pack (pre-swizzled + pi-permuted K for attn) ---------
__global__ __launch_bounds__(256) void vt_pack_kernel(const bf16_t* __restrict__ qkvb,
                                                      bf16_t* __restrict__ vt) {
  int b = blockIdx.x >> 3, h = blockIdx.x & 7;
  int nb = b * 256;
  size_t voff = 1024 + (size_t)h * 64;
  char* out = (char*)(vt + (size_t)blockIdx.x * (64 * 256));
  __shared__ bf16_t tile[64][80];
  int tid = threadIdx.x;
  for (int kb = 0; kb < 4; ++kb) {
    __syncthreads();
#pragma unroll
    for (int p = 0; p < 2; ++p) {
      int k = p * 32 + (tid >> 3);
      int d8 = tid & 7;
      bf16x8 v = *(const bf16x8*)(qkvb + (size_t)(nb + kb * 64 + k) * 1536 + voff + d8 * 8);
      *(bf16x8*)(&tile[k][d8 * 8]) = v;
    }
    __syncthreads();
#pragma unroll
    for (int p = 0; p < 2; ++p) {
      int d = p * 32 + (tid >> 3);
      int k8 = tid & 7;
      bf16x8 v;
#pragma unroll
      for (int j = 0; j < 8; ++j) {
        int pos = k8 * 8 + j;
        int sl = pos & 31;
        int srck = (pos & 32) + ((sl >> 3) << 2) + (sl & 3) + (((sl >> 2) & 1) << 4);
        v[j] = tile[srck][d];
      }
      int byteoff = d * 512 + ((kb * 128 + k8 * 16) ^ ((d & 7) << 4));
      *(bf16x8*)(out + byteoff) = v;
    }
  }
}

// ---------------- MFMA attention (shuffle-free PV) ----------------
__global__ __launch_bounds__(256, 2) void attn_mfma_kernel(
    const bf16_t* __restrict__ qkvb, const bf16_t* __restrict__ vt,
    bf16_t* __restrict__ o) {
  const int b = blockIdx.x >> 3;
  const int h = blockIdx.x & 7;
  const int nb = b * 256;
  const int tid = threadIdx.x;
  const int lane = tid & 63;
  const int wv = tid >> 6;
  const int l15 = lane & 15;
  const int g = lane >> 4;
  const int swzk = (l15 & 7) << 4;
  __shared__ __align__(16) bf16_t Klds[256 * 64];
  __shared__ __align__(16) bf16_t Vtlds[64 * 256];
  const size_t qoff = (size_t)h * 64;
  const size_t koff = 512 + (size_t)h * 64;

  {
    const int dcol = 16 * ((tid & 7) ^ ((tid >> 3) & 7));
    const bf16_t* srcb = qkvb + koff + (dcol >> 1);
#pragma unroll
    for (int i = 0; i < 8; ++i) {
      int k = i * 32 + (tid >> 3);
      gl_lds16(srcb + (size_t)(nb + k) * 1536, Klds + ((i * 4096 + wv * 1024) >> 1));
    }
  }
  {
    const bf16_t* vsrc = vt + (size_t)blockIdx.x * (64 * 256);
#pragma unroll
    for (int i = 0; i < 8; ++i) {
      int base = i * 4096 + wv * 1024;
      gl_lds16(vsrc + ((base >> 1) + lane * 8), Vtlds + (base >> 1));
    }
  }

  bf16x8 qf[4][2];
#pragma unroll
  for (int n = 0; n < 4; ++n) {
    const bf16_t* qp = qkvb + (size_t)(nb + wv * 64 + 16 * n + l15) * 1536 + qoff + g * 8;
    qf[n][0] = *(const bf16x8*)(qp);
    qf[n][1] = *(const bf16x8*)(qp + 32);
  }

  __syncthreads();

  f32x4v oacc[4][4] = {};
  float mrun[4] = {-1e30f, -1e30f, -1e30f, -1e30f};
  float lrun[4] = {0.f, 0.f, 0.f, 0.f};

  for (int kc = 0; kc < 4; ++kc) {
    f32x4v sacc[4][4] = {};
    const int kb128 = (kc * 64 + l15) * 128;
#pragma unroll
    for (int m = 0; m < 4; ++m) {
      bf16x8 a0 = *(const bf16x8*)(Klds + ((kb128 + m * 2048 + ((g * 16) ^ swzk)) >> 1));
      bf16x8 a1 =
          *(const bf16x8*)(Klds + ((kb128 + m * 2048 + ((64 + g * 16) ^ swzk)) >> 1));
#pragma unroll
      for (int n = 0; n < 4; ++n) {
        sacc[m][n] = __builtin_amdgcn_mfma_f32_16x16x32_bf16(a0, qf[n][0], sacc[m][n], 0, 0, 0);
        sacc[m][n] = __builtin_amdgcn_mfma_f32_16x16x32_bf16(a1, qf[n][1], sacc[m][n], 0, 0, 0);
      }
    }
    uint2 pb[4][4];
#pragma unroll
    for (int n = 0; n < 4; ++n) {
      float mx = sacc[0][n][0];
#pragma unroll
      for (int m = 0; m < 4; ++m)
#pragma unroll
        for (int r = 0; r < 4; ++r) mx = fmaxf(mx, sacc[m][n][r]);
      mx = fmaxf(mx, __shfl_xor(mx, 16));
      mx = fmaxf(mx, __shfl_xor(mx, 32));
      float mnew = fmaxf(mrun[n], mx);
      float c = __expf((mrun[n] - mnew) * 0.125f);
      mrun[n] = mnew;
      float s = 0.f;
#pragma unroll
      for (int m = 0; m < 4; ++m) {
        float p0 = __expf((sacc[m][n][0] - mnew) * 0.125f);
        float p1 = __expf((sacc[m][n][1] - mnew) * 0.125f);
        float p2 = __expf((sacc[m][n][2] - mnew) * 0.125f);
        float p3 = __expf((sacc[m][n][3] - mnew) * 0.125f);
        s += (p0 + p1) + (p2 + p3);
        union { bf16x4 v; uint2 u; } cv;
        cv.v[0] = (bf16_t)p0; cv.v[1] = (bf16_t)p1;
        cv.v[2] = (bf16_t)p2; cv.v[3] = (bf16_t)p3;
        pb[m][n] = cv.u;
      }
      s += __shfl_xor(s, 16);
      s += __shfl_xor(s, 32);
      lrun[n] = lrun[n] * c + s;
#pragma unroll
      for (int m = 0; m < 4; ++m)
#pragma unroll
        for (int r = 0; r < 4; ++r) oacc[m][n][r] *= c;
    }
#pragma unroll
    for (int h2 = 0; h2 < 2; ++h2) {
      bf16x8 vf[4];
#pragma unroll
      for (int m = 0; m < 4; ++m)
        vf[m] = *(const bf16x8*)(Vtlds + (((16 * m + l15) * 512 +
                                          ((kc * 128 + h2 * 64 + g * 16) ^ swzk)) >> 1));
#pragma unroll
      for (int n = 0; n < 4; ++n) {
        union { uint2 u[2]; bf16x8 v; } pf;
        pf.u[0] = pb[2 * h2][n];
        pf.u[1] = pb[2 * h2 + 1][n];
#pragma unroll
        for (int m = 0; m < 4; ++m)
          oacc[m][n] =
              __builtin_amdgcn_mfma_f32_16x16x32_bf16(vf[m], pf.v, oacc[m][n], 0, 0, 0);
      }
    }
  }
  float inv[4];
#pragma unroll
  for (int n = 0; n < 4; ++n) inv[n] = 1.0f / lrun[n];
#pragma unroll
  for (int m = 0; m < 4; ++m)
#pragma unroll
    for (int n = 0; n < 4; ++n) {
      bf16x4 pk;
#pragma unroll
      for (int r = 0; r < 4; ++r) pk[r] = (bf16_t)(oacc[m][n][r] * inv[n]);
      *(bf16x4*)(o + (size_t)(nb + wv * 64 + 16 * n + l15) * 512 + h * 64 + 16 * m +
                 4 * g) = pk;
    }
}

// ---------------- launch ----------------

static inline char* alignp(char* p, size_t a) {
  return (char*)(((uintptr_t)p + a - 1) & ~(uintptr_t)(a - 1));
}

extern "C" void kernel_launch(void* const* d_in, const int* in_sizes, int n_in,
                              void* d_out, int out_size, void* d_ws, size_t ws_size,
                              hipStream_t stream) {
  const float* x = (const float*)d_in[0];
  const float* edge_attr = (const float*)d_in[1];
  const float* gcn_w = (const float*)d_in[2];
  const float* gcn_b = (const float*)d_in[3];
  const float* ep_w = (const float*)d_in[4];
  const float* ep_b = (const float*)d_in[5];
  const float* gate_w = (const float*)d_in[6];
  const float* gate_b = (const float*)d_in[7];
  const float* n1_g = (const float*)d_in[8];
  const float* n1_b = (const float*)d_in[9];
  const float* in_w = (const float*)d_in[10];
  const float* in_b = (const float*)d_in[11];
  const float* out_w = (const float*)d_in[12];
  const float* out_b = (const float*)d_in[13];
  const float* tn_g = (const float*)d_in[14];
  const float* tn_b = (const float*)d_in[15];
  const float* m_w1 = (const float*)d_in[16];
  const float* m_b1 = (const float*)d_in[17];
  const float* m_w2 = (const float*)d_in[18];
  const float* m_b2 = (const float*)d_in[19];
  const float* fn_g = (const float*)d_in[20];
  const float* fn_b = (const float*)d_in[21];
  const int* eidx = (const int*)d_in[22];
  const int* src = eidx;
  const int* dst = eidx + EE;

  float* ws = (float*)d_ws;
  float* R1 = ws;
  float* R2 = R1 + (size_t)NN * 3 * CC;
  float* R3 = R2 + (size_t)NN * CC;
  float* R4 = R3 + (size_t)NN * CC;
  float* dinv = R4 + (size_t)NN * CC;
  int* ip = (int*)(dinv + NN);
  int* ghist = ip;      ip += 64;
  int* gstart = ip;     ip += 65;
  int* gcur = ip;       ip += 64;
  int* elist_src = ip;  ip += EE;
  int* nid_src = ip;    ip += EE + 32;
  int* start_src = ip;  ip += NN + 1;
  int* start_dst = ip;  ip += NN + 1;
  char* bp = alignp((char*)ip, 64);
  int2* grec = (int2*)bp;             bp += (size_t)EE * 8;
  float* ewg = (float*)bp;            bp += (size_t)EE * 4;
  float2* dstrec = (float2*)bp;       bp += (size_t)EE * 8;
  bf16_t* x2b = (bf16_t*)bp;          bp += (size_t)NN * CC * 2;
  bf16_t* gcn_wt = (bf16_t*)bp;       bp += (size_t)CC * CC * 2;
  bf16_t* gate_wt = (bf16_t*)bp;      bp += (size_t)CC * 2 * CC * 2;
  bf16_t* in_wt = (bf16_t*)bp;        bp += (size_t)3 * CC * CC * 2;
  bf16_t* out_wt = (bf16_t*)bp;       bp += (size_t)CC * CC * 2;
  bf16_t* m_w1t = (bf16_t*)bp;        bp += (size_t)2 * CC * CC * 2;
  bf16_t* m_w2t = (bf16_t*)bp;        bp += (size_t)CC * 2 * CC * 2;

  bf16_t* xb = (bf16_t*)R1;      // bf16(x)
  bf16_t* xcefb = (bf16_t*)R1;   // [x_conv | ef] bf16 N x 2C
  bf16_t* qkvb = (bf16_t*)R1;    // qkv bf16 N x 1536
  bf16_t* hb = (bf16_t*)R1;      // mlp hidden bf16 N x 2C
  bf16_t* eacsr = (bf16_t*)((char*)R1 + (size_t)64 * 1024 * 1024);  // 16.8MB
  bf16_t* xwT = (bf16_t*)R2;     // (x@gcn_w)^T bf16 [512][16384]
  bf16_t* gpreb = (bf16_t*)R2;   // gate pre-act bf16 (after xwT dead)
  bf16_t* ob = (bf16_t*)R2;      // attn out bf16 (first half of R2)
  bf16_t* vt = ob + (size_t)NN * CC;  // V^T packed (second half of R2)
  bf16_t* x3b = (bf16_t*)R2;     // bf16(x3) (after ob dead)
  bf16_t* AnFull = (bf16_t*)R3;  // dense adjacency bf16 [16384][256] (8MB)
  bf16_t* oprjb = (bf16_t*)R4;   // out-proj bf16
  float* yf = R4;                // mlp2 f32 out (after oprjb dead)

  // --- edge prep ---
  init_kernel<<<1, 256, 0, stream>>>(ghist, nid_src, eacsr);
  edge_pass1<<<EE / 256, 256, 0, stream>>>(dst, ghist);
  gexscan_kernel<<<1, 64, 0, stream>>>(ghist, gstart, gcur);
  graph_scatter_kernel<<<EE / 2048, 256, 0, stream>>>(src, dst, edge_attr, gcur,
                                                      grec, ewg);
  graph_sort2_kernel<<<128, 1024, 0, stream>>>(grec, ewg, gstart, elist_src, nid_src,
                                               start_src, dstrec, start_dst, dinv);
  ea_gather_kernel<<<(EE * 2 + 255) / 256, 256, 0, stream>>>(edge_attr, elist_src,
                                                             eacsr);
  an_build_kernel<<<128, 256, 0, stream>>>(dstrec, start_dst, dinv, AnFull);

  // --- weight transposes ---
  wt_kernel<<<dim3(CC / 32, CC / 32), 256, 0, stream>>>(gcn_w, gcn_wt, CC, CC);
  wt_kernel<<<dim3(CC / 32, 2 * CC / 32), 256, 0, stream>>>(gate_w, gate_wt, 2 * CC, CC);
  wt_kernel<<<dim3(3 * CC / 32, CC / 32), 256, 0, stream>>>(in_w, in_wt, CC, 3 * CC);
  wt_kernel<<<dim3(CC / 32, CC / 32), 256, 0, stream>>>(out_w, out_wt, CC, CC);
  wt_kernel<<<dim3(2 * CC / 32, CC / 32), 256, 0, stream>>>(m_w1, m_w1t, CC, 2 * CC);
  wt_kernel<<<dim3(CC / 32, 2 * CC / 32), 256, 0, stream>>>(m_w2, m_w2t, 2 * CC, CC);

  // --- GCN conv: xwT = (x @ gcn_w)^T via flipped GEMM, then dense An GEMM ---
  cvt_bf16_kernel<<<(NN * CC / 4 + 255) / 256, 256, 0, stream>>>(x, xb, NN * CC / 4);
  gemm_bf16_kernel<0, 1><<<dim3(NN / 128, CC / 128), 256, 0, stream>>>(
      gcn_wt, xb, nullptr, xwT, CC, NN, CC);
  an_gemm_kernel<<<dim3(CC / 128, NN / 128), 256, 0, stream>>>(AnFull, xwT, gcn_b,
                                                               xcefb);
  ef_mfma_kernel<<<NN / 16, 512, 0, stream>>>(eacsr, ep_w, ep_b, nid_src, start_src,
                                              xcefb);
  dim3 gA(CC / 128, NN / 128);
  gemm_bf16_kernel<0, 1><<<gA, 256, 0, stream>>>(xcefb, gate_wt, nullptr, gpreb, NN,
                                                 CC, 2 * CC);
  ln_gate_kernel<<<NN, 256, 0, stream>>>(gpreb, gate_b, xcefb, n1_g, n1_b, x, x2b);

  // --- MHA ---
  dim3 gQ(3 * CC / 128, NN / 128);
  gemm_bf16_kernel<0, 1><<<gQ, 256, 0, stream>>>(x2b, in_wt, in_b, qkvb, NN, 3 * CC, CC);
  vt_pack_kernel<<<BB * HH, 256, 0, stream>>>(qkvb, vt);
  attn_mfma_kernel<<<BB * HH, 256, 0, stream>>>(qkvb, vt, ob);
  gemm_bf16_kernel<0, 1><<<gA, 256, 0, stream>>>(ob, out_wt, out_b, oprjb, NN, CC, CC);
  ln_addT_kernel<1, 1, 0><<<NN, 256, 0, stream>>>(x2b, oprjb, tn_g, tn_b, nullptr, x3b);

  // --- MLP ---
  dim3 gH(2 * CC / 128, NN / 128);
  gemm_bf16_kernel<1, 1><<<gH, 256, 0, stream>>>(x3b, m_w1t, m_b1, hb, NN, 2 * CC, CC);
  gemm_bf16_kernel<0, 0><<<gA, 256, 0, stream>>>(hb, m_w2t, m_b2, yf, NN, CC, 2 * CC);
  ln_addT_kernel<1, 0, 1><<<NN, 256, 0, stream>>>(x3b, yf, fn_g, fn_b, (float*)d_out,
                                                  nullptr);
}